// Round 1
// baseline (1225.841 us; speedup 1.0000x reference)
//
#include <hip/hip_runtime.h>
#include <hip/hip_bf16.h>

#define BSZ   8
#define NPER  8192
#define NNODE 65536       // BSZ*NPER
#define EPG   131072      // edges per graph
#define EMB   128
#define ENCD  512
#define LQ    512
#define NHE   4096
#define NE    1048576
#define NP    1048576
#define NROW  4096        // BSZ*LQ
#define NSPLIT 16
#define SLOT_N 64
#define SLOT_E 384
#define EBLK  1024        // edge-build blocks: NE/4 edges-per-thread/256 threads

typedef _Float16 f16;
typedef _Float16 f16x2 __attribute__((ext_vector_type(2)));
typedef _Float16 f16x8 __attribute__((ext_vector_type(8)));
typedef float f32x4 __attribute__((ext_vector_type(4)));

// ========== combined CSR build, single pass, global-atomic scatter.
// blocks [0,EBLK): edges (4 edges/thread), [EBLK,EBLK+4096): pairs ==========
__global__ __launch_bounds__(256) void k_build(const int* __restrict__ eidx,
    const int* __restrict__ hidx,
    int* __restrict__ du, int* __restrict__ cnt_dst, int* __restrict__ csr_dst,
    int* __restrict__ cnt_pn, int* __restrict__ cnt_pe,
    int* __restrict__ csr_pn, int* __restrict__ csr_pe)
{
  if (blockIdx.x < EBLK){
    int t = blockIdx.x*256 + threadIdx.x;         // covers NE/4
    int4 s4 = ((const int4*)eidx)[t];
    int4 d4 = ((const int4*)(eidx + NE))[t];
    int ss[4] = {s4.x, s4.y, s4.z, s4.w};
    int dd[4] = {d4.x, d4.y, d4.z, d4.w};
    #pragma unroll
    for (int u = 0; u < 4; ++u){
      atomicAdd(&du[ss[u]], 1);
      int c = atomicAdd(&cnt_dst[dd[u]], 1);
      if (c < SLOT_N) csr_dst[(size_t)dd[u]*SLOT_N + c] = ss[u];
    }
  } else {
    int i = (blockIdx.x - EBLK)*256 + threadIdx.x;   // covers exactly NP
    int2 p = ((const int2*)hidx)[i];
    int pn = p.x, pe = p.y;
    int q1 = atomicAdd(&cnt_pn[pn], 1);
    if (q1 < SLOT_N) csr_pn[pn*SLOT_N + q1] = pe;
    int q2 = atomicAdd(&cnt_pe[pe], 1);
    if (q2 < SLOT_E) csr_pe[pe*SLOT_E + q2] = pn;
  }
}

// ========== nfr16 = f16(nfr * rsqrt(max(du,1))) ==========
__global__ __launch_bounds__(256) void k_pre(const float* __restrict__ nfr,
    const int* __restrict__ du, f16* __restrict__ out)
{
  int i = blockIdx.x*256 + threadIdx.x;         // NNODE*64
  int node = i >> 6, j = i & 63;
  float ds = rsqrtf(fmaxf((float)du[node], 1.f));
  float2 v = ((const float2*)(nfr + (size_t)node*128))[j];
  f16x2 o = { (f16)(v.x*ds), (f16)(v.y*ds) };
  ((f16x2*)(out + (size_t)node*128))[j] = o;
}

// ========== gconv gather (f16 src): agg16[d] = f16(sum src16[s]), 4 nodes/wave ==========
__global__ __launch_bounds__(256) void k_gagg16(const int* __restrict__ cnt,
    const int* __restrict__ csr, const f16* __restrict__ src, f16* __restrict__ agg)
{
  int blk  = blockIdx.x;                        // NNODE/16 blocks, XCD swizzle
  int wv = threadIdx.x >> 6, lane = threadIdx.x & 63;
  int n0 = (blk & 7)*NPER + (blk >> 3)*16 + wv*4;
  int c[4]; const int* r[4];
  float ax[4] = {0,0,0,0}, ay[4] = {0,0,0,0};
  #pragma unroll
  for (int u = 0; u < 4; ++u){
    int nd = cnt[n0+u];
    c[u] = nd < SLOT_N ? nd : SLOT_N;
    r[u] = csr + (size_t)(n0+u)*SLOT_N;
  }
  int m = c[0];
  #pragma unroll
  for (int u = 1; u < 4; ++u) m = c[u] > m ? c[u] : m;
  for (int j = 0; j < m; ++j){
    #pragma unroll
    for (int u = 0; u < 4; ++u){
      if (j < c[u]){
        f16x2 v = ((const f16x2*)(src + (size_t)r[u][j]*128))[lane];
        ax[u] += (float)v.x; ay[u] += (float)v.y;
      }
    }
  }
  #pragma unroll
  for (int u = 0; u < 4; ++u)
    ((f16x2*)(agg + (size_t)(n0+u)*128))[lane] = (f16x2){ (f16)ax[u], (f16)ay[u] };
}

// ========== hconv stage 1 (f16 source): ef0[e] = (1/|e|) * sum src16[pn] ==========
__global__ __launch_bounds__(256) void k_hea16(const int* __restrict__ cnt,
    const int* __restrict__ csr, const f16* __restrict__ src, float* __restrict__ ef)
{
  __shared__ float red[4][128];
  int e = blockIdx.x;
  int wv = threadIdx.x >> 6, lane = threadIdx.x & 63;
  int nd = cnt[e];
  int n = nd < SLOT_E ? nd : SLOT_E;
  const int* row = csr + e*SLOT_E;
  float ax = 0.f, ay = 0.f;
  for (int j = wv; j < n; j += 4){
    int p = row[j];
    f16x2 v = ((const f16x2*)(src + (size_t)p*128))[lane];
    ax += (float)v.x; ay += (float)v.y;
  }
  red[wv][lane*2] = ax; red[wv][lane*2+1] = ay;
  __syncthreads();
  if (wv == 0){
    float s = nd > 0 ? 1.f/(float)nd : 0.f;
    float2 o = { (red[0][lane*2]+red[1][lane*2]+red[2][lane*2]+red[3][lane*2])*s,
                 (red[0][lane*2+1]+red[1][lane*2+1]+red[2][lane*2+1]+red[3][lane*2+1])*s };
    ((float2*)(ef + (size_t)e*128))[lane] = o;
  }
}

// ========== register-blocked 128x128 GEMM.  IN16: input rows are f16.
// MODE 0: f32 raw   MODE 1: f16(acc*rsqrt(max(cnt,1)) + bias)   MODE 2: f16(relu(acc+bias)) ==========
template<int MODE, int IN16>
__global__ __launch_bounds__(256, 2) void k_gemm(const void* __restrict__ inp,
    const float* __restrict__ W, const int* __restrict__ cnt,
    const float* __restrict__ bias, void* __restrict__ outp)
{
  __shared__ float Wl[128*128];
  __shared__ float Rl[32*128];
  const int tid = threadIdx.x;
  const int rbase = blockIdx.x*32;
  for (int i = tid; i < 16384; i += 256) Wl[i] = W[i];
  if (IN16){
    const f16x2* s2 = (const f16x2*)(((const f16*)inp) + (size_t)rbase*128);
    for (int i = tid; i < 2048; i += 256){
      f16x2 v = s2[i];
      ((float2*)Rl)[i] = make_float2((float)v.x, (float)v.y);
    }
  } else {
    const float* src = ((const float*)inp) + (size_t)rbase*128;
    for (int i = tid; i < 4096; i += 256) Rl[i] = src[i];
  }
  __syncthreads();
  const int c0 = (tid & 31)*4;
  const int r0 = (tid >> 5)*4;
  f32x4 acc[4];
  #pragma unroll
  for (int j = 0; j < 4; ++j) acc[j] = (f32x4){0.f,0.f,0.f,0.f};
  for (int d = 0; d < 128; d += 4){
    f32x4 w0 = *(const f32x4*)&Wl[(d+0)*128 + c0];
    f32x4 w1 = *(const f32x4*)&Wl[(d+1)*128 + c0];
    f32x4 w2 = *(const f32x4*)&Wl[(d+2)*128 + c0];
    f32x4 w3 = *(const f32x4*)&Wl[(d+3)*128 + c0];
    #pragma unroll
    for (int j = 0; j < 4; ++j){
      f32x4 rr = *(const f32x4*)&Rl[(r0+j)*128 + d];
      acc[j] += rr.x*w0 + rr.y*w1 + rr.z*w2 + rr.w*w3;
    }
  }
  #pragma unroll
  for (int j = 0; j < 4; ++j){
    const int row = rbase + r0 + j;
    if (MODE == 0){
      *(f32x4*)(((float*)outp) + (size_t)row*128 + c0) = acc[j];
    } else if (MODE == 1){
      float sc = rsqrtf(fmaxf((float)cnt[row], 1.f));
      f16* o = ((f16*)outp) + (size_t)row*128 + c0;
      #pragma unroll
      for (int k = 0; k < 4; ++k) o[k] = (f16)(acc[j][k]*sc + bias[c0+k]);
    } else {
      f16* o = ((f16*)outp) + (size_t)row*128 + c0;
      #pragma unroll
      for (int k = 0; k < 4; ++k) o[k] = (f16)fmaxf(acc[j][k] + bias[c0+k], 0.f);
    }
  }
}

// ========== hconv stage 2 + relu + residual, 4 nodes/wave, f16 out.
// PRES: scale by rsqrt(du) (for next layer's prescaled input) ==========
template<int PRES>
__global__ __launch_bounds__(256) void k_nha(const int* __restrict__ cnt,
    const int* __restrict__ csr, const float* __restrict__ ef,
    const float* __restrict__ bias, const float* __restrict__ nfr,
    const int* __restrict__ du, f16* __restrict__ outp)
{
  int wv = threadIdx.x >> 6, lane = threadIdx.x & 63;
  int n0 = blockIdx.x*16 + wv*4;
  int dcnt[4], c[4]; const int* r[4];
  float ax[4] = {0,0,0,0}, ay[4] = {0,0,0,0};
  #pragma unroll
  for (int u = 0; u < 4; ++u){
    dcnt[u] = cnt[n0+u];
    c[u] = dcnt[u] < SLOT_N ? dcnt[u] : SLOT_N;
    r[u] = csr + (size_t)(n0+u)*SLOT_N;
  }
  int m = c[0];
  #pragma unroll
  for (int u = 1; u < 4; ++u) m = c[u] > m ? c[u] : m;
  for (int j = 0; j < m; ++j){
    #pragma unroll
    for (int u = 0; u < 4; ++u){
      if (j < c[u]){
        float2 v = ((const float2*)(ef + (size_t)r[u][j]*128))[lane];
        ax[u] += v.x; ay[u] += v.y;
      }
    }
  }
  float bx = bias[lane*2], by = bias[lane*2+1];
  #pragma unroll
  for (int u = 0; u < 4; ++u){
    float s = dcnt[u] > 0 ? 1.f/(float)dcnt[u] : 0.f;
    float2 nf = ((const float2*)(nfr + (size_t)(n0+u)*128))[lane];
    float vx = fmaxf(ax[u]*s + bx, 0.f) + nf.x;
    float vy = fmaxf(ay[u]*s + by, 0.f) + nf.y;
    float e0 = PRES ? rsqrtf(fmaxf((float)du[n0+u], 1.f)) : 1.f;
    ((f16x2*)(outp + (size_t)(n0+u)*128))[lane] = (f16x2){ (f16)(vx*e0), (f16)(vy*e0) };
  }
}

// ========== q = f16(relu(x @ Wm + bm)), K=512 in 4 LDS chunks ==========
__global__ __launch_bounds__(256) void k_qgemm(const float* __restrict__ x,
    const float* __restrict__ Wm, const float* __restrict__ bm, f16* __restrict__ q)
{
  __shared__ float Wl[128*128];
  const int c = threadIdx.x & 127, rh = threadIdx.x >> 7;
  const int base = blockIdx.x*16 + rh*8;
  float acc[8] = {0,0,0,0,0,0,0,0};
  for (int kc = 0; kc < 4; ++kc){
    __syncthreads();
    for (int i = threadIdx.x; i < 128*128; i += 256) Wl[i] = Wm[kc*128*128 + i];
    __syncthreads();
    #pragma unroll
    for (int r = 0; r < 8; ++r){
      const float* xr = x + (size_t)(base+r)*512 + kc*128;
      float a0=0.f,a1=0.f,a2=0.f,a3=0.f;
      #pragma unroll
      for (int d = 0; d < 128; d += 4){
        a0 += xr[d+0] * Wl[(d+0)*128 + c];
        a1 += xr[d+1] * Wl[(d+1)*128 + c];
        a2 += xr[d+2] * Wl[(d+2)*128 + c];
        a3 += xr[d+3] * Wl[(d+3)*128 + c];
      }
      acc[r] += (a0+a1)+(a2+a3);
    }
  }
  float bv = bm[c];
  #pragma unroll
  for (int r = 0; r < 8; ++r)
    q[(size_t)(base+r)*128 + c] = (f16)fmaxf(acc[r]+bv, 0.f);
}

// ========== gT[b][c][n] = h16[b*NPER+n][c]  (f16 transpose) ==========
__global__ __launch_bounds__(256) void k_gt(const f16* __restrict__ g, f16* __restrict__ gT)
{
  __shared__ f16 t[64][66];
  int b = blockIdx.z, n0 = blockIdx.x*64, c0 = blockIdx.y*64;
  for (int i = threadIdx.x; i < 64*64; i += 256){
    int n = i >> 6, c = i & 63;
    t[n][c] = g[((size_t)(b*NPER + n0 + n))*128 + c0 + c];
  }
  __syncthreads();
  for (int i = threadIdx.x; i < 64*64; i += 256){
    int c = i >> 6, n = i & 63;
    gT[((size_t)(b*128 + c0 + c))*NPER + n0 + n] = t[n][c];
  }
}

// ========== flash attention (R7 config): 64 q-rows/block, n-slab 512, 128-n chunks,
// wave-local P transform, f32 Opart, launch_bounds(256,4) -- no spills ==========
__global__ __launch_bounds__(256, 4) void k_flash(const f16* __restrict__ qb,
    const f16* __restrict__ kb, const f16* __restrict__ gT,
    float* __restrict__ Opart, float* __restrict__ mZ)
{
  __shared__ f16 Plds[4][16][136];             // per-wave slice
  const int sp = blockIdx.x, l0 = blockIdx.y*64, b = blockIdx.z;
  const int w = threadIdx.x >> 6, lane = threadIdx.x & 63;
  const int quad = lane >> 4, col = lane & 15;
  const int koff = quad*8;
  const f16* qrow = qb + ((size_t)(b*LQ + l0 + w*16 + col))*128 + koff;
  f16x8 aq[4];
  #pragma unroll
  for (int ks = 0; ks < 4; ++ks) aq[ks] = *(const f16x8*)(qrow + ks*32);
  float mrun[4] = {-1e30f,-1e30f,-1e30f,-1e30f};
  float zrun[4] = {0.f,0.f,0.f,0.f};
  f32x4 O[8];
  #pragma unroll
  for (int i = 0; i < 8; ++i) O[i] = (f32x4){0.f,0.f,0.f,0.f};
  const int nbase = sp*(NPER/NSPLIT);          // 512-wide n slab
  #pragma unroll 1
  for (int it = 0; it < (NPER/NSPLIT)/128; ++it){
    const int n0 = nbase + it*128;
    f32x4 st[8];
    #pragma unroll
    for (int t = 0; t < 8; ++t){
      st[t] = (f32x4){0.f,0.f,0.f,0.f};
      const f16* kp = kb + ((size_t)(b*NPER + n0 + t*16 + col))*128 + koff;
      #pragma unroll
      for (int ks = 0; ks < 4; ++ks){
        f16x8 bf = *(const f16x8*)(kp + ks*32);
        st[t] = __builtin_amdgcn_mfma_f32_16x16x32_f16(aq[ks], bf, st[t], 0, 0, 0);
      }
    }
    float alr[4];
    #pragma unroll
    for (int r = 0; r < 4; ++r){
      float rm = st[0][r];
      #pragma unroll
      for (int t = 1; t < 8; ++t) rm = fmaxf(rm, st[t][r]);
      rm = fmaxf(rm, __shfl_xor(rm, 1));
      rm = fmaxf(rm, __shfl_xor(rm, 2));
      rm = fmaxf(rm, __shfl_xor(rm, 4));
      rm = fmaxf(rm, __shfl_xor(rm, 8));
      float mn = fmaxf(mrun[r], rm);
      float al = __expf(mrun[r] - mn);
      float ps[8], rs = 0.f;
      #pragma unroll
      for (int t = 0; t < 8; ++t){ ps[t] = __expf(st[t][r] - mn); rs += ps[t]; }
      rs += __shfl_xor(rs, 1);
      rs += __shfl_xor(rs, 2);
      rs += __shfl_xor(rs, 4);
      rs += __shfl_xor(rs, 8);
      zrun[r] = zrun[r]*al + rs;
      mrun[r] = mn;
      alr[r] = al;
      #pragma unroll
      for (int t = 0; t < 8; ++t) Plds[w][quad*4+r][t*16+col] = (f16)ps[t];
    }
    #pragma unroll
    for (int dt = 0; dt < 8; ++dt)
      #pragma unroll
      for (int r = 0; r < 4; ++r) O[dt][r] *= alr[r];
    __builtin_amdgcn_wave_barrier();
    #pragma unroll
    for (int kk = 0; kk < 4; ++kk){
      f16x8 ap = *(const f16x8*)&Plds[w][col][kk*32 + koff];
      const f16* gv = gT + ((size_t)(b*128 + col))*NPER + n0 + kk*32 + koff;
      #pragma unroll
      for (int dt = 0; dt < 8; ++dt){
        f16x8 bv = *(const f16x8*)(gv + (size_t)dt*16*NPER);
        O[dt] = __builtin_amdgcn_mfma_f32_16x16x32_f16(ap, bv, O[dt], 0, 0, 0);
      }
    }
    __builtin_amdgcn_wave_barrier();
  }
  const int growb = b*LQ + l0 + w*16 + quad*4;
  #pragma unroll
  for (int r = 0; r < 4; ++r){
    float* od = Opart + ((size_t)sp*NROW + growb + r)*128 + col;
    #pragma unroll
    for (int dt = 0; dt < 8; ++dt) od[dt*16] = O[dt][r];
  }
  if (col == 0){
    #pragma unroll
    for (int r = 0; r < 4; ++r){
      ((float2*)mZ)[(size_t)sp*NROW + growb + r] = make_float2(mrun[r], zrun[r]);
    }
  }
}

// ========== combine splits -> Hbuf[row][d] ==========
__global__ __launch_bounds__(256) void k_comb(const float* __restrict__ Opart,
    const float* __restrict__ mZ, float* __restrict__ Hbuf)
{
  int i = blockIdx.x*256 + threadIdx.x;         // NROW*64
  int row = i >> 6, d2 = (i & 63)*2;
  float ms[NSPLIT], zs[NSPLIT];
  float M = -1e30f;
  #pragma unroll
  for (int s = 0; s < NSPLIT; ++s){
    float2 v = ((const float2*)mZ)[(size_t)s*NROW + row];
    ms[s] = v.x; zs[s] = v.y;
    M = fmaxf(M, v.x);
  }
  float Zt = 0.f, ax = 0.f, ay = 0.f;
  #pragma unroll
  for (int s = 0; s < NSPLIT; ++s){
    float e = __expf(ms[s] - M);
    Zt += zs[s]*e;
    const float* op = Opart + ((size_t)s*NROW + row)*128 + d2;
    ax += e*op[0]; ay += e*op[1];
  }
  float inv = 1.f/Zt;
  float* o = Hbuf + (size_t)row*128 + d2;
  o[0] = ax*inv; o[1] = ay*inv;
}

// ========== final: [sigmoid([x,H]@Ws+bs), tanh([x,H]@Wt+bt)] -> f32 ==========
__global__ __launch_bounds__(256) void k_final(const float* __restrict__ x,
    const float* __restrict__ Hbuf,
    const float* __restrict__ Wsg, const float* __restrict__ bsg,
    const float* __restrict__ Wtn, const float* __restrict__ btn,
    float* __restrict__ out)
{
  __shared__ f16 Wl[2*128*128];
  const int c = threadIdx.x;
  const int hsel = c >> 7;
  const int cc = c & 127;
  const int base = blockIdx.x * 16;
  float acc[16];
  #pragma unroll
  for (int r = 0; r < 16; ++r) acc[r] = 0.f;
  for (int kc = 0; kc < 5; ++kc){
    __syncthreads();
    for (int i = threadIdx.x; i < 128*128; i += 256){
      Wl[i]         = (f16)Wsg[kc*16384 + i];
      Wl[16384 + i] = (f16)Wtn[kc*16384 + i];
    }
    __syncthreads();
    const f16* wp = Wl + hsel*16384;
    #pragma unroll
    for (int rg = 0; rg < 4; ++rg){
      const float *cr0, *cr1, *cr2, *cr3;
      if (kc < 4){
        cr0 = x + (size_t)(base + rg*4)*512 + kc*128;
        cr1 = cr0 + 512; cr2 = cr1 + 512; cr3 = cr2 + 512;
      } else {
        cr0 = Hbuf + (size_t)(base + rg*4)*128;
        cr1 = cr0 + 128; cr2 = cr1 + 128; cr3 = cr2 + 128;
      }
      float a0=acc[rg*4], a1=acc[rg*4+1], a2=acc[rg*4+2], a3=acc[rg*4+3];
      #pragma unroll 8
      for (int d = 0; d < 128; ++d){
        float wv = (float)wp[d*128 + cc];
        a0 += cr0[d]*wv; a1 += cr1[d]*wv; a2 += cr2[d]*wv; a3 += cr3[d]*wv;
      }
      acc[rg*4]=a0; acc[rg*4+1]=a1; acc[rg*4+2]=a2; acc[rg*4+3]=a3;
    }
  }
  float bv = hsel ? btn[cc] : bsg[cc];
  #pragma unroll
  for (int r = 0; r < 16; ++r){
    float v = acc[r] + bv;
    v = hsel ? tanhf(v) : 1.f/(1.f + __expf(-v));
    out[(size_t)(base+r)*256 + c] = v;
  }
}

extern "C" void kernel_launch(void* const* d_in, const int* in_sizes, int n_in,
                              void* d_out, int out_size, void* d_ws, size_t ws_size,
                              hipStream_t stream)
{
  const float* x    = (const float*)d_in[0];
  const float* nfr  = (const float*)d_in[1];
  const int*   eidx = (const int*)d_in[2];
  const int*   hidx = (const int*)d_in[3];
  const float *Wg1=(const float*)d_in[4],  *bg1=(const float*)d_in[5];
  const float *Wg2=(const float*)d_in[6],  *bg2=(const float*)d_in[7];
  const float *Wh1=(const float*)d_in[8],  *bh1=(const float*)d_in[9];
  const float *Wh2=(const float*)d_in[10], *bh2=(const float*)d_in[11];
  const float *Wm =(const float*)d_in[12], *bm =(const float*)d_in[13];
  const float *Wm2=(const float*)d_in[14], *bm2=(const float*)d_in[15];
  const float *Wsg=(const float*)d_in[16], *bsg=(const float*)d_in[17];
  const float *Wtn=(const float*)d_in[18], *btn=(const float*)d_in[19];
  float* out = (float*)d_out;

  // ---- workspace layout. Aliases:
  //  h4_16 at base; agg16 + Hbuf in second region (both only live when the other's
  //  phase is dead is NOT true for agg16/Hbuf -- they are at distinct offsets);
  //  Opart f32 (32MB, NSPLIT16) aliases dead bufA+bufB; kb/gT alias csr_dst/csr_pn. ----
  char* base = (char*)d_ws;
  f16*   h4_16  = (f16*)(base);                          // 16 MB
  f16*   agg16  = (f16*)(base + 33554432);               // 16 MB (graph phase only)
  float* Hbuf   = (float*)(base + 50331648);             // 2 MB  (attention phase)
  f16*   bufA   = (f16*)(base + 67108864);               // 16 MB  (nfr16 / h2_16)
  f16*   bufB   = (f16*)(base + 83886080);               // 16 MB  (h1_16 / h3_16)
  float* Opart  = (float*)(base + 67108864);             // 32 MB  (aliases bufA+bufB)
  int*   csr_dst= (int*)(base + 100663296);              // 16 MB
  f16*   kb     = (f16*)(base + 100663296);              //   (aliases csr_dst)
  int*   csr_pn = (int*)(base + 117440512);              // 16 MB
  f16*   gT     = (f16*)(base + 117440512);              //   (aliases csr_pn)
  int*   csr_pe = (int*)(base + 134217728);              // 6 MB
  int*   cnt_dst= (int*)(base + 140509184);
  int*   cnt_pn = (int*)(base + 140771328);
  int*   cnt_pe = (int*)(base + 141033472);
  int*   du     = (int*)(base + 141049856);
  float* ef0    = (float*)(base + 141312000);            // 2 MB
  float* ef1    = (float*)(base + 143409152);            // 2 MB
  f16*   qb     = (f16*)(base + 145506304);              // 1 MB
  float* mZ     = (float*)(base + 146554880);            // 512 KB (NSPLIT16)
  const size_t needB = (size_t)147079168;
  if (ws_size < needB) return;

  // ---- CSR build (edges + pairs in one launch, single-pass global atomics) ----
  // cnt_dst / cnt_pn / cnt_pe / du are contiguous: zero all four (802816 B)
  hipMemsetAsync(cnt_dst, 0, 802816, stream);
  k_build<<<EBLK + NP/256, 256, 0, stream>>>(eidx, hidx, du, cnt_dst, csr_dst,
                                             cnt_pn, cnt_pe, csr_pn, csr_pe);

  // ---- layer 1 ----
  k_pre<<<NNODE*64/256, 256, 0, stream>>>(nfr, du, bufA);
  k_gagg16<<<NNODE/16, 256, 0, stream>>>(cnt_dst, csr_dst, bufA, agg16);
  k_gemm<1,1><<<NNODE/32, 256, 0, stream>>>(agg16, Wg1, cnt_dst, bg1, bufB);
  k_hea16<<<NHE, 256, 0, stream>>>(cnt_pe, csr_pe, bufB, ef0);
  k_gemm<0,0><<<NHE/32, 256, 0, stream>>>(ef0, Wh1, nullptr, nullptr, ef1);
  k_nha<1><<<NNODE/16, 256, 0, stream>>>(cnt_pn, csr_pn, ef1, bh1, nfr, du, bufA);

  // ---- layer 2 ----
  k_gagg16<<<NNODE/16, 256, 0, stream>>>(cnt_dst, csr_dst, bufA, agg16);
  k_gemm<1,1><<<NNODE/32, 256, 0, stream>>>(agg16, Wg2, cnt_dst, bg2, bufB);
  k_hea16<<<NHE, 256, 0, stream>>>(cnt_pe, csr_pe, bufB, ef0);
  k_gemm<0,0><<<NHE/32, 256, 0, stream>>>(ef0, Wh2, nullptr, nullptr, ef1);
  k_nha<0><<<NNODE/16, 256, 0, stream>>>(cnt_pn, csr_pn, ef1, bh2, nfr, nullptr, h4_16);

  // ---- attention ----
  k_qgemm<<<NROW/16, 256, 0, stream>>>(x, Wm, bm, qb);
  k_gemm<2,1><<<NNODE/32, 256, 0, stream>>>(h4_16, Wm2, nullptr, bm2, kb);
  k_gt<<<dim3(NPER/64, 2, BSZ), 256, 0, stream>>>(h4_16, gT);
  k_flash<<<dim3(NSPLIT, LQ/64, BSZ), 256, 0, stream>>>(qb, kb, gT, Opart, mZ);
  k_comb<<<NROW*64/256, 256, 0, stream>>>(Opart, mZ, Hbuf);
  k_final<<<NROW/16, 256, 0, stream>>>(x, Hbuf, Wsg, bsg, Wtn, btn, out);

  (void)in_sizes; (void)n_in; (void)out_size;
}

// Round 2
// 1194.841 us; speedup vs baseline: 1.0259x; 1.0259x over previous
//
#include <hip/hip_runtime.h>
#include <hip/hip_bf16.h>

#define BSZ   8
#define NPER  8192
#define NNODE 65536       // BSZ*NPER
#define EPG   131072      // edges per graph
#define EMB   128
#define ENCD  512
#define LQ    512
#define NHE   4096
#define NE    1048576
#define NP    1048576
#define NROW  4096        // BSZ*LQ
#define NSPLIT 16
#define SLOT_N 64
#define SLOT_E 384
#define EPART 64          // edge-build partitions per graph (128 nodes each)

typedef _Float16 f16;
typedef _Float16 f16x2 __attribute__((ext_vector_type(2)));
typedef _Float16 f16x8 __attribute__((ext_vector_type(8)));
typedef float f32x4 __attribute__((ext_vector_type(4)));
typedef unsigned short u16;

// ========== combined CSR build: blocks [0,512) edges (LDS cursors, windowed u16
// writes), [512,4608) pairs (global atomics, u16 payload) ==========
__global__ __launch_bounds__(256) void k_build(const int* __restrict__ eidx,
    const int* __restrict__ hidx,
    int* __restrict__ du, int* __restrict__ cnt_dst, u16* __restrict__ csr_dst,
    int* __restrict__ cnt_pn, int* __restrict__ cnt_pe,
    u16* __restrict__ csr_pn, u16* __restrict__ csr_pe)
{
  if (blockIdx.x < BSZ*EPART){
    __shared__ int cur[NPER/EPART];
    __shared__ int duc[NPER/EPART];
    const int g  = blockIdx.x & 7;
    const int p  = blockIdx.x >> 3;
    const int lo = p * (NPER/EPART);
    if (threadIdx.x < NPER/EPART){ cur[threadIdx.x] = 0; duc[threadIdx.x] = 0; }
    __syncthreads();
    const int4* srcv = (const int4*)(eidx + g*EPG);
    const int4* dstv = (const int4*)(eidx + NE + g*EPG);
    for (int t = threadIdx.x; t < EPG/4; t += 256){
      int4 s4 = srcv[t];
      int4 d4 = dstv[t];
      int ss[4] = {s4.x, s4.y, s4.z, s4.w};
      int dd[4] = {d4.x, d4.y, d4.z, d4.w};
      #pragma unroll
      for (int u = 0; u < 4; ++u){
        int sl = (ss[u] & (NPER-1)) - lo;
        if ((unsigned)sl < (unsigned)(NPER/EPART)) atomicAdd(&duc[sl], 1);
        int dl = (dd[u] & (NPER-1)) - lo;
        if ((unsigned)dl < (unsigned)(NPER/EPART)){
          int c = atomicAdd(&cur[dl], 1);
          if (c < SLOT_N) csr_dst[(size_t)dd[u]*SLOT_N + c] = (u16)ss[u];
        }
      }
    }
    __syncthreads();
    if (threadIdx.x < NPER/EPART){
      int nb = g*NPER + lo + threadIdx.x;
      du[nb]      = duc[threadIdx.x];
      cnt_dst[nb] = cur[threadIdx.x];
    }
  } else {
    int i = (blockIdx.x - BSZ*EPART)*256 + threadIdx.x;   // covers exactly NP
    int2 pp = ((const int2*)hidx)[i];
    int pn = pp.x, pe = pp.y;
    int q1 = atomicAdd(&cnt_pn[pn], 1);
    if (q1 < SLOT_N) csr_pn[pn*SLOT_N + q1] = (u16)pe;
    int q2 = atomicAdd(&cnt_pe[pe], 1);
    if (q2 < SLOT_E) csr_pe[pe*SLOT_E + q2] = (u16)pn;
  }
}

// ========== nfr16 = f16(nfr * rsqrt(max(du,1))) ==========
__global__ __launch_bounds__(256) void k_pre(const float* __restrict__ nfr,
    const int* __restrict__ du, f16* __restrict__ out)
{
  int i = blockIdx.x*256 + threadIdx.x;         // NNODE*64
  int node = i >> 6, j = i & 63;
  float ds = rsqrtf(fmaxf((float)du[node], 1.f));
  float2 v = ((const float2*)(nfr + (size_t)node*128))[j];
  f16x2 o = { (f16)(v.x*ds), (f16)(v.y*ds) };
  ((f16x2*)(out + (size_t)node*128))[j] = o;
}

// ========== gconv gather (f16 src): agg16[d] = f16(sum src16[s]), 4 nodes/wave ==========
__global__ __launch_bounds__(256) void k_gagg16(const int* __restrict__ cnt,
    const u16* __restrict__ csr, const f16* __restrict__ src, f16* __restrict__ agg)
{
  int blk  = blockIdx.x;                        // NNODE/16 blocks, XCD swizzle
  int wv = threadIdx.x >> 6, lane = threadIdx.x & 63;
  int n0 = (blk & 7)*NPER + (blk >> 3)*16 + wv*4;
  int c[4]; const u16* r[4];
  float ax[4] = {0,0,0,0}, ay[4] = {0,0,0,0};
  #pragma unroll
  for (int u = 0; u < 4; ++u){
    int nd = cnt[n0+u];
    c[u] = nd < SLOT_N ? nd : SLOT_N;
    r[u] = csr + (size_t)(n0+u)*SLOT_N;
  }
  int m = c[0];
  #pragma unroll
  for (int u = 1; u < 4; ++u) m = c[u] > m ? c[u] : m;
  for (int j = 0; j < m; ++j){
    #pragma unroll
    for (int u = 0; u < 4; ++u){
      if (j < c[u]){
        int idx = r[u][j];
        f16x2 v = ((const f16x2*)(src + (size_t)idx*128))[lane];
        ax[u] += (float)v.x; ay[u] += (float)v.y;
      }
    }
  }
  #pragma unroll
  for (int u = 0; u < 4; ++u)
    ((f16x2*)(agg + (size_t)(n0+u)*128))[lane] = (f16x2){ (f16)ax[u], (f16)ay[u] };
}

// ========== hconv stage 1 (f16 source): ef0[e] = (1/|e|) * sum src16[pn] ==========
__global__ __launch_bounds__(256) void k_hea16(const int* __restrict__ cnt,
    const u16* __restrict__ csr, const f16* __restrict__ src, float* __restrict__ ef)
{
  __shared__ float red[4][128];
  int e = blockIdx.x;
  int wv = threadIdx.x >> 6, lane = threadIdx.x & 63;
  int nd = cnt[e];
  int n = nd < SLOT_E ? nd : SLOT_E;
  const u16* row = csr + (size_t)e*SLOT_E;
  float ax = 0.f, ay = 0.f;
  for (int j = wv; j < n; j += 4){
    int p = row[j];
    f16x2 v = ((const f16x2*)(src + (size_t)p*128))[lane];
    ax += (float)v.x; ay += (float)v.y;
  }
  red[wv][lane*2] = ax; red[wv][lane*2+1] = ay;
  __syncthreads();
  if (wv == 0){
    float s = nd > 0 ? 1.f/(float)nd : 0.f;
    float2 o = { (red[0][lane*2]+red[1][lane*2]+red[2][lane*2]+red[3][lane*2])*s,
                 (red[0][lane*2+1]+red[1][lane*2+1]+red[2][lane*2+1]+red[3][lane*2+1])*s };
    ((float2*)(ef + (size_t)e*128))[lane] = o;
  }
}

// ========== register-blocked 128x128 GEMM.  IN16: input rows are f16.
// MODE 0: f32 raw   MODE 1: f16(acc*rsqrt(max(cnt,1)) + bias)   MODE 2: f16(relu(acc+bias)) ==========
template<int MODE, int IN16>
__global__ __launch_bounds__(256, 2) void k_gemm(const void* __restrict__ inp,
    const float* __restrict__ W, const int* __restrict__ cnt,
    const float* __restrict__ bias, void* __restrict__ outp)
{
  __shared__ float Wl[128*128];
  __shared__ float Rl[32*128];
  const int tid = threadIdx.x;
  const int rbase = blockIdx.x*32;
  for (int i = tid; i < 16384; i += 256) Wl[i] = W[i];
  if (IN16){
    const f16x2* s2 = (const f16x2*)(((const f16*)inp) + (size_t)rbase*128);
    for (int i = tid; i < 2048; i += 256){
      f16x2 v = s2[i];
      ((float2*)Rl)[i] = make_float2((float)v.x, (float)v.y);
    }
  } else {
    const float* src = ((const float*)inp) + (size_t)rbase*128;
    for (int i = tid; i < 4096; i += 256) Rl[i] = src[i];
  }
  __syncthreads();
  const int c0 = (tid & 31)*4;
  const int r0 = (tid >> 5)*4;
  f32x4 acc[4];
  #pragma unroll
  for (int j = 0; j < 4; ++j) acc[j] = (f32x4){0.f,0.f,0.f,0.f};
  for (int d = 0; d < 128; d += 4){
    f32x4 w0 = *(const f32x4*)&Wl[(d+0)*128 + c0];
    f32x4 w1 = *(const f32x4*)&Wl[(d+1)*128 + c0];
    f32x4 w2 = *(const f32x4*)&Wl[(d+2)*128 + c0];
    f32x4 w3 = *(const f32x4*)&Wl[(d+3)*128 + c0];
    #pragma unroll
    for (int j = 0; j < 4; ++j){
      f32x4 rr = *(const f32x4*)&Rl[(r0+j)*128 + d];
      acc[j] += rr.x*w0 + rr.y*w1 + rr.z*w2 + rr.w*w3;
    }
  }
  #pragma unroll
  for (int j = 0; j < 4; ++j){
    const int row = rbase + r0 + j;
    if (MODE == 0){
      *(f32x4*)(((float*)outp) + (size_t)row*128 + c0) = acc[j];
    } else if (MODE == 1){
      float sc = rsqrtf(fmaxf((float)cnt[row], 1.f));
      f16* o = ((f16*)outp) + (size_t)row*128 + c0;
      #pragma unroll
      for (int k = 0; k < 4; ++k) o[k] = (f16)(acc[j][k]*sc + bias[c0+k]);
    } else {
      f16* o = ((f16*)outp) + (size_t)row*128 + c0;
      #pragma unroll
      for (int k = 0; k < 4; ++k) o[k] = (f16)fmaxf(acc[j][k] + bias[c0+k], 0.f);
    }
  }
}

// ========== hconv stage 2 + relu + residual, 4 nodes/wave, f16 out.
// PRES: scale by rsqrt(du) (for next layer's prescaled input) ==========
template<int PRES>
__global__ __launch_bounds__(256) void k_nha(const int* __restrict__ cnt,
    const u16* __restrict__ csr, const float* __restrict__ ef,
    const float* __restrict__ bias, const float* __restrict__ nfr,
    const int* __restrict__ du, f16* __restrict__ outp)
{
  int wv = threadIdx.x >> 6, lane = threadIdx.x & 63;
  int n0 = blockIdx.x*16 + wv*4;
  int dcnt[4], c[4]; const u16* r[4];
  float ax[4] = {0,0,0,0}, ay[4] = {0,0,0,0};
  #pragma unroll
  for (int u = 0; u < 4; ++u){
    dcnt[u] = cnt[n0+u];
    c[u] = dcnt[u] < SLOT_N ? dcnt[u] : SLOT_N;
    r[u] = csr + (size_t)(n0+u)*SLOT_N;
  }
  int m = c[0];
  #pragma unroll
  for (int u = 1; u < 4; ++u) m = c[u] > m ? c[u] : m;
  for (int j = 0; j < m; ++j){
    #pragma unroll
    for (int u = 0; u < 4; ++u){
      if (j < c[u]){
        int idx = r[u][j];
        float2 v = ((const float2*)(ef + (size_t)idx*128))[lane];
        ax[u] += v.x; ay[u] += v.y;
      }
    }
  }
  float bx = bias[lane*2], by = bias[lane*2+1];
  #pragma unroll
  for (int u = 0; u < 4; ++u){
    float s = dcnt[u] > 0 ? 1.f/(float)dcnt[u] : 0.f;
    float2 nf = ((const float2*)(nfr + (size_t)(n0+u)*128))[lane];
    float vx = fmaxf(ax[u]*s + bx, 0.f) + nf.x;
    float vy = fmaxf(ay[u]*s + by, 0.f) + nf.y;
    float e0 = PRES ? rsqrtf(fmaxf((float)du[n0+u], 1.f)) : 1.f;
    ((f16x2*)(outp + (size_t)(n0+u)*128))[lane] = (f16x2){ (f16)(vx*e0), (f16)(vy*e0) };
  }
}

// ========== q = f16(relu(x @ Wm + bm)), K=512 in 4 LDS chunks ==========
__global__ __launch_bounds__(256) void k_qgemm(const float* __restrict__ x,
    const float* __restrict__ Wm, const float* __restrict__ bm, f16* __restrict__ q)
{
  __shared__ float Wl[128*128];
  const int c = threadIdx.x & 127, rh = threadIdx.x >> 7;
  const int base = blockIdx.x*16 + rh*8;
  float acc[8] = {0,0,0,0,0,0,0,0};
  for (int kc = 0; kc < 4; ++kc){
    __syncthreads();
    for (int i = threadIdx.x; i < 128*128; i += 256) Wl[i] = Wm[kc*128*128 + i];
    __syncthreads();
    #pragma unroll
    for (int r = 0; r < 8; ++r){
      const float* xr = x + (size_t)(base+r)*512 + kc*128;
      float a0=0.f,a1=0.f,a2=0.f,a3=0.f;
      #pragma unroll
      for (int d = 0; d < 128; d += 4){
        a0 += xr[d+0] * Wl[(d+0)*128 + c];
        a1 += xr[d+1] * Wl[(d+1)*128 + c];
        a2 += xr[d+2] * Wl[(d+2)*128 + c];
        a3 += xr[d+3] * Wl[(d+3)*128 + c];
      }
      acc[r] += (a0+a1)+(a2+a3);
    }
  }
  float bv = bm[c];
  #pragma unroll
  for (int r = 0; r < 8; ++r)
    q[(size_t)(base+r)*128 + c] = (f16)fmaxf(acc[r]+bv, 0.f);
}

// ========== gT[b][c][n] = h16[b*NPER+n][c]  (f16 transpose) ==========
__global__ __launch_bounds__(256) void k_gt(const f16* __restrict__ g, f16* __restrict__ gT)
{
  __shared__ f16 t[64][66];
  int b = blockIdx.z, n0 = blockIdx.x*64, c0 = blockIdx.y*64;
  for (int i = threadIdx.x; i < 64*64; i += 256){
    int n = i >> 6, c = i & 63;
    t[n][c] = g[((size_t)(b*NPER + n0 + n))*128 + c0 + c];
  }
  __syncthreads();
  for (int i = threadIdx.x; i < 64*64; i += 256){
    int c = i >> 6, n = i & 63;
    gT[((size_t)(b*128 + c0 + c))*NPER + n0 + n] = t[n][c];
  }
}

// ========== flash attention (R7 config): 64 q-rows/block, n-slab 512, 128-n chunks,
// wave-local P transform, f32 Opart, launch_bounds(256,4) -- no spills ==========
__global__ __launch_bounds__(256, 4) void k_flash(const f16* __restrict__ qb,
    const f16* __restrict__ kb, const f16* __restrict__ gT,
    float* __restrict__ Opart, float* __restrict__ mZ)
{
  __shared__ f16 Plds[4][16][136];             // per-wave slice
  const int sp = blockIdx.x, l0 = blockIdx.y*64, b = blockIdx.z;
  const int w = threadIdx.x >> 6, lane = threadIdx.x & 63;
  const int quad = lane >> 4, col = lane & 15;
  const int koff = quad*8;
  const f16* qrow = qb + ((size_t)(b*LQ + l0 + w*16 + col))*128 + koff;
  f16x8 aq[4];
  #pragma unroll
  for (int ks = 0; ks < 4; ++ks) aq[ks] = *(const f16x8*)(qrow + ks*32);
  float mrun[4] = {-1e30f,-1e30f,-1e30f,-1e30f};
  float zrun[4] = {0.f,0.f,0.f,0.f};
  f32x4 O[8];
  #pragma unroll
  for (int i = 0; i < 8; ++i) O[i] = (f32x4){0.f,0.f,0.f,0.f};
  const int nbase = sp*(NPER/NSPLIT);          // 512-wide n slab
  #pragma unroll 1
  for (int it = 0; it < (NPER/NSPLIT)/128; ++it){
    const int n0 = nbase + it*128;
    f32x4 st[8];
    #pragma unroll
    for (int t = 0; t < 8; ++t){
      st[t] = (f32x4){0.f,0.f,0.f,0.f};
      const f16* kp = kb + ((size_t)(b*NPER + n0 + t*16 + col))*128 + koff;
      #pragma unroll
      for (int ks = 0; ks < 4; ++ks){
        f16x8 bf = *(const f16x8*)(kp + ks*32);
        st[t] = __builtin_amdgcn_mfma_f32_16x16x32_f16(aq[ks], bf, st[t], 0, 0, 0);
      }
    }
    float alr[4];
    #pragma unroll
    for (int r = 0; r < 4; ++r){
      float rm = st[0][r];
      #pragma unroll
      for (int t = 1; t < 8; ++t) rm = fmaxf(rm, st[t][r]);
      rm = fmaxf(rm, __shfl_xor(rm, 1));
      rm = fmaxf(rm, __shfl_xor(rm, 2));
      rm = fmaxf(rm, __shfl_xor(rm, 4));
      rm = fmaxf(rm, __shfl_xor(rm, 8));
      float mn = fmaxf(mrun[r], rm);
      float al = __expf(mrun[r] - mn);
      float ps[8], rs = 0.f;
      #pragma unroll
      for (int t = 0; t < 8; ++t){ ps[t] = __expf(st[t][r] - mn); rs += ps[t]; }
      rs += __shfl_xor(rs, 1);
      rs += __shfl_xor(rs, 2);
      rs += __shfl_xor(rs, 4);
      rs += __shfl_xor(rs, 8);
      zrun[r] = zrun[r]*al + rs;
      mrun[r] = mn;
      alr[r] = al;
      #pragma unroll
      for (int t = 0; t < 8; ++t) Plds[w][quad*4+r][t*16+col] = (f16)ps[t];
    }
    #pragma unroll
    for (int dt = 0; dt < 8; ++dt)
      #pragma unroll
      for (int r = 0; r < 4; ++r) O[dt][r] *= alr[r];
    __builtin_amdgcn_wave_barrier();
    #pragma unroll
    for (int kk = 0; kk < 4; ++kk){
      f16x8 ap = *(const f16x8*)&Plds[w][col][kk*32 + koff];
      const f16* gv = gT + ((size_t)(b*128 + col))*NPER + n0 + kk*32 + koff;
      #pragma unroll
      for (int dt = 0; dt < 8; ++dt){
        f16x8 bv = *(const f16x8*)(gv + (size_t)dt*16*NPER);
        O[dt] = __builtin_amdgcn_mfma_f32_16x16x32_f16(ap, bv, O[dt], 0, 0, 0);
      }
    }
    __builtin_amdgcn_wave_barrier();
  }
  const int growb = b*LQ + l0 + w*16 + quad*4;
  #pragma unroll
  for (int r = 0; r < 4; ++r){
    float* od = Opart + ((size_t)sp*NROW + growb + r)*128 + col;
    #pragma unroll
    for (int dt = 0; dt < 8; ++dt) od[dt*16] = O[dt][r];
  }
  if (col == 0){
    #pragma unroll
    for (int r = 0; r < 4; ++r){
      ((float2*)mZ)[(size_t)sp*NROW + growb + r] = make_float2(mrun[r], zrun[r]);
    }
  }
}

// ========== combine splits -> Hbuf[row][d] ==========
__global__ __launch_bounds__(256) void k_comb(const float* __restrict__ Opart,
    const float* __restrict__ mZ, float* __restrict__ Hbuf)
{
  int i = blockIdx.x*256 + threadIdx.x;         // NROW*64
  int row = i >> 6, d2 = (i & 63)*2;
  float ms[NSPLIT], zs[NSPLIT];
  float M = -1e30f;
  #pragma unroll
  for (int s = 0; s < NSPLIT; ++s){
    float2 v = ((const float2*)mZ)[(size_t)s*NROW + row];
    ms[s] = v.x; zs[s] = v.y;
    M = fmaxf(M, v.x);
  }
  float Zt = 0.f, ax = 0.f, ay = 0.f;
  #pragma unroll
  for (int s = 0; s < NSPLIT; ++s){
    float e = __expf(ms[s] - M);
    Zt += zs[s]*e;
    const float* op = Opart + ((size_t)s*NROW + row)*128 + d2;
    ax += e*op[0]; ay += e*op[1];
  }
  float inv = 1.f/Zt;
  float* o = Hbuf + (size_t)row*128 + d2;
  o[0] = ax*inv; o[1] = ay*inv;
}

// ========== final: [sigmoid([x,H]@Ws+bs), tanh([x,H]@Wt+bt)] -> f32 ==========
__global__ __launch_bounds__(256) void k_final(const float* __restrict__ x,
    const float* __restrict__ Hbuf,
    const float* __restrict__ Wsg, const float* __restrict__ bsg,
    const float* __restrict__ Wtn, const float* __restrict__ btn,
    float* __restrict__ out)
{
  __shared__ f16 Wl[2*128*128];
  const int c = threadIdx.x;
  const int hsel = c >> 7;
  const int cc = c & 127;
  const int base = blockIdx.x * 16;
  float acc[16];
  #pragma unroll
  for (int r = 0; r < 16; ++r) acc[r] = 0.f;
  for (int kc = 0; kc < 5; ++kc){
    __syncthreads();
    for (int i = threadIdx.x; i < 128*128; i += 256){
      Wl[i]         = (f16)Wsg[kc*16384 + i];
      Wl[16384 + i] = (f16)Wtn[kc*16384 + i];
    }
    __syncthreads();
    const f16* wp = Wl + hsel*16384;
    #pragma unroll
    for (int rg = 0; rg < 4; ++rg){
      const float *cr0, *cr1, *cr2, *cr3;
      if (kc < 4){
        cr0 = x + (size_t)(base + rg*4)*512 + kc*128;
        cr1 = cr0 + 512; cr2 = cr1 + 512; cr3 = cr2 + 512;
      } else {
        cr0 = Hbuf + (size_t)(base + rg*4)*128;
        cr1 = cr0 + 128; cr2 = cr1 + 128; cr3 = cr2 + 128;
      }
      float a0=acc[rg*4], a1=acc[rg*4+1], a2=acc[rg*4+2], a3=acc[rg*4+3];
      #pragma unroll 8
      for (int d = 0; d < 128; ++d){
        float wv = (float)wp[d*128 + cc];
        a0 += cr0[d]*wv; a1 += cr1[d]*wv; a2 += cr2[d]*wv; a3 += cr3[d]*wv;
      }
      acc[rg*4]=a0; acc[rg*4+1]=a1; acc[rg*4+2]=a2; acc[rg*4+3]=a3;
    }
  }
  float bv = hsel ? btn[cc] : bsg[cc];
  #pragma unroll
  for (int r = 0; r < 16; ++r){
    float v = acc[r] + bv;
    v = hsel ? tanhf(v) : 1.f/(1.f + __expf(-v));
    out[(size_t)(base+r)*256 + c] = v;
  }
}

extern "C" void kernel_launch(void* const* d_in, const int* in_sizes, int n_in,
                              void* d_out, int out_size, void* d_ws, size_t ws_size,
                              hipStream_t stream)
{
  const float* x    = (const float*)d_in[0];
  const float* nfr  = (const float*)d_in[1];
  const int*   eidx = (const int*)d_in[2];
  const int*   hidx = (const int*)d_in[3];
  const float *Wg1=(const float*)d_in[4],  *bg1=(const float*)d_in[5];
  const float *Wg2=(const float*)d_in[6],  *bg2=(const float*)d_in[7];
  const float *Wh1=(const float*)d_in[8],  *bh1=(const float*)d_in[9];
  const float *Wh2=(const float*)d_in[10], *bh2=(const float*)d_in[11];
  const float *Wm =(const float*)d_in[12], *bm =(const float*)d_in[13];
  const float *Wm2=(const float*)d_in[14], *bm2=(const float*)d_in[15];
  const float *Wsg=(const float*)d_in[16], *bsg=(const float*)d_in[17];
  const float *Wtn=(const float*)d_in[18], *btn=(const float*)d_in[19];
  float* out = (float*)d_out;

  // ---- workspace layout. Aliases:
  //  h4_16 at base; agg16 + Hbuf in second region; Opart f32 (32MB, NSPLIT16)
  //  aliases dead bufA+bufB; kb/gT alias csr_dst/csr_pn (csr now u16, half-used). ----
  char* base = (char*)d_ws;
  f16*   h4_16  = (f16*)(base);                          // 16 MB
  f16*   agg16  = (f16*)(base + 33554432);               // 16 MB (graph phase only)
  float* Hbuf   = (float*)(base + 50331648);             // 2 MB  (attention phase)
  f16*   bufA   = (f16*)(base + 67108864);               // 16 MB  (nfr16 / h2_16)
  f16*   bufB   = (f16*)(base + 83886080);               // 16 MB  (h1_16 / h3_16)
  float* Opart  = (float*)(base + 67108864);             // 32 MB  (aliases bufA+bufB)
  u16*   csr_dst= (u16*)(base + 100663296);              // 8 MB used of 16 MB region
  f16*   kb     = (f16*)(base + 100663296);              //   (aliases csr_dst)
  u16*   csr_pn = (u16*)(base + 117440512);              // 8 MB used of 16 MB region
  f16*   gT     = (f16*)(base + 117440512);              //   (aliases csr_pn)
  u16*   csr_pe = (u16*)(base + 134217728);              // 3 MB used of 6 MB region
  int*   cnt_dst= (int*)(base + 140509184);
  int*   cnt_pn = (int*)(base + 140771328);
  int*   cnt_pe = (int*)(base + 141033472);
  int*   du     = (int*)(base + 141049856);
  float* ef0    = (float*)(base + 141312000);            // 2 MB
  float* ef1    = (float*)(base + 143409152);            // 2 MB
  f16*   qb     = (f16*)(base + 145506304);              // 1 MB
  float* mZ     = (float*)(base + 146554880);            // 512 KB (NSPLIT16)
  const size_t needB = (size_t)147079168;
  if (ws_size < needB) return;

  // ---- CSR build (edges + pairs in one launch) ----
  hipMemsetAsync(cnt_pn, 0, 278528, stream);    // cnt_pn + cnt_pe
  k_build<<<BSZ*EPART + NP/256, 256, 0, stream>>>(eidx, hidx, du, cnt_dst, csr_dst,
                                                  cnt_pn, cnt_pe, csr_pn, csr_pe);

  // ---- layer 1 ----
  k_pre<<<NNODE*64/256, 256, 0, stream>>>(nfr, du, bufA);
  k_gagg16<<<NNODE/16, 256, 0, stream>>>(cnt_dst, csr_dst, bufA, agg16);
  k_gemm<1,1><<<NNODE/32, 256, 0, stream>>>(agg16, Wg1, cnt_dst, bg1, bufB);
  k_hea16<<<NHE, 256, 0, stream>>>(cnt_pe, csr_pe, bufB, ef0);
  k_gemm<0,0><<<NHE/32, 256, 0, stream>>>(ef0, Wh1, nullptr, nullptr, ef1);
  k_nha<1><<<NNODE/16, 256, 0, stream>>>(cnt_pn, csr_pn, ef1, bh1, nfr, du, bufA);

  // ---- layer 2 ----
  k_gagg16<<<NNODE/16, 256, 0, stream>>>(cnt_dst, csr_dst, bufA, agg16);
  k_gemm<1,1><<<NNODE/32, 256, 0, stream>>>(agg16, Wg2, cnt_dst, bg2, bufB);
  k_hea16<<<NHE, 256, 0, stream>>>(cnt_pe, csr_pe, bufB, ef0);
  k_gemm<0,0><<<NHE/32, 256, 0, stream>>>(ef0, Wh2, nullptr, nullptr, ef1);
  k_nha<0><<<NNODE/16, 256, 0, stream>>>(cnt_pn, csr_pn, ef1, bh2, nfr, nullptr, h4_16);

  // ---- attention ----
  k_qgemm<<<NROW/16, 256, 0, stream>>>(x, Wm, bm, qb);
  k_gemm<2,1><<<NNODE/32, 256, 0, stream>>>(h4_16, Wm2, nullptr, bm2, kb);
  k_gt<<<dim3(NPER/64, 2, BSZ), 256, 0, stream>>>(h4_16, gT);
  k_flash<<<dim3(NSPLIT, LQ/64, BSZ), 256, 0, stream>>>(qb, kb, gT, Opart, mZ);
  k_comb<<<NROW*64/256, 256, 0, stream>>>(Opart, mZ, Hbuf);
  k_final<<<NROW/16, 256, 0, stream>>>(x, Hbuf, Wsg, bsg, Wtn, btn, out);

  (void)in_sizes; (void)n_in; (void)out_size;
}

// Round 3
// 1100.171 us; speedup vs baseline: 1.1142x; 1.0861x over previous
//
#include <hip/hip_runtime.h>
#include <hip/hip_bf16.h>

#define BSZ   8
#define NPER  8192
#define NNODE 65536       // BSZ*NPER
#define EPG   131072      // edges per graph
#define EMB   128
#define ENCD  512
#define LQ    512
#define NHE   4096
#define NE    1048576
#define NP    1048576
#define NROW  4096        // BSZ*LQ
#define NSPLIT 16
#define SLOT_N 64
#define SLOT_E 384
// binning: 128 node-buckets (512 nodes), 64 he-buckets (64 hyperedges)
#define CAP_E  10240      // per node-bucket capacity, edges  (mean 8192, +22 sigma)
#define CAP_PN 10240      // per node-bucket capacity, pairs  (mean 8192)
#define CAP_PE 18432      // per he-bucket capacity, pairs    (mean 16384, +16 sigma)

typedef _Float16 f16;
typedef _Float16 f16x2 __attribute__((ext_vector_type(2)));
typedef _Float16 f16x8 __attribute__((ext_vector_type(8)));
typedef float f32x4 __attribute__((ext_vector_type(4)));
typedef unsigned short u16;
typedef unsigned int u32;

// ========== phase A: bin edges (by dst) and pairs (by pn and by pe) into
// contiguous per-bucket arrays; du via global atomics.
// gcur layout: [0,128) edge-dst, [128,256) pn, [256,320) pe ==========
__global__ __launch_bounds__(256) void k_bin(const int* __restrict__ eidx,
    const int* __restrict__ hidx, int* __restrict__ du, int* __restrict__ gcur,
    u32* __restrict__ bin_e, u32* __restrict__ bin_pn, u32* __restrict__ bin_pe)
{
  __shared__ int lh[320];
  __shared__ int gb[320];
  const int tid = threadIdx.x;
  for (int i = tid; i < 320; i += 256) lh[i] = 0;
  __syncthreads();
  if (blockIdx.x < 512){
    // 2048 edges per block
    const int eb4 = blockIdx.x*512;
    int4 sa = ((const int4*)eidx)[eb4 + tid];
    int4 sb = ((const int4*)eidx)[eb4 + 256 + tid];
    int4 da = ((const int4*)(eidx + NE))[eb4 + tid];
    int4 db = ((const int4*)(eidx + NE))[eb4 + 256 + tid];
    int ss[8] = {sa.x,sa.y,sa.z,sa.w, sb.x,sb.y,sb.z,sb.w};
    int dd[8] = {da.x,da.y,da.z,da.w, db.x,db.y,db.z,db.w};
    int rr[8];
    #pragma unroll
    for (int u = 0; u < 8; ++u){
      atomicAdd(&du[ss[u]], 1);
      rr[u] = atomicAdd(&lh[dd[u] >> 9], 1);
    }
    __syncthreads();
    if (tid < 128 && lh[tid]) gb[tid] = atomicAdd(&gcur[tid], lh[tid]);
    __syncthreads();
    #pragma unroll
    for (int u = 0; u < 8; ++u){
      int b = dd[u] >> 9;
      int pos = gb[b] + rr[u];
      if (pos < CAP_E)
        bin_e[(size_t)b*CAP_E + pos] = (u32)(dd[u] & 0xffff) | ((u32)ss[u] << 16);
    }
  } else {
    // 2048 pairs per block, binned both directions
    const int pb4 = (blockIdx.x - 512)*1024;
    int4 pa = ((const int4*)hidx)[pb4 + tid];
    int4 pb = ((const int4*)hidx)[pb4 + 256 + tid];
    int4 pc = ((const int4*)hidx)[pb4 + 512 + tid];
    int4 pd = ((const int4*)hidx)[pb4 + 768 + tid];
    int pn[8] = {pa.x,pa.z, pb.x,pb.z, pc.x,pc.z, pd.x,pd.z};
    int pe[8] = {pa.y,pa.w, pb.y,pb.w, pc.y,pc.w, pd.y,pd.w};
    int rn[8], re[8];
    #pragma unroll
    for (int u = 0; u < 8; ++u){
      rn[u] = atomicAdd(&lh[128 + (pn[u] >> 9)], 1);
      re[u] = atomicAdd(&lh[256 + (pe[u] >> 6)], 1);
    }
    __syncthreads();
    if (tid < 192 && lh[128 + tid]) gb[128 + tid] = atomicAdd(&gcur[128 + tid], lh[128 + tid]);
    __syncthreads();
    #pragma unroll
    for (int u = 0; u < 8; ++u){
      int bn = pn[u] >> 9;
      int pos = gb[128 + bn] + rn[u];
      if (pos < CAP_PN)
        bin_pn[(size_t)bn*CAP_PN + pos] = (u32)pn[u] | ((u32)pe[u] << 16);
      int be = pe[u] >> 6;
      int pos2 = gb[256 + be] + re[u];
      if (pos2 < CAP_PE)
        bin_pe[(size_t)be*CAP_PE + pos2] = (u32)pe[u] | ((u32)pn[u] << 16);
    }
  }
}

// ========== phase B: per-bucket CSR insert (LDS cursors, windowed u16 writes).
// blocks [0,128) edge-dst, [128,256) pn, [256,320) pe ==========
__global__ __launch_bounds__(256) void k_csr(const int* __restrict__ gcur,
    const u32* __restrict__ bin_e, const u32* __restrict__ bin_pn,
    const u32* __restrict__ bin_pe,
    int* __restrict__ cnt_dst, u16* __restrict__ csr_dst,
    int* __restrict__ cnt_pn, u16* __restrict__ csr_pn,
    int* __restrict__ cnt_pe, u16* __restrict__ csr_pe)
{
  const int tid = threadIdx.x;
  if (blockIdx.x < 256){
    __shared__ int cur[512];
    const int isP = blockIdx.x >= 128;
    const int b = blockIdx.x & 127;
    cur[tid] = 0; cur[tid + 256] = 0;
    __syncthreads();
    const int n0 = b*512;
    const int cap = isP ? CAP_PN : CAP_E;
    int raw = gcur[isP ? 128 + b : b];
    int count = raw < cap ? raw : cap;
    const u32* bin = (isP ? bin_pn : bin_e) + (size_t)b*cap;
    u16* csr = isP ? csr_pn : csr_dst;
    for (int i = tid; i < count; i += 256){
      u32 v = bin[i];
      int row = v & 0xffff, val = v >> 16;
      int c = atomicAdd(&cur[row - n0], 1);
      if (c < SLOT_N) csr[(size_t)row*SLOT_N + c] = (u16)val;
    }
    __syncthreads();
    int* cnt = isP ? cnt_pn : cnt_dst;
    cnt[n0 + tid]       = cur[tid];
    cnt[n0 + 256 + tid] = cur[tid + 256];
  } else {
    __shared__ int cur[64];
    const int b = blockIdx.x - 256;
    if (tid < 64) cur[tid] = 0;
    __syncthreads();
    const int e0 = b*64;
    int raw = gcur[256 + b];
    int count = raw < CAP_PE ? raw : CAP_PE;
    const u32* bin = bin_pe + (size_t)b*CAP_PE;
    for (int i = tid; i < count; i += 256){
      u32 v = bin[i];
      int row = v & 0xffff, val = v >> 16;
      int c = atomicAdd(&cur[row - e0], 1);
      if (c < SLOT_E) csr_pe[(size_t)row*SLOT_E + c] = (u16)val;
    }
    __syncthreads();
    if (tid < 64) cnt_pe[e0 + tid] = cur[tid];
  }
}

// ========== nfr16 = f16(nfr * rsqrt(max(du,1))) ==========
__global__ __launch_bounds__(256) void k_pre(const float* __restrict__ nfr,
    const int* __restrict__ du, f16* __restrict__ out)
{
  int i = blockIdx.x*256 + threadIdx.x;         // NNODE*64
  int node = i >> 6, j = i & 63;
  float ds = rsqrtf(fmaxf((float)du[node], 1.f));
  float2 v = ((const float2*)(nfr + (size_t)node*128))[j];
  f16x2 o = { (f16)(v.x*ds), (f16)(v.y*ds) };
  ((f16x2*)(out + (size_t)node*128))[j] = o;
}

// ========== gconv gather (f16 src): agg16[d] = f16(sum src16[s]), 4 nodes/wave ==========
__global__ __launch_bounds__(256) void k_gagg16(const int* __restrict__ cnt,
    const u16* __restrict__ csr, const f16* __restrict__ src, f16* __restrict__ agg)
{
  int blk  = blockIdx.x;                        // NNODE/16 blocks, XCD swizzle
  int wv = threadIdx.x >> 6, lane = threadIdx.x & 63;
  int n0 = (blk & 7)*NPER + (blk >> 3)*16 + wv*4;
  int c[4]; const u16* r[4];
  float ax[4] = {0,0,0,0}, ay[4] = {0,0,0,0};
  #pragma unroll
  for (int u = 0; u < 4; ++u){
    int nd = cnt[n0+u];
    c[u] = nd < SLOT_N ? nd : SLOT_N;
    r[u] = csr + (size_t)(n0+u)*SLOT_N;
  }
  int m = c[0];
  #pragma unroll
  for (int u = 1; u < 4; ++u) m = c[u] > m ? c[u] : m;
  for (int j = 0; j < m; ++j){
    #pragma unroll
    for (int u = 0; u < 4; ++u){
      if (j < c[u]){
        int idx = r[u][j];
        f16x2 v = ((const f16x2*)(src + (size_t)idx*128))[lane];
        ax[u] += (float)v.x; ay[u] += (float)v.y;
      }
    }
  }
  #pragma unroll
  for (int u = 0; u < 4; ++u)
    ((f16x2*)(agg + (size_t)(n0+u)*128))[lane] = (f16x2){ (f16)ax[u], (f16)ay[u] };
}

// ========== hconv stage 1 (f16 source): ef0[e] = (1/|e|) * sum src16[pn] ==========
__global__ __launch_bounds__(256) void k_hea16(const int* __restrict__ cnt,
    const u16* __restrict__ csr, const f16* __restrict__ src, float* __restrict__ ef)
{
  __shared__ float red[4][128];
  int e = blockIdx.x;
  int wv = threadIdx.x >> 6, lane = threadIdx.x & 63;
  int nd = cnt[e];
  int n = nd < SLOT_E ? nd : SLOT_E;
  const u16* row = csr + (size_t)e*SLOT_E;
  float ax = 0.f, ay = 0.f;
  for (int j = wv; j < n; j += 4){
    int p = row[j];
    f16x2 v = ((const f16x2*)(src + (size_t)p*128))[lane];
    ax += (float)v.x; ay += (float)v.y;
  }
  red[wv][lane*2] = ax; red[wv][lane*2+1] = ay;
  __syncthreads();
  if (wv == 0){
    float s = nd > 0 ? 1.f/(float)nd : 0.f;
    float2 o = { (red[0][lane*2]+red[1][lane*2]+red[2][lane*2]+red[3][lane*2])*s,
                 (red[0][lane*2+1]+red[1][lane*2+1]+red[2][lane*2+1]+red[3][lane*2+1])*s };
    ((float2*)(ef + (size_t)e*128))[lane] = o;
  }
}

// ========== register-blocked 128x128 GEMM.  IN16: input rows are f16.
// MODE 0: f32 raw   MODE 1: f16(acc*rsqrt(max(cnt,1)) + bias)   MODE 2: f16(relu(acc+bias)) ==========
template<int MODE, int IN16>
__global__ __launch_bounds__(256, 2) void k_gemm(const void* __restrict__ inp,
    const float* __restrict__ W, const int* __restrict__ cnt,
    const float* __restrict__ bias, void* __restrict__ outp)
{
  __shared__ float Wl[128*128];
  __shared__ float Rl[32*128];
  const int tid = threadIdx.x;
  const int rbase = blockIdx.x*32;
  for (int i = tid; i < 16384; i += 256) Wl[i] = W[i];
  if (IN16){
    const f16x2* s2 = (const f16x2*)(((const f16*)inp) + (size_t)rbase*128);
    for (int i = tid; i < 2048; i += 256){
      f16x2 v = s2[i];
      ((float2*)Rl)[i] = make_float2((float)v.x, (float)v.y);
    }
  } else {
    const float* src = ((const float*)inp) + (size_t)rbase*128;
    for (int i = tid; i < 4096; i += 256) Rl[i] = src[i];
  }
  __syncthreads();
  const int c0 = (tid & 31)*4;
  const int r0 = (tid >> 5)*4;
  f32x4 acc[4];
  #pragma unroll
  for (int j = 0; j < 4; ++j) acc[j] = (f32x4){0.f,0.f,0.f,0.f};
  for (int d = 0; d < 128; d += 4){
    f32x4 w0 = *(const f32x4*)&Wl[(d+0)*128 + c0];
    f32x4 w1 = *(const f32x4*)&Wl[(d+1)*128 + c0];
    f32x4 w2 = *(const f32x4*)&Wl[(d+2)*128 + c0];
    f32x4 w3 = *(const f32x4*)&Wl[(d+3)*128 + c0];
    #pragma unroll
    for (int j = 0; j < 4; ++j){
      f32x4 rr = *(const f32x4*)&Rl[(r0+j)*128 + d];
      acc[j] += rr.x*w0 + rr.y*w1 + rr.z*w2 + rr.w*w3;
    }
  }
  #pragma unroll
  for (int j = 0; j < 4; ++j){
    const int row = rbase + r0 + j;
    if (MODE == 0){
      *(f32x4*)(((float*)outp) + (size_t)row*128 + c0) = acc[j];
    } else if (MODE == 1){
      float sc = rsqrtf(fmaxf((float)cnt[row], 1.f));
      f16* o = ((f16*)outp) + (size_t)row*128 + c0;
      #pragma unroll
      for (int k = 0; k < 4; ++k) o[k] = (f16)(acc[j][k]*sc + bias[c0+k]);
    } else {
      f16* o = ((f16*)outp) + (size_t)row*128 + c0;
      #pragma unroll
      for (int k = 0; k < 4; ++k) o[k] = (f16)fmaxf(acc[j][k] + bias[c0+k], 0.f);
    }
  }
}

// ========== hconv stage 2 + relu + residual, 4 nodes/wave, f16 out.
// PRES: scale by rsqrt(du) (for next layer's prescaled input) ==========
template<int PRES>
__global__ __launch_bounds__(256) void k_nha(const int* __restrict__ cnt,
    const u16* __restrict__ csr, const float* __restrict__ ef,
    const float* __restrict__ bias, const float* __restrict__ nfr,
    const int* __restrict__ du, f16* __restrict__ outp)
{
  int wv = threadIdx.x >> 6, lane = threadIdx.x & 63;
  int n0 = blockIdx.x*16 + wv*4;
  int dcnt[4], c[4]; const u16* r[4];
  float ax[4] = {0,0,0,0}, ay[4] = {0,0,0,0};
  #pragma unroll
  for (int u = 0; u < 4; ++u){
    dcnt[u] = cnt[n0+u];
    c[u] = dcnt[u] < SLOT_N ? dcnt[u] : SLOT_N;
    r[u] = csr + (size_t)(n0+u)*SLOT_N;
  }
  int m = c[0];
  #pragma unroll
  for (int u = 1; u < 4; ++u) m = c[u] > m ? c[u] : m;
  for (int j = 0; j < m; ++j){
    #pragma unroll
    for (int u = 0; u < 4; ++u){
      if (j < c[u]){
        int idx = r[u][j];
        float2 v = ((const float2*)(ef + (size_t)idx*128))[lane];
        ax[u] += v.x; ay[u] += v.y;
      }
    }
  }
  float bx = bias[lane*2], by = bias[lane*2+1];
  #pragma unroll
  for (int u = 0; u < 4; ++u){
    float s = dcnt[u] > 0 ? 1.f/(float)dcnt[u] : 0.f;
    float2 nf = ((const float2*)(nfr + (size_t)(n0+u)*128))[lane];
    float vx = fmaxf(ax[u]*s + bx, 0.f) + nf.x;
    float vy = fmaxf(ay[u]*s + by, 0.f) + nf.y;
    float e0 = PRES ? rsqrtf(fmaxf((float)du[n0+u], 1.f)) : 1.f;
    ((f16x2*)(outp + (size_t)(n0+u)*128))[lane] = (f16x2){ (f16)(vx*e0), (f16)(vy*e0) };
  }
}

// ========== q = f16(relu(x @ Wm + bm)), K=512 in 4 LDS chunks ==========
__global__ __launch_bounds__(256) void k_qgemm(const float* __restrict__ x,
    const float* __restrict__ Wm, const float* __restrict__ bm, f16* __restrict__ q)
{
  __shared__ float Wl[128*128];
  const int c = threadIdx.x & 127, rh = threadIdx.x >> 7;
  const int base = blockIdx.x*16 + rh*8;
  float acc[8] = {0,0,0,0,0,0,0,0};
  for (int kc = 0; kc < 4; ++kc){
    __syncthreads();
    for (int i = threadIdx.x; i < 128*128; i += 256) Wl[i] = Wm[kc*128*128 + i];
    __syncthreads();
    #pragma unroll
    for (int r = 0; r < 8; ++r){
      const float* xr = x + (size_t)(base+r)*512 + kc*128;
      float a0=0.f,a1=0.f,a2=0.f,a3=0.f;
      #pragma unroll
      for (int d = 0; d < 128; d += 4){
        a0 += xr[d+0] * Wl[(d+0)*128 + c];
        a1 += xr[d+1] * Wl[(d+1)*128 + c];
        a2 += xr[d+2] * Wl[(d+2)*128 + c];
        a3 += xr[d+3] * Wl[(d+3)*128 + c];
      }
      acc[r] += (a0+a1)+(a2+a3);
    }
  }
  float bv = bm[c];
  #pragma unroll
  for (int r = 0; r < 8; ++r)
    q[(size_t)(base+r)*128 + c] = (f16)fmaxf(acc[r]+bv, 0.f);
}

// ========== gT[b][c][n] = h16[b*NPER+n][c]  (f16 transpose) ==========
__global__ __launch_bounds__(256) void k_gt(const f16* __restrict__ g, f16* __restrict__ gT)
{
  __shared__ f16 t[64][66];
  int b = blockIdx.z, n0 = blockIdx.x*64, c0 = blockIdx.y*64;
  for (int i = threadIdx.x; i < 64*64; i += 256){
    int n = i >> 6, c = i & 63;
    t[n][c] = g[((size_t)(b*NPER + n0 + n))*128 + c0 + c];
  }
  __syncthreads();
  for (int i = threadIdx.x; i < 64*64; i += 256){
    int c = i >> 6, n = i & 63;
    gT[((size_t)(b*128 + c0 + c))*NPER + n0 + n] = t[n][c];
  }
}

// ========== flash attention (R7 config): 64 q-rows/block, n-slab 512, 128-n chunks,
// wave-local P transform, f32 Opart, launch_bounds(256,4) -- no spills ==========
__global__ __launch_bounds__(256, 4) void k_flash(const f16* __restrict__ qb,
    const f16* __restrict__ kb, const f16* __restrict__ gT,
    float* __restrict__ Opart, float* __restrict__ mZ)
{
  __shared__ f16 Plds[4][16][136];             // per-wave slice
  const int sp = blockIdx.x, l0 = blockIdx.y*64, b = blockIdx.z;
  const int w = threadIdx.x >> 6, lane = threadIdx.x & 63;
  const int quad = lane >> 4, col = lane & 15;
  const int koff = quad*8;
  const f16* qrow = qb + ((size_t)(b*LQ + l0 + w*16 + col))*128 + koff;
  f16x8 aq[4];
  #pragma unroll
  for (int ks = 0; ks < 4; ++ks) aq[ks] = *(const f16x8*)(qrow + ks*32);
  float mrun[4] = {-1e30f,-1e30f,-1e30f,-1e30f};
  float zrun[4] = {0.f,0.f,0.f,0.f};
  f32x4 O[8];
  #pragma unroll
  for (int i = 0; i < 8; ++i) O[i] = (f32x4){0.f,0.f,0.f,0.f};
  const int nbase = sp*(NPER/NSPLIT);          // 512-wide n slab
  #pragma unroll 1
  for (int it = 0; it < (NPER/NSPLIT)/128; ++it){
    const int n0 = nbase + it*128;
    f32x4 st[8];
    #pragma unroll
    for (int t = 0; t < 8; ++t){
      st[t] = (f32x4){0.f,0.f,0.f,0.f};
      const f16* kp = kb + ((size_t)(b*NPER + n0 + t*16 + col))*128 + koff;
      #pragma unroll
      for (int ks = 0; ks < 4; ++ks){
        f16x8 bf = *(const f16x8*)(kp + ks*32);
        st[t] = __builtin_amdgcn_mfma_f32_16x16x32_f16(aq[ks], bf, st[t], 0, 0, 0);
      }
    }
    float alr[4];
    #pragma unroll
    for (int r = 0; r < 4; ++r){
      float rm = st[0][r];
      #pragma unroll
      for (int t = 1; t < 8; ++t) rm = fmaxf(rm, st[t][r]);
      rm = fmaxf(rm, __shfl_xor(rm, 1));
      rm = fmaxf(rm, __shfl_xor(rm, 2));
      rm = fmaxf(rm, __shfl_xor(rm, 4));
      rm = fmaxf(rm, __shfl_xor(rm, 8));
      float mn = fmaxf(mrun[r], rm);
      float al = __expf(mrun[r] - mn);
      float ps[8], rs = 0.f;
      #pragma unroll
      for (int t = 0; t < 8; ++t){ ps[t] = __expf(st[t][r] - mn); rs += ps[t]; }
      rs += __shfl_xor(rs, 1);
      rs += __shfl_xor(rs, 2);
      rs += __shfl_xor(rs, 4);
      rs += __shfl_xor(rs, 8);
      zrun[r] = zrun[r]*al + rs;
      mrun[r] = mn;
      alr[r] = al;
      #pragma unroll
      for (int t = 0; t < 8; ++t) Plds[w][quad*4+r][t*16+col] = (f16)ps[t];
    }
    #pragma unroll
    for (int dt = 0; dt < 8; ++dt)
      #pragma unroll
      for (int r = 0; r < 4; ++r) O[dt][r] *= alr[r];
    __builtin_amdgcn_wave_barrier();
    #pragma unroll
    for (int kk = 0; kk < 4; ++kk){
      f16x8 ap = *(const f16x8*)&Plds[w][col][kk*32 + koff];
      const f16* gv = gT + ((size_t)(b*128 + col))*NPER + n0 + kk*32 + koff;
      #pragma unroll
      for (int dt = 0; dt < 8; ++dt){
        f16x8 bv = *(const f16x8*)(gv + (size_t)dt*16*NPER);
        O[dt] = __builtin_amdgcn_mfma_f32_16x16x32_f16(ap, bv, O[dt], 0, 0, 0);
      }
    }
    __builtin_amdgcn_wave_barrier();
  }
  const int growb = b*LQ + l0 + w*16 + quad*4;
  #pragma unroll
  for (int r = 0; r < 4; ++r){
    float* od = Opart + ((size_t)sp*NROW + growb + r)*128 + col;
    #pragma unroll
    for (int dt = 0; dt < 8; ++dt) od[dt*16] = O[dt][r];
  }
  if (col == 0){
    #pragma unroll
    for (int r = 0; r < 4; ++r){
      ((float2*)mZ)[(size_t)sp*NROW + growb + r] = make_float2(mrun[r], zrun[r]);
    }
  }
}

// ========== combine splits -> Hbuf[row][d] ==========
__global__ __launch_bounds__(256) void k_comb(const float* __restrict__ Opart,
    const float* __restrict__ mZ, float* __restrict__ Hbuf)
{
  int i = blockIdx.x*256 + threadIdx.x;         // NROW*64
  int row = i >> 6, d2 = (i & 63)*2;
  float ms[NSPLIT], zs[NSPLIT];
  float M = -1e30f;
  #pragma unroll
  for (int s = 0; s < NSPLIT; ++s){
    float2 v = ((const float2*)mZ)[(size_t)s*NROW + row];
    ms[s] = v.x; zs[s] = v.y;
    M = fmaxf(M, v.x);
  }
  float Zt = 0.f, ax = 0.f, ay = 0.f;
  #pragma unroll
  for (int s = 0; s < NSPLIT; ++s){
    float e = __expf(ms[s] - M);
    Zt += zs[s]*e;
    const float* op = Opart + ((size_t)s*NROW + row)*128 + d2;
    ax += e*op[0]; ay += e*op[1];
  }
  float inv = 1.f/Zt;
  float* o = Hbuf + (size_t)row*128 + d2;
  o[0] = ax*inv; o[1] = ay*inv;
}

// ========== final: [sigmoid([x,H]@Ws+bs), tanh([x,H]@Wt+bt)] -> f32 ==========
__global__ __launch_bounds__(256) void k_final(const float* __restrict__ x,
    const float* __restrict__ Hbuf,
    const float* __restrict__ Wsg, const float* __restrict__ bsg,
    const float* __restrict__ Wtn, const float* __restrict__ btn,
    float* __restrict__ out)
{
  __shared__ f16 Wl[2*128*128];
  const int c = threadIdx.x;
  const int hsel = c >> 7;
  const int cc = c & 127;
  const int base = blockIdx.x * 16;
  float acc[16];
  #pragma unroll
  for (int r = 0; r < 16; ++r) acc[r] = 0.f;
  for (int kc = 0; kc < 5; ++kc){
    __syncthreads();
    for (int i = threadIdx.x; i < 128*128; i += 256){
      Wl[i]         = (f16)Wsg[kc*16384 + i];
      Wl[16384 + i] = (f16)Wtn[kc*16384 + i];
    }
    __syncthreads();
    const f16* wp = Wl + hsel*16384;
    #pragma unroll
    for (int rg = 0; rg < 4; ++rg){
      const float *cr0, *cr1, *cr2, *cr3;
      if (kc < 4){
        cr0 = x + (size_t)(base + rg*4)*512 + kc*128;
        cr1 = cr0 + 512; cr2 = cr1 + 512; cr3 = cr2 + 512;
      } else {
        cr0 = Hbuf + (size_t)(base + rg*4)*128;
        cr1 = cr0 + 128; cr2 = cr1 + 128; cr3 = cr2 + 128;
      }
      float a0=acc[rg*4], a1=acc[rg*4+1], a2=acc[rg*4+2], a3=acc[rg*4+3];
      #pragma unroll 8
      for (int d = 0; d < 128; ++d){
        float wv = (float)wp[d*128 + cc];
        a0 += cr0[d]*wv; a1 += cr1[d]*wv; a2 += cr2[d]*wv; a3 += cr3[d]*wv;
      }
      acc[rg*4]=a0; acc[rg*4+1]=a1; acc[rg*4+2]=a2; acc[rg*4+3]=a3;
    }
  }
  float bv = hsel ? btn[cc] : bsg[cc];
  #pragma unroll
  for (int r = 0; r < 16; ++r){
    float v = acc[r] + bv;
    v = hsel ? tanhf(v) : 1.f/(1.f + __expf(-v));
    out[(size_t)(base+r)*256 + c] = v;
  }
}

extern "C" void kernel_launch(void* const* d_in, const int* in_sizes, int n_in,
                              void* d_out, int out_size, void* d_ws, size_t ws_size,
                              hipStream_t stream)
{
  const float* x    = (const float*)d_in[0];
  const float* nfr  = (const float*)d_in[1];
  const int*   eidx = (const int*)d_in[2];
  const int*   hidx = (const int*)d_in[3];
  const float *Wg1=(const float*)d_in[4],  *bg1=(const float*)d_in[5];
  const float *Wg2=(const float*)d_in[6],  *bg2=(const float*)d_in[7];
  const float *Wh1=(const float*)d_in[8],  *bh1=(const float*)d_in[9];
  const float *Wh2=(const float*)d_in[10], *bh2=(const float*)d_in[11];
  const float *Wm =(const float*)d_in[12], *bm =(const float*)d_in[13];
  const float *Wm2=(const float*)d_in[14], *bm2=(const float*)d_in[15];
  const float *Wsg=(const float*)d_in[16], *bsg=(const float*)d_in[17];
  const float *Wtn=(const float*)d_in[18], *btn=(const float*)d_in[19];
  float* out = (float*)d_out;

  // ---- workspace layout. Aliases:
  //  h4_16 at base; bins + gcur live only before k_gagg16, alias agg16 region;
  //  Opart f32 (32MB, NSPLIT16) aliases dead bufA+bufB; kb/gT alias csr_dst/csr_pn. ----
  char* base = (char*)d_ws;
  f16*   h4_16  = (f16*)(base);                          // 16 MB
  f16*   agg16  = (f16*)(base + 33554432);               // 16 MB (graph phase only)
  u32*   bin_e  = (u32*)(base + 33554432);               // 5 MB   (aliases agg16)
  u32*   bin_pn = (u32*)(base + 38797312);               // 5 MB
  u32*   bin_pe = (u32*)(base + 44040192);               // 4.5 MB
  int*   gcur   = (int*)(base + 48758784);               // 1.25 KB
  float* Hbuf   = (float*)(base + 50331648);             // 2 MB  (attention phase)
  f16*   bufA   = (f16*)(base + 67108864);               // 16 MB  (nfr16 / h2_16)
  f16*   bufB   = (f16*)(base + 83886080);               // 16 MB  (h1_16 / h3_16)
  float* Opart  = (float*)(base + 67108864);             // 32 MB  (aliases bufA+bufB)
  u16*   csr_dst= (u16*)(base + 100663296);              // 8 MB used of 16 MB region
  f16*   kb     = (f16*)(base + 100663296);              //   (aliases csr_dst)
  u16*   csr_pn = (u16*)(base + 117440512);              // 8 MB used of 16 MB region
  f16*   gT     = (f16*)(base + 117440512);              //   (aliases csr_pn)
  u16*   csr_pe = (u16*)(base + 134217728);              // 3 MB used of 6 MB region
  int*   cnt_dst= (int*)(base + 140509184);
  int*   cnt_pn = (int*)(base + 140771328);
  int*   cnt_pe = (int*)(base + 141033472);
  int*   du     = (int*)(base + 141049856);              // 256 KB
  float* ef0    = (float*)(base + 141312000);            // 2 MB
  float* ef1    = (float*)(base + 143409152);            // 2 MB
  f16*   qb     = (f16*)(base + 145506304);              // 1 MB
  float* mZ     = (float*)(base + 146554880);            // 512 KB (NSPLIT16)
  const size_t needB = (size_t)147079168;
  if (ws_size < needB) return;

  // ---- CSR build: bin (phase A) then per-bucket insert (phase B) ----
  hipMemsetAsync(du, 0, 262144, stream);
  hipMemsetAsync(gcur, 0, 1280, stream);
  k_bin<<<1024, 256, 0, stream>>>(eidx, hidx, du, gcur, bin_e, bin_pn, bin_pe);
  k_csr<<<320, 256, 0, stream>>>(gcur, bin_e, bin_pn, bin_pe,
                                 cnt_dst, csr_dst, cnt_pn, csr_pn, cnt_pe, csr_pe);

  // ---- layer 1 ----
  k_pre<<<NNODE*64/256, 256, 0, stream>>>(nfr, du, bufA);
  k_gagg16<<<NNODE/16, 256, 0, stream>>>(cnt_dst, csr_dst, bufA, agg16);
  k_gemm<1,1><<<NNODE/32, 256, 0, stream>>>(agg16, Wg1, cnt_dst, bg1, bufB);
  k_hea16<<<NHE, 256, 0, stream>>>(cnt_pe, csr_pe, bufB, ef0);
  k_gemm<0,0><<<NHE/32, 256, 0, stream>>>(ef0, Wh1, nullptr, nullptr, ef1);
  k_nha<1><<<NNODE/16, 256, 0, stream>>>(cnt_pn, csr_pn, ef1, bh1, nfr, du, bufA);

  // ---- layer 2 ----
  k_gagg16<<<NNODE/16, 256, 0, stream>>>(cnt_dst, csr_dst, bufA, agg16);
  k_gemm<1,1><<<NNODE/32, 256, 0, stream>>>(agg16, Wg2, cnt_dst, bg2, bufB);
  k_hea16<<<NHE, 256, 0, stream>>>(cnt_pe, csr_pe, bufB, ef0);
  k_gemm<0,0><<<NHE/32, 256, 0, stream>>>(ef0, Wh2, nullptr, nullptr, ef1);
  k_nha<0><<<NNODE/16, 256, 0, stream>>>(cnt_pn, csr_pn, ef1, bh2, nfr, nullptr, h4_16);

  // ---- attention ----
  k_qgemm<<<NROW/16, 256, 0, stream>>>(x, Wm, bm, qb);
  k_gemm<2,1><<<NNODE/32, 256, 0, stream>>>(h4_16, Wm2, nullptr, bm2, kb);
  k_gt<<<dim3(NPER/64, 2, BSZ), 256, 0, stream>>>(h4_16, gT);
  k_flash<<<dim3(NSPLIT, LQ/64, BSZ), 256, 0, stream>>>(qb, kb, gT, Opart, mZ);
  k_comb<<<NROW*64/256, 256, 0, stream>>>(Opart, mZ, Hbuf);
  k_final<<<NROW/16, 256, 0, stream>>>(x, Hbuf, Wsg, bsg, Wtn, btn, out);

  (void)in_sizes; (void)n_in; (void)out_size;
}

// Round 4
// 1007.124 us; speedup vs baseline: 1.2172x; 1.0924x over previous
//
#include <hip/hip_runtime.h>
#include <hip/hip_bf16.h>

#define BSZ   8
#define NPER  8192
#define NNODE 65536       // BSZ*NPER
#define EPG   131072      // edges per graph
#define EMB   128
#define ENCD  512
#define LQ    512
#define NHE   4096
#define NE    1048576
#define NP    1048576
#define NROW  4096        // BSZ*LQ
#define NSPLIT 16
#define SLOT_N 64
#define SLOT_E 384
// binning: 128 node-buckets (512 nodes), 64 he-buckets (64 hyperedges)
#define CAP_E  10240      // per node-bucket capacity, edges  (mean 8192, +22 sigma)
#define CAP_PN 10240      // per node-bucket capacity, pairs  (mean 8192)
#define CAP_PE 18432      // per he-bucket capacity, pairs    (mean 16384, +16 sigma)

typedef _Float16 f16;
typedef _Float16 f16x2 __attribute__((ext_vector_type(2)));
typedef _Float16 f16x4 __attribute__((ext_vector_type(4)));
typedef _Float16 f16x8 __attribute__((ext_vector_type(8)));
typedef float f32x4 __attribute__((ext_vector_type(4)));
typedef unsigned short u16;
typedef unsigned int u32;

// ========== phase A: bin edges (by dst) and pairs (by pn and by pe) into
// contiguous per-bucket arrays; du via global atomics.
// gcur layout: [0,128) edge-dst, [128,256) pn, [256,320) pe ==========
__global__ __launch_bounds__(256) void k_bin(const int* __restrict__ eidx,
    const int* __restrict__ hidx, int* __restrict__ du, int* __restrict__ gcur,
    u32* __restrict__ bin_e, u32* __restrict__ bin_pn, u32* __restrict__ bin_pe)
{
  __shared__ int lh[320];
  __shared__ int gb[320];
  const int tid = threadIdx.x;
  for (int i = tid; i < 320; i += 256) lh[i] = 0;
  __syncthreads();
  if (blockIdx.x < 512){
    // 2048 edges per block
    const int eb4 = blockIdx.x*512;
    int4 sa = ((const int4*)eidx)[eb4 + tid];
    int4 sb = ((const int4*)eidx)[eb4 + 256 + tid];
    int4 da = ((const int4*)(eidx + NE))[eb4 + tid];
    int4 db = ((const int4*)(eidx + NE))[eb4 + 256 + tid];
    int ss[8] = {sa.x,sa.y,sa.z,sa.w, sb.x,sb.y,sb.z,sb.w};
    int dd[8] = {da.x,da.y,da.z,da.w, db.x,db.y,db.z,db.w};
    int rr[8];
    #pragma unroll
    for (int u = 0; u < 8; ++u){
      atomicAdd(&du[ss[u]], 1);
      rr[u] = atomicAdd(&lh[dd[u] >> 9], 1);
    }
    __syncthreads();
    if (tid < 128 && lh[tid]) gb[tid] = atomicAdd(&gcur[tid], lh[tid]);
    __syncthreads();
    #pragma unroll
    for (int u = 0; u < 8; ++u){
      int b = dd[u] >> 9;
      int pos = gb[b] + rr[u];
      if (pos < CAP_E)
        bin_e[(size_t)b*CAP_E + pos] = (u32)(dd[u] & 0xffff) | ((u32)ss[u] << 16);
    }
  } else {
    // 2048 pairs per block, binned both directions
    const int pb4 = (blockIdx.x - 512)*1024;
    int4 pa = ((const int4*)hidx)[pb4 + tid];
    int4 pb = ((const int4*)hidx)[pb4 + 256 + tid];
    int4 pc = ((const int4*)hidx)[pb4 + 512 + tid];
    int4 pd = ((const int4*)hidx)[pb4 + 768 + tid];
    int pn[8] = {pa.x,pa.z, pb.x,pb.z, pc.x,pc.z, pd.x,pd.z};
    int pe[8] = {pa.y,pa.w, pb.y,pb.w, pc.y,pc.w, pd.y,pd.w};
    int rn[8], re[8];
    #pragma unroll
    for (int u = 0; u < 8; ++u){
      rn[u] = atomicAdd(&lh[128 + (pn[u] >> 9)], 1);
      re[u] = atomicAdd(&lh[256 + (pe[u] >> 6)], 1);
    }
    __syncthreads();
    if (tid < 192 && lh[128 + tid]) gb[128 + tid] = atomicAdd(&gcur[128 + tid], lh[128 + tid]);
    __syncthreads();
    #pragma unroll
    for (int u = 0; u < 8; ++u){
      int bn = pn[u] >> 9;
      int pos = gb[128 + bn] + rn[u];
      if (pos < CAP_PN)
        bin_pn[(size_t)bn*CAP_PN + pos] = (u32)pn[u] | ((u32)pe[u] << 16);
      int be = pe[u] >> 6;
      int pos2 = gb[256 + be] + re[u];
      if (pos2 < CAP_PE)
        bin_pe[(size_t)be*CAP_PE + pos2] = (u32)pe[u] | ((u32)pn[u] << 16);
    }
  }
}

// ========== phase B: per-bucket CSR insert (LDS cursors, windowed u16 writes).
// blocks [0,128) edge-dst, [128,256) pn, [256,320) pe ==========
__global__ __launch_bounds__(256) void k_csr(const int* __restrict__ gcur,
    const u32* __restrict__ bin_e, const u32* __restrict__ bin_pn,
    const u32* __restrict__ bin_pe,
    int* __restrict__ cnt_dst, u16* __restrict__ csr_dst,
    int* __restrict__ cnt_pn, u16* __restrict__ csr_pn,
    int* __restrict__ cnt_pe, u16* __restrict__ csr_pe)
{
  const int tid = threadIdx.x;
  if (blockIdx.x < 256){
    __shared__ int cur[512];
    const int isP = blockIdx.x >= 128;
    const int b = blockIdx.x & 127;
    cur[tid] = 0; cur[tid + 256] = 0;
    __syncthreads();
    const int n0 = b*512;
    const int cap = isP ? CAP_PN : CAP_E;
    int raw = gcur[isP ? 128 + b : b];
    int count = raw < cap ? raw : cap;
    const u32* bin = (isP ? bin_pn : bin_e) + (size_t)b*cap;
    u16* csr = isP ? csr_pn : csr_dst;
    for (int i = tid; i < count; i += 256){
      u32 v = bin[i];
      int row = v & 0xffff, val = v >> 16;
      int c = atomicAdd(&cur[row - n0], 1);
      if (c < SLOT_N) csr[(size_t)row*SLOT_N + c] = (u16)val;
    }
    __syncthreads();
    int* cnt = isP ? cnt_pn : cnt_dst;
    cnt[n0 + tid]       = cur[tid];
    cnt[n0 + 256 + tid] = cur[tid + 256];
  } else {
    __shared__ int cur[64];
    const int b = blockIdx.x - 256;
    if (tid < 64) cur[tid] = 0;
    __syncthreads();
    const int e0 = b*64;
    int raw = gcur[256 + b];
    int count = raw < CAP_PE ? raw : CAP_PE;
    const u32* bin = bin_pe + (size_t)b*CAP_PE;
    for (int i = tid; i < count; i += 256){
      u32 v = bin[i];
      int row = v & 0xffff, val = v >> 16;
      int c = atomicAdd(&cur[row - e0], 1);
      if (c < SLOT_E) csr_pe[(size_t)row*SLOT_E + c] = (u16)val;
    }
    __syncthreads();
    if (tid < 64) cnt_pe[e0 + tid] = cur[tid];
  }
}

// ========== nfr16 = f16(nfr * rsqrt(max(du,1))) ==========
__global__ __launch_bounds__(256) void k_pre(const float* __restrict__ nfr,
    const int* __restrict__ du, f16* __restrict__ out)
{
  int i = blockIdx.x*256 + threadIdx.x;         // NNODE*64
  int node = i >> 6, j = i & 63;
  float ds = rsqrtf(fmaxf((float)du[node], 1.f));
  float2 v = ((const float2*)(nfr + (size_t)node*128))[j];
  f16x2 o = { (f16)(v.x*ds), (f16)(v.y*ds) };
  ((f16x2*)(out + (size_t)node*128))[j] = o;
}

// ========== gconv gather (f16 src): agg16[d] = f16(sum src16[s]), 4 nodes/wave ==========
__global__ __launch_bounds__(256) void k_gagg16(const int* __restrict__ cnt,
    const u16* __restrict__ csr, const f16* __restrict__ src, f16* __restrict__ agg)
{
  int blk  = blockIdx.x;                        // NNODE/16 blocks, XCD swizzle
  int wv = threadIdx.x >> 6, lane = threadIdx.x & 63;
  int n0 = (blk & 7)*NPER + (blk >> 3)*16 + wv*4;
  int c[4]; const u16* r[4];
  float ax[4] = {0,0,0,0}, ay[4] = {0,0,0,0};
  #pragma unroll
  for (int u = 0; u < 4; ++u){
    int nd = cnt[n0+u];
    c[u] = nd < SLOT_N ? nd : SLOT_N;
    r[u] = csr + (size_t)(n0+u)*SLOT_N;
  }
  int m = c[0];
  #pragma unroll
  for (int u = 1; u < 4; ++u) m = c[u] > m ? c[u] : m;
  for (int j = 0; j < m; ++j){
    #pragma unroll
    for (int u = 0; u < 4; ++u){
      if (j < c[u]){
        int idx = r[u][j];
        f16x2 v = ((const f16x2*)(src + (size_t)idx*128))[lane];
        ax[u] += (float)v.x; ay[u] += (float)v.y;
      }
    }
  }
  #pragma unroll
  for (int u = 0; u < 4; ++u)
    ((f16x2*)(agg + (size_t)(n0+u)*128))[lane] = (f16x2){ (f16)ax[u], (f16)ay[u] };
}

// ========== hconv stage 1 (f16 source): ef0[e] = (1/|e|) * sum src16[pn] ==========
__global__ __launch_bounds__(256) void k_hea16(const int* __restrict__ cnt,
    const u16* __restrict__ csr, const f16* __restrict__ src, float* __restrict__ ef)
{
  __shared__ float red[4][128];
  int e = blockIdx.x;
  int wv = threadIdx.x >> 6, lane = threadIdx.x & 63;
  int nd = cnt[e];
  int n = nd < SLOT_E ? nd : SLOT_E;
  const u16* row = csr + (size_t)e*SLOT_E;
  float ax = 0.f, ay = 0.f;
  for (int j = wv; j < n; j += 4){
    int p = row[j];
    f16x2 v = ((const f16x2*)(src + (size_t)p*128))[lane];
    ax += (float)v.x; ay += (float)v.y;
  }
  red[wv][lane*2] = ax; red[wv][lane*2+1] = ay;
  __syncthreads();
  if (wv == 0){
    float s = nd > 0 ? 1.f/(float)nd : 0.f;
    float2 o = { (red[0][lane*2]+red[1][lane*2]+red[2][lane*2]+red[3][lane*2])*s,
                 (red[0][lane*2+1]+red[1][lane*2+1]+red[2][lane*2+1]+red[3][lane*2+1])*s };
    ((float2*)(ef + (size_t)e*128))[lane] = o;
  }
}

// ========== register-blocked 128x128 GEMM.  IN16: input rows are f16.
// MODE 0: f32 raw   MODE 1: f16(acc*rsqrt(max(cnt,1)) + bias)   MODE 2: f16(relu(acc+bias)) ==========
template<int MODE, int IN16>
__global__ __launch_bounds__(256, 2) void k_gemm(const void* __restrict__ inp,
    const float* __restrict__ W, const int* __restrict__ cnt,
    const float* __restrict__ bias, void* __restrict__ outp)
{
  __shared__ float Wl[128*128];
  __shared__ float Rl[32*128];
  const int tid = threadIdx.x;
  const int rbase = blockIdx.x*32;
  for (int i = tid; i < 16384; i += 256) Wl[i] = W[i];
  if (IN16){
    const f16x2* s2 = (const f16x2*)(((const f16*)inp) + (size_t)rbase*128);
    for (int i = tid; i < 2048; i += 256){
      f16x2 v = s2[i];
      ((float2*)Rl)[i] = make_float2((float)v.x, (float)v.y);
    }
  } else {
    const float* src = ((const float*)inp) + (size_t)rbase*128;
    for (int i = tid; i < 4096; i += 256) Rl[i] = src[i];
  }
  __syncthreads();
  const int c0 = (tid & 31)*4;
  const int r0 = (tid >> 5)*4;
  f32x4 acc[4];
  #pragma unroll
  for (int j = 0; j < 4; ++j) acc[j] = (f32x4){0.f,0.f,0.f,0.f};
  for (int d = 0; d < 128; d += 4){
    f32x4 w0 = *(const f32x4*)&Wl[(d+0)*128 + c0];
    f32x4 w1 = *(const f32x4*)&Wl[(d+1)*128 + c0];
    f32x4 w2 = *(const f32x4*)&Wl[(d+2)*128 + c0];
    f32x4 w3 = *(const f32x4*)&Wl[(d+3)*128 + c0];
    #pragma unroll
    for (int j = 0; j < 4; ++j){
      f32x4 rr = *(const f32x4*)&Rl[(r0+j)*128 + d];
      acc[j] += rr.x*w0 + rr.y*w1 + rr.z*w2 + rr.w*w3;
    }
  }
  #pragma unroll
  for (int j = 0; j < 4; ++j){
    const int row = rbase + r0 + j;
    if (MODE == 0){
      *(f32x4*)(((float*)outp) + (size_t)row*128 + c0) = acc[j];
    } else if (MODE == 1){
      float sc = rsqrtf(fmaxf((float)cnt[row], 1.f));
      f16* o = ((f16*)outp) + (size_t)row*128 + c0;
      #pragma unroll
      for (int k = 0; k < 4; ++k) o[k] = (f16)(acc[j][k]*sc + bias[c0+k]);
    } else {
      f16* o = ((f16*)outp) + (size_t)row*128 + c0;
      #pragma unroll
      for (int k = 0; k < 4; ++k) o[k] = (f16)fmaxf(acc[j][k] + bias[c0+k], 0.f);
    }
  }
}

// ========== hconv stage 2 + relu + residual, 4 nodes/wave, f16 out.
// PRES: scale by rsqrt(du) (for next layer's prescaled input) ==========
template<int PRES>
__global__ __launch_bounds__(256) void k_nha(const int* __restrict__ cnt,
    const u16* __restrict__ csr, const float* __restrict__ ef,
    const float* __restrict__ bias, const float* __restrict__ nfr,
    const int* __restrict__ du, f16* __restrict__ outp)
{
  int wv = threadIdx.x >> 6, lane = threadIdx.x & 63;
  int n0 = blockIdx.x*16 + wv*4;
  int dcnt[4], c[4]; const u16* r[4];
  float ax[4] = {0,0,0,0}, ay[4] = {0,0,0,0};
  #pragma unroll
  for (int u = 0; u < 4; ++u){
    dcnt[u] = cnt[n0+u];
    c[u] = dcnt[u] < SLOT_N ? dcnt[u] : SLOT_N;
    r[u] = csr + (size_t)(n0+u)*SLOT_N;
  }
  int m = c[0];
  #pragma unroll
  for (int u = 1; u < 4; ++u) m = c[u] > m ? c[u] : m;
  for (int j = 0; j < m; ++j){
    #pragma unroll
    for (int u = 0; u < 4; ++u){
      if (j < c[u]){
        int idx = r[u][j];
        float2 v = ((const float2*)(ef + (size_t)idx*128))[lane];
        ax[u] += v.x; ay[u] += v.y;
      }
    }
  }
  float bx = bias[lane*2], by = bias[lane*2+1];
  #pragma unroll
  for (int u = 0; u < 4; ++u){
    float s = dcnt[u] > 0 ? 1.f/(float)dcnt[u] : 0.f;
    float2 nf = ((const float2*)(nfr + (size_t)(n0+u)*128))[lane];
    float vx = fmaxf(ax[u]*s + bx, 0.f) + nf.x;
    float vy = fmaxf(ay[u]*s + by, 0.f) + nf.y;
    float e0 = PRES ? rsqrtf(fmaxf((float)du[n0+u], 1.f)) : 1.f;
    ((f16x2*)(outp + (size_t)(n0+u)*128))[lane] = (f16x2){ (f16)(vx*e0), (f16)(vy*e0) };
  }
}

// ========== q = f16(relu(x @ Wm + bm)), K=512 in 4 LDS chunks ==========
__global__ __launch_bounds__(256) void k_qgemm(const float* __restrict__ x,
    const float* __restrict__ Wm, const float* __restrict__ bm, f16* __restrict__ q)
{
  __shared__ float Wl[128*128];
  const int c = threadIdx.x & 127, rh = threadIdx.x >> 7;
  const int base = blockIdx.x*16 + rh*8;
  float acc[8] = {0,0,0,0,0,0,0,0};
  for (int kc = 0; kc < 4; ++kc){
    __syncthreads();
    for (int i = threadIdx.x; i < 128*128; i += 256) Wl[i] = Wm[kc*128*128 + i];
    __syncthreads();
    #pragma unroll
    for (int r = 0; r < 8; ++r){
      const float* xr = x + (size_t)(base+r)*512 + kc*128;
      float a0=0.f,a1=0.f,a2=0.f,a3=0.f;
      #pragma unroll
      for (int d = 0; d < 128; d += 4){
        a0 += xr[d+0] * Wl[(d+0)*128 + c];
        a1 += xr[d+1] * Wl[(d+1)*128 + c];
        a2 += xr[d+2] * Wl[(d+2)*128 + c];
        a3 += xr[d+3] * Wl[(d+3)*128 + c];
      }
      acc[r] += (a0+a1)+(a2+a3);
    }
  }
  float bv = bm[c];
  #pragma unroll
  for (int r = 0; r < 8; ++r)
    q[(size_t)(base+r)*128 + c] = (f16)fmaxf(acc[r]+bv, 0.f);
}

// ========== gT[b][c][n] = h16[b*NPER+n][c]  (f16 transpose) ==========
__global__ __launch_bounds__(256) void k_gt(const f16* __restrict__ g, f16* __restrict__ gT)
{
  __shared__ f16 t[64][66];
  int b = blockIdx.z, n0 = blockIdx.x*64, c0 = blockIdx.y*64;
  for (int i = threadIdx.x; i < 64*64; i += 256){
    int n = i >> 6, c = i & 63;
    t[n][c] = g[((size_t)(b*NPER + n0 + n))*128 + c0 + c];
  }
  __syncthreads();
  for (int i = threadIdx.x; i < 64*64; i += 256){
    int c = i >> 6, n = i & 63;
    gT[((size_t)(b*128 + c0 + c))*NPER + n0 + n] = t[n][c];
  }
}

// ========== flash attention (R7 config): 64 q-rows/block, n-slab 512, 128-n chunks,
// wave-local P transform, f32 Opart, launch_bounds(256,4) -- no spills ==========
__global__ __launch_bounds__(256, 4) void k_flash(const f16* __restrict__ qb,
    const f16* __restrict__ kb, const f16* __restrict__ gT,
    float* __restrict__ Opart, float* __restrict__ mZ)
{
  __shared__ f16 Plds[4][16][136];             // per-wave slice
  const int sp = blockIdx.x, l0 = blockIdx.y*64, b = blockIdx.z;
  const int w = threadIdx.x >> 6, lane = threadIdx.x & 63;
  const int quad = lane >> 4, col = lane & 15;
  const int koff = quad*8;
  const f16* qrow = qb + ((size_t)(b*LQ + l0 + w*16 + col))*128 + koff;
  f16x8 aq[4];
  #pragma unroll
  for (int ks = 0; ks < 4; ++ks) aq[ks] = *(const f16x8*)(qrow + ks*32);
  float mrun[4] = {-1e30f,-1e30f,-1e30f,-1e30f};
  float zrun[4] = {0.f,0.f,0.f,0.f};
  f32x4 O[8];
  #pragma unroll
  for (int i = 0; i < 8; ++i) O[i] = (f32x4){0.f,0.f,0.f,0.f};
  const int nbase = sp*(NPER/NSPLIT);          // 512-wide n slab
  #pragma unroll 1
  for (int it = 0; it < (NPER/NSPLIT)/128; ++it){
    const int n0 = nbase + it*128;
    f32x4 st[8];
    #pragma unroll
    for (int t = 0; t < 8; ++t){
      st[t] = (f32x4){0.f,0.f,0.f,0.f};
      const f16* kp = kb + ((size_t)(b*NPER + n0 + t*16 + col))*128 + koff;
      #pragma unroll
      for (int ks = 0; ks < 4; ++ks){
        f16x8 bf = *(const f16x8*)(kp + ks*32);
        st[t] = __builtin_amdgcn_mfma_f32_16x16x32_f16(aq[ks], bf, st[t], 0, 0, 0);
      }
    }
    float alr[4];
    #pragma unroll
    for (int r = 0; r < 4; ++r){
      float rm = st[0][r];
      #pragma unroll
      for (int t = 1; t < 8; ++t) rm = fmaxf(rm, st[t][r]);
      rm = fmaxf(rm, __shfl_xor(rm, 1));
      rm = fmaxf(rm, __shfl_xor(rm, 2));
      rm = fmaxf(rm, __shfl_xor(rm, 4));
      rm = fmaxf(rm, __shfl_xor(rm, 8));
      float mn = fmaxf(mrun[r], rm);
      float al = __expf(mrun[r] - mn);
      float ps[8], rs = 0.f;
      #pragma unroll
      for (int t = 0; t < 8; ++t){ ps[t] = __expf(st[t][r] - mn); rs += ps[t]; }
      rs += __shfl_xor(rs, 1);
      rs += __shfl_xor(rs, 2);
      rs += __shfl_xor(rs, 4);
      rs += __shfl_xor(rs, 8);
      zrun[r] = zrun[r]*al + rs;
      mrun[r] = mn;
      alr[r] = al;
      #pragma unroll
      for (int t = 0; t < 8; ++t) Plds[w][quad*4+r][t*16+col] = (f16)ps[t];
    }
    #pragma unroll
    for (int dt = 0; dt < 8; ++dt)
      #pragma unroll
      for (int r = 0; r < 4; ++r) O[dt][r] *= alr[r];
    __builtin_amdgcn_wave_barrier();
    #pragma unroll
    for (int kk = 0; kk < 4; ++kk){
      f16x8 ap = *(const f16x8*)&Plds[w][col][kk*32 + koff];
      const f16* gv = gT + ((size_t)(b*128 + col))*NPER + n0 + kk*32 + koff;
      #pragma unroll
      for (int dt = 0; dt < 8; ++dt){
        f16x8 bv = *(const f16x8*)(gv + (size_t)dt*16*NPER);
        O[dt] = __builtin_amdgcn_mfma_f32_16x16x32_f16(ap, bv, O[dt], 0, 0, 0);
      }
    }
    __builtin_amdgcn_wave_barrier();
  }
  const int growb = b*LQ + l0 + w*16 + quad*4;
  #pragma unroll
  for (int r = 0; r < 4; ++r){
    float* od = Opart + ((size_t)sp*NROW + growb + r)*128 + col;
    #pragma unroll
    for (int dt = 0; dt < 8; ++dt) od[dt*16] = O[dt][r];
  }
  if (col == 0){
    #pragma unroll
    for (int r = 0; r < 4; ++r){
      ((float2*)mZ)[(size_t)sp*NROW + growb + r] = make_float2(mrun[r], zrun[r]);
    }
  }
}

// ========== combine splits -> cat16 H columns [512,640) as f16 ==========
__global__ __launch_bounds__(256) void k_comb(const float* __restrict__ Opart,
    const float* __restrict__ mZ, f16* __restrict__ cat)
{
  int i = blockIdx.x*256 + threadIdx.x;         // NROW*64
  int row = i >> 6, d2 = (i & 63)*2;
  float ms[NSPLIT], zs[NSPLIT];
  float M = -1e30f;
  #pragma unroll
  for (int s = 0; s < NSPLIT; ++s){
    float2 v = ((const float2*)mZ)[(size_t)s*NROW + row];
    ms[s] = v.x; zs[s] = v.y;
    M = fmaxf(M, v.x);
  }
  float Zt = 0.f, ax = 0.f, ay = 0.f;
  #pragma unroll
  for (int s = 0; s < NSPLIT; ++s){
    float e = __expf(ms[s] - M);
    Zt += zs[s]*e;
    const float* op = Opart + ((size_t)s*NROW + row)*128 + d2;
    ax += e*op[0]; ay += e*op[1];
  }
  float inv = 1.f/Zt;
  f16x2 o = { (f16)(ax*inv), (f16)(ay*inv) };
  *(f16x2*)(cat + (size_t)row*640 + 512 + d2) = o;
}

// ========== prep for final MFMA GEMM: cat16 x-part + W^T f16.
// blocks [0,2048): x f32 -> cat16 cols [0,512).  [2048,2208): w16[n][k] = W[k][n]. ==========
__global__ __launch_bounds__(256) void k_prep(const float* __restrict__ x,
    const float* __restrict__ Wsg, const float* __restrict__ Wtn,
    f16* __restrict__ cat, f16* __restrict__ w16)
{
  if (blockIdx.x < 2048){
    int id = blockIdx.x*256 + threadIdx.x;     // 524288 = 4096 rows * 128 quads
    int row = id >> 7, c4 = (id & 127)*4;
    float4 v = *(const float4*)(x + (size_t)row*512 + c4);
    f16x4 o = { (f16)v.x, (f16)v.y, (f16)v.z, (f16)v.w };
    *(f16x4*)(cat + (size_t)row*640 + c4) = o;
  } else {
    int id = (blockIdx.x - 2048)*256 + threadIdx.x;   // 40960 = 256 n * 160 k-quads
    int n = id / 160;
    int k0 = (id - n*160)*4;
    const float* src = n < 128 ? (Wsg + n) : (Wtn + (n - 128));
    f16x4 o = { (f16)src[(k0+0)*128], (f16)src[(k0+1)*128],
                (f16)src[(k0+2)*128], (f16)src[(k0+3)*128] };
    *(f16x4*)(w16 + (size_t)n*640 + k0) = o;
  }
}

// ========== final MFMA GEMM: out[4096][256] = act(cat16 @ w16^T + bias).
// 1 wave per 16 rows, 16 n-tiles, K=640 in 20 mfma steps. n<128: sigmoid, else tanh ==========
__global__ __launch_bounds__(64) void k_fin2(const f16* __restrict__ cat,
    const f16* __restrict__ w16, const float* __restrict__ bsg,
    const float* __restrict__ btn, float* __restrict__ out)
{
  const int lane = threadIdx.x;
  const int quad = lane >> 4, col = lane & 15;
  const int koff = quad*8;
  const int row0 = blockIdx.x * 16;
  const f16* ar = cat + (size_t)(row0 + col)*640 + koff;
  const f16* br = w16 + (size_t)col*640 + koff;
  f32x4 acc[16];
  #pragma unroll
  for (int nt = 0; nt < 16; ++nt) acc[nt] = (f32x4){0.f,0.f,0.f,0.f};
  for (int ks = 0; ks < 20; ++ks){
    f16x8 a = *(const f16x8*)(ar + ks*32);
    #pragma unroll
    for (int nt = 0; nt < 16; ++nt){
      f16x8 b = *(const f16x8*)(br + (size_t)nt*16*640 + ks*32);
      acc[nt] = __builtin_amdgcn_mfma_f32_16x16x32_f16(a, b, acc[nt], 0, 0, 0);
    }
  }
  #pragma unroll
  for (int nt = 0; nt < 16; ++nt){
    int n = nt*16 + col;
    float bv = n < 128 ? bsg[n] : btn[n - 128];
    #pragma unroll
    for (int r = 0; r < 4; ++r){
      float v = acc[nt][r] + bv;
      v = n < 128 ? 1.f/(1.f + __expf(-v)) : tanhf(v);
      out[(size_t)(row0 + quad*4 + r)*256 + n] = v;
    }
  }
}

extern "C" void kernel_launch(void* const* d_in, const int* in_sizes, int n_in,
                              void* d_out, int out_size, void* d_ws, size_t ws_size,
                              hipStream_t stream)
{
  const float* x    = (const float*)d_in[0];
  const float* nfr  = (const float*)d_in[1];
  const int*   eidx = (const int*)d_in[2];
  const int*   hidx = (const int*)d_in[3];
  const float *Wg1=(const float*)d_in[4],  *bg1=(const float*)d_in[5];
  const float *Wg2=(const float*)d_in[6],  *bg2=(const float*)d_in[7];
  const float *Wh1=(const float*)d_in[8],  *bh1=(const float*)d_in[9];
  const float *Wh2=(const float*)d_in[10], *bh2=(const float*)d_in[11];
  const float *Wm =(const float*)d_in[12], *bm =(const float*)d_in[13];
  const float *Wm2=(const float*)d_in[14], *bm2=(const float*)d_in[15];
  const float *Wsg=(const float*)d_in[16], *bsg=(const float*)d_in[17];
  const float *Wtn=(const float*)d_in[18], *btn=(const float*)d_in[19];
  float* out = (float*)d_out;

  // ---- workspace layout. Aliases:
  //  h4_16 at base; bins + gcur live only until k_csr, alias agg16 region;
  //  cat16/w16 alias agg16 region too (live only in attention phase, after
  //  agg16's last use); Opart f32 (32MB) aliases dead bufA+bufB;
  //  kb/gT alias csr_dst/csr_pn. ----
  char* base = (char*)d_ws;
  f16*   h4_16  = (f16*)(base);                          // 16 MB
  f16*   agg16  = (f16*)(base + 33554432);               // 16 MB (graph phase only)
  u32*   bin_e  = (u32*)(base + 33554432);               // 5 MB   (aliases agg16)
  u32*   bin_pn = (u32*)(base + 38797312);               // 5 MB
  u32*   bin_pe = (u32*)(base + 44040192);               // 4.5 MB
  int*   gcur   = (int*)(base + 48758784);               // 1.25 KB
  f16*   cat16  = (f16*)(base + 33554432);               // 5.24 MB (attention phase)
  f16*   w16    = (f16*)(base + 38797312);               // 320 KB  (attention phase)
  f16*   bufA   = (f16*)(base + 67108864);               // 16 MB  (nfr16 / h2_16)
  f16*   bufB   = (f16*)(base + 83886080);               // 16 MB  (h1_16 / h3_16)
  float* Opart  = (float*)(base + 67108864);             // 32 MB  (aliases bufA+bufB)
  u16*   csr_dst= (u16*)(base + 100663296);              // 8 MB used of 16 MB region
  f16*   kb     = (f16*)(base + 100663296);              //   (aliases csr_dst)
  u16*   csr_pn = (u16*)(base + 117440512);              // 8 MB used of 16 MB region
  f16*   gT     = (f16*)(base + 117440512);              //   (aliases csr_pn)
  u16*   csr_pe = (u16*)(base + 134217728);              // 3 MB used of 6 MB region
  int*   cnt_dst= (int*)(base + 140509184);
  int*   cnt_pn = (int*)(base + 140771328);
  int*   cnt_pe = (int*)(base + 141033472);
  int*   du     = (int*)(base + 141049856);              // 256 KB
  float* ef0    = (float*)(base + 141312000);            // 2 MB
  float* ef1    = (float*)(base + 143409152);            // 2 MB
  f16*   qb     = (f16*)(base + 145506304);              // 1 MB
  float* mZ     = (float*)(base + 146554880);            // 512 KB (NSPLIT16)
  const size_t needB = (size_t)147079168;
  if (ws_size < needB) return;

  // ---- CSR build: bin (phase A) then per-bucket insert (phase B) ----
  hipMemsetAsync(du, 0, 262144, stream);
  hipMemsetAsync(gcur, 0, 1280, stream);
  k_bin<<<1024, 256, 0, stream>>>(eidx, hidx, du, gcur, bin_e, bin_pn, bin_pe);
  k_csr<<<320, 256, 0, stream>>>(gcur, bin_e, bin_pn, bin_pe,
                                 cnt_dst, csr_dst, cnt_pn, csr_pn, cnt_pe, csr_pe);

  // ---- layer 1 ----
  k_pre<<<NNODE*64/256, 256, 0, stream>>>(nfr, du, bufA);
  k_gagg16<<<NNODE/16, 256, 0, stream>>>(cnt_dst, csr_dst, bufA, agg16);
  k_gemm<1,1><<<NNODE/32, 256, 0, stream>>>(agg16, Wg1, cnt_dst, bg1, bufB);
  k_hea16<<<NHE, 256, 0, stream>>>(cnt_pe, csr_pe, bufB, ef0);
  k_gemm<0,0><<<NHE/32, 256, 0, stream>>>(ef0, Wh1, nullptr, nullptr, ef1);
  k_nha<1><<<NNODE/16, 256, 0, stream>>>(cnt_pn, csr_pn, ef1, bh1, nfr, du, bufA);

  // ---- layer 2 ----
  k_gagg16<<<NNODE/16, 256, 0, stream>>>(cnt_dst, csr_dst, bufA, agg16);
  k_gemm<1,1><<<NNODE/32, 256, 0, stream>>>(agg16, Wg2, cnt_dst, bg2, bufB);
  k_hea16<<<NHE, 256, 0, stream>>>(cnt_pe, csr_pe, bufB, ef0);
  k_gemm<0,0><<<NHE/32, 256, 0, stream>>>(ef0, Wh2, nullptr, nullptr, ef1);
  k_nha<0><<<NNODE/16, 256, 0, stream>>>(cnt_pn, csr_pn, ef1, bh2, nfr, nullptr, h4_16);

  // ---- attention (agg16/bins dead from here: cat16/w16 safe) ----
  k_prep<<<2208, 256, 0, stream>>>(x, Wsg, Wtn, cat16, w16);
  k_qgemm<<<NROW/16, 256, 0, stream>>>(x, Wm, bm, qb);
  k_gemm<2,1><<<NNODE/32, 256, 0, stream>>>(h4_16, Wm2, nullptr, bm2, kb);
  k_gt<<<dim3(NPER/64, 2, BSZ), 256, 0, stream>>>(h4_16, gT);
  k_flash<<<dim3(NSPLIT, LQ/64, BSZ), 256, 0, stream>>>(qb, kb, gT, Opart, mZ);
  k_comb<<<NROW*64/256, 256, 0, stream>>>(Opart, mZ, cat16);
  k_fin2<<<NROW/16, 64, 0, stream>>>(cat16, w16, bsg, btn, out);

  (void)in_sizes; (void)n_in; (void)out_size;
}

// Round 5
// 973.963 us; speedup vs baseline: 1.2586x; 1.0340x over previous
//
#include <hip/hip_runtime.h>
#include <hip/hip_bf16.h>

#define BSZ   8
#define NPER  8192
#define NNODE 65536       // BSZ*NPER
#define EPG   131072      // edges per graph
#define EMB   128
#define ENCD  512
#define LQ    512
#define NHE   4096
#define NE    1048576
#define NP    1048576
#define NROW  4096        // BSZ*LQ
#define NSPLIT 16
#define SLOT_N 64
#define SLOT_E 384
// binning: 128 node-buckets (512 nodes), 64 he-buckets (64 hyperedges)
#define CAP_E  10240      // per node-bucket capacity, edges  (mean 8192, +22 sigma)
#define CAP_PN 10240      // per node-bucket capacity, pairs  (mean 8192)
#define CAP_PE 18432      // per he-bucket capacity, pairs    (mean 16384, +16 sigma)

typedef _Float16 f16;
typedef _Float16 f16x2 __attribute__((ext_vector_type(2)));
typedef _Float16 f16x4 __attribute__((ext_vector_type(4)));
typedef _Float16 f16x8 __attribute__((ext_vector_type(8)));
typedef float f32x4 __attribute__((ext_vector_type(4)));
typedef unsigned short u16;
typedef unsigned int u32;

// ========== phase A: bin edges (by dst) and pairs (by pn and by pe) into
// contiguous per-bucket arrays; du via global atomics.
// gcur layout: [0,128) edge-dst, [128,256) pn, [256,320) pe ==========
__global__ __launch_bounds__(256) void k_bin(const int* __restrict__ eidx,
    const int* __restrict__ hidx, int* __restrict__ du, int* __restrict__ gcur,
    u32* __restrict__ bin_e, u32* __restrict__ bin_pn, u32* __restrict__ bin_pe)
{
  __shared__ int lh[320];
  __shared__ int gb[320];
  const int tid = threadIdx.x;
  for (int i = tid; i < 320; i += 256) lh[i] = 0;
  __syncthreads();
  if (blockIdx.x < 512){
    // 2048 edges per block
    const int eb4 = blockIdx.x*512;
    int4 sa = ((const int4*)eidx)[eb4 + tid];
    int4 sb = ((const int4*)eidx)[eb4 + 256 + tid];
    int4 da = ((const int4*)(eidx + NE))[eb4 + tid];
    int4 db = ((const int4*)(eidx + NE))[eb4 + 256 + tid];
    int ss[8] = {sa.x,sa.y,sa.z,sa.w, sb.x,sb.y,sb.z,sb.w};
    int dd[8] = {da.x,da.y,da.z,da.w, db.x,db.y,db.z,db.w};
    int rr[8];
    #pragma unroll
    for (int u = 0; u < 8; ++u){
      atomicAdd(&du[ss[u]], 1);
      rr[u] = atomicAdd(&lh[dd[u] >> 9], 1);
    }
    __syncthreads();
    if (tid < 128 && lh[tid]) gb[tid] = atomicAdd(&gcur[tid], lh[tid]);
    __syncthreads();
    #pragma unroll
    for (int u = 0; u < 8; ++u){
      int b = dd[u] >> 9;
      int pos = gb[b] + rr[u];
      if (pos < CAP_E)
        bin_e[(size_t)b*CAP_E + pos] = (u32)(dd[u] & 0xffff) | ((u32)ss[u] << 16);
    }
  } else {
    // 2048 pairs per block, binned both directions
    const int pb4 = (blockIdx.x - 512)*1024;
    int4 pa = ((const int4*)hidx)[pb4 + tid];
    int4 pb = ((const int4*)hidx)[pb4 + 256 + tid];
    int4 pc = ((const int4*)hidx)[pb4 + 512 + tid];
    int4 pd = ((const int4*)hidx)[pb4 + 768 + tid];
    int pn[8] = {pa.x,pa.z, pb.x,pb.z, pc.x,pc.z, pd.x,pd.z};
    int pe[8] = {pa.y,pa.w, pb.y,pb.w, pc.y,pc.w, pd.y,pd.w};
    int rn[8], re[8];
    #pragma unroll
    for (int u = 0; u < 8; ++u){
      rn[u] = atomicAdd(&lh[128 + (pn[u] >> 9)], 1);
      re[u] = atomicAdd(&lh[256 + (pe[u] >> 6)], 1);
    }
    __syncthreads();
    if (tid < 192 && lh[128 + tid]) gb[128 + tid] = atomicAdd(&gcur[128 + tid], lh[128 + tid]);
    __syncthreads();
    #pragma unroll
    for (int u = 0; u < 8; ++u){
      int bn = pn[u] >> 9;
      int pos = gb[128 + bn] + rn[u];
      if (pos < CAP_PN)
        bin_pn[(size_t)bn*CAP_PN + pos] = (u32)pn[u] | ((u32)pe[u] << 16);
      int be = pe[u] >> 6;
      int pos2 = gb[256 + be] + re[u];
      if (pos2 < CAP_PE)
        bin_pe[(size_t)be*CAP_PE + pos2] = (u32)pe[u] | ((u32)pn[u] << 16);
    }
  }
}

// ========== phase B: per-bucket CSR insert (LDS cursors, windowed u16 writes).
// blocks [0,128) edge-dst, [128,256) pn, [256,320) pe ==========
__global__ __launch_bounds__(256) void k_csr(const int* __restrict__ gcur,
    const u32* __restrict__ bin_e, const u32* __restrict__ bin_pn,
    const u32* __restrict__ bin_pe,
    int* __restrict__ cnt_dst, u16* __restrict__ csr_dst,
    int* __restrict__ cnt_pn, u16* __restrict__ csr_pn,
    int* __restrict__ cnt_pe, u16* __restrict__ csr_pe)
{
  const int tid = threadIdx.x;
  if (blockIdx.x < 256){
    __shared__ int cur[512];
    const int isP = blockIdx.x >= 128;
    const int b = blockIdx.x & 127;
    cur[tid] = 0; cur[tid + 256] = 0;
    __syncthreads();
    const int n0 = b*512;
    const int cap = isP ? CAP_PN : CAP_E;
    int raw = gcur[isP ? 128 + b : b];
    int count = raw < cap ? raw : cap;
    const u32* bin = (isP ? bin_pn : bin_e) + (size_t)b*cap;
    u16* csr = isP ? csr_pn : csr_dst;
    for (int i = tid; i < count; i += 256){
      u32 v = bin[i];
      int row = v & 0xffff, val = v >> 16;
      int c = atomicAdd(&cur[row - n0], 1);
      if (c < SLOT_N) csr[(size_t)row*SLOT_N + c] = (u16)val;
    }
    __syncthreads();
    int* cnt = isP ? cnt_pn : cnt_dst;
    cnt[n0 + tid]       = cur[tid];
    cnt[n0 + 256 + tid] = cur[tid + 256];
  } else {
    __shared__ int cur[64];
    const int b = blockIdx.x - 256;
    if (tid < 64) cur[tid] = 0;
    __syncthreads();
    const int e0 = b*64;
    int raw = gcur[256 + b];
    int count = raw < CAP_PE ? raw : CAP_PE;
    const u32* bin = bin_pe + (size_t)b*CAP_PE;
    for (int i = tid; i < count; i += 256){
      u32 v = bin[i];
      int row = v & 0xffff, val = v >> 16;
      int c = atomicAdd(&cur[row - e0], 1);
      if (c < SLOT_E) csr_pe[(size_t)row*SLOT_E + c] = (u16)val;
    }
    __syncthreads();
    if (tid < 64) cnt_pe[e0 + tid] = cur[tid];
  }
}

// ========== nfr16 = f16(nfr * rsqrt(max(du,1))) ==========
__global__ __launch_bounds__(256) void k_pre(const float* __restrict__ nfr,
    const int* __restrict__ du, f16* __restrict__ out)
{
  int i = blockIdx.x*256 + threadIdx.x;         // NNODE*64
  int node = i >> 6, j = i & 63;
  float ds = rsqrtf(fmaxf((float)du[node], 1.f));
  float2 v = ((const float2*)(nfr + (size_t)node*128))[j];
  f16x2 o = { (f16)(v.x*ds), (f16)(v.y*ds) };
  ((f16x2*)(out + (size_t)node*128))[j] = o;
}

// ========== gconv gather (f16 src): agg16[d] = f16(sum src16[s]), 4 nodes/wave ==========
__global__ __launch_bounds__(256) void k_gagg16(const int* __restrict__ cnt,
    const u16* __restrict__ csr, const f16* __restrict__ src, f16* __restrict__ agg)
{
  int blk  = blockIdx.x;                        // NNODE/16 blocks, XCD swizzle
  int wv = threadIdx.x >> 6, lane = threadIdx.x & 63;
  int n0 = (blk & 7)*NPER + (blk >> 3)*16 + wv*4;
  int c[4]; const u16* r[4];
  float ax[4] = {0,0,0,0}, ay[4] = {0,0,0,0};
  #pragma unroll
  for (int u = 0; u < 4; ++u){
    int nd = cnt[n0+u];
    c[u] = nd < SLOT_N ? nd : SLOT_N;
    r[u] = csr + (size_t)(n0+u)*SLOT_N;
  }
  int m = c[0];
  #pragma unroll
  for (int u = 1; u < 4; ++u) m = c[u] > m ? c[u] : m;
  for (int j = 0; j < m; ++j){
    #pragma unroll
    for (int u = 0; u < 4; ++u){
      if (j < c[u]){
        int idx = r[u][j];
        f16x2 v = ((const f16x2*)(src + (size_t)idx*128))[lane];
        ax[u] += (float)v.x; ay[u] += (float)v.y;
      }
    }
  }
  #pragma unroll
  for (int u = 0; u < 4; ++u)
    ((f16x2*)(agg + (size_t)(n0+u)*128))[lane] = (f16x2){ (f16)ax[u], (f16)ay[u] };
}

// ========== hconv stage 1 (f16 source): ef0[e] = (1/|e|) * sum src16[pn] ==========
__global__ __launch_bounds__(256) void k_hea16(const int* __restrict__ cnt,
    const u16* __restrict__ csr, const f16* __restrict__ src, float* __restrict__ ef)
{
  __shared__ float red[4][128];
  int e = blockIdx.x;
  int wv = threadIdx.x >> 6, lane = threadIdx.x & 63;
  int nd = cnt[e];
  int n = nd < SLOT_E ? nd : SLOT_E;
  const u16* row = csr + (size_t)e*SLOT_E;
  float ax = 0.f, ay = 0.f;
  for (int j = wv; j < n; j += 4){
    int p = row[j];
    f16x2 v = ((const f16x2*)(src + (size_t)p*128))[lane];
    ax += (float)v.x; ay += (float)v.y;
  }
  red[wv][lane*2] = ax; red[wv][lane*2+1] = ay;
  __syncthreads();
  if (wv == 0){
    float s = nd > 0 ? 1.f/(float)nd : 0.f;
    float2 o = { (red[0][lane*2]+red[1][lane*2]+red[2][lane*2]+red[3][lane*2])*s,
                 (red[0][lane*2+1]+red[1][lane*2+1]+red[2][lane*2+1]+red[3][lane*2+1])*s };
    ((float2*)(ef + (size_t)e*128))[lane] = o;
  }
}

// ========== register-blocked 128x128 GEMM.  IN16: input rows are f16.
// MODE 0: f32 raw   MODE 1: f16(acc*rsqrt(max(cnt,1)) + bias)   MODE 2: f16(relu(acc+bias)) ==========
template<int MODE, int IN16>
__global__ __launch_bounds__(256, 2) void k_gemm(const void* __restrict__ inp,
    const float* __restrict__ W, const int* __restrict__ cnt,
    const float* __restrict__ bias, void* __restrict__ outp)
{
  __shared__ float Wl[128*128];
  __shared__ float Rl[32*128];
  const int tid = threadIdx.x;
  const int rbase = blockIdx.x*32;
  for (int i = tid; i < 16384; i += 256) Wl[i] = W[i];
  if (IN16){
    const f16x2* s2 = (const f16x2*)(((const f16*)inp) + (size_t)rbase*128);
    for (int i = tid; i < 2048; i += 256){
      f16x2 v = s2[i];
      ((float2*)Rl)[i] = make_float2((float)v.x, (float)v.y);
    }
  } else {
    const float* src = ((const float*)inp) + (size_t)rbase*128;
    for (int i = tid; i < 4096; i += 256) Rl[i] = src[i];
  }
  __syncthreads();
  const int c0 = (tid & 31)*4;
  const int r0 = (tid >> 5)*4;
  f32x4 acc[4];
  #pragma unroll
  for (int j = 0; j < 4; ++j) acc[j] = (f32x4){0.f,0.f,0.f,0.f};
  for (int d = 0; d < 128; d += 4){
    f32x4 w0 = *(const f32x4*)&Wl[(d+0)*128 + c0];
    f32x4 w1 = *(const f32x4*)&Wl[(d+1)*128 + c0];
    f32x4 w2 = *(const f32x4*)&Wl[(d+2)*128 + c0];
    f32x4 w3 = *(const f32x4*)&Wl[(d+3)*128 + c0];
    #pragma unroll
    for (int j = 0; j < 4; ++j){
      f32x4 rr = *(const f32x4*)&Rl[(r0+j)*128 + d];
      acc[j] += rr.x*w0 + rr.y*w1 + rr.z*w2 + rr.w*w3;
    }
  }
  #pragma unroll
  for (int j = 0; j < 4; ++j){
    const int row = rbase + r0 + j;
    if (MODE == 0){
      *(f32x4*)(((float*)outp) + (size_t)row*128 + c0) = acc[j];
    } else if (MODE == 1){
      float sc = rsqrtf(fmaxf((float)cnt[row], 1.f));
      f16* o = ((f16*)outp) + (size_t)row*128 + c0;
      #pragma unroll
      for (int k = 0; k < 4; ++k) o[k] = (f16)(acc[j][k]*sc + bias[c0+k]);
    } else {
      f16* o = ((f16*)outp) + (size_t)row*128 + c0;
      #pragma unroll
      for (int k = 0; k < 4; ++k) o[k] = (f16)fmaxf(acc[j][k] + bias[c0+k], 0.f);
    }
  }
}

// ========== hconv stage 2 + relu + residual, 4 nodes/wave, f16 out.
// PRES: scale by rsqrt(du) (for next layer's prescaled input) ==========
template<int PRES>
__global__ __launch_bounds__(256) void k_nha(const int* __restrict__ cnt,
    const u16* __restrict__ csr, const float* __restrict__ ef,
    const float* __restrict__ bias, const float* __restrict__ nfr,
    const int* __restrict__ du, f16* __restrict__ outp)
{
  int wv = threadIdx.x >> 6, lane = threadIdx.x & 63;
  int n0 = blockIdx.x*16 + wv*4;
  int dcnt[4], c[4]; const u16* r[4];
  float ax[4] = {0,0,0,0}, ay[4] = {0,0,0,0};
  #pragma unroll
  for (int u = 0; u < 4; ++u){
    dcnt[u] = cnt[n0+u];
    c[u] = dcnt[u] < SLOT_N ? dcnt[u] : SLOT_N;
    r[u] = csr + (size_t)(n0+u)*SLOT_N;
  }
  int m = c[0];
  #pragma unroll
  for (int u = 1; u < 4; ++u) m = c[u] > m ? c[u] : m;
  for (int j = 0; j < m; ++j){
    #pragma unroll
    for (int u = 0; u < 4; ++u){
      if (j < c[u]){
        int idx = r[u][j];
        float2 v = ((const float2*)(ef + (size_t)idx*128))[lane];
        ax[u] += v.x; ay[u] += v.y;
      }
    }
  }
  float bx = bias[lane*2], by = bias[lane*2+1];
  #pragma unroll
  for (int u = 0; u < 4; ++u){
    float s = dcnt[u] > 0 ? 1.f/(float)dcnt[u] : 0.f;
    float2 nf = ((const float2*)(nfr + (size_t)(n0+u)*128))[lane];
    float vx = fmaxf(ax[u]*s + bx, 0.f) + nf.x;
    float vy = fmaxf(ay[u]*s + by, 0.f) + nf.y;
    float e0 = PRES ? rsqrtf(fmaxf((float)du[n0+u], 1.f)) : 1.f;
    ((f16x2*)(outp + (size_t)(n0+u)*128))[lane] = (f16x2){ (f16)(vx*e0), (f16)(vy*e0) };
  }
}

// ========== q = f16(relu(x @ Wm + bm)), K=512 in 4 LDS chunks ==========
__global__ __launch_bounds__(256) void k_qgemm(const float* __restrict__ x,
    const float* __restrict__ Wm, const float* __restrict__ bm, f16* __restrict__ q)
{
  __shared__ float Wl[128*128];
  const int c = threadIdx.x & 127, rh = threadIdx.x >> 7;
  const int base = blockIdx.x*16 + rh*8;
  float acc[8] = {0,0,0,0,0,0,0,0};
  for (int kc = 0; kc < 4; ++kc){
    __syncthreads();
    for (int i = threadIdx.x; i < 128*128; i += 256) Wl[i] = Wm[kc*128*128 + i];
    __syncthreads();
    #pragma unroll
    for (int r = 0; r < 8; ++r){
      const float* xr = x + (size_t)(base+r)*512 + kc*128;
      float a0=0.f,a1=0.f,a2=0.f,a3=0.f;
      #pragma unroll
      for (int d = 0; d < 128; d += 4){
        a0 += xr[d+0] * Wl[(d+0)*128 + c];
        a1 += xr[d+1] * Wl[(d+1)*128 + c];
        a2 += xr[d+2] * Wl[(d+2)*128 + c];
        a3 += xr[d+3] * Wl[(d+3)*128 + c];
      }
      acc[r] += (a0+a1)+(a2+a3);
    }
  }
  float bv = bm[c];
  #pragma unroll
  for (int r = 0; r < 8; ++r)
    q[(size_t)(base+r)*128 + c] = (f16)fmaxf(acc[r]+bv, 0.f);
}

// ========== gT[b][c][n] = h16[b*NPER+n][c]  (f16 transpose) ==========
__global__ __launch_bounds__(256) void k_gt(const f16* __restrict__ g, f16* __restrict__ gT)
{
  __shared__ f16 t[64][66];
  int b = blockIdx.z, n0 = blockIdx.x*64, c0 = blockIdx.y*64;
  for (int i = threadIdx.x; i < 64*64; i += 256){
    int n = i >> 6, c = i & 63;
    t[n][c] = g[((size_t)(b*NPER + n0 + n))*128 + c0 + c];
  }
  __syncthreads();
  for (int i = threadIdx.x; i < 64*64; i += 256){
    int c = i >> 6, n = i & 63;
    gT[((size_t)(b*128 + c0 + c))*NPER + n0 + n] = t[n][c];
  }
}

// ========== flash attention (R5 rewrite): 64 q-rows/block, n-slab 512, n-chunk 64,
// cooperative XOR-swizzled LDS staging of K/V, register double-buffer (T14),
// Plds in swizzled LDS. 40 KB LDS -> 4 blocks/CU. ==========
#define NCH 64
__global__ __launch_bounds__(256, 4) void k_flash(const f16* __restrict__ qb,
    const f16* __restrict__ kb, const f16* __restrict__ gT,
    float* __restrict__ Opart, float* __restrict__ mZ)
{
  __shared__ f16 Kl[64*128];        // 16 KB  [n 64][k 128], chunk-swizzled
  __shared__ f16 Vl[128*64];        // 16 KB  [d 128][n 64], chunk-swizzled
  __shared__ f16 Pl[4*16*64];       //  8 KB  per-wave [q 16][n 64], chunk-swizzled
  const int sp = blockIdx.x, l0 = blockIdx.y*64, b = blockIdx.z;
  const int tid = threadIdx.x;
  const int w = tid >> 6, lane = tid & 63;
  const int quad = lane >> 4, col = lane & 15;
  const int koff = quad*8;
  // staging lane mapping
  const int krow = tid >> 4;        // K: rows 0..15 (+16/iter), chunks 0..15
  const int kc8  = tid & 15;
  const int vrow = tid >> 3;        // V: rows 0..31 (+32/iter), chunks 0..7
  const int vc8  = tid & 7;

  const f16* qrow = qb + ((size_t)(b*LQ + l0 + w*16 + col))*128 + koff;
  f16x8 aq[4];
  #pragma unroll
  for (int ks = 0; ks < 4; ++ks) aq[ks] = *(const f16x8*)(qrow + ks*32);
  float mrun[4] = {-1e30f,-1e30f,-1e30f,-1e30f};
  float zrun[4] = {0.f,0.f,0.f,0.f};
  f32x4 O[8];
  #pragma unroll
  for (int i = 0; i < 8; ++i) O[i] = (f32x4){0.f,0.f,0.f,0.f};

  const int nbase = sp*(NPER/NSPLIT);          // 512-wide n slab
  f16x8 kr[4], vr[4];
#define LOADKV(N0)                                                           \
  { _Pragma("unroll")                                                        \
    for (int i2 = 0; i2 < 4; ++i2){                                          \
      kr[i2] = *(const f16x8*)(kb + ((size_t)(b*NPER + (N0) + krow + i2*16))*128 + kc8*8); \
      vr[i2] = *(const f16x8*)(gT + ((size_t)(b*128 + vrow + i2*32))*NPER + (N0) + vc8*8); \
    } }
  LOADKV(nbase);
  #pragma unroll 1
  for (int it = 0; it < (NPER/NSPLIT)/NCH; ++it){
    const int n0 = nbase + it*NCH;
    __syncthreads();                            // prior-iter LDS reads done
    #pragma unroll
    for (int i2 = 0; i2 < 4; ++i2){
      int r = krow + i2*16;
      *(f16x8*)&Kl[r*128 + ((kc8 ^ (r & 7))*8)] = kr[i2];
      int d = vrow + i2*32;
      *(f16x8*)&Vl[d*64  + ((vc8 ^ (d & 7))*8)] = vr[i2];
    }
    __syncthreads();                            // staging visible
    if (it < (NPER/NSPLIT)/NCH - 1) LOADKV(n0 + NCH);   // prefetch next tile

    // ---- QK^T from LDS ----
    f32x4 st[4];
    #pragma unroll
    for (int t = 0; t < 4; ++t){
      st[t] = (f32x4){0.f,0.f,0.f,0.f};
      const int r = t*16 + col, rs = r & 7;
      #pragma unroll
      for (int ks = 0; ks < 4; ++ks){
        f16x8 bf = *(const f16x8*)&Kl[r*128 + (((ks*4 + quad) ^ rs)*8)];
        st[t] = __builtin_amdgcn_mfma_f32_16x16x32_f16(aq[ks], bf, st[t], 0, 0, 0);
      }
    }
    // ---- softmax over 64 n ----
    float alr[4];
    #pragma unroll
    for (int r = 0; r < 4; ++r){
      float rm = st[0][r];
      #pragma unroll
      for (int t = 1; t < 4; ++t) rm = fmaxf(rm, st[t][r]);
      rm = fmaxf(rm, __shfl_xor(rm, 1));
      rm = fmaxf(rm, __shfl_xor(rm, 2));
      rm = fmaxf(rm, __shfl_xor(rm, 4));
      rm = fmaxf(rm, __shfl_xor(rm, 8));
      float mn = fmaxf(mrun[r], rm);
      float al = __expf(mrun[r] - mn);
      float ps[4], rsum = 0.f;
      #pragma unroll
      for (int t = 0; t < 4; ++t){ ps[t] = __expf(st[t][r] - mn); rsum += ps[t]; }
      rsum += __shfl_xor(rsum, 1);
      rsum += __shfl_xor(rsum, 2);
      rsum += __shfl_xor(rsum, 4);
      rsum += __shfl_xor(rsum, 8);
      zrun[r] = zrun[r]*al + rsum;
      mrun[r] = mn;
      alr[r] = al;
      const int prow = quad*4 + r, pswz = prow & 7;
      #pragma unroll
      for (int t = 0; t < 4; ++t)
        Pl[w*1024 + prow*64 + (((t*2 + (col >> 3)) ^ pswz)*8) + (col & 7)] = (f16)ps[t];
    }
    #pragma unroll
    for (int dt = 0; dt < 8; ++dt)
      #pragma unroll
      for (int r = 0; r < 4; ++r) O[dt][r] *= alr[r];
    __builtin_amdgcn_wave_barrier();
    // ---- PV from LDS ----
    #pragma unroll
    for (int kk = 0; kk < 2; ++kk){
      f16x8 ap = *(const f16x8*)&Pl[w*1024 + col*64 + (((kk*4 + quad) ^ (col & 7))*8)];
      #pragma unroll
      for (int dt = 0; dt < 8; ++dt){
        const int d = col + dt*16;
        f16x8 bv = *(const f16x8*)&Vl[d*64 + (((kk*4 + quad) ^ (d & 7))*8)];
        O[dt] = __builtin_amdgcn_mfma_f32_16x16x32_f16(ap, bv, O[dt], 0, 0, 0);
      }
    }
    __builtin_amdgcn_wave_barrier();
  }
#undef LOADKV
  const int growb = b*LQ + l0 + w*16 + quad*4;
  #pragma unroll
  for (int r = 0; r < 4; ++r){
    float* od = Opart + ((size_t)sp*NROW + growb + r)*128 + col;
    #pragma unroll
    for (int dt = 0; dt < 8; ++dt) od[dt*16] = O[dt][r];
  }
  if (col == 0){
    #pragma unroll
    for (int r = 0; r < 4; ++r){
      ((float2*)mZ)[(size_t)sp*NROW + growb + r] = make_float2(mrun[r], zrun[r]);
    }
  }
}

// ========== combine splits -> cat16 H columns [512,640) as f16 ==========
__global__ __launch_bounds__(256) void k_comb(const float* __restrict__ Opart,
    const float* __restrict__ mZ, f16* __restrict__ cat)
{
  int i = blockIdx.x*256 + threadIdx.x;         // NROW*64
  int row = i >> 6, d2 = (i & 63)*2;
  float ms[NSPLIT], zs[NSPLIT];
  float M = -1e30f;
  #pragma unroll
  for (int s = 0; s < NSPLIT; ++s){
    float2 v = ((const float2*)mZ)[(size_t)s*NROW + row];
    ms[s] = v.x; zs[s] = v.y;
    M = fmaxf(M, v.x);
  }
  float Zt = 0.f, ax = 0.f, ay = 0.f;
  #pragma unroll
  for (int s = 0; s < NSPLIT; ++s){
    float e = __expf(ms[s] - M);
    Zt += zs[s]*e;
    const float* op = Opart + ((size_t)s*NROW + row)*128 + d2;
    ax += e*op[0]; ay += e*op[1];
  }
  float inv = 1.f/Zt;
  f16x2 o = { (f16)(ax*inv), (f16)(ay*inv) };
  *(f16x2*)(cat + (size_t)row*640 + 512 + d2) = o;
}

// ========== prep for final MFMA GEMM: cat16 x-part + W^T f16.
// blocks [0,2048): x f32 -> cat16 cols [0,512).  [2048,2208): w16[n][k] = W[k][n]. ==========
__global__ __launch_bounds__(256) void k_prep(const float* __restrict__ x,
    const float* __restrict__ Wsg, const float* __restrict__ Wtn,
    f16* __restrict__ cat, f16* __restrict__ w16)
{
  if (blockIdx.x < 2048){
    int id = blockIdx.x*256 + threadIdx.x;     // 524288 = 4096 rows * 128 quads
    int row = id >> 7, c4 = (id & 127)*4;
    float4 v = *(const float4*)(x + (size_t)row*512 + c4);
    f16x4 o = { (f16)v.x, (f16)v.y, (f16)v.z, (f16)v.w };
    *(f16x4*)(cat + (size_t)row*640 + c4) = o;
  } else {
    int id = (blockIdx.x - 2048)*256 + threadIdx.x;   // 40960 = 256 n * 160 k-quads
    int n = id / 160;
    int k0 = (id - n*160)*4;
    const float* src = n < 128 ? (Wsg + n) : (Wtn + (n - 128));
    f16x4 o = { (f16)src[(k0+0)*128], (f16)src[(k0+1)*128],
                (f16)src[(k0+2)*128], (f16)src[(k0+3)*128] };
    *(f16x4*)(w16 + (size_t)n*640 + k0) = o;
  }
}

// ========== final MFMA GEMM: out[4096][256] = act(cat16 @ w16^T + bias).
// 1 wave per 16 rows, 16 n-tiles, K=640 in 20 mfma steps. n<128: sigmoid, else tanh ==========
__global__ __launch_bounds__(64) void k_fin2(const f16* __restrict__ cat,
    const f16* __restrict__ w16, const float* __restrict__ bsg,
    const float* __restrict__ btn, float* __restrict__ out)
{
  const int lane = threadIdx.x;
  const int quad = lane >> 4, col = lane & 15;
  const int koff = quad*8;
  const int row0 = blockIdx.x * 16;
  const f16* ar = cat + (size_t)(row0 + col)*640 + koff;
  const f16* br = w16 + (size_t)col*640 + koff;
  f32x4 acc[16];
  #pragma unroll
  for (int nt = 0; nt < 16; ++nt) acc[nt] = (f32x4){0.f,0.f,0.f,0.f};
  for (int ks = 0; ks < 20; ++ks){
    f16x8 a = *(const f16x8*)(ar + ks*32);
    #pragma unroll
    for (int nt = 0; nt < 16; ++nt){
      f16x8 b = *(const f16x8*)(br + (size_t)nt*16*640 + ks*32);
      acc[nt] = __builtin_amdgcn_mfma_f32_16x16x32_f16(a, b, acc[nt], 0, 0, 0);
    }
  }
  #pragma unroll
  for (int nt = 0; nt < 16; ++nt){
    int n = nt*16 + col;
    float bv = n < 128 ? bsg[n] : btn[n - 128];
    #pragma unroll
    for (int r = 0; r < 4; ++r){
      float v = acc[nt][r] + bv;
      v = n < 128 ? 1.f/(1.f + __expf(-v)) : tanhf(v);
      out[(size_t)(row0 + quad*4 + r)*256 + n] = v;
    }
  }
}

extern "C" void kernel_launch(void* const* d_in, const int* in_sizes, int n_in,
                              void* d_out, int out_size, void* d_ws, size_t ws_size,
                              hipStream_t stream)
{
  const float* x    = (const float*)d_in[0];
  const float* nfr  = (const float*)d_in[1];
  const int*   eidx = (const int*)d_in[2];
  const int*   hidx = (const int*)d_in[3];
  const float *Wg1=(const float*)d_in[4],  *bg1=(const float*)d_in[5];
  const float *Wg2=(const float*)d_in[6],  *bg2=(const float*)d_in[7];
  const float *Wh1=(const float*)d_in[8],  *bh1=(const float*)d_in[9];
  const float *Wh2=(const float*)d_in[10], *bh2=(const float*)d_in[11];
  const float *Wm =(const float*)d_in[12], *bm =(const float*)d_in[13];
  const float *Wm2=(const float*)d_in[14], *bm2=(const float*)d_in[15];
  const float *Wsg=(const float*)d_in[16], *bsg=(const float*)d_in[17];
  const float *Wtn=(const float*)d_in[18], *btn=(const float*)d_in[19];
  float* out = (float*)d_out;

  // ---- workspace layout. Aliases:
  //  h4_16 at base; bins + gcur live only until k_csr, alias agg16 region;
  //  cat16/w16 alias agg16 region too (live only in attention phase, after
  //  agg16's last use); Opart f32 (32MB) aliases dead bufA+bufB;
  //  kb/gT alias csr_dst/csr_pn. ----
  char* base = (char*)d_ws;
  f16*   h4_16  = (f16*)(base);                          // 16 MB
  f16*   agg16  = (f16*)(base + 33554432);               // 16 MB (graph phase only)
  u32*   bin_e  = (u32*)(base + 33554432);               // 5 MB   (aliases agg16)
  u32*   bin_pn = (u32*)(base + 38797312);               // 5 MB
  u32*   bin_pe = (u32*)(base + 44040192);               // 4.5 MB
  int*   gcur   = (int*)(base + 48758784);               // 1.25 KB
  f16*   cat16  = (f16*)(base + 33554432);               // 5.24 MB (attention phase)
  f16*   w16    = (f16*)(base + 38797312);               // 320 KB  (attention phase)
  f16*   bufA   = (f16*)(base + 67108864);               // 16 MB  (nfr16 / h2_16)
  f16*   bufB   = (f16*)(base + 83886080);               // 16 MB  (h1_16 / h3_16)
  float* Opart  = (float*)(base + 67108864);             // 32 MB  (aliases bufA+bufB)
  u16*   csr_dst= (u16*)(base + 100663296);              // 8 MB used of 16 MB region
  f16*   kb     = (f16*)(base + 100663296);              //   (aliases csr_dst)
  u16*   csr_pn = (u16*)(base + 117440512);              // 8 MB used of 16 MB region
  f16*   gT     = (f16*)(base + 117440512);              //   (aliases csr_pn)
  u16*   csr_pe = (u16*)(base + 134217728);              // 3 MB used of 6 MB region
  int*   cnt_dst= (int*)(base + 140509184);
  int*   cnt_pn = (int*)(base + 140771328);
  int*   cnt_pe = (int*)(base + 141033472);
  int*   du     = (int*)(base + 141049856);              // 256 KB
  float* ef0    = (float*)(base + 141312000);            // 2 MB
  float* ef1    = (float*)(base + 143409152);            // 2 MB
  f16*   qb     = (f16*)(base + 145506304);              // 1 MB
  float* mZ     = (float*)(base + 146554880);            // 512 KB (NSPLIT16)
  const size_t needB = (size_t)147079168;
  if (ws_size < needB) return;

  // ---- CSR build: bin (phase A) then per-bucket insert (phase B) ----
  hipMemsetAsync(du, 0, 262144, stream);
  hipMemsetAsync(gcur, 0, 1280, stream);
  k_bin<<<1024, 256, 0, stream>>>(eidx, hidx, du, gcur, bin_e, bin_pn, bin_pe);
  k_csr<<<320, 256, 0, stream>>>(gcur, bin_e, bin_pn, bin_pe,
                                 cnt_dst, csr_dst, cnt_pn, csr_pn, cnt_pe, csr_pe);

  // ---- layer 1 ----
  k_pre<<<NNODE*64/256, 256, 0, stream>>>(nfr, du, bufA);
  k_gagg16<<<NNODE/16, 256, 0, stream>>>(cnt_dst, csr_dst, bufA, agg16);
  k_gemm<1,1><<<NNODE/32, 256, 0, stream>>>(agg16, Wg1, cnt_dst, bg1, bufB);
  k_hea16<<<NHE, 256, 0, stream>>>(cnt_pe, csr_pe, bufB, ef0);
  k_gemm<0,0><<<NHE/32, 256, 0, stream>>>(ef0, Wh1, nullptr, nullptr, ef1);
  k_nha<1><<<NNODE/16, 256, 0, stream>>>(cnt_pn, csr_pn, ef1, bh1, nfr, du, bufA);

  // ---- layer 2 ----
  k_gagg16<<<NNODE/16, 256, 0, stream>>>(cnt_dst, csr_dst, bufA, agg16);
  k_gemm<1,1><<<NNODE/32, 256, 0, stream>>>(agg16, Wg2, cnt_dst, bg2, bufB);
  k_hea16<<<NHE, 256, 0, stream>>>(cnt_pe, csr_pe, bufB, ef0);
  k_gemm<0,0><<<NHE/32, 256, 0, stream>>>(ef0, Wh2, nullptr, nullptr, ef1);
  k_nha<0><<<NNODE/16, 256, 0, stream>>>(cnt_pn, csr_pn, ef1, bh2, nfr, nullptr, h4_16);

  // ---- attention (agg16/bins dead from here: cat16/w16 safe) ----
  k_prep<<<2208, 256, 0, stream>>>(x, Wsg, Wtn, cat16, w16);
  k_qgemm<<<NROW/16, 256, 0, stream>>>(x, Wm, bm, qb);
  k_gemm<2,1><<<NNODE/32, 256, 0, stream>>>(h4_16, Wm2, nullptr, bm2, kb);
  k_gt<<<dim3(NPER/64, 2, BSZ), 256, 0, stream>>>(h4_16, gT);
  k_flash<<<dim3(NSPLIT, LQ/64, BSZ), 256, 0, stream>>>(qb, kb, gT, Opart, mZ);
  k_comb<<<NROW*64/256, 256, 0, stream>>>(Opart, mZ, cat16);
  k_fin2<<<NROW/16, 64, 0, stream>>>(cat16, w16, bsg, btn, out);

  (void)in_sizes; (void)n_in; (void)out_size;
}

// Round 6
// 925.532 us; speedup vs baseline: 1.3245x; 1.0523x over previous
//
#include <hip/hip_runtime.h>
#include <hip/hip_bf16.h>

#define BSZ   8
#define NPER  8192
#define NNODE 65536       // BSZ*NPER
#define EPG   131072      // edges per graph
#define EMB   128
#define ENCD  512
#define LQ    512
#define NHE   4096
#define NE    1048576
#define NP    1048576
#define NROW  4096        // BSZ*LQ
#define NSPLIT 16
#define SLOT_N 64
#define SLOT_E 384
// binning: 128 node-buckets (512 nodes), 64 he-buckets (64 hyperedges)
#define CAP_E  10240      // per node-bucket capacity, edges  (mean 8192, +22 sigma)
#define CAP_PN 10240      // per node-bucket capacity, pairs  (mean 8192)
#define CAP_PE 18432      // per he-bucket capacity, pairs    (mean 16384, +16 sigma)

typedef _Float16 f16;
typedef _Float16 f16x2 __attribute__((ext_vector_type(2)));
typedef _Float16 f16x4 __attribute__((ext_vector_type(4)));
typedef _Float16 f16x8 __attribute__((ext_vector_type(8)));
typedef float f32x4 __attribute__((ext_vector_type(4)));
typedef unsigned short u16;
typedef unsigned int u32;

// ========== phase A: bin edges (by dst) and pairs (by pn and by pe) into
// contiguous per-bucket arrays; du via global atomics.
// gcur layout: [0,128) edge-dst, [128,256) pn, [256,320) pe ==========
__global__ __launch_bounds__(256) void k_bin(const int* __restrict__ eidx,
    const int* __restrict__ hidx, int* __restrict__ du, int* __restrict__ gcur,
    u32* __restrict__ bin_e, u32* __restrict__ bin_pn, u32* __restrict__ bin_pe)
{
  __shared__ int lh[320];
  __shared__ int gb[320];
  const int tid = threadIdx.x;
  for (int i = tid; i < 320; i += 256) lh[i] = 0;
  __syncthreads();
  if (blockIdx.x < 512){
    // 2048 edges per block
    const int eb4 = blockIdx.x*512;
    int4 sa = ((const int4*)eidx)[eb4 + tid];
    int4 sb = ((const int4*)eidx)[eb4 + 256 + tid];
    int4 da = ((const int4*)(eidx + NE))[eb4 + tid];
    int4 db = ((const int4*)(eidx + NE))[eb4 + 256 + tid];
    int ss[8] = {sa.x,sa.y,sa.z,sa.w, sb.x,sb.y,sb.z,sb.w};
    int dd[8] = {da.x,da.y,da.z,da.w, db.x,db.y,db.z,db.w};
    int rr[8];
    #pragma unroll
    for (int u = 0; u < 8; ++u){
      atomicAdd(&du[ss[u]], 1);
      rr[u] = atomicAdd(&lh[dd[u] >> 9], 1);
    }
    __syncthreads();
    if (tid < 128 && lh[tid]) gb[tid] = atomicAdd(&gcur[tid], lh[tid]);
    __syncthreads();
    #pragma unroll
    for (int u = 0; u < 8; ++u){
      int b = dd[u] >> 9;
      int pos = gb[b] + rr[u];
      if (pos < CAP_E)
        bin_e[(size_t)b*CAP_E + pos] = (u32)(dd[u] & 0xffff) | ((u32)ss[u] << 16);
    }
  } else {
    // 2048 pairs per block, binned both directions
    const int pb4 = (blockIdx.x - 512)*1024;
    int4 pa = ((const int4*)hidx)[pb4 + tid];
    int4 pb = ((const int4*)hidx)[pb4 + 256 + tid];
    int4 pc = ((const int4*)hidx)[pb4 + 512 + tid];
    int4 pd = ((const int4*)hidx)[pb4 + 768 + tid];
    int pn[8] = {pa.x,pa.z, pb.x,pb.z, pc.x,pc.z, pd.x,pd.z};
    int pe[8] = {pa.y,pa.w, pb.y,pb.w, pc.y,pc.w, pd.y,pd.w};
    int rn[8], re[8];
    #pragma unroll
    for (int u = 0; u < 8; ++u){
      rn[u] = atomicAdd(&lh[128 + (pn[u] >> 9)], 1);
      re[u] = atomicAdd(&lh[256 + (pe[u] >> 6)], 1);
    }
    __syncthreads();
    if (tid < 192 && lh[128 + tid]) gb[128 + tid] = atomicAdd(&gcur[128 + tid], lh[128 + tid]);
    __syncthreads();
    #pragma unroll
    for (int u = 0; u < 8; ++u){
      int bn = pn[u] >> 9;
      int pos = gb[128 + bn] + rn[u];
      if (pos < CAP_PN)
        bin_pn[(size_t)bn*CAP_PN + pos] = (u32)pn[u] | ((u32)pe[u] << 16);
      int be = pe[u] >> 6;
      int pos2 = gb[256 + be] + re[u];
      if (pos2 < CAP_PE)
        bin_pe[(size_t)be*CAP_PE + pos2] = (u32)pe[u] | ((u32)pn[u] << 16);
    }
  }
}

// ========== phase B: per-bucket CSR insert (LDS cursors, windowed u16 writes).
// blocks [0,128) edge-dst, [128,256) pn, [256,320) pe ==========
__global__ __launch_bounds__(256) void k_csr(const int* __restrict__ gcur,
    const u32* __restrict__ bin_e, const u32* __restrict__ bin_pn,
    const u32* __restrict__ bin_pe,
    int* __restrict__ cnt_dst, u16* __restrict__ csr_dst,
    int* __restrict__ cnt_pn, u16* __restrict__ csr_pn,
    int* __restrict__ cnt_pe, u16* __restrict__ csr_pe)
{
  const int tid = threadIdx.x;
  if (blockIdx.x < 256){
    __shared__ int cur[512];
    const int isP = blockIdx.x >= 128;
    const int b = blockIdx.x & 127;
    cur[tid] = 0; cur[tid + 256] = 0;
    __syncthreads();
    const int n0 = b*512;
    const int cap = isP ? CAP_PN : CAP_E;
    int raw = gcur[isP ? 128 + b : b];
    int count = raw < cap ? raw : cap;
    const u32* bin = (isP ? bin_pn : bin_e) + (size_t)b*cap;
    u16* csr = isP ? csr_pn : csr_dst;
    for (int i = tid; i < count; i += 256){
      u32 v = bin[i];
      int row = v & 0xffff, val = v >> 16;
      int c = atomicAdd(&cur[row - n0], 1);
      if (c < SLOT_N) csr[(size_t)row*SLOT_N + c] = (u16)val;
    }
    __syncthreads();
    int* cnt = isP ? cnt_pn : cnt_dst;
    cnt[n0 + tid]       = cur[tid];
    cnt[n0 + 256 + tid] = cur[tid + 256];
  } else {
    __shared__ int cur[64];
    const int b = blockIdx.x - 256;
    if (tid < 64) cur[tid] = 0;
    __syncthreads();
    const int e0 = b*64;
    int raw = gcur[256 + b];
    int count = raw < CAP_PE ? raw : CAP_PE;
    const u32* bin = bin_pe + (size_t)b*CAP_PE;
    for (int i = tid; i < count; i += 256){
      u32 v = bin[i];
      int row = v & 0xffff, val = v >> 16;
      int c = atomicAdd(&cur[row - e0], 1);
      if (c < SLOT_E) csr_pe[(size_t)row*SLOT_E + c] = (u16)val;
    }
    __syncthreads();
    if (tid < 64) cnt_pe[e0 + tid] = cur[tid];
  }
}

// ========== nfr16 = f16(nfr * rsqrt(max(du,1))) ==========
__global__ __launch_bounds__(256) void k_pre(const float* __restrict__ nfr,
    const int* __restrict__ du, f16* __restrict__ out)
{
  int i = blockIdx.x*256 + threadIdx.x;         // NNODE*64
  int node = i >> 6, j = i & 63;
  float ds = rsqrtf(fmaxf((float)du[node], 1.f));
  float2 v = ((const float2*)(nfr + (size_t)node*128))[j];
  f16x2 o = { (f16)(v.x*ds), (f16)(v.y*ds) };
  ((f16x2*)(out + (size_t)node*128))[j] = o;
}

// ========== gconv gather (f16 src): agg16[d] = f16(sum src16[s]), 4 nodes/wave ==========
__global__ __launch_bounds__(256) void k_gagg16(const int* __restrict__ cnt,
    const u16* __restrict__ csr, const f16* __restrict__ src, f16* __restrict__ agg)
{
  int blk  = blockIdx.x;                        // NNODE/16 blocks, XCD swizzle
  int wv = threadIdx.x >> 6, lane = threadIdx.x & 63;
  int n0 = (blk & 7)*NPER + (blk >> 3)*16 + wv*4;
  int c[4]; const u16* r[4];
  float ax[4] = {0,0,0,0}, ay[4] = {0,0,0,0};
  #pragma unroll
  for (int u = 0; u < 4; ++u){
    int nd = cnt[n0+u];
    c[u] = nd < SLOT_N ? nd : SLOT_N;
    r[u] = csr + (size_t)(n0+u)*SLOT_N;
  }
  int m = c[0];
  #pragma unroll
  for (int u = 1; u < 4; ++u) m = c[u] > m ? c[u] : m;
  for (int j = 0; j < m; ++j){
    #pragma unroll
    for (int u = 0; u < 4; ++u){
      if (j < c[u]){
        int idx = r[u][j];
        f16x2 v = ((const f16x2*)(src + (size_t)idx*128))[lane];
        ax[u] += (float)v.x; ay[u] += (float)v.y;
      }
    }
  }
  #pragma unroll
  for (int u = 0; u < 4; ++u)
    ((f16x2*)(agg + (size_t)(n0+u)*128))[lane] = (f16x2){ (f16)ax[u], (f16)ay[u] };
}

// ========== hconv stage 1 (f16 source): ef0[e] = (1/|e|) * sum src16[pn] ==========
__global__ __launch_bounds__(256) void k_hea16(const int* __restrict__ cnt,
    const u16* __restrict__ csr, const f16* __restrict__ src, float* __restrict__ ef)
{
  __shared__ float red[4][128];
  int e = blockIdx.x;
  int wv = threadIdx.x >> 6, lane = threadIdx.x & 63;
  int nd = cnt[e];
  int n = nd < SLOT_E ? nd : SLOT_E;
  const u16* row = csr + (size_t)e*SLOT_E;
  float ax = 0.f, ay = 0.f;
  for (int j = wv; j < n; j += 4){
    int p = row[j];
    f16x2 v = ((const f16x2*)(src + (size_t)p*128))[lane];
    ax += (float)v.x; ay += (float)v.y;
  }
  red[wv][lane*2] = ax; red[wv][lane*2+1] = ay;
  __syncthreads();
  if (wv == 0){
    float s = nd > 0 ? 1.f/(float)nd : 0.f;
    float2 o = { (red[0][lane*2]+red[1][lane*2]+red[2][lane*2]+red[3][lane*2])*s,
                 (red[0][lane*2+1]+red[1][lane*2+1]+red[2][lane*2+1]+red[3][lane*2+1])*s };
    ((float2*)(ef + (size_t)e*128))[lane] = o;
  }
}

// ========== register-blocked 128x128 GEMM.  IN16: input rows are f16.
// MODE 0: f32 raw   MODE 1: f16(acc*rsqrt(max(cnt,1)) + bias)   MODE 2: f16(relu(acc+bias)) ==========
template<int MODE, int IN16>
__global__ __launch_bounds__(256, 2) void k_gemm(const void* __restrict__ inp,
    const float* __restrict__ W, const int* __restrict__ cnt,
    const float* __restrict__ bias, void* __restrict__ outp)
{
  __shared__ float Wl[128*128];
  __shared__ float Rl[32*128];
  const int tid = threadIdx.x;
  const int rbase = blockIdx.x*32;
  for (int i = tid; i < 16384; i += 256) Wl[i] = W[i];
  if (IN16){
    const f16x2* s2 = (const f16x2*)(((const f16*)inp) + (size_t)rbase*128);
    for (int i = tid; i < 2048; i += 256){
      f16x2 v = s2[i];
      ((float2*)Rl)[i] = make_float2((float)v.x, (float)v.y);
    }
  } else {
    const float* src = ((const float*)inp) + (size_t)rbase*128;
    for (int i = tid; i < 4096; i += 256) Rl[i] = src[i];
  }
  __syncthreads();
  const int c0 = (tid & 31)*4;
  const int r0 = (tid >> 5)*4;
  f32x4 acc[4];
  #pragma unroll
  for (int j = 0; j < 4; ++j) acc[j] = (f32x4){0.f,0.f,0.f,0.f};
  for (int d = 0; d < 128; d += 4){
    f32x4 w0 = *(const f32x4*)&Wl[(d+0)*128 + c0];
    f32x4 w1 = *(const f32x4*)&Wl[(d+1)*128 + c0];
    f32x4 w2 = *(const f32x4*)&Wl[(d+2)*128 + c0];
    f32x4 w3 = *(const f32x4*)&Wl[(d+3)*128 + c0];
    #pragma unroll
    for (int j = 0; j < 4; ++j){
      f32x4 rr = *(const f32x4*)&Rl[(r0+j)*128 + d];
      acc[j] += rr.x*w0 + rr.y*w1 + rr.z*w2 + rr.w*w3;
    }
  }
  #pragma unroll
  for (int j = 0; j < 4; ++j){
    const int row = rbase + r0 + j;
    if (MODE == 0){
      *(f32x4*)(((float*)outp) + (size_t)row*128 + c0) = acc[j];
    } else if (MODE == 1){
      float sc = rsqrtf(fmaxf((float)cnt[row], 1.f));
      f16* o = ((f16*)outp) + (size_t)row*128 + c0;
      #pragma unroll
      for (int k = 0; k < 4; ++k) o[k] = (f16)(acc[j][k]*sc + bias[c0+k]);
    } else {
      f16* o = ((f16*)outp) + (size_t)row*128 + c0;
      #pragma unroll
      for (int k = 0; k < 4; ++k) o[k] = (f16)fmaxf(acc[j][k] + bias[c0+k], 0.f);
    }
  }
}

// ========== hconv stage 2 + relu + residual, 4 nodes/wave, f16 out.
// PRES: scale by rsqrt(du) (for next layer's prescaled input) ==========
template<int PRES>
__global__ __launch_bounds__(256) void k_nha(const int* __restrict__ cnt,
    const u16* __restrict__ csr, const float* __restrict__ ef,
    const float* __restrict__ bias, const float* __restrict__ nfr,
    const int* __restrict__ du, f16* __restrict__ outp)
{
  int wv = threadIdx.x >> 6, lane = threadIdx.x & 63;
  int n0 = blockIdx.x*16 + wv*4;
  int dcnt[4], c[4]; const u16* r[4];
  float ax[4] = {0,0,0,0}, ay[4] = {0,0,0,0};
  #pragma unroll
  for (int u = 0; u < 4; ++u){
    dcnt[u] = cnt[n0+u];
    c[u] = dcnt[u] < SLOT_N ? dcnt[u] : SLOT_N;
    r[u] = csr + (size_t)(n0+u)*SLOT_N;
  }
  int m = c[0];
  #pragma unroll
  for (int u = 1; u < 4; ++u) m = c[u] > m ? c[u] : m;
  for (int j = 0; j < m; ++j){
    #pragma unroll
    for (int u = 0; u < 4; ++u){
      if (j < c[u]){
        int idx = r[u][j];
        float2 v = ((const float2*)(ef + (size_t)idx*128))[lane];
        ax[u] += v.x; ay[u] += v.y;
      }
    }
  }
  float bx = bias[lane*2], by = bias[lane*2+1];
  #pragma unroll
  for (int u = 0; u < 4; ++u){
    float s = dcnt[u] > 0 ? 1.f/(float)dcnt[u] : 0.f;
    float2 nf = ((const float2*)(nfr + (size_t)(n0+u)*128))[lane];
    float vx = fmaxf(ax[u]*s + bx, 0.f) + nf.x;
    float vy = fmaxf(ay[u]*s + by, 0.f) + nf.y;
    float e0 = PRES ? rsqrtf(fmaxf((float)du[n0+u], 1.f)) : 1.f;
    ((f16x2*)(outp + (size_t)(n0+u)*128))[lane] = (f16x2){ (f16)(vx*e0), (f16)(vy*e0) };
  }
}

// ========== q = f16(relu(x @ Wm + bm)), K=512 in 4 LDS chunks ==========
__global__ __launch_bounds__(256) void k_qgemm(const float* __restrict__ x,
    const float* __restrict__ Wm, const float* __restrict__ bm, f16* __restrict__ q)
{
  __shared__ float Wl[128*128];
  const int c = threadIdx.x & 127, rh = threadIdx.x >> 7;
  const int base = blockIdx.x*16 + rh*8;
  float acc[8] = {0,0,0,0,0,0,0,0};
  for (int kc = 0; kc < 4; ++kc){
    __syncthreads();
    for (int i = threadIdx.x; i < 128*128; i += 256) Wl[i] = Wm[kc*128*128 + i];
    __syncthreads();
    #pragma unroll
    for (int r = 0; r < 8; ++r){
      const float* xr = x + (size_t)(base+r)*512 + kc*128;
      float a0=0.f,a1=0.f,a2=0.f,a3=0.f;
      #pragma unroll
      for (int d = 0; d < 128; d += 4){
        a0 += xr[d+0] * Wl[(d+0)*128 + c];
        a1 += xr[d+1] * Wl[(d+1)*128 + c];
        a2 += xr[d+2] * Wl[(d+2)*128 + c];
        a3 += xr[d+3] * Wl[(d+3)*128 + c];
      }
      acc[r] += (a0+a1)+(a2+a3);
    }
  }
  float bv = bm[c];
  #pragma unroll
  for (int r = 0; r < 8; ++r)
    q[(size_t)(base+r)*128 + c] = (f16)fmaxf(acc[r]+bv, 0.f);
}

// ========== gT[b][c][n] = h16[b*NPER+n][c]  (f16 transpose) ==========
__global__ __launch_bounds__(256) void k_gt(const f16* __restrict__ g, f16* __restrict__ gT)
{
  __shared__ f16 t[64][66];
  int b = blockIdx.z, n0 = blockIdx.x*64, c0 = blockIdx.y*64;
  for (int i = threadIdx.x; i < 64*64; i += 256){
    int n = i >> 6, c = i & 63;
    t[n][c] = g[((size_t)(b*NPER + n0 + n))*128 + c0 + c];
  }
  __syncthreads();
  for (int i = threadIdx.x; i < 64*64; i += 256){
    int c = i >> 6, n = i & 63;
    gT[((size_t)(b*128 + c0 + c))*NPER + n0 + n] = t[n][c];
  }
}

// ========== flash attention (R6): 128 q-rows/block (8 waves), n-slab 512, n-chunk 64,
// cooperative XOR-swizzled LDS staging, register prefetch, f16 Opart.
// 48 KB LDS, launch_bounds(512,4) -> 2 blocks/CU, 128 VGPR cap. ==========
#define NCH 64
__global__ __launch_bounds__(512, 4) void k_flash(const f16* __restrict__ qb,
    const f16* __restrict__ kb, const f16* __restrict__ gT,
    f16* __restrict__ Opart, float* __restrict__ mZ)
{
  __shared__ f16 Kl[64*128];        // 16 KB  [n 64][k 128], chunk-swizzled
  __shared__ f16 Vl[128*64];        // 16 KB  [d 128][n 64], chunk-swizzled
  __shared__ f16 Pl[8*16*64];       // 16 KB  per-wave [q 16][n 64], chunk-swizzled
  const int sp = blockIdx.x, l0 = blockIdx.y*128, b = blockIdx.z;
  const int tid = threadIdx.x;
  const int w = tid >> 6, lane = tid & 63;
  const int quad = lane >> 4, col = lane & 15;
  const int koff = quad*8;
  // staging lane mapping (512 threads)
  const int krow = tid >> 4;        // K: rows 0..31 (+32), chunks 0..15
  const int kc8  = tid & 15;
  const int vrow = tid >> 3;        // V: rows 0..63 (+64), chunks 0..7
  const int vc8  = tid & 7;

  const f16* qrow = qb + ((size_t)(b*LQ + l0 + w*16 + col))*128 + koff;
  f16x8 aq[4];
  #pragma unroll
  for (int ks = 0; ks < 4; ++ks) aq[ks] = *(const f16x8*)(qrow + ks*32);
  float mrun[4] = {-1e30f,-1e30f,-1e30f,-1e30f};
  float zrun[4] = {0.f,0.f,0.f,0.f};
  f32x4 O[8];
  #pragma unroll
  for (int i = 0; i < 8; ++i) O[i] = (f32x4){0.f,0.f,0.f,0.f};

  const int nbase = sp*(NPER/NSPLIT);          // 512-wide n slab
  f16x8 kr[2], vr[2];
#define LOADKV(N0)                                                           \
  { _Pragma("unroll")                                                        \
    for (int i2 = 0; i2 < 2; ++i2){                                          \
      kr[i2] = *(const f16x8*)(kb + ((size_t)(b*NPER + (N0) + krow + i2*32))*128 + kc8*8); \
      vr[i2] = *(const f16x8*)(gT + ((size_t)(b*128 + vrow + i2*64))*NPER + (N0) + vc8*8); \
    } }
  LOADKV(nbase);
  #pragma unroll 1
  for (int it = 0; it < (NPER/NSPLIT)/NCH; ++it){
    const int n0 = nbase + it*NCH;
    __syncthreads();                            // prior-iter LDS reads done
    #pragma unroll
    for (int i2 = 0; i2 < 2; ++i2){
      int r = krow + i2*32;
      *(f16x8*)&Kl[r*128 + ((kc8 ^ (r & 7))*8)] = kr[i2];
      int d = vrow + i2*64;
      *(f16x8*)&Vl[d*64  + ((vc8 ^ (d & 7))*8)] = vr[i2];
    }
    __syncthreads();                            // staging visible
    if (it < (NPER/NSPLIT)/NCH - 1) LOADKV(n0 + NCH);   // prefetch next tile

    // ---- QK^T from LDS ----
    f32x4 st[4];
    #pragma unroll
    for (int t = 0; t < 4; ++t){
      st[t] = (f32x4){0.f,0.f,0.f,0.f};
      const int r = t*16 + col, rs = r & 7;
      #pragma unroll
      for (int ks = 0; ks < 4; ++ks){
        f16x8 bf = *(const f16x8*)&Kl[r*128 + (((ks*4 + quad) ^ rs)*8)];
        st[t] = __builtin_amdgcn_mfma_f32_16x16x32_f16(aq[ks], bf, st[t], 0, 0, 0);
      }
    }
    // ---- softmax over 64 n ----
    float alr[4];
    #pragma unroll
    for (int r = 0; r < 4; ++r){
      float rm = st[0][r];
      #pragma unroll
      for (int t = 1; t < 4; ++t) rm = fmaxf(rm, st[t][r]);
      rm = fmaxf(rm, __shfl_xor(rm, 1));
      rm = fmaxf(rm, __shfl_xor(rm, 2));
      rm = fmaxf(rm, __shfl_xor(rm, 4));
      rm = fmaxf(rm, __shfl_xor(rm, 8));
      float mn = fmaxf(mrun[r], rm);
      float al = __expf(mrun[r] - mn);
      float ps[4], rsum = 0.f;
      #pragma unroll
      for (int t = 0; t < 4; ++t){ ps[t] = __expf(st[t][r] - mn); rsum += ps[t]; }
      rsum += __shfl_xor(rsum, 1);
      rsum += __shfl_xor(rsum, 2);
      rsum += __shfl_xor(rsum, 4);
      rsum += __shfl_xor(rsum, 8);
      zrun[r] = zrun[r]*al + rsum;
      mrun[r] = mn;
      alr[r] = al;
      const int prow = quad*4 + r, pswz = prow & 7;
      #pragma unroll
      for (int t = 0; t < 4; ++t)
        Pl[w*1024 + prow*64 + (((t*2 + (col >> 3)) ^ pswz)*8) + (col & 7)] = (f16)ps[t];
    }
    #pragma unroll
    for (int dt = 0; dt < 8; ++dt)
      #pragma unroll
      for (int r = 0; r < 4; ++r) O[dt][r] *= alr[r];
    __builtin_amdgcn_wave_barrier();
    // ---- PV from LDS ----
    #pragma unroll
    for (int kk = 0; kk < 2; ++kk){
      f16x8 ap = *(const f16x8*)&Pl[w*1024 + col*64 + (((kk*4 + quad) ^ (col & 7))*8)];
      #pragma unroll
      for (int dt = 0; dt < 8; ++dt){
        const int d = col + dt*16;
        f16x8 bv = *(const f16x8*)&Vl[d*64 + (((kk*4 + quad) ^ (d & 7))*8)];
        O[dt] = __builtin_amdgcn_mfma_f32_16x16x32_f16(ap, bv, O[dt], 0, 0, 0);
      }
    }
    __builtin_amdgcn_wave_barrier();
  }
#undef LOADKV
  const int growb = b*LQ + l0 + w*16 + quad*4;
  #pragma unroll
  for (int r = 0; r < 4; ++r){
    f16* od = Opart + ((size_t)sp*NROW + growb + r)*128 + col;
    #pragma unroll
    for (int dt = 0; dt < 8; ++dt) od[dt*16] = (f16)O[dt][r];
  }
  if (col == 0){
    #pragma unroll
    for (int r = 0; r < 4; ++r){
      ((float2*)mZ)[(size_t)sp*NROW + growb + r] = make_float2(mrun[r], zrun[r]);
    }
  }
}

// ========== combine splits (f16 partials) -> cat16 H columns [512,640) ==========
__global__ __launch_bounds__(256) void k_comb(const f16* __restrict__ Opart,
    const float* __restrict__ mZ, f16* __restrict__ cat)
{
  int i = blockIdx.x*256 + threadIdx.x;         // NROW*64
  int row = i >> 6, d2 = (i & 63)*2;
  float ms[NSPLIT], zs[NSPLIT];
  float M = -1e30f;
  #pragma unroll
  for (int s = 0; s < NSPLIT; ++s){
    float2 v = ((const float2*)mZ)[(size_t)s*NROW + row];
    ms[s] = v.x; zs[s] = v.y;
    M = fmaxf(M, v.x);
  }
  float Zt = 0.f, ax = 0.f, ay = 0.f;
  #pragma unroll
  for (int s = 0; s < NSPLIT; ++s){
    float e = __expf(ms[s] - M);
    Zt += zs[s]*e;
    f16x2 op = *(const f16x2*)(Opart + ((size_t)s*NROW + row)*128 + d2);
    ax += e*(float)op.x; ay += e*(float)op.y;
  }
  float inv = 1.f/Zt;
  f16x2 o = { (f16)(ax*inv), (f16)(ay*inv) };
  *(f16x2*)(cat + (size_t)row*640 + 512 + d2) = o;
}

// ========== prep for final MFMA GEMM: cat16 x-part + W^T f16.
// blocks [0,2048): x f32 -> cat16 cols [0,512).  [2048,2208): w16[n][k] = W[k][n]. ==========
__global__ __launch_bounds__(256) void k_prep(const float* __restrict__ x,
    const float* __restrict__ Wsg, const float* __restrict__ Wtn,
    f16* __restrict__ cat, f16* __restrict__ w16)
{
  if (blockIdx.x < 2048){
    int id = blockIdx.x*256 + threadIdx.x;     // 524288 = 4096 rows * 128 quads
    int row = id >> 7, c4 = (id & 127)*4;
    float4 v = *(const float4*)(x + (size_t)row*512 + c4);
    f16x4 o = { (f16)v.x, (f16)v.y, (f16)v.z, (f16)v.w };
    *(f16x4*)(cat + (size_t)row*640 + c4) = o;
  } else {
    int id = (blockIdx.x - 2048)*256 + threadIdx.x;   // 40960 = 256 n * 160 k-quads
    int n = id / 160;
    int k0 = (id - n*160)*4;
    const float* src = n < 128 ? (Wsg + n) : (Wtn + (n - 128));
    f16x4 o = { (f16)src[(k0+0)*128], (f16)src[(k0+1)*128],
                (f16)src[(k0+2)*128], (f16)src[(k0+3)*128] };
    *(f16x4*)(w16 + (size_t)n*640 + k0) = o;
  }
}

// ========== final MFMA GEMM: out[4096][256] = act(cat16 @ w16^T + bias).
// 1 wave per 16 rows, 16 n-tiles, K=640 in 20 mfma steps. n<128: sigmoid, else tanh ==========
__global__ __launch_bounds__(64) void k_fin2(const f16* __restrict__ cat,
    const f16* __restrict__ w16, const float* __restrict__ bsg,
    const float* __restrict__ btn, float* __restrict__ out)
{
  const int lane = threadIdx.x;
  const int quad = lane >> 4, col = lane & 15;
  const int koff = quad*8;
  const int row0 = blockIdx.x * 16;
  const f16* ar = cat + (size_t)(row0 + col)*640 + koff;
  const f16* br = w16 + (size_t)col*640 + koff;
  f32x4 acc[16];
  #pragma unroll
  for (int nt = 0; nt < 16; ++nt) acc[nt] = (f32x4){0.f,0.f,0.f,0.f};
  for (int ks = 0; ks < 20; ++ks){
    f16x8 a = *(const f16x8*)(ar + ks*32);
    #pragma unroll
    for (int nt = 0; nt < 16; ++nt){
      f16x8 b = *(const f16x8*)(br + (size_t)nt*16*640 + ks*32);
      acc[nt] = __builtin_amdgcn_mfma_f32_16x16x32_f16(a, b, acc[nt], 0, 0, 0);
    }
  }
  #pragma unroll
  for (int nt = 0; nt < 16; ++nt){
    int n = nt*16 + col;
    float bv = n < 128 ? bsg[n] : btn[n - 128];
    #pragma unroll
    for (int r = 0; r < 4; ++r){
      float v = acc[nt][r] + bv;
      v = n < 128 ? 1.f/(1.f + __expf(-v)) : tanhf(v);
      out[(size_t)(row0 + quad*4 + r)*256 + n] = v;
    }
  }
}

extern "C" void kernel_launch(void* const* d_in, const int* in_sizes, int n_in,
                              void* d_out, int out_size, void* d_ws, size_t ws_size,
                              hipStream_t stream)
{
  const float* x    = (const float*)d_in[0];
  const float* nfr  = (const float*)d_in[1];
  const int*   eidx = (const int*)d_in[2];
  const int*   hidx = (const int*)d_in[3];
  const float *Wg1=(const float*)d_in[4],  *bg1=(const float*)d_in[5];
  const float *Wg2=(const float*)d_in[6],  *bg2=(const float*)d_in[7];
  const float *Wh1=(const float*)d_in[8],  *bh1=(const float*)d_in[9];
  const float *Wh2=(const float*)d_in[10], *bh2=(const float*)d_in[11];
  const float *Wm =(const float*)d_in[12], *bm =(const float*)d_in[13];
  const float *Wm2=(const float*)d_in[14], *bm2=(const float*)d_in[15];
  const float *Wsg=(const float*)d_in[16], *bsg=(const float*)d_in[17];
  const float *Wtn=(const float*)d_in[18], *btn=(const float*)d_in[19];
  float* out = (float*)d_out;

  // ---- workspace layout. Aliases:
  //  h4_16 at base; bins + gcur live only until k_csr, alias agg16 region;
  //  cat16/w16 alias agg16 region too (live only in attention phase, after
  //  agg16's last use); Opart f16 (16MB) aliases dead bufA;
  //  kb/gT alias csr_dst/csr_pn. ----
  char* base = (char*)d_ws;
  f16*   h4_16  = (f16*)(base);                          // 16 MB
  f16*   agg16  = (f16*)(base + 33554432);               // 16 MB (graph phase only)
  u32*   bin_e  = (u32*)(base + 33554432);               // 5 MB   (aliases agg16)
  u32*   bin_pn = (u32*)(base + 38797312);               // 5 MB
  u32*   bin_pe = (u32*)(base + 44040192);               // 4.5 MB
  int*   gcur   = (int*)(base + 48758784);               // 1.25 KB
  f16*   cat16  = (f16*)(base + 33554432);               // 5.24 MB (attention phase)
  f16*   w16    = (f16*)(base + 38797312);               // 320 KB  (attention phase)
  f16*   bufA   = (f16*)(base + 67108864);               // 16 MB  (nfr16 / h2_16)
  f16*   bufB   = (f16*)(base + 83886080);               // 16 MB  (h1_16 / h3_16)
  f16*   Opart  = (f16*)(base + 67108864);               // 16 MB f16 (aliases bufA)
  u16*   csr_dst= (u16*)(base + 100663296);              // 8 MB used of 16 MB region
  f16*   kb     = (f16*)(base + 100663296);              //   (aliases csr_dst)
  u16*   csr_pn = (u16*)(base + 117440512);              // 8 MB used of 16 MB region
  f16*   gT     = (f16*)(base + 117440512);              //   (aliases csr_pn)
  u16*   csr_pe = (u16*)(base + 134217728);              // 3 MB used of 6 MB region
  int*   cnt_dst= (int*)(base + 140509184);
  int*   cnt_pn = (int*)(base + 140771328);
  int*   cnt_pe = (int*)(base + 141033472);
  int*   du     = (int*)(base + 141049856);              // 256 KB
  float* ef0    = (float*)(base + 141312000);            // 2 MB
  float* ef1    = (float*)(base + 143409152);            // 2 MB
  f16*   qb     = (f16*)(base + 145506304);              // 1 MB
  float* mZ     = (float*)(base + 146554880);            // 512 KB (NSPLIT16)
  const size_t needB = (size_t)147079168;
  if (ws_size < needB) return;

  // ---- CSR build: bin (phase A) then per-bucket insert (phase B) ----
  hipMemsetAsync(du, 0, 262144, stream);
  hipMemsetAsync(gcur, 0, 1280, stream);
  k_bin<<<1024, 256, 0, stream>>>(eidx, hidx, du, gcur, bin_e, bin_pn, bin_pe);
  k_csr<<<320, 256, 0, stream>>>(gcur, bin_e, bin_pn, bin_pe,
                                 cnt_dst, csr_dst, cnt_pn, csr_pn, cnt_pe, csr_pe);

  // ---- layer 1 ----
  k_pre<<<NNODE*64/256, 256, 0, stream>>>(nfr, du, bufA);
  k_gagg16<<<NNODE/16, 256, 0, stream>>>(cnt_dst, csr_dst, bufA, agg16);
  k_gemm<1,1><<<NNODE/32, 256, 0, stream>>>(agg16, Wg1, cnt_dst, bg1, bufB);
  k_hea16<<<NHE, 256, 0, stream>>>(cnt_pe, csr_pe, bufB, ef0);
  k_gemm<0,0><<<NHE/32, 256, 0, stream>>>(ef0, Wh1, nullptr, nullptr, ef1);
  k_nha<1><<<NNODE/16, 256, 0, stream>>>(cnt_pn, csr_pn, ef1, bh1, nfr, du, bufA);

  // ---- layer 2 ----
  k_gagg16<<<NNODE/16, 256, 0, stream>>>(cnt_dst, csr_dst, bufA, agg16);
  k_gemm<1,1><<<NNODE/32, 256, 0, stream>>>(agg16, Wg2, cnt_dst, bg2, bufB);
  k_hea16<<<NHE, 256, 0, stream>>>(cnt_pe, csr_pe, bufB, ef0);
  k_gemm<0,0><<<NHE/32, 256, 0, stream>>>(ef0, Wh2, nullptr, nullptr, ef1);
  k_nha<0><<<NNODE/16, 256, 0, stream>>>(cnt_pn, csr_pn, ef1, bh2, nfr, nullptr, h4_16);

  // ---- attention (agg16/bins dead from here: cat16/w16 safe) ----
  k_prep<<<2208, 256, 0, stream>>>(x, Wsg, Wtn, cat16, w16);
  k_qgemm<<<NROW/16, 256, 0, stream>>>(x, Wm, bm, qb);
  k_gemm<2,1><<<NNODE/32, 256, 0, stream>>>(h4_16, Wm2, nullptr, bm2, kb);
  k_gt<<<dim3(NPER/64, 2, BSZ), 256, 0, stream>>>(h4_16, gT);
  k_flash<<<dim3(NSPLIT, LQ/128, BSZ), 512, 0, stream>>>(qb, kb, gT, Opart, mZ);
  k_comb<<<NROW*64/256, 256, 0, stream>>>(Opart, mZ, cat16);
  k_fin2<<<NROW/16, 64, 0, stream>>>(cat16, w16, bsg, btn, out);

  (void)in_sizes; (void)n_in; (void)out_size;
}

// Round 7
// 827.725 us; speedup vs baseline: 1.4810x; 1.1182x over previous
//
#include <hip/hip_runtime.h>
#include <hip/hip_bf16.h>

#define BSZ   8
#define NPER  8192
#define NNODE 65536       // BSZ*NPER
#define EPG   131072      // edges per graph
#define EMB   128
#define ENCD  512
#define LQ    512
#define NHE   4096
#define NE    1048576
#define NP    1048576
#define NROW  4096        // BSZ*LQ
#define NSPLIT 16
#define SLOT_N 64
#define SLOT_E 384
// binning: 128 node-buckets (512 nodes), 64 he-buckets (64 hyperedges)
#define CAP_E  10240      // per node-bucket capacity, edges  (mean 8192, +22 sigma)
#define CAP_PN 10240      // per node-bucket capacity, pairs  (mean 8192)
#define CAP_PE 18432      // per he-bucket capacity, pairs    (mean 16384, +16 sigma)

typedef _Float16 f16;
typedef _Float16 f16x2 __attribute__((ext_vector_type(2)));
typedef _Float16 f16x4 __attribute__((ext_vector_type(4)));
typedef _Float16 f16x8 __attribute__((ext_vector_type(8)));
typedef float f32x4 __attribute__((ext_vector_type(4)));
typedef unsigned short u16;
typedef unsigned int u32;

// ========== phase A: bin edges (by dst) and pairs (by pn and by pe) into
// contiguous per-bucket arrays; du via global atomics.
// gcur layout: [0,128) edge-dst, [128,256) pn, [256,320) pe ==========
__global__ __launch_bounds__(256) void k_bin(const int* __restrict__ eidx,
    const int* __restrict__ hidx, int* __restrict__ du, int* __restrict__ gcur,
    u32* __restrict__ bin_e, u32* __restrict__ bin_pn, u32* __restrict__ bin_pe)
{
  __shared__ int lh[320];
  __shared__ int gb[320];
  const int tid = threadIdx.x;
  for (int i = tid; i < 320; i += 256) lh[i] = 0;
  __syncthreads();
  if (blockIdx.x < 512){
    // 2048 edges per block
    const int eb4 = blockIdx.x*512;
    int4 sa = ((const int4*)eidx)[eb4 + tid];
    int4 sb = ((const int4*)eidx)[eb4 + 256 + tid];
    int4 da = ((const int4*)(eidx + NE))[eb4 + tid];
    int4 db = ((const int4*)(eidx + NE))[eb4 + 256 + tid];
    int ss[8] = {sa.x,sa.y,sa.z,sa.w, sb.x,sb.y,sb.z,sb.w};
    int dd[8] = {da.x,da.y,da.z,da.w, db.x,db.y,db.z,db.w};
    int rr[8];
    #pragma unroll
    for (int u = 0; u < 8; ++u){
      atomicAdd(&du[ss[u]], 1);
      rr[u] = atomicAdd(&lh[dd[u] >> 9], 1);
    }
    __syncthreads();
    if (tid < 128 && lh[tid]) gb[tid] = atomicAdd(&gcur[tid], lh[tid]);
    __syncthreads();
    #pragma unroll
    for (int u = 0; u < 8; ++u){
      int b = dd[u] >> 9;
      int pos = gb[b] + rr[u];
      if (pos < CAP_E)
        bin_e[(size_t)b*CAP_E + pos] = (u32)(dd[u] & 0xffff) | ((u32)ss[u] << 16);
    }
  } else {
    // 2048 pairs per block, binned both directions
    const int pb4 = (blockIdx.x - 512)*1024;
    int4 pa = ((const int4*)hidx)[pb4 + tid];
    int4 pb = ((const int4*)hidx)[pb4 + 256 + tid];
    int4 pc = ((const int4*)hidx)[pb4 + 512 + tid];
    int4 pd = ((const int4*)hidx)[pb4 + 768 + tid];
    int pn[8] = {pa.x,pa.z, pb.x,pb.z, pc.x,pc.z, pd.x,pd.z};
    int pe[8] = {pa.y,pa.w, pb.y,pb.w, pc.y,pc.w, pd.y,pd.w};
    int rn[8], re[8];
    #pragma unroll
    for (int u = 0; u < 8; ++u){
      rn[u] = atomicAdd(&lh[128 + (pn[u] >> 9)], 1);
      re[u] = atomicAdd(&lh[256 + (pe[u] >> 6)], 1);
    }
    __syncthreads();
    if (tid < 192 && lh[128 + tid]) gb[128 + tid] = atomicAdd(&gcur[128 + tid], lh[128 + tid]);
    __syncthreads();
    #pragma unroll
    for (int u = 0; u < 8; ++u){
      int bn = pn[u] >> 9;
      int pos = gb[128 + bn] + rn[u];
      if (pos < CAP_PN)
        bin_pn[(size_t)bn*CAP_PN + pos] = (u32)pn[u] | ((u32)pe[u] << 16);
      int be = pe[u] >> 6;
      int pos2 = gb[256 + be] + re[u];
      if (pos2 < CAP_PE)
        bin_pe[(size_t)be*CAP_PE + pos2] = (u32)pe[u] | ((u32)pn[u] << 16);
    }
  }
}

// ========== phase B: per-bucket CSR insert (LDS cursors, windowed u16 writes).
// blocks [0,128) edge-dst, [128,256) pn, [256,320) pe ==========
__global__ __launch_bounds__(256) void k_csr(const int* __restrict__ gcur,
    const u32* __restrict__ bin_e, const u32* __restrict__ bin_pn,
    const u32* __restrict__ bin_pe,
    int* __restrict__ cnt_dst, u16* __restrict__ csr_dst,
    int* __restrict__ cnt_pn, u16* __restrict__ csr_pn,
    int* __restrict__ cnt_pe, u16* __restrict__ csr_pe)
{
  const int tid = threadIdx.x;
  if (blockIdx.x < 256){
    __shared__ int cur[512];
    const int isP = blockIdx.x >= 128;
    const int b = blockIdx.x & 127;
    cur[tid] = 0; cur[tid + 256] = 0;
    __syncthreads();
    const int n0 = b*512;
    const int cap = isP ? CAP_PN : CAP_E;
    int raw = gcur[isP ? 128 + b : b];
    int count = raw < cap ? raw : cap;
    const u32* bin = (isP ? bin_pn : bin_e) + (size_t)b*cap;
    u16* csr = isP ? csr_pn : csr_dst;
    for (int i = tid; i < count; i += 256){
      u32 v = bin[i];
      int row = v & 0xffff, val = v >> 16;
      int c = atomicAdd(&cur[row - n0], 1);
      if (c < SLOT_N) csr[(size_t)row*SLOT_N + c] = (u16)val;
    }
    __syncthreads();
    int* cnt = isP ? cnt_pn : cnt_dst;
    cnt[n0 + tid]       = cur[tid];
    cnt[n0 + 256 + tid] = cur[tid + 256];
  } else {
    __shared__ int cur[64];
    const int b = blockIdx.x - 256;
    if (tid < 64) cur[tid] = 0;
    __syncthreads();
    const int e0 = b*64;
    int raw = gcur[256 + b];
    int count = raw < CAP_PE ? raw : CAP_PE;
    const u32* bin = bin_pe + (size_t)b*CAP_PE;
    for (int i = tid; i < count; i += 256){
      u32 v = bin[i];
      int row = v & 0xffff, val = v >> 16;
      int c = atomicAdd(&cur[row - e0], 1);
      if (c < SLOT_E) csr_pe[(size_t)row*SLOT_E + c] = (u16)val;
    }
    __syncthreads();
    if (tid < 64) cnt_pe[e0 + tid] = cur[tid];
  }
}

// ========== nfr16 = f16(nfr * rsqrt(max(du,1))) ==========
__global__ __launch_bounds__(256) void k_pre(const float* __restrict__ nfr,
    const int* __restrict__ du, f16* __restrict__ out)
{
  int i = blockIdx.x*256 + threadIdx.x;         // NNODE*64
  int node = i >> 6, j = i & 63;
  float ds = rsqrtf(fmaxf((float)du[node], 1.f));
  float2 v = ((const float2*)(nfr + (size_t)node*128))[j];
  f16x2 o = { (f16)(v.x*ds), (f16)(v.y*ds) };
  ((f16x2*)(out + (size_t)node*128))[j] = o;
}

// ========== gconv gather (f16 src): agg16[d] = f16(sum src16[s]), 4 nodes/wave,
// j-loop unrolled x2 -> 8 outstanding loads/wave ==========
__global__ __launch_bounds__(256) void k_gagg16(const int* __restrict__ cnt,
    const u16* __restrict__ csr, const f16* __restrict__ src, f16* __restrict__ agg)
{
  int blk  = blockIdx.x;                        // NNODE/16 blocks, XCD swizzle
  int wv = threadIdx.x >> 6, lane = threadIdx.x & 63;
  int n0 = (blk & 7)*NPER + (blk >> 3)*16 + wv*4;
  const f16x2* s2 = (const f16x2*)src;
  int c[4]; const u16* r[4];
  float ax[4] = {0,0,0,0}, ay[4] = {0,0,0,0};
  #pragma unroll
  for (int u = 0; u < 4; ++u){
    int nd = cnt[n0+u];
    c[u] = nd < SLOT_N ? nd : SLOT_N;
    r[u] = csr + (size_t)(n0+u)*SLOT_N;
  }
  int m = c[0];
  #pragma unroll
  for (int u = 1; u < 4; ++u) m = c[u] > m ? c[u] : m;
  int j = 0;
  for (; j + 1 < m; j += 2){
    #pragma unroll
    for (int u = 0; u < 4; ++u){
      float bx = 0.f, by = 0.f;
      if (j < c[u]){
        f16x2 v = s2[(size_t)r[u][j]*64 + lane];
        bx = (float)v.x; by = (float)v.y;
      }
      if (j + 1 < c[u]){
        f16x2 v = s2[(size_t)r[u][j+1]*64 + lane];
        bx += (float)v.x; by += (float)v.y;
      }
      ax[u] += bx; ay[u] += by;
    }
  }
  if (j < m){
    #pragma unroll
    for (int u = 0; u < 4; ++u){
      if (j < c[u]){
        f16x2 v = s2[(size_t)r[u][j]*64 + lane];
        ax[u] += (float)v.x; ay[u] += (float)v.y;
      }
    }
  }
  #pragma unroll
  for (int u = 0; u < 4; ++u)
    ((f16x2*)(agg + (size_t)(n0+u)*128))[lane] = (f16x2){ (f16)ax[u], (f16)ay[u] };
}

// ========== hconv stage 1 (f16 source): ef0[e] = (1/|e|) * sum src16[pn].
// R7: 1 wave per hyperedge (4/block), 8-deep unrolled gather -> 8 loads in flight ==========
__global__ __launch_bounds__(256) void k_hea16(const int* __restrict__ cnt,
    const u16* __restrict__ csr, const f16* __restrict__ src, float* __restrict__ ef)
{
  const int wv = threadIdx.x >> 6, lane = threadIdx.x & 63;
  const int e = blockIdx.x*4 + wv;
  const int nd = cnt[e];
  const int n = nd < SLOT_E ? nd : SLOT_E;
  const u16* row = csr + (size_t)e*SLOT_E;
  const f16x2* s2 = (const f16x2*)src;
  float ax = 0.f, ay = 0.f;
  int j = 0;
  for (; j + 7 < n; j += 8){
    int p0 = row[j],   p1 = row[j+1], p2 = row[j+2], p3 = row[j+3];
    int p4 = row[j+4], p5 = row[j+5], p6 = row[j+6], p7 = row[j+7];
    f16x2 v0 = s2[(size_t)p0*64 + lane];
    f16x2 v1 = s2[(size_t)p1*64 + lane];
    f16x2 v2 = s2[(size_t)p2*64 + lane];
    f16x2 v3 = s2[(size_t)p3*64 + lane];
    f16x2 v4 = s2[(size_t)p4*64 + lane];
    f16x2 v5 = s2[(size_t)p5*64 + lane];
    f16x2 v6 = s2[(size_t)p6*64 + lane];
    f16x2 v7 = s2[(size_t)p7*64 + lane];
    ax += (((float)v0.x + (float)v1.x) + ((float)v2.x + (float)v3.x))
        + (((float)v4.x + (float)v5.x) + ((float)v6.x + (float)v7.x));
    ay += (((float)v0.y + (float)v1.y) + ((float)v2.y + (float)v3.y))
        + (((float)v4.y + (float)v5.y) + ((float)v6.y + (float)v7.y));
  }
  for (; j < n; ++j){
    f16x2 v = s2[(size_t)row[j]*64 + lane];
    ax += (float)v.x; ay += (float)v.y;
  }
  float s = nd > 0 ? 1.f/(float)nd : 0.f;
  ((float2*)(ef + (size_t)e*128))[lane] = make_float2(ax*s, ay*s);
}

// ========== register-blocked 128x128 GEMM.  IN16: input rows are f16.
// MODE 0: f32 raw   MODE 1: f16(acc*rsqrt(max(cnt,1)) + bias)   MODE 2: f16(relu(acc+bias)) ==========
template<int MODE, int IN16>
__global__ __launch_bounds__(256, 2) void k_gemm(const void* __restrict__ inp,
    const float* __restrict__ W, const int* __restrict__ cnt,
    const float* __restrict__ bias, void* __restrict__ outp)
{
  __shared__ float Wl[128*128];
  __shared__ float Rl[32*128];
  const int tid = threadIdx.x;
  const int rbase = blockIdx.x*32;
  for (int i = tid; i < 16384; i += 256) Wl[i] = W[i];
  if (IN16){
    const f16x2* s2 = (const f16x2*)(((const f16*)inp) + (size_t)rbase*128);
    for (int i = tid; i < 2048; i += 256){
      f16x2 v = s2[i];
      ((float2*)Rl)[i] = make_float2((float)v.x, (float)v.y);
    }
  } else {
    const float* src = ((const float*)inp) + (size_t)rbase*128;
    for (int i = tid; i < 4096; i += 256) Rl[i] = src[i];
  }
  __syncthreads();
  const int c0 = (tid & 31)*4;
  const int r0 = (tid >> 5)*4;
  f32x4 acc[4];
  #pragma unroll
  for (int j = 0; j < 4; ++j) acc[j] = (f32x4){0.f,0.f,0.f,0.f};
  for (int d = 0; d < 128; d += 4){
    f32x4 w0 = *(const f32x4*)&Wl[(d+0)*128 + c0];
    f32x4 w1 = *(const f32x4*)&Wl[(d+1)*128 + c0];
    f32x4 w2 = *(const f32x4*)&Wl[(d+2)*128 + c0];
    f32x4 w3 = *(const f32x4*)&Wl[(d+3)*128 + c0];
    #pragma unroll
    for (int j = 0; j < 4; ++j){
      f32x4 rr = *(const f32x4*)&Rl[(r0+j)*128 + d];
      acc[j] += rr.x*w0 + rr.y*w1 + rr.z*w2 + rr.w*w3;
    }
  }
  #pragma unroll
  for (int j = 0; j < 4; ++j){
    const int row = rbase + r0 + j;
    if (MODE == 0){
      *(f32x4*)(((float*)outp) + (size_t)row*128 + c0) = acc[j];
    } else if (MODE == 1){
      float sc = rsqrtf(fmaxf((float)cnt[row], 1.f));
      f16* o = ((f16*)outp) + (size_t)row*128 + c0;
      #pragma unroll
      for (int k = 0; k < 4; ++k) o[k] = (f16)(acc[j][k]*sc + bias[c0+k]);
    } else {
      f16* o = ((f16*)outp) + (size_t)row*128 + c0;
      #pragma unroll
      for (int k = 0; k < 4; ++k) o[k] = (f16)fmaxf(acc[j][k] + bias[c0+k], 0.f);
    }
  }
}

// ========== hconv stage 2 + relu + residual, 4 nodes/wave, f16 out.
// PRES: scale by rsqrt(du) (for next layer's prescaled input) ==========
template<int PRES>
__global__ __launch_bounds__(256) void k_nha(const int* __restrict__ cnt,
    const u16* __restrict__ csr, const float* __restrict__ ef,
    const float* __restrict__ bias, const float* __restrict__ nfr,
    const int* __restrict__ du, f16* __restrict__ outp)
{
  int wv = threadIdx.x >> 6, lane = threadIdx.x & 63;
  int n0 = blockIdx.x*16 + wv*4;
  int dcnt[4], c[4]; const u16* r[4];
  float ax[4] = {0,0,0,0}, ay[4] = {0,0,0,0};
  #pragma unroll
  for (int u = 0; u < 4; ++u){
    dcnt[u] = cnt[n0+u];
    c[u] = dcnt[u] < SLOT_N ? dcnt[u] : SLOT_N;
    r[u] = csr + (size_t)(n0+u)*SLOT_N;
  }
  int m = c[0];
  #pragma unroll
  for (int u = 1; u < 4; ++u) m = c[u] > m ? c[u] : m;
  for (int j = 0; j < m; ++j){
    #pragma unroll
    for (int u = 0; u < 4; ++u){
      if (j < c[u]){
        int idx = r[u][j];
        float2 v = ((const float2*)(ef + (size_t)idx*128))[lane];
        ax[u] += v.x; ay[u] += v.y;
      }
    }
  }
  float bx = bias[lane*2], by = bias[lane*2+1];
  #pragma unroll
  for (int u = 0; u < 4; ++u){
    float s = dcnt[u] > 0 ? 1.f/(float)dcnt[u] : 0.f;
    float2 nf = ((const float2*)(nfr + (size_t)(n0+u)*128))[lane];
    float vx = fmaxf(ax[u]*s + bx, 0.f) + nf.x;
    float vy = fmaxf(ay[u]*s + by, 0.f) + nf.y;
    float e0 = PRES ? rsqrtf(fmaxf((float)du[n0+u], 1.f)) : 1.f;
    ((f16x2*)(outp + (size_t)(n0+u)*128))[lane] = (f16x2){ (f16)(vx*e0), (f16)(vy*e0) };
  }
}

// ========== q = f16(relu(x @ Wm + bm)), K=512 in 4 LDS chunks ==========
__global__ __launch_bounds__(256) void k_qgemm(const float* __restrict__ x,
    const float* __restrict__ Wm, const float* __restrict__ bm, f16* __restrict__ q)
{
  __shared__ float Wl[128*128];
  const int c = threadIdx.x & 127, rh = threadIdx.x >> 7;
  const int base = blockIdx.x*16 + rh*8;
  float acc[8] = {0,0,0,0,0,0,0,0};
  for (int kc = 0; kc < 4; ++kc){
    __syncthreads();
    for (int i = threadIdx.x; i < 128*128; i += 256) Wl[i] = Wm[kc*128*128 + i];
    __syncthreads();
    #pragma unroll
    for (int r = 0; r < 8; ++r){
      const float* xr = x + (size_t)(base+r)*512 + kc*128;
      float a0=0.f,a1=0.f,a2=0.f,a3=0.f;
      #pragma unroll
      for (int d = 0; d < 128; d += 4){
        a0 += xr[d+0] * Wl[(d+0)*128 + c];
        a1 += xr[d+1] * Wl[(d+1)*128 + c];
        a2 += xr[d+2] * Wl[(d+2)*128 + c];
        a3 += xr[d+3] * Wl[(d+3)*128 + c];
      }
      acc[r] += (a0+a1)+(a2+a3);
    }
  }
  float bv = bm[c];
  #pragma unroll
  for (int r = 0; r < 8; ++r)
    q[(size_t)(base+r)*128 + c] = (f16)fmaxf(acc[r]+bv, 0.f);
}

// ========== gT[b][c][n] = h16[b*NPER+n][c]  (f16 transpose) ==========
__global__ __launch_bounds__(256) void k_gt(const f16* __restrict__ g, f16* __restrict__ gT)
{
  __shared__ f16 t[64][66];
  int b = blockIdx.z, n0 = blockIdx.x*64, c0 = blockIdx.y*64;
  for (int i = threadIdx.x; i < 64*64; i += 256){
    int n = i >> 6, c = i & 63;
    t[n][c] = g[((size_t)(b*NPER + n0 + n))*128 + c0 + c];
  }
  __syncthreads();
  for (int i = threadIdx.x; i < 64*64; i += 256){
    int c = i >> 6, n = i & 63;
    gT[((size_t)(b*128 + c0 + c))*NPER + n0 + n] = t[n][c];
  }
}

// ========== flash attention (R6): 128 q-rows/block (8 waves), n-slab 512, n-chunk 64,
// cooperative XOR-swizzled LDS staging, register prefetch, f16 Opart.
// 48 KB LDS, launch_bounds(512,4) -> 2 blocks/CU, 128 VGPR cap. ==========
#define NCH 64
__global__ __launch_bounds__(512, 4) void k_flash(const f16* __restrict__ qb,
    const f16* __restrict__ kb, const f16* __restrict__ gT,
    f16* __restrict__ Opart, float* __restrict__ mZ)
{
  __shared__ f16 Kl[64*128];        // 16 KB  [n 64][k 128], chunk-swizzled
  __shared__ f16 Vl[128*64];        // 16 KB  [d 128][n 64], chunk-swizzled
  __shared__ f16 Pl[8*16*64];       // 16 KB  per-wave [q 16][n 64], chunk-swizzled
  const int sp = blockIdx.x, l0 = blockIdx.y*128, b = blockIdx.z;
  const int tid = threadIdx.x;
  const int w = tid >> 6, lane = tid & 63;
  const int quad = lane >> 4, col = lane & 15;
  const int koff = quad*8;
  // staging lane mapping (512 threads)
  const int krow = tid >> 4;        // K: rows 0..31 (+32), chunks 0..15
  const int kc8  = tid & 15;
  const int vrow = tid >> 3;        // V: rows 0..63 (+64), chunks 0..7
  const int vc8  = tid & 7;

  const f16* qrow = qb + ((size_t)(b*LQ + l0 + w*16 + col))*128 + koff;
  f16x8 aq[4];
  #pragma unroll
  for (int ks = 0; ks < 4; ++ks) aq[ks] = *(const f16x8*)(qrow + ks*32);
  float mrun[4] = {-1e30f,-1e30f,-1e30f,-1e30f};
  float zrun[4] = {0.f,0.f,0.f,0.f};
  f32x4 O[8];
  #pragma unroll
  for (int i = 0; i < 8; ++i) O[i] = (f32x4){0.f,0.f,0.f,0.f};

  const int nbase = sp*(NPER/NSPLIT);          // 512-wide n slab
  f16x8 kr[2], vr[2];
#define LOADKV(N0)                                                           \
  { _Pragma("unroll")                                                        \
    for (int i2 = 0; i2 < 2; ++i2){                                          \
      kr[i2] = *(const f16x8*)(kb + ((size_t)(b*NPER + (N0) + krow + i2*32))*128 + kc8*8); \
      vr[i2] = *(const f16x8*)(gT + ((size_t)(b*128 + vrow + i2*64))*NPER + (N0) + vc8*8); \
    } }
  LOADKV(nbase);
  #pragma unroll 1
  for (int it = 0; it < (NPER/NSPLIT)/NCH; ++it){
    const int n0 = nbase + it*NCH;
    __syncthreads();                            // prior-iter LDS reads done
    #pragma unroll
    for (int i2 = 0; i2 < 2; ++i2){
      int r = krow + i2*32;
      *(f16x8*)&Kl[r*128 + ((kc8 ^ (r & 7))*8)] = kr[i2];
      int d = vrow + i2*64;
      *(f16x8*)&Vl[d*64  + ((vc8 ^ (d & 7))*8)] = vr[i2];
    }
    __syncthreads();                            // staging visible
    if (it < (NPER/NSPLIT)/NCH - 1) LOADKV(n0 + NCH);   // prefetch next tile

    // ---- QK^T from LDS ----
    f32x4 st[4];
    #pragma unroll
    for (int t = 0; t < 4; ++t){
      st[t] = (f32x4){0.f,0.f,0.f,0.f};
      const int r = t*16 + col, rs = r & 7;
      #pragma unroll
      for (int ks = 0; ks < 4; ++ks){
        f16x8 bf = *(const f16x8*)&Kl[r*128 + (((ks*4 + quad) ^ rs)*8)];
        st[t] = __builtin_amdgcn_mfma_f32_16x16x32_f16(aq[ks], bf, st[t], 0, 0, 0);
      }
    }
    // ---- softmax over 64 n ----
    float alr[4];
    #pragma unroll
    for (int r = 0; r < 4; ++r){
      float rm = st[0][r];
      #pragma unroll
      for (int t = 1; t < 4; ++t) rm = fmaxf(rm, st[t][r]);
      rm = fmaxf(rm, __shfl_xor(rm, 1));
      rm = fmaxf(rm, __shfl_xor(rm, 2));
      rm = fmaxf(rm, __shfl_xor(rm, 4));
      rm = fmaxf(rm, __shfl_xor(rm, 8));
      float mn = fmaxf(mrun[r], rm);
      float al = __expf(mrun[r] - mn);
      float ps[4], rsum = 0.f;
      #pragma unroll
      for (int t = 0; t < 4; ++t){ ps[t] = __expf(st[t][r] - mn); rsum += ps[t]; }
      rsum += __shfl_xor(rsum, 1);
      rsum += __shfl_xor(rsum, 2);
      rsum += __shfl_xor(rsum, 4);
      rsum += __shfl_xor(rsum, 8);
      zrun[r] = zrun[r]*al + rsum;
      mrun[r] = mn;
      alr[r] = al;
      const int prow = quad*4 + r, pswz = prow & 7;
      #pragma unroll
      for (int t = 0; t < 4; ++t)
        Pl[w*1024 + prow*64 + (((t*2 + (col >> 3)) ^ pswz)*8) + (col & 7)] = (f16)ps[t];
    }
    #pragma unroll
    for (int dt = 0; dt < 8; ++dt)
      #pragma unroll
      for (int r = 0; r < 4; ++r) O[dt][r] *= alr[r];
    __builtin_amdgcn_wave_barrier();
    // ---- PV from LDS ----
    #pragma unroll
    for (int kk = 0; kk < 2; ++kk){
      f16x8 ap = *(const f16x8*)&Pl[w*1024 + col*64 + (((kk*4 + quad) ^ (col & 7))*8)];
      #pragma unroll
      for (int dt = 0; dt < 8; ++dt){
        const int d = col + dt*16;
        f16x8 bv = *(const f16x8*)&Vl[d*64 + (((kk*4 + quad) ^ (d & 7))*8)];
        O[dt] = __builtin_amdgcn_mfma_f32_16x16x32_f16(ap, bv, O[dt], 0, 0, 0);
      }
    }
    __builtin_amdgcn_wave_barrier();
  }
#undef LOADKV
  const int growb = b*LQ + l0 + w*16 + quad*4;
  #pragma unroll
  for (int r = 0; r < 4; ++r){
    f16* od = Opart + ((size_t)sp*NROW + growb + r)*128 + col;
    #pragma unroll
    for (int dt = 0; dt < 8; ++dt) od[dt*16] = (f16)O[dt][r];
  }
  if (col == 0){
    #pragma unroll
    for (int r = 0; r < 4; ++r){
      ((float2*)mZ)[(size_t)sp*NROW + growb + r] = make_float2(mrun[r], zrun[r]);
    }
  }
}

// ========== combine splits (f16 partials) -> cat16 H columns [512,640) ==========
__global__ __launch_bounds__(256) void k_comb(const f16* __restrict__ Opart,
    const float* __restrict__ mZ, f16* __restrict__ cat)
{
  int i = blockIdx.x*256 + threadIdx.x;         // NROW*64
  int row = i >> 6, d2 = (i & 63)*2;
  float ms[NSPLIT], zs[NSPLIT];
  float M = -1e30f;
  #pragma unroll
  for (int s = 0; s < NSPLIT; ++s){
    float2 v = ((const float2*)mZ)[(size_t)s*NROW + row];
    ms[s] = v.x; zs[s] = v.y;
    M = fmaxf(M, v.x);
  }
  float Zt = 0.f, ax = 0.f, ay = 0.f;
  #pragma unroll
  for (int s = 0; s < NSPLIT; ++s){
    float e = __expf(ms[s] - M);
    Zt += zs[s]*e;
    f16x2 op = *(const f16x2*)(Opart + ((size_t)s*NROW + row)*128 + d2);
    ax += e*(float)op.x; ay += e*(float)op.y;
  }
  float inv = 1.f/Zt;
  f16x2 o = { (f16)(ax*inv), (f16)(ay*inv) };
  *(f16x2*)(cat + (size_t)row*640 + 512 + d2) = o;
}

// ========== prep for final MFMA GEMM: cat16 x-part + W^T f16.
// blocks [0,2048): x f32 -> cat16 cols [0,512).  [2048,2208): w16[n][k] = W[k][n]. ==========
__global__ __launch_bounds__(256) void k_prep(const float* __restrict__ x,
    const float* __restrict__ Wsg, const float* __restrict__ Wtn,
    f16* __restrict__ cat, f16* __restrict__ w16)
{
  if (blockIdx.x < 2048){
    int id = blockIdx.x*256 + threadIdx.x;     // 524288 = 4096 rows * 128 quads
    int row = id >> 7, c4 = (id & 127)*4;
    float4 v = *(const float4*)(x + (size_t)row*512 + c4);
    f16x4 o = { (f16)v.x, (f16)v.y, (f16)v.z, (f16)v.w };
    *(f16x4*)(cat + (size_t)row*640 + c4) = o;
  } else {
    int id = (blockIdx.x - 2048)*256 + threadIdx.x;   // 40960 = 256 n * 160 k-quads
    int n = id / 160;
    int k0 = (id - n*160)*4;
    const float* src = n < 128 ? (Wsg + n) : (Wtn + (n - 128));
    f16x4 o = { (f16)src[(k0+0)*128], (f16)src[(k0+1)*128],
                (f16)src[(k0+2)*128], (f16)src[(k0+3)*128] };
    *(f16x4*)(w16 + (size_t)n*640 + k0) = o;
  }
}

// ========== final MFMA GEMM: out[4096][256] = act(cat16 @ w16^T + bias).
// 1 wave per 16 rows, 16 n-tiles, K=640 in 20 mfma steps. n<128: sigmoid, else tanh ==========
__global__ __launch_bounds__(64) void k_fin2(const f16* __restrict__ cat,
    const f16* __restrict__ w16, const float* __restrict__ bsg,
    const float* __restrict__ btn, float* __restrict__ out)
{
  const int lane = threadIdx.x;
  const int quad = lane >> 4, col = lane & 15;
  const int koff = quad*8;
  const int row0 = blockIdx.x * 16;
  const f16* ar = cat + (size_t)(row0 + col)*640 + koff;
  const f16* br = w16 + (size_t)col*640 + koff;
  f32x4 acc[16];
  #pragma unroll
  for (int nt = 0; nt < 16; ++nt) acc[nt] = (f32x4){0.f,0.f,0.f,0.f};
  for (int ks = 0; ks < 20; ++ks){
    f16x8 a = *(const f16x8*)(ar + ks*32);
    #pragma unroll
    for (int nt = 0; nt < 16; ++nt){
      f16x8 b = *(const f16x8*)(br + (size_t)nt*16*640 + ks*32);
      acc[nt] = __builtin_amdgcn_mfma_f32_16x16x32_f16(a, b, acc[nt], 0, 0, 0);
    }
  }
  #pragma unroll
  for (int nt = 0; nt < 16; ++nt){
    int n = nt*16 + col;
    float bv = n < 128 ? bsg[n] : btn[n - 128];
    #pragma unroll
    for (int r = 0; r < 4; ++r){
      float v = acc[nt][r] + bv;
      v = n < 128 ? 1.f/(1.f + __expf(-v)) : tanhf(v);
      out[(size_t)(row0 + quad*4 + r)*256 + n] = v;
    }
  }
}

extern "C" void kernel_launch(void* const* d_in, const int* in_sizes, int n_in,
                              void* d_out, int out_size, void* d_ws, size_t ws_size,
                              hipStream_t stream)
{
  const float* x    = (const float*)d_in[0];
  const float* nfr  = (const float*)d_in[1];
  const int*   eidx = (const int*)d_in[2];
  const int*   hidx = (const int*)d_in[3];
  const float *Wg1=(const float*)d_in[4],  *bg1=(const float*)d_in[5];
  const float *Wg2=(const float*)d_in[6],  *bg2=(const float*)d_in[7];
  const float *Wh1=(const float*)d_in[8],  *bh1=(const float*)d_in[9];
  const float *Wh2=(const float*)d_in[10], *bh2=(const float*)d_in[11];
  const float *Wm =(const float*)d_in[12], *bm =(const float*)d_in[13];
  const float *Wm2=(const float*)d_in[14], *bm2=(const float*)d_in[15];
  const float *Wsg=(const float*)d_in[16], *bsg=(const float*)d_in[17];
  const float *Wtn=(const float*)d_in[18], *btn=(const float*)d_in[19];
  float* out = (float*)d_out;

  // ---- workspace layout. Aliases:
  //  h4_16 at base; bins + gcur live only until k_csr, alias agg16 region;
  //  cat16/w16 alias agg16 region too (live only in attention phase, after
  //  agg16's last use); Opart f16 (16MB) aliases dead bufA;
  //  kb/gT alias csr_dst/csr_pn. ----
  char* base = (char*)d_ws;
  f16*   h4_16  = (f16*)(base);                          // 16 MB
  f16*   agg16  = (f16*)(base + 33554432);               // 16 MB (graph phase only)
  u32*   bin_e  = (u32*)(base + 33554432);               // 5 MB   (aliases agg16)
  u32*   bin_pn = (u32*)(base + 38797312);               // 5 MB
  u32*   bin_pe = (u32*)(base + 44040192);               // 4.5 MB
  int*   gcur   = (int*)(base + 48758784);               // 1.25 KB
  f16*   cat16  = (f16*)(base + 33554432);               // 5.24 MB (attention phase)
  f16*   w16    = (f16*)(base + 38797312);               // 320 KB  (attention phase)
  f16*   bufA   = (f16*)(base + 67108864);               // 16 MB  (nfr16 / h2_16)
  f16*   bufB   = (f16*)(base + 83886080);               // 16 MB  (h1_16 / h3_16)
  f16*   Opart  = (f16*)(base + 67108864);               // 16 MB f16 (aliases bufA)
  u16*   csr_dst= (u16*)(base + 100663296);              // 8 MB used of 16 MB region
  f16*   kb     = (f16*)(base + 100663296);              //   (aliases csr_dst)
  u16*   csr_pn = (u16*)(base + 117440512);              // 8 MB used of 16 MB region
  f16*   gT     = (f16*)(base + 117440512);              //   (aliases csr_pn)
  u16*   csr_pe = (u16*)(base + 134217728);              // 3 MB used of 6 MB region
  int*   cnt_dst= (int*)(base + 140509184);
  int*   cnt_pn = (int*)(base + 140771328);
  int*   cnt_pe = (int*)(base + 141033472);
  int*   du     = (int*)(base + 141049856);              // 256 KB
  float* ef0    = (float*)(base + 141312000);            // 2 MB
  float* ef1    = (float*)(base + 143409152);            // 2 MB
  f16*   qb     = (f16*)(base + 145506304);              // 1 MB
  float* mZ     = (float*)(base + 146554880);            // 512 KB (NSPLIT16)
  const size_t needB = (size_t)147079168;
  if (ws_size < needB) return;

  // ---- CSR build: bin (phase A) then per-bucket insert (phase B) ----
  hipMemsetAsync(du, 0, 262144, stream);
  hipMemsetAsync(gcur, 0, 1280, stream);
  k_bin<<<1024, 256, 0, stream>>>(eidx, hidx, du, gcur, bin_e, bin_pn, bin_pe);
  k_csr<<<320, 256, 0, stream>>>(gcur, bin_e, bin_pn, bin_pe,
                                 cnt_dst, csr_dst, cnt_pn, csr_pn, cnt_pe, csr_pe);

  // ---- layer 1 ----
  k_pre<<<NNODE*64/256, 256, 0, stream>>>(nfr, du, bufA);
  k_gagg16<<<NNODE/16, 256, 0, stream>>>(cnt_dst, csr_dst, bufA, agg16);
  k_gemm<1,1><<<NNODE/32, 256, 0, stream>>>(agg16, Wg1, cnt_dst, bg1, bufB);
  k_hea16<<<NHE/4, 256, 0, stream>>>(cnt_pe, csr_pe, bufB, ef0);
  k_gemm<0,0><<<NHE/32, 256, 0, stream>>>(ef0, Wh1, nullptr, nullptr, ef1);
  k_nha<1><<<NNODE/16, 256, 0, stream>>>(cnt_pn, csr_pn, ef1, bh1, nfr, du, bufA);

  // ---- layer 2 ----
  k_gagg16<<<NNODE/16, 256, 0, stream>>>(cnt_dst, csr_dst, bufA, agg16);
  k_gemm<1,1><<<NNODE/32, 256, 0, stream>>>(agg16, Wg2, cnt_dst, bg2, bufB);
  k_hea16<<<NHE/4, 256, 0, stream>>>(cnt_pe, csr_pe, bufB, ef0);
  k_gemm<0,0><<<NHE/32, 256, 0, stream>>>(ef0, Wh2, nullptr, nullptr, ef1);
  k_nha<0><<<NNODE/16, 256, 0, stream>>>(cnt_pn, csr_pn, ef1, bh2, nfr, nullptr, h4_16);

  // ---- attention (agg16/bins dead from here: cat16/w16 safe) ----
  k_prep<<<2208, 256, 0, stream>>>(x, Wsg, Wtn, cat16, w16);
  k_qgemm<<<NROW/16, 256, 0, stream>>>(x, Wm, bm, qb);
  k_gemm<2,1><<<NNODE/32, 256, 0, stream>>>(h4_16, Wm2, nullptr, bm2, kb);
  k_gt<<<dim3(NPER/64, 2, BSZ), 256, 0, stream>>>(h4_16, gT);
  k_flash<<<dim3(NSPLIT, LQ/128, BSZ), 512, 0, stream>>>(qb, kb, gT, Opart, mZ);
  k_comb<<<NROW*64/256, 256, 0, stream>>>(Opart, mZ, cat16);
  k_fin2<<<NROW/16, 64, 0, stream>>>(cat16, w16, bsg, btn, out);

  (void)in_sizes; (void)n_in; (void)out_size;
}

// Round 8
// 812.687 us; speedup vs baseline: 1.5084x; 1.0185x over previous
//
#include <hip/hip_runtime.h>
#include <hip/hip_bf16.h>

#define BSZ   8
#define NPER  8192
#define NNODE 65536       // BSZ*NPER
#define EPG   131072      // edges per graph
#define EMB   128
#define ENCD  512
#define LQ    512
#define NHE   4096
#define NE    1048576
#define NP    1048576
#define NROW  4096        // BSZ*LQ
#define NSPLIT 16
#define SLOT_N 64
#define SLOT_E 384
// binning: 128 node-buckets (512 nodes), 64 he-buckets (64 hyperedges)
#define CAP_E  10240      // per node-bucket capacity, edges  (mean 8192, +22 sigma)
#define CAP_PN 10240      // per node-bucket capacity, pairs  (mean 8192)
#define CAP_PE 18432      // per he-bucket capacity, pairs    (mean 16384, +16 sigma)

typedef _Float16 f16;
typedef _Float16 f16x2 __attribute__((ext_vector_type(2)));
typedef _Float16 f16x4 __attribute__((ext_vector_type(4)));
typedef _Float16 f16x8 __attribute__((ext_vector_type(8)));
typedef float f32x4 __attribute__((ext_vector_type(4)));
typedef unsigned short u16;
typedef unsigned int u32;

// ========== phase A: bin edges (by dst) and pairs (by pn and by pe) into
// contiguous per-bucket arrays; du via global atomics.
// gcur layout: [0,128) edge-dst, [128,256) pn, [256,320) pe ==========
__global__ __launch_bounds__(256) void k_bin(const int* __restrict__ eidx,
    const int* __restrict__ hidx, int* __restrict__ du, int* __restrict__ gcur,
    u32* __restrict__ bin_e, u32* __restrict__ bin_pn, u32* __restrict__ bin_pe)
{
  __shared__ int lh[320];
  __shared__ int gb[320];
  const int tid = threadIdx.x;
  for (int i = tid; i < 320; i += 256) lh[i] = 0;
  __syncthreads();
  if (blockIdx.x < 512){
    // 2048 edges per block
    const int eb4 = blockIdx.x*512;
    int4 sa = ((const int4*)eidx)[eb4 + tid];
    int4 sb = ((const int4*)eidx)[eb4 + 256 + tid];
    int4 da = ((const int4*)(eidx + NE))[eb4 + tid];
    int4 db = ((const int4*)(eidx + NE))[eb4 + 256 + tid];
    int ss[8] = {sa.x,sa.y,sa.z,sa.w, sb.x,sb.y,sb.z,sb.w};
    int dd[8] = {da.x,da.y,da.z,da.w, db.x,db.y,db.z,db.w};
    int rr[8];
    #pragma unroll
    for (int u = 0; u < 8; ++u){
      atomicAdd(&du[ss[u]], 1);
      rr[u] = atomicAdd(&lh[dd[u] >> 9], 1);
    }
    __syncthreads();
    if (tid < 128 && lh[tid]) gb[tid] = atomicAdd(&gcur[tid], lh[tid]);
    __syncthreads();
    #pragma unroll
    for (int u = 0; u < 8; ++u){
      int b = dd[u] >> 9;
      int pos = gb[b] + rr[u];
      if (pos < CAP_E)
        bin_e[(size_t)b*CAP_E + pos] = (u32)(dd[u] & 0xffff) | ((u32)ss[u] << 16);
    }
  } else {
    // 2048 pairs per block, binned both directions
    const int pb4 = (blockIdx.x - 512)*1024;
    int4 pa = ((const int4*)hidx)[pb4 + tid];
    int4 pb = ((const int4*)hidx)[pb4 + 256 + tid];
    int4 pc = ((const int4*)hidx)[pb4 + 512 + tid];
    int4 pd = ((const int4*)hidx)[pb4 + 768 + tid];
    int pn[8] = {pa.x,pa.z, pb.x,pb.z, pc.x,pc.z, pd.x,pd.z};
    int pe[8] = {pa.y,pa.w, pb.y,pb.w, pc.y,pc.w, pd.y,pd.w};
    int rn[8], re[8];
    #pragma unroll
    for (int u = 0; u < 8; ++u){
      rn[u] = atomicAdd(&lh[128 + (pn[u] >> 9)], 1);
      re[u] = atomicAdd(&lh[256 + (pe[u] >> 6)], 1);
    }
    __syncthreads();
    if (tid < 192 && lh[128 + tid]) gb[128 + tid] = atomicAdd(&gcur[128 + tid], lh[128 + tid]);
    __syncthreads();
    #pragma unroll
    for (int u = 0; u < 8; ++u){
      int bn = pn[u] >> 9;
      int pos = gb[128 + bn] + rn[u];
      if (pos < CAP_PN)
        bin_pn[(size_t)bn*CAP_PN + pos] = (u32)pn[u] | ((u32)pe[u] << 16);
      int be = pe[u] >> 6;
      int pos2 = gb[256 + be] + re[u];
      if (pos2 < CAP_PE)
        bin_pe[(size_t)be*CAP_PE + pos2] = (u32)pe[u] | ((u32)pn[u] << 16);
    }
  }
}

// ========== phase B: per-bucket CSR insert (LDS cursors, windowed u16 writes).
// blocks [0,128) edge-dst, [128,256) pn, [256,320) pe ==========
__global__ __launch_bounds__(256) void k_csr(const int* __restrict__ gcur,
    const u32* __restrict__ bin_e, const u32* __restrict__ bin_pn,
    const u32* __restrict__ bin_pe,
    int* __restrict__ cnt_dst, u16* __restrict__ csr_dst,
    int* __restrict__ cnt_pn, u16* __restrict__ csr_pn,
    int* __restrict__ cnt_pe, u16* __restrict__ csr_pe)
{
  const int tid = threadIdx.x;
  if (blockIdx.x < 256){
    __shared__ int cur[512];
    const int isP = blockIdx.x >= 128;
    const int b = blockIdx.x & 127;
    cur[tid] = 0; cur[tid + 256] = 0;
    __syncthreads();
    const int n0 = b*512;
    const int cap = isP ? CAP_PN : CAP_E;
    int raw = gcur[isP ? 128 + b : b];
    int count = raw < cap ? raw : cap;
    const u32* bin = (isP ? bin_pn : bin_e) + (size_t)b*cap;
    u16* csr = isP ? csr_pn : csr_dst;
    for (int i = tid; i < count; i += 256){
      u32 v = bin[i];
      int row = v & 0xffff, val = v >> 16;
      int c = atomicAdd(&cur[row - n0], 1);
      if (c < SLOT_N) csr[(size_t)row*SLOT_N + c] = (u16)val;
    }
    __syncthreads();
    int* cnt = isP ? cnt_pn : cnt_dst;
    cnt[n0 + tid]       = cur[tid];
    cnt[n0 + 256 + tid] = cur[tid + 256];
  } else {
    __shared__ int cur[64];
    const int b = blockIdx.x - 256;
    if (tid < 64) cur[tid] = 0;
    __syncthreads();
    const int e0 = b*64;
    int raw = gcur[256 + b];
    int count = raw < CAP_PE ? raw : CAP_PE;
    const u32* bin = bin_pe + (size_t)b*CAP_PE;
    for (int i = tid; i < count; i += 256){
      u32 v = bin[i];
      int row = v & 0xffff, val = v >> 16;
      int c = atomicAdd(&cur[row - e0], 1);
      if (c < SLOT_E) csr_pe[(size_t)row*SLOT_E + c] = (u16)val;
    }
    __syncthreads();
    if (tid < 64) cnt_pe[e0 + tid] = cur[tid];
  }
}

// ========== nfr16 = f16(nfr * rsqrt(max(du,1))) ==========
__global__ __launch_bounds__(256) void k_pre(const float* __restrict__ nfr,
    const int* __restrict__ du, f16* __restrict__ out)
{
  int i = blockIdx.x*256 + threadIdx.x;         // NNODE*64
  int node = i >> 6, j = i & 63;
  float ds = rsqrtf(fmaxf((float)du[node], 1.f));
  float2 v = ((const float2*)(nfr + (size_t)node*128))[j];
  f16x2 o = { (f16)(v.x*ds), (f16)(v.y*ds) };
  ((f16x2*)(out + (size_t)node*128))[j] = o;
}

// ========== gconv gather (f16 src): agg16[d] = f16(sum src16[s]), 4 nodes/wave,
// j-loop unrolled x2 -> 8 outstanding loads/wave ==========
__global__ __launch_bounds__(256) void k_gagg16(const int* __restrict__ cnt,
    const u16* __restrict__ csr, const f16* __restrict__ src, f16* __restrict__ agg)
{
  int blk  = blockIdx.x;                        // NNODE/16 blocks, XCD swizzle
  int wv = threadIdx.x >> 6, lane = threadIdx.x & 63;
  int n0 = (blk & 7)*NPER + (blk >> 3)*16 + wv*4;
  const f16x2* s2 = (const f16x2*)src;
  int c[4]; const u16* r[4];
  float ax[4] = {0,0,0,0}, ay[4] = {0,0,0,0};
  #pragma unroll
  for (int u = 0; u < 4; ++u){
    int nd = cnt[n0+u];
    c[u] = nd < SLOT_N ? nd : SLOT_N;
    r[u] = csr + (size_t)(n0+u)*SLOT_N;
  }
  int m = c[0];
  #pragma unroll
  for (int u = 1; u < 4; ++u) m = c[u] > m ? c[u] : m;
  int j = 0;
  for (; j + 1 < m; j += 2){
    #pragma unroll
    for (int u = 0; u < 4; ++u){
      float bx = 0.f, by = 0.f;
      if (j < c[u]){
        f16x2 v = s2[(size_t)r[u][j]*64 + lane];
        bx = (float)v.x; by = (float)v.y;
      }
      if (j + 1 < c[u]){
        f16x2 v = s2[(size_t)r[u][j+1]*64 + lane];
        bx += (float)v.x; by += (float)v.y;
      }
      ax[u] += bx; ay[u] += by;
    }
  }
  if (j < m){
    #pragma unroll
    for (int u = 0; u < 4; ++u){
      if (j < c[u]){
        f16x2 v = s2[(size_t)r[u][j]*64 + lane];
        ax[u] += (float)v.x; ay[u] += (float)v.y;
      }
    }
  }
  #pragma unroll
  for (int u = 0; u < 4; ++u)
    ((f16x2*)(agg + (size_t)(n0+u)*128))[lane] = (f16x2){ (f16)ax[u], (f16)ay[u] };
}

// ========== hconv stage 1 (f16 source): ef0[e] = (1/|e|) * sum src16[pn].
// 1 wave per hyperedge (4/block), 8-deep unrolled gather -> 8 loads in flight ==========
__global__ __launch_bounds__(256) void k_hea16(const int* __restrict__ cnt,
    const u16* __restrict__ csr, const f16* __restrict__ src, float* __restrict__ ef)
{
  const int wv = threadIdx.x >> 6, lane = threadIdx.x & 63;
  const int e = blockIdx.x*4 + wv;
  const int nd = cnt[e];
  const int n = nd < SLOT_E ? nd : SLOT_E;
  const u16* row = csr + (size_t)e*SLOT_E;
  const f16x2* s2 = (const f16x2*)src;
  float ax = 0.f, ay = 0.f;
  int j = 0;
  for (; j + 7 < n; j += 8){
    int p0 = row[j],   p1 = row[j+1], p2 = row[j+2], p3 = row[j+3];
    int p4 = row[j+4], p5 = row[j+5], p6 = row[j+6], p7 = row[j+7];
    f16x2 v0 = s2[(size_t)p0*64 + lane];
    f16x2 v1 = s2[(size_t)p1*64 + lane];
    f16x2 v2 = s2[(size_t)p2*64 + lane];
    f16x2 v3 = s2[(size_t)p3*64 + lane];
    f16x2 v4 = s2[(size_t)p4*64 + lane];
    f16x2 v5 = s2[(size_t)p5*64 + lane];
    f16x2 v6 = s2[(size_t)p6*64 + lane];
    f16x2 v7 = s2[(size_t)p7*64 + lane];
    ax += (((float)v0.x + (float)v1.x) + ((float)v2.x + (float)v3.x))
        + (((float)v4.x + (float)v5.x) + ((float)v6.x + (float)v7.x));
    ay += (((float)v0.y + (float)v1.y) + ((float)v2.y + (float)v3.y))
        + (((float)v4.y + (float)v5.y) + ((float)v6.y + (float)v7.y));
  }
  for (; j < n; ++j){
    f16x2 v = s2[(size_t)row[j]*64 + lane];
    ax += (float)v.x; ay += (float)v.y;
  }
  float s = nd > 0 ? 1.f/(float)nd : 0.f;
  ((float2*)(ef + (size_t)e*128))[lane] = make_float2(ax*s, ay*s);
}

// ========== register-blocked 128x128 GEMM.  IN16: input rows are f16.
// MODE 0: f32 raw  MODE 1: f16(acc*rsqrt(max(cnt,1))+bias)  MODE 2: f16(relu(acc+bias))
// MODE 3: f16 raw ==========
template<int MODE, int IN16>
__global__ __launch_bounds__(256, 2) void k_gemm(const void* __restrict__ inp,
    const float* __restrict__ W, const int* __restrict__ cnt,
    const float* __restrict__ bias, void* __restrict__ outp)
{
  __shared__ float Wl[128*128];
  __shared__ float Rl[32*128];
  const int tid = threadIdx.x;
  const int rbase = blockIdx.x*32;
  for (int i = tid; i < 16384; i += 256) Wl[i] = W[i];
  if (IN16){
    const f16x2* s2 = (const f16x2*)(((const f16*)inp) + (size_t)rbase*128);
    for (int i = tid; i < 2048; i += 256){
      f16x2 v = s2[i];
      ((float2*)Rl)[i] = make_float2((float)v.x, (float)v.y);
    }
  } else {
    const float* src = ((const float*)inp) + (size_t)rbase*128;
    for (int i = tid; i < 4096; i += 256) Rl[i] = src[i];
  }
  __syncthreads();
  const int c0 = (tid & 31)*4;
  const int r0 = (tid >> 5)*4;
  f32x4 acc[4];
  #pragma unroll
  for (int j = 0; j < 4; ++j) acc[j] = (f32x4){0.f,0.f,0.f,0.f};
  for (int d = 0; d < 128; d += 4){
    f32x4 w0 = *(const f32x4*)&Wl[(d+0)*128 + c0];
    f32x4 w1 = *(const f32x4*)&Wl[(d+1)*128 + c0];
    f32x4 w2 = *(const f32x4*)&Wl[(d+2)*128 + c0];
    f32x4 w3 = *(const f32x4*)&Wl[(d+3)*128 + c0];
    #pragma unroll
    for (int j = 0; j < 4; ++j){
      f32x4 rr = *(const f32x4*)&Rl[(r0+j)*128 + d];
      acc[j] += rr.x*w0 + rr.y*w1 + rr.z*w2 + rr.w*w3;
    }
  }
  #pragma unroll
  for (int j = 0; j < 4; ++j){
    const int row = rbase + r0 + j;
    if (MODE == 0){
      *(f32x4*)(((float*)outp) + (size_t)row*128 + c0) = acc[j];
    } else if (MODE == 1){
      float sc = rsqrtf(fmaxf((float)cnt[row], 1.f));
      f16* o = ((f16*)outp) + (size_t)row*128 + c0;
      #pragma unroll
      for (int k = 0; k < 4; ++k) o[k] = (f16)(acc[j][k]*sc + bias[c0+k]);
    } else if (MODE == 2){
      f16* o = ((f16*)outp) + (size_t)row*128 + c0;
      #pragma unroll
      for (int k = 0; k < 4; ++k) o[k] = (f16)fmaxf(acc[j][k] + bias[c0+k], 0.f);
    } else {
      f16* o = ((f16*)outp) + (size_t)row*128 + c0;
      #pragma unroll
      for (int k = 0; k < 4; ++k) o[k] = (f16)acc[j][k];
    }
  }
}

// ========== hconv stage 2 + relu + residual, 4 nodes/wave, f16 ef source,
// j-loop unrolled x2 -> 8 outstanding loads/wave.  f16 out.
// PRES: scale by rsqrt(du) (for next layer's prescaled input) ==========
template<int PRES>
__global__ __launch_bounds__(256) void k_nha(const int* __restrict__ cnt,
    const u16* __restrict__ csr, const f16* __restrict__ ef,
    const float* __restrict__ bias, const float* __restrict__ nfr,
    const int* __restrict__ du, f16* __restrict__ outp)
{
  int wv = threadIdx.x >> 6, lane = threadIdx.x & 63;
  int n0 = blockIdx.x*16 + wv*4;
  const f16x2* s2 = (const f16x2*)ef;
  int dcnt[4], c[4]; const u16* r[4];
  float ax[4] = {0,0,0,0}, ay[4] = {0,0,0,0};
  #pragma unroll
  for (int u = 0; u < 4; ++u){
    dcnt[u] = cnt[n0+u];
    c[u] = dcnt[u] < SLOT_N ? dcnt[u] : SLOT_N;
    r[u] = csr + (size_t)(n0+u)*SLOT_N;
  }
  int m = c[0];
  #pragma unroll
  for (int u = 1; u < 4; ++u) m = c[u] > m ? c[u] : m;
  int j = 0;
  for (; j + 1 < m; j += 2){
    #pragma unroll
    for (int u = 0; u < 4; ++u){
      float bx = 0.f, by = 0.f;
      if (j < c[u]){
        f16x2 v = s2[(size_t)r[u][j]*64 + lane];
        bx = (float)v.x; by = (float)v.y;
      }
      if (j + 1 < c[u]){
        f16x2 v = s2[(size_t)r[u][j+1]*64 + lane];
        bx += (float)v.x; by += (float)v.y;
      }
      ax[u] += bx; ay[u] += by;
    }
  }
  if (j < m){
    #pragma unroll
    for (int u = 0; u < 4; ++u){
      if (j < c[u]){
        f16x2 v = s2[(size_t)r[u][j]*64 + lane];
        ax[u] += (float)v.x; ay[u] += (float)v.y;
      }
    }
  }
  float bx = bias[lane*2], by = bias[lane*2+1];
  #pragma unroll
  for (int u = 0; u < 4; ++u){
    float s = dcnt[u] > 0 ? 1.f/(float)dcnt[u] : 0.f;
    float2 nf = ((const float2*)(nfr + (size_t)(n0+u)*128))[lane];
    float vx = fmaxf(ax[u]*s + bx, 0.f) + nf.x;
    float vy = fmaxf(ay[u]*s + by, 0.f) + nf.y;
    float e0 = PRES ? rsqrtf(fmaxf((float)du[n0+u], 1.f)) : 1.f;
    ((f16x2*)(outp + (size_t)(n0+u)*128))[lane] = (f16x2){ (f16)(vx*e0), (f16)(vy*e0) };
  }
}

// ========== q = f16(relu(x @ Wm + bm)), K=512 in 4 LDS chunks ==========
__global__ __launch_bounds__(256) void k_qgemm(const float* __restrict__ x,
    const float* __restrict__ Wm, const float* __restrict__ bm, f16* __restrict__ q)
{
  __shared__ float Wl[128*128];
  const int c = threadIdx.x & 127, rh = threadIdx.x >> 7;
  const int base = blockIdx.x*16 + rh*8;
  float acc[8] = {0,0,0,0,0,0,0,0};
  for (int kc = 0; kc < 4; ++kc){
    __syncthreads();
    for (int i = threadIdx.x; i < 128*128; i += 256) Wl[i] = Wm[kc*128*128 + i];
    __syncthreads();
    #pragma unroll
    for (int r = 0; r < 8; ++r){
      const float* xr = x + (size_t)(base+r)*512 + kc*128;
      float a0=0.f,a1=0.f,a2=0.f,a3=0.f;
      #pragma unroll
      for (int d = 0; d < 128; d += 4){
        a0 += xr[d+0] * Wl[(d+0)*128 + c];
        a1 += xr[d+1] * Wl[(d+1)*128 + c];
        a2 += xr[d+2] * Wl[(d+2)*128 + c];
        a3 += xr[d+3] * Wl[(d+3)*128 + c];
      }
      acc[r] += (a0+a1)+(a2+a3);
    }
  }
  float bv = bm[c];
  #pragma unroll
  for (int r = 0; r < 8; ++r)
    q[(size_t)(base+r)*128 + c] = (f16)fmaxf(acc[r]+bv, 0.f);
}

// ========== gT[b][c][n] = h16[b*NPER+n][c]  (f16 transpose) ==========
__global__ __launch_bounds__(256) void k_gt(const f16* __restrict__ g, f16* __restrict__ gT)
{
  __shared__ f16 t[64][66];
  int b = blockIdx.z, n0 = blockIdx.x*64, c0 = blockIdx.y*64;
  for (int i = threadIdx.x; i < 64*64; i += 256){
    int n = i >> 6, c = i & 63;
    t[n][c] = g[((size_t)(b*NPER + n0 + n))*128 + c0 + c];
  }
  __syncthreads();
  for (int i = threadIdx.x; i < 64*64; i += 256){
    int c = i >> 6, n = i & 63;
    gT[((size_t)(b*128 + c0 + c))*NPER + n0 + n] = t[n][c];
  }
}

// ========== flash attention (R6): 128 q-rows/block (8 waves), n-slab 512, n-chunk 64,
// cooperative XOR-swizzled LDS staging, register prefetch, f16 Opart.
// 48 KB LDS, launch_bounds(512,4) -> 2 blocks/CU, 128 VGPR cap. ==========
#define NCH 64
__global__ __launch_bounds__(512, 4) void k_flash(const f16* __restrict__ qb,
    const f16* __restrict__ kb, const f16* __restrict__ gT,
    f16* __restrict__ Opart, float* __restrict__ mZ)
{
  __shared__ f16 Kl[64*128];        // 16 KB  [n 64][k 128], chunk-swizzled
  __shared__ f16 Vl[128*64];        // 16 KB  [d 128][n 64], chunk-swizzled
  __shared__ f16 Pl[8*16*64];       // 16 KB  per-wave [q 16][n 64], chunk-swizzled
  const int sp = blockIdx.x, l0 = blockIdx.y*128, b = blockIdx.z;
  const int tid = threadIdx.x;
  const int w = tid >> 6, lane = tid & 63;
  const int quad = lane >> 4, col = lane & 15;
  const int koff = quad*8;
  // staging lane mapping (512 threads)
  const int krow = tid >> 4;        // K: rows 0..31 (+32), chunks 0..15
  const int kc8  = tid & 15;
  const int vrow = tid >> 3;        // V: rows 0..63 (+64), chunks 0..7
  const int vc8  = tid & 7;

  const f16* qrow = qb + ((size_t)(b*LQ + l0 + w*16 + col))*128 + koff;
  f16x8 aq[4];
  #pragma unroll
  for (int ks = 0; ks < 4; ++ks) aq[ks] = *(const f16x8*)(qrow + ks*32);
  float mrun[4] = {-1e30f,-1e30f,-1e30f,-1e30f};
  float zrun[4] = {0.f,0.f,0.f,0.f};
  f32x4 O[8];
  #pragma unroll
  for (int i = 0; i < 8; ++i) O[i] = (f32x4){0.f,0.f,0.f,0.f};

  const int nbase = sp*(NPER/NSPLIT);          // 512-wide n slab
  f16x8 kr[2], vr[2];
#define LOADKV(N0)                                                           \
  { _Pragma("unroll")                                                        \
    for (int i2 = 0; i2 < 2; ++i2){                                          \
      kr[i2] = *(const f16x8*)(kb + ((size_t)(b*NPER + (N0) + krow + i2*32))*128 + kc8*8); \
      vr[i2] = *(const f16x8*)(gT + ((size_t)(b*128 + vrow + i2*64))*NPER + (N0) + vc8*8); \
    } }
  LOADKV(nbase);
  #pragma unroll 1
  for (int it = 0; it < (NPER/NSPLIT)/NCH; ++it){
    const int n0 = nbase + it*NCH;
    __syncthreads();                            // prior-iter LDS reads done
    #pragma unroll
    for (int i2 = 0; i2 < 2; ++i2){
      int r = krow + i2*32;
      *(f16x8*)&Kl[r*128 + ((kc8 ^ (r & 7))*8)] = kr[i2];
      int d = vrow + i2*64;
      *(f16x8*)&Vl[d*64  + ((vc8 ^ (d & 7))*8)] = vr[i2];
    }
    __syncthreads();                            // staging visible
    if (it < (NPER/NSPLIT)/NCH - 1) LOADKV(n0 + NCH);   // prefetch next tile

    // ---- QK^T from LDS ----
    f32x4 st[4];
    #pragma unroll
    for (int t = 0; t < 4; ++t){
      st[t] = (f32x4){0.f,0.f,0.f,0.f};
      const int r = t*16 + col, rs = r & 7;
      #pragma unroll
      for (int ks = 0; ks < 4; ++ks){
        f16x8 bf = *(const f16x8*)&Kl[r*128 + (((ks*4 + quad) ^ rs)*8)];
        st[t] = __builtin_amdgcn_mfma_f32_16x16x32_f16(aq[ks], bf, st[t], 0, 0, 0);
      }
    }
    // ---- softmax over 64 n ----
    float alr[4];
    #pragma unroll
    for (int r = 0; r < 4; ++r){
      float rm = st[0][r];
      #pragma unroll
      for (int t = 1; t < 4; ++t) rm = fmaxf(rm, st[t][r]);
      rm = fmaxf(rm, __shfl_xor(rm, 1));
      rm = fmaxf(rm, __shfl_xor(rm, 2));
      rm = fmaxf(rm, __shfl_xor(rm, 4));
      rm = fmaxf(rm, __shfl_xor(rm, 8));
      float mn = fmaxf(mrun[r], rm);
      float al = __expf(mrun[r] - mn);
      float ps[4], rsum = 0.f;
      #pragma unroll
      for (int t = 0; t < 4; ++t){ ps[t] = __expf(st[t][r] - mn); rsum += ps[t]; }
      rsum += __shfl_xor(rsum, 1);
      rsum += __shfl_xor(rsum, 2);
      rsum += __shfl_xor(rsum, 4);
      rsum += __shfl_xor(rsum, 8);
      zrun[r] = zrun[r]*al + rsum;
      mrun[r] = mn;
      alr[r] = al;
      const int prow = quad*4 + r, pswz = prow & 7;
      #pragma unroll
      for (int t = 0; t < 4; ++t)
        Pl[w*1024 + prow*64 + (((t*2 + (col >> 3)) ^ pswz)*8) + (col & 7)] = (f16)ps[t];
    }
    #pragma unroll
    for (int dt = 0; dt < 8; ++dt)
      #pragma unroll
      for (int r = 0; r < 4; ++r) O[dt][r] *= alr[r];
    __builtin_amdgcn_wave_barrier();
    // ---- PV from LDS ----
    #pragma unroll
    for (int kk = 0; kk < 2; ++kk){
      f16x8 ap = *(const f16x8*)&Pl[w*1024 + col*64 + (((kk*4 + quad) ^ (col & 7))*8)];
      #pragma unroll
      for (int dt = 0; dt < 8; ++dt){
        const int d = col + dt*16;
        f16x8 bv = *(const f16x8*)&Vl[d*64 + (((kk*4 + quad) ^ (d & 7))*8)];
        O[dt] = __builtin_amdgcn_mfma_f32_16x16x32_f16(ap, bv, O[dt], 0, 0, 0);
      }
    }
    __builtin_amdgcn_wave_barrier();
  }
#undef LOADKV
  const int growb = b*LQ + l0 + w*16 + quad*4;
  #pragma unroll
  for (int r = 0; r < 4; ++r){
    f16* od = Opart + ((size_t)sp*NROW + growb + r)*128 + col;
    #pragma unroll
    for (int dt = 0; dt < 8; ++dt) od[dt*16] = (f16)O[dt][r];
  }
  if (col == 0){
    #pragma unroll
    for (int r = 0; r < 4; ++r){
      ((float2*)mZ)[(size_t)sp*NROW + growb + r] = make_float2(mrun[r], zrun[r]);
    }
  }
}

// ========== combine splits (f16 partials) -> cat16 H columns [512,640) ==========
__global__ __launch_bounds__(256) void k_comb(const f16* __restrict__ Opart,
    const float* __restrict__ mZ, f16* __restrict__ cat)
{
  int i = blockIdx.x*256 + threadIdx.x;         // NROW*64
  int row = i >> 6, d2 = (i & 63)*2;
  float ms[NSPLIT], zs[NSPLIT];
  float M = -1e30f;
  #pragma unroll
  for (int s = 0; s < NSPLIT; ++s){
    float2 v = ((const float2*)mZ)[(size_t)s*NROW + row];
    ms[s] = v.x; zs[s] = v.y;
    M = fmaxf(M, v.x);
  }
  float Zt = 0.f, ax = 0.f, ay = 0.f;
  #pragma unroll
  for (int s = 0; s < NSPLIT; ++s){
    float e = __expf(ms[s] - M);
    Zt += zs[s]*e;
    f16x2 op = *(const f16x2*)(Opart + ((size_t)s*NROW + row)*128 + d2);
    ax += e*(float)op.x; ay += e*(float)op.y;
  }
  float inv = 1.f/Zt;
  f16x2 o = { (f16)(ax*inv), (f16)(ay*inv) };
  *(f16x2*)(cat + (size_t)row*640 + 512 + d2) = o;
}

// ========== prep for final MFMA GEMM: cat16 x-part + W^T f16.
// blocks [0,2048): x f32 -> cat16 cols [0,512).  [2048,2208): w16[n][k] = W[k][n]. ==========
__global__ __launch_bounds__(256) void k_prep(const float* __restrict__ x,
    const float* __restrict__ Wsg, const float* __restrict__ Wtn,
    f16* __restrict__ cat, f16* __restrict__ w16)
{
  if (blockIdx.x < 2048){
    int id = blockIdx.x*256 + threadIdx.x;     // 524288 = 4096 rows * 128 quads
    int row = id >> 7, c4 = (id & 127)*4;
    float4 v = *(const float4*)(x + (size_t)row*512 + c4);
    f16x4 o = { (f16)v.x, (f16)v.y, (f16)v.z, (f16)v.w };
    *(f16x4*)(cat + (size_t)row*640 + c4) = o;
  } else {
    int id = (blockIdx.x - 2048)*256 + threadIdx.x;   // 40960 = 256 n * 160 k-quads
    int n = id / 160;
    int k0 = (id - n*160)*4;
    const float* src = n < 128 ? (Wsg + n) : (Wtn + (n - 128));
    f16x4 o = { (f16)src[(k0+0)*128], (f16)src[(k0+1)*128],
                (f16)src[(k0+2)*128], (f16)src[(k0+3)*128] };
    *(f16x4*)(w16 + (size_t)n*640 + k0) = o;
  }
}

// ========== final MFMA GEMM: out[4096][256] = act(cat16 @ w16^T + bias).
// 1 wave per 16 rows, 16 n-tiles, K=640 in 20 mfma steps. n<128: sigmoid, else tanh ==========
__global__ __launch_bounds__(64) void k_fin2(const f16* __restrict__ cat,
    const f16* __restrict__ w16, const float* __restrict__ bsg,
    const float* __restrict__ btn, float* __restrict__ out)
{
  const int lane = threadIdx.x;
  const int quad = lane >> 4, col = lane & 15;
  const int koff = quad*8;
  const int row0 = blockIdx.x * 16;
  const f16* ar = cat + (size_t)(row0 + col)*640 + koff;
  const f16* br = w16 + (size_t)col*640 + koff;
  f32x4 acc[16];
  #pragma unroll
  for (int nt = 0; nt < 16; ++nt) acc[nt] = (f32x4){0.f,0.f,0.f,0.f};
  for (int ks = 0; ks < 20; ++ks){
    f16x8 a = *(const f16x8*)(ar + ks*32);
    #pragma unroll
    for (int nt = 0; nt < 16; ++nt){
      f16x8 b = *(const f16x8*)(br + (size_t)nt*16*640 + ks*32);
      acc[nt] = __builtin_amdgcn_mfma_f32_16x16x32_f16(a, b, acc[nt], 0, 0, 0);
    }
  }
  #pragma unroll
  for (int nt = 0; nt < 16; ++nt){
    int n = nt*16 + col;
    float bv = n < 128 ? bsg[n] : btn[n - 128];
    #pragma unroll
    for (int r = 0; r < 4; ++r){
      float v = acc[nt][r] + bv;
      v = n < 128 ? 1.f/(1.f + __expf(-v)) : tanhf(v);
      out[(size_t)(row0 + quad*4 + r)*256 + n] = v;
    }
  }
}

extern "C" void kernel_launch(void* const* d_in, const int* in_sizes, int n_in,
                              void* d_out, int out_size, void* d_ws, size_t ws_size,
                              hipStream_t stream)
{
  const float* x    = (const float*)d_in[0];
  const float* nfr  = (const float*)d_in[1];
  const int*   eidx = (const int*)d_in[2];
  const int*   hidx = (const int*)d_in[3];
  const float *Wg1=(const float*)d_in[4],  *bg1=(const float*)d_in[5];
  const float *Wg2=(const float*)d_in[6],  *bg2=(const float*)d_in[7];
  const float *Wh1=(const float*)d_in[8],  *bh1=(const float*)d_in[9];
  const float *Wh2=(const float*)d_in[10], *bh2=(const float*)d_in[11];
  const float *Wm =(const float*)d_in[12], *bm =(const float*)d_in[13];
  const float *Wm2=(const float*)d_in[14], *bm2=(const float*)d_in[15];
  const float *Wsg=(const float*)d_in[16], *bsg=(const float*)d_in[17];
  const float *Wtn=(const float*)d_in[18], *btn=(const float*)d_in[19];
  float* out = (float*)d_out;

  // ---- workspace layout. Aliases:
  //  h4_16 at base; bins + gcur live only until k_csr, alias agg16 region;
  //  cat16/w16 alias agg16 region too (live only in attention phase, after
  //  agg16's last use); Opart f16 (16MB) aliases dead bufA;
  //  kb/gT alias csr_dst/csr_pn. ----
  char* base = (char*)d_ws;
  f16*   h4_16  = (f16*)(base);                          // 16 MB
  f16*   agg16  = (f16*)(base + 33554432);               // 16 MB (graph phase only)
  u32*   bin_e  = (u32*)(base + 33554432);               // 5 MB   (aliases agg16)
  u32*   bin_pn = (u32*)(base + 38797312);               // 5 MB
  u32*   bin_pe = (u32*)(base + 44040192);               // 4.5 MB
  int*   gcur   = (int*)(base + 48758784);               // 1.25 KB
  f16*   cat16  = (f16*)(base + 33554432);               // 5.24 MB (attention phase)
  f16*   w16    = (f16*)(base + 38797312);               // 320 KB  (attention phase)
  f16*   bufA   = (f16*)(base + 67108864);               // 16 MB  (nfr16 / h2_16)
  f16*   bufB   = (f16*)(base + 83886080);               // 16 MB  (h1_16 / h3_16)
  f16*   Opart  = (f16*)(base + 67108864);               // 16 MB f16 (aliases bufA)
  u16*   csr_dst= (u16*)(base + 100663296);              // 8 MB used of 16 MB region
  f16*   kb     = (f16*)(base + 100663296);              //   (aliases csr_dst)
  u16*   csr_pn = (u16*)(base + 117440512);              // 8 MB used of 16 MB region
  f16*   gT     = (f16*)(base + 117440512);              //   (aliases csr_pn)
  u16*   csr_pe = (u16*)(base + 134217728);              // 3 MB used of 6 MB region
  int*   cnt_dst= (int*)(base + 140509184);
  int*   cnt_pn = (int*)(base + 140771328);
  int*   cnt_pe = (int*)(base + 141033472);
  int*   du     = (int*)(base + 141049856);              // 256 KB
  float* ef0    = (float*)(base + 141312000);            // 2 MB
  f16*   ef1    = (f16*)(base + 143409152);              // 1 MB (f16)
  f16*   qb     = (f16*)(base + 145506304);              // 1 MB
  float* mZ     = (float*)(base + 146554880);            // 512 KB (NSPLIT16)
  const size_t needB = (size_t)147079168;
  if (ws_size < needB) return;

  // ---- CSR build: bin (phase A) then per-bucket insert (phase B) ----
  hipMemsetAsync(du, 0, 262144, stream);
  hipMemsetAsync(gcur, 0, 1280, stream);
  k_bin<<<1024, 256, 0, stream>>>(eidx, hidx, du, gcur, bin_e, bin_pn, bin_pe);
  k_csr<<<320, 256, 0, stream>>>(gcur, bin_e, bin_pn, bin_pe,
                                 cnt_dst, csr_dst, cnt_pn, csr_pn, cnt_pe, csr_pe);

  // ---- layer 1 ----
  k_pre<<<NNODE*64/256, 256, 0, stream>>>(nfr, du, bufA);
  k_gagg16<<<NNODE/16, 256, 0, stream>>>(cnt_dst, csr_dst, bufA, agg16);
  k_gemm<1,1><<<NNODE/32, 256, 0, stream>>>(agg16, Wg1, cnt_dst, bg1, bufB);
  k_hea16<<<NHE/4, 256, 0, stream>>>(cnt_pe, csr_pe, bufB, ef0);
  k_gemm<3,0><<<NHE/32, 256, 0, stream>>>(ef0, Wh1, nullptr, nullptr, ef1);
  k_nha<1><<<NNODE/16, 256, 0, stream>>>(cnt_pn, csr_pn, ef1, bh1, nfr, du, bufA);

  // ---- layer 2 ----
  k_gagg16<<<NNODE/16, 256, 0, stream>>>(cnt_dst, csr_dst, bufA, agg16);
  k_gemm<1,1><<<NNODE/32, 256, 0, stream>>>(agg16, Wg2, cnt_dst, bg2, bufB);
  k_hea16<<<NHE/4, 256, 0, stream>>>(cnt_pe, csr_pe, bufB, ef0);
  k_gemm<3,0><<<NHE/32, 256, 0, stream>>>(ef0, Wh2, nullptr, nullptr, ef1);
  k_nha<0><<<NNODE/16, 256, 0, stream>>>(cnt_pn, csr_pn, ef1, bh2, nfr, nullptr, h4_16);

  // ---- attention (agg16/bins dead from here: cat16/w16 safe) ----
  k_prep<<<2208, 256, 0, stream>>>(x, Wsg, Wtn, cat16, w16);
  k_qgemm<<<NROW/16, 256, 0, stream>>>(x, Wm, bm, qb);
  k_gemm<2,1><<<NNODE/32, 256, 0, stream>>>(h4_16, Wm2, nullptr, bm2, kb);
  k_gt<<<dim3(NPER/64, 2, BSZ), 256, 0, stream>>>(h4_16, gT);
  k_flash<<<dim3(NSPLIT, LQ/128, BSZ), 512, 0, stream>>>(qb, kb, gT, Opart, mZ);
  k_comb<<<NROW*64/256, 256, 0, stream>>>(Opart, mZ, cat16);
  k_fin2<<<NROW/16, 64, 0, stream>>>(cat16, w16, bsg, btn, out);

  (void)in_sizes; (void)n_in; (void)out_size;
}

// Round 9
// 701.430 us; speedup vs baseline: 1.7476x; 1.1586x over previous
//
#include <hip/hip_runtime.h>
#include <hip/hip_bf16.h>

#define BSZ   8
#define NPER  8192
#define NNODE 65536       // BSZ*NPER
#define EPG   131072      // edges per graph
#define EMB   128
#define ENCD  512
#define LQ    512
#define NHE   4096
#define NE    1048576
#define NP    1048576
#define NROW  4096        // BSZ*LQ
#define NSPLIT 16
#define SLOT_N 64
#define SLOT_E 384
// binning: 128 node-buckets (512 nodes), 64 he-buckets (64 hyperedges)
#define CAP_E  10240      // per node-bucket capacity, edges  (mean 8192, +22 sigma)
#define CAP_PN 10240      // per node-bucket capacity, pairs  (mean 8192)
#define CAP_PE 18432      // per he-bucket capacity, pairs    (mean 16384, +16 sigma)

typedef _Float16 f16;
typedef _Float16 f16x2 __attribute__((ext_vector_type(2)));
typedef _Float16 f16x4 __attribute__((ext_vector_type(4)));
typedef _Float16 f16x8 __attribute__((ext_vector_type(8)));
typedef float f32x4 __attribute__((ext_vector_type(4)));
typedef unsigned short u16;
typedef unsigned int u32;

// ========== phase A: bin edges (by dst) and pairs (by pn and by pe) into
// contiguous per-bucket arrays; du via global atomics.
// gcur layout: [0,128) edge-dst, [128,256) pn, [256,320) pe ==========
__global__ __launch_bounds__(256) void k_bin(const int* __restrict__ eidx,
    const int* __restrict__ hidx, int* __restrict__ du, int* __restrict__ gcur,
    u32* __restrict__ bin_e, u32* __restrict__ bin_pn, u32* __restrict__ bin_pe)
{
  __shared__ int lh[320];
  __shared__ int gb[320];
  const int tid = threadIdx.x;
  for (int i = tid; i < 320; i += 256) lh[i] = 0;
  __syncthreads();
  if (blockIdx.x < 512){
    // 2048 edges per block
    const int eb4 = blockIdx.x*512;
    int4 sa = ((const int4*)eidx)[eb4 + tid];
    int4 sb = ((const int4*)eidx)[eb4 + 256 + tid];
    int4 da = ((const int4*)(eidx + NE))[eb4 + tid];
    int4 db = ((const int4*)(eidx + NE))[eb4 + 256 + tid];
    int ss[8] = {sa.x,sa.y,sa.z,sa.w, sb.x,sb.y,sb.z,sb.w};
    int dd[8] = {da.x,da.y,da.z,da.w, db.x,db.y,db.z,db.w};
    int rr[8];
    #pragma unroll
    for (int u = 0; u < 8; ++u){
      atomicAdd(&du[ss[u]], 1);
      rr[u] = atomicAdd(&lh[dd[u] >> 9], 1);
    }
    __syncthreads();
    if (tid < 128 && lh[tid]) gb[tid] = atomicAdd(&gcur[tid], lh[tid]);
    __syncthreads();
    #pragma unroll
    for (int u = 0; u < 8; ++u){
      int b = dd[u] >> 9;
      int pos = gb[b] + rr[u];
      if (pos < CAP_E)
        bin_e[(size_t)b*CAP_E + pos] = (u32)(dd[u] & 0xffff) | ((u32)ss[u] << 16);
    }
  } else {
    // 2048 pairs per block, binned both directions
    const int pb4 = (blockIdx.x - 512)*1024;
    int4 pa = ((const int4*)hidx)[pb4 + tid];
    int4 pb = ((const int4*)hidx)[pb4 + 256 + tid];
    int4 pc = ((const int4*)hidx)[pb4 + 512 + tid];
    int4 pd = ((const int4*)hidx)[pb4 + 768 + tid];
    int pn[8] = {pa.x,pa.z, pb.x,pb.z, pc.x,pc.z, pd.x,pd.z};
    int pe[8] = {pa.y,pa.w, pb.y,pb.w, pc.y,pc.w, pd.y,pd.w};
    int rn[8], re[8];
    #pragma unroll
    for (int u = 0; u < 8; ++u){
      rn[u] = atomicAdd(&lh[128 + (pn[u] >> 9)], 1);
      re[u] = atomicAdd(&lh[256 + (pe[u] >> 6)], 1);
    }
    __syncthreads();
    if (tid < 192 && lh[128 + tid]) gb[128 + tid] = atomicAdd(&gcur[128 + tid], lh[128 + tid]);
    __syncthreads();
    #pragma unroll
    for (int u = 0; u < 8; ++u){
      int bn = pn[u] >> 9;
      int pos = gb[128 + bn] + rn[u];
      if (pos < CAP_PN)
        bin_pn[(size_t)bn*CAP_PN + pos] = (u32)pn[u] | ((u32)pe[u] << 16);
      int be = pe[u] >> 6;
      int pos2 = gb[256 + be] + re[u];
      if (pos2 < CAP_PE)
        bin_pe[(size_t)be*CAP_PE + pos2] = (u32)pe[u] | ((u32)pn[u] << 16);
    }
  }
}

// ========== phase B: per-bucket CSR insert (LDS cursors, windowed u16 writes).
// blocks [0,128) edge-dst, [128,256) pn, [256,320) pe ==========
__global__ __launch_bounds__(256) void k_csr(const int* __restrict__ gcur,
    const u32* __restrict__ bin_e, const u32* __restrict__ bin_pn,
    const u32* __restrict__ bin_pe,
    int* __restrict__ cnt_dst, u16* __restrict__ csr_dst,
    int* __restrict__ cnt_pn, u16* __restrict__ csr_pn,
    int* __restrict__ cnt_pe, u16* __restrict__ csr_pe)
{
  const int tid = threadIdx.x;
  if (blockIdx.x < 256){
    __shared__ int cur[512];
    const int isP = blockIdx.x >= 128;
    const int b = blockIdx.x & 127;
    cur[tid] = 0; cur[tid + 256] = 0;
    __syncthreads();
    const int n0 = b*512;
    const int cap = isP ? CAP_PN : CAP_E;
    int raw = gcur[isP ? 128 + b : b];
    int count = raw < cap ? raw : cap;
    const u32* bin = (isP ? bin_pn : bin_e) + (size_t)b*cap;
    u16* csr = isP ? csr_pn : csr_dst;
    for (int i = tid; i < count; i += 256){
      u32 v = bin[i];
      int row = v & 0xffff, val = v >> 16;
      int c = atomicAdd(&cur[row - n0], 1);
      if (c < SLOT_N) csr[(size_t)row*SLOT_N + c] = (u16)val;
    }
    __syncthreads();
    int* cnt = isP ? cnt_pn : cnt_dst;
    cnt[n0 + tid]       = cur[tid];
    cnt[n0 + 256 + tid] = cur[tid + 256];
  } else {
    __shared__ int cur[64];
    const int b = blockIdx.x - 256;
    if (tid < 64) cur[tid] = 0;
    __syncthreads();
    const int e0 = b*64;
    int raw = gcur[256 + b];
    int count = raw < CAP_PE ? raw : CAP_PE;
    const u32* bin = bin_pe + (size_t)b*CAP_PE;
    for (int i = tid; i < count; i += 256){
      u32 v = bin[i];
      int row = v & 0xffff, val = v >> 16;
      int c = atomicAdd(&cur[row - e0], 1);
      if (c < SLOT_E) csr_pe[(size_t)row*SLOT_E + c] = (u16)val;
    }
    __syncthreads();
    if (tid < 64) cnt_pe[e0 + tid] = cur[tid];
  }
}

// ========== nfr16 = f16(nfr * rsqrt(max(du,1))) ==========
__global__ __launch_bounds__(256) void k_pre(const float* __restrict__ nfr,
    const int* __restrict__ du, f16* __restrict__ out)
{
  int i = blockIdx.x*256 + threadIdx.x;         // NNODE*64
  int node = i >> 6, j = i & 63;
  float ds = rsqrtf(fmaxf((float)du[node], 1.f));
  float2 v = ((const float2*)(nfr + (size_t)node*128))[j];
  f16x2 o = { (f16)(v.x*ds), (f16)(v.y*ds) };
  ((f16x2*)(out + (size_t)node*128))[j] = o;
}

// ========== gconv gather (f16 src): 1 wave per node, branchless 8-batches.
// Indices loaded as int4 (8 u16) per batch; masked slots redirect to row[0]
// (hot line) with adds skipped.  Graph->XCD swizzle keeps each graph's
// source slab in one XCD's L2. ==========
__global__ __launch_bounds__(256) void k_gagg16(const int* __restrict__ cnt,
    const u16* __restrict__ csr, const f16* __restrict__ src, f16* __restrict__ agg)
{
  const int wv = threadIdx.x >> 6, lane = threadIdx.x & 63;
  const int blk = blockIdx.x;                   // NNODE/4 blocks
  const int n = (blk & 7)*NPER + (blk >> 3)*4 + wv;
  const int nd = cnt[n];
  const int c = nd < SLOT_N ? nd : SLOT_N;
  const u16* row = csr + (size_t)n*SLOT_N;
  const f16x2* s2 = (const f16x2*)src;
  float ax = 0.f, ay = 0.f;
  if (c > 0){
    const int i0 = row[0];
    #pragma unroll 1
    for (int b = 0; b < 8; ++b){
      if (b*8 >= c) break;                      // wave-uniform
      int4 iv = *(const int4*)(row + b*8);
      int ix[8] = { iv.x & 0xffff, (iv.x >> 16) & 0xffff,
                    iv.y & 0xffff, (iv.y >> 16) & 0xffff,
                    iv.z & 0xffff, (iv.z >> 16) & 0xffff,
                    iv.w & 0xffff, (iv.w >> 16) & 0xffff };
      f16x2 vv[8];
      #pragma unroll
      for (int k = 0; k < 8; ++k){
        int id = (b*8 + k < c) ? ix[k] : i0;
        vv[k] = s2[(size_t)id*64 + lane];
      }
      #pragma unroll
      for (int k = 0; k < 8; ++k){
        if (b*8 + k < c){ ax += (float)vv[k].x; ay += (float)vv[k].y; }
      }
    }
  }
  ((f16x2*)(agg + (size_t)n*128))[lane] = (f16x2){ (f16)ax, (f16)ay };
}

// ========== hconv stage 1 (f16 source): ef0[e] = (1/|e|) * sum src16[pn].
// 1 wave per hyperedge (4/block), 8-deep unrolled gather -> 8 loads in flight ==========
__global__ __launch_bounds__(256) void k_hea16(const int* __restrict__ cnt,
    const u16* __restrict__ csr, const f16* __restrict__ src, float* __restrict__ ef)
{
  const int wv = threadIdx.x >> 6, lane = threadIdx.x & 63;
  const int e = blockIdx.x*4 + wv;
  const int nd = cnt[e];
  const int n = nd < SLOT_E ? nd : SLOT_E;
  const u16* row = csr + (size_t)e*SLOT_E;
  const f16x2* s2 = (const f16x2*)src;
  float ax = 0.f, ay = 0.f;
  int j = 0;
  for (; j + 7 < n; j += 8){
    int p0 = row[j],   p1 = row[j+1], p2 = row[j+2], p3 = row[j+3];
    int p4 = row[j+4], p5 = row[j+5], p6 = row[j+6], p7 = row[j+7];
    f16x2 v0 = s2[(size_t)p0*64 + lane];
    f16x2 v1 = s2[(size_t)p1*64 + lane];
    f16x2 v2 = s2[(size_t)p2*64 + lane];
    f16x2 v3 = s2[(size_t)p3*64 + lane];
    f16x2 v4 = s2[(size_t)p4*64 + lane];
    f16x2 v5 = s2[(size_t)p5*64 + lane];
    f16x2 v6 = s2[(size_t)p6*64 + lane];
    f16x2 v7 = s2[(size_t)p7*64 + lane];
    ax += (((float)v0.x + (float)v1.x) + ((float)v2.x + (float)v3.x))
        + (((float)v4.x + (float)v5.x) + ((float)v6.x + (float)v7.x));
    ay += (((float)v0.y + (float)v1.y) + ((float)v2.y + (float)v3.y))
        + (((float)v4.y + (float)v5.y) + ((float)v6.y + (float)v7.y));
  }
  for (; j < n; ++j){
    f16x2 v = s2[(size_t)row[j]*64 + lane];
    ax += (float)v.x; ay += (float)v.y;
  }
  float s = nd > 0 ? 1.f/(float)nd : 0.f;
  ((float2*)(ef + (size_t)e*128))[lane] = make_float2(ax*s, ay*s);
}

// ========== register-blocked 128x128 GEMM.  IN16: input rows are f16.
// MODE 0: f32 raw  MODE 1: f16(acc*rsqrt(max(cnt,1))+bias)  MODE 2: f16(relu(acc+bias))
// MODE 3: f16 raw ==========
template<int MODE, int IN16>
__global__ __launch_bounds__(256, 2) void k_gemm(const void* __restrict__ inp,
    const float* __restrict__ W, const int* __restrict__ cnt,
    const float* __restrict__ bias, void* __restrict__ outp)
{
  __shared__ float Wl[128*128];
  __shared__ float Rl[32*128];
  const int tid = threadIdx.x;
  const int rbase = blockIdx.x*32;
  for (int i = tid; i < 16384; i += 256) Wl[i] = W[i];
  if (IN16){
    const f16x2* s2 = (const f16x2*)(((const f16*)inp) + (size_t)rbase*128);
    for (int i = tid; i < 2048; i += 256){
      f16x2 v = s2[i];
      ((float2*)Rl)[i] = make_float2((float)v.x, (float)v.y);
    }
  } else {
    const float* src = ((const float*)inp) + (size_t)rbase*128;
    for (int i = tid; i < 4096; i += 256) Rl[i] = src[i];
  }
  __syncthreads();
  const int c0 = (tid & 31)*4;
  const int r0 = (tid >> 5)*4;
  f32x4 acc[4];
  #pragma unroll
  for (int j = 0; j < 4; ++j) acc[j] = (f32x4){0.f,0.f,0.f,0.f};
  for (int d = 0; d < 128; d += 4){
    f32x4 w0 = *(const f32x4*)&Wl[(d+0)*128 + c0];
    f32x4 w1 = *(const f32x4*)&Wl[(d+1)*128 + c0];
    f32x4 w2 = *(const f32x4*)&Wl[(d+2)*128 + c0];
    f32x4 w3 = *(const f32x4*)&Wl[(d+3)*128 + c0];
    #pragma unroll
    for (int j = 0; j < 4; ++j){
      f32x4 rr = *(const f32x4*)&Rl[(r0+j)*128 + d];
      acc[j] += rr.x*w0 + rr.y*w1 + rr.z*w2 + rr.w*w3;
    }
  }
  #pragma unroll
  for (int j = 0; j < 4; ++j){
    const int row = rbase + r0 + j;
    if (MODE == 0){
      *(f32x4*)(((float*)outp) + (size_t)row*128 + c0) = acc[j];
    } else if (MODE == 1){
      float sc = rsqrtf(fmaxf((float)cnt[row], 1.f));
      f16* o = ((f16*)outp) + (size_t)row*128 + c0;
      #pragma unroll
      for (int k = 0; k < 4; ++k) o[k] = (f16)(acc[j][k]*sc + bias[c0+k]);
    } else if (MODE == 2){
      f16* o = ((f16*)outp) + (size_t)row*128 + c0;
      #pragma unroll
      for (int k = 0; k < 4; ++k) o[k] = (f16)fmaxf(acc[j][k] + bias[c0+k], 0.f);
    } else {
      f16* o = ((f16*)outp) + (size_t)row*128 + c0;
      #pragma unroll
      for (int k = 0; k < 4; ++k) o[k] = (f16)acc[j][k];
    }
  }
}

// ========== hconv stage 2 + relu + residual: 1 wave per node, branchless
// 8-batches (int4 index loads, masked adds, row[0] redirect).  f16 ef source,
// early nfr (HBM) load overlaps the gathers.  f16 out.
// PRES: scale by rsqrt(du) (for next layer's prescaled input) ==========
template<int PRES>
__global__ __launch_bounds__(256) void k_nha(const int* __restrict__ cnt,
    const u16* __restrict__ csr, const f16* __restrict__ ef,
    const float* __restrict__ bias, const float* __restrict__ nfr,
    const int* __restrict__ du, f16* __restrict__ outp)
{
  const int wv = threadIdx.x >> 6, lane = threadIdx.x & 63;
  const int n = blockIdx.x*4 + wv;
  const int nd = cnt[n];
  const int c = nd < SLOT_N ? nd : SLOT_N;
  const u16* row = csr + (size_t)n*SLOT_N;
  const f16x2* s2 = (const f16x2*)ef;
  float2 nf = ((const float2*)(nfr + (size_t)n*128))[lane];   // early: hides under gathers
  float e0 = PRES ? rsqrtf(fmaxf((float)du[n], 1.f)) : 1.f;
  float ax = 0.f, ay = 0.f;
  if (c > 0){
    const int i0 = row[0];
    #pragma unroll 1
    for (int b = 0; b < 8; ++b){
      if (b*8 >= c) break;                      // wave-uniform
      int4 iv = *(const int4*)(row + b*8);
      int ix[8] = { iv.x & 0xffff, (iv.x >> 16) & 0xffff,
                    iv.y & 0xffff, (iv.y >> 16) & 0xffff,
                    iv.z & 0xffff, (iv.z >> 16) & 0xffff,
                    iv.w & 0xffff, (iv.w >> 16) & 0xffff };
      f16x2 vv[8];
      #pragma unroll
      for (int k = 0; k < 8; ++k){
        int id = (b*8 + k < c) ? ix[k] : i0;
        vv[k] = s2[(size_t)id*64 + lane];
      }
      #pragma unroll
      for (int k = 0; k < 8; ++k){
        if (b*8 + k < c){ ax += (float)vv[k].x; ay += (float)vv[k].y; }
      }
    }
  }
  float bx = bias[lane*2], by = bias[lane*2+1];
  float s = nd > 0 ? 1.f/(float)nd : 0.f;
  float vx = fmaxf(ax*s + bx, 0.f) + nf.x;
  float vy = fmaxf(ay*s + by, 0.f) + nf.y;
  ((f16x2*)(outp + (size_t)n*128))[lane] = (f16x2){ (f16)(vx*e0), (f16)(vy*e0) };
}

// ========== q = f16(relu(x @ Wm + bm)), K=512 in 4 LDS chunks ==========
__global__ __launch_bounds__(256) void k_qgemm(const float* __restrict__ x,
    const float* __restrict__ Wm, const float* __restrict__ bm, f16* __restrict__ q)
{
  __shared__ float Wl[128*128];
  const int c = threadIdx.x & 127, rh = threadIdx.x >> 7;
  const int base = blockIdx.x*16 + rh*8;
  float acc[8] = {0,0,0,0,0,0,0,0};
  for (int kc = 0; kc < 4; ++kc){
    __syncthreads();
    for (int i = threadIdx.x; i < 128*128; i += 256) Wl[i] = Wm[kc*128*128 + i];
    __syncthreads();
    #pragma unroll
    for (int r = 0; r < 8; ++r){
      const float* xr = x + (size_t)(base+r)*512 + kc*128;
      float a0=0.f,a1=0.f,a2=0.f,a3=0.f;
      #pragma unroll
      for (int d = 0; d < 128; d += 4){
        a0 += xr[d+0] * Wl[(d+0)*128 + c];
        a1 += xr[d+1] * Wl[(d+1)*128 + c];
        a2 += xr[d+2] * Wl[(d+2)*128 + c];
        a3 += xr[d+3] * Wl[(d+3)*128 + c];
      }
      acc[r] += (a0+a1)+(a2+a3);
    }
  }
  float bv = bm[c];
  #pragma unroll
  for (int r = 0; r < 8; ++r)
    q[(size_t)(base+r)*128 + c] = (f16)fmaxf(acc[r]+bv, 0.f);
}

// ========== gT[b][c][n] = h16[b*NPER+n][c]  (f16 transpose) ==========
__global__ __launch_bounds__(256) void k_gt(const f16* __restrict__ g, f16* __restrict__ gT)
{
  __shared__ f16 t[64][66];
  int b = blockIdx.z, n0 = blockIdx.x*64, c0 = blockIdx.y*64;
  for (int i = threadIdx.x; i < 64*64; i += 256){
    int n = i >> 6, c = i & 63;
    t[n][c] = g[((size_t)(b*NPER + n0 + n))*128 + c0 + c];
  }
  __syncthreads();
  for (int i = threadIdx.x; i < 64*64; i += 256){
    int c = i >> 6, n = i & 63;
    gT[((size_t)(b*128 + c0 + c))*NPER + n0 + n] = t[n][c];
  }
}

// ========== flash attention (R6): 128 q-rows/block (8 waves), n-slab 512, n-chunk 64,
// cooperative XOR-swizzled LDS staging, register prefetch, f16 Opart.
// 48 KB LDS, launch_bounds(512,4) -> 2 blocks/CU, 128 VGPR cap. ==========
#define NCH 64
__global__ __launch_bounds__(512, 4) void k_flash(const f16* __restrict__ qb,
    const f16* __restrict__ kb, const f16* __restrict__ gT,
    f16* __restrict__ Opart, float* __restrict__ mZ)
{
  __shared__ f16 Kl[64*128];        // 16 KB  [n 64][k 128], chunk-swizzled
  __shared__ f16 Vl[128*64];        // 16 KB  [d 128][n 64], chunk-swizzled
  __shared__ f16 Pl[8*16*64];       // 16 KB  per-wave [q 16][n 64], chunk-swizzled
  const int sp = blockIdx.x, l0 = blockIdx.y*128, b = blockIdx.z;
  const int tid = threadIdx.x;
  const int w = tid >> 6, lane = tid & 63;
  const int quad = lane >> 4, col = lane & 15;
  const int koff = quad*8;
  // staging lane mapping (512 threads)
  const int krow = tid >> 4;        // K: rows 0..31 (+32), chunks 0..15
  const int kc8  = tid & 15;
  const int vrow = tid >> 3;        // V: rows 0..63 (+64), chunks 0..7
  const int vc8  = tid & 7;

  const f16* qrow = qb + ((size_t)(b*LQ + l0 + w*16 + col))*128 + koff;
  f16x8 aq[4];
  #pragma unroll
  for (int ks = 0; ks < 4; ++ks) aq[ks] = *(const f16x8*)(qrow + ks*32);
  float mrun[4] = {-1e30f,-1e30f,-1e30f,-1e30f};
  float zrun[4] = {0.f,0.f,0.f,0.f};
  f32x4 O[8];
  #pragma unroll
  for (int i = 0; i < 8; ++i) O[i] = (f32x4){0.f,0.f,0.f,0.f};

  const int nbase = sp*(NPER/NSPLIT);          // 512-wide n slab
  f16x8 kr[2], vr[2];
#define LOADKV(N0)                                                           \
  { _Pragma("unroll")                                                        \
    for (int i2 = 0; i2 < 2; ++i2){                                          \
      kr[i2] = *(const f16x8*)(kb + ((size_t)(b*NPER + (N0) + krow + i2*32))*128 + kc8*8); \
      vr[i2] = *(const f16x8*)(gT + ((size_t)(b*128 + vrow + i2*64))*NPER + (N0) + vc8*8); \
    } }
  LOADKV(nbase);
  #pragma unroll 1
  for (int it = 0; it < (NPER/NSPLIT)/NCH; ++it){
    const int n0 = nbase + it*NCH;
    __syncthreads();                            // prior-iter LDS reads done
    #pragma unroll
    for (int i2 = 0; i2 < 2; ++i2){
      int r = krow + i2*32;
      *(f16x8*)&Kl[r*128 + ((kc8 ^ (r & 7))*8)] = kr[i2];
      int d = vrow + i2*64;
      *(f16x8*)&Vl[d*64  + ((vc8 ^ (d & 7))*8)] = vr[i2];
    }
    __syncthreads();                            // staging visible
    if (it < (NPER/NSPLIT)/NCH - 1) LOADKV(n0 + NCH);   // prefetch next tile

    // ---- QK^T from LDS ----
    f32x4 st[4];
    #pragma unroll
    for (int t = 0; t < 4; ++t){
      st[t] = (f32x4){0.f,0.f,0.f,0.f};
      const int r = t*16 + col, rs = r & 7;
      #pragma unroll
      for (int ks = 0; ks < 4; ++ks){
        f16x8 bf = *(const f16x8*)&Kl[r*128 + (((ks*4 + quad) ^ rs)*8)];
        st[t] = __builtin_amdgcn_mfma_f32_16x16x32_f16(aq[ks], bf, st[t], 0, 0, 0);
      }
    }
    // ---- softmax over 64 n ----
    float alr[4];
    #pragma unroll
    for (int r = 0; r < 4; ++r){
      float rm = st[0][r];
      #pragma unroll
      for (int t = 1; t < 4; ++t) rm = fmaxf(rm, st[t][r]);
      rm = fmaxf(rm, __shfl_xor(rm, 1));
      rm = fmaxf(rm, __shfl_xor(rm, 2));
      rm = fmaxf(rm, __shfl_xor(rm, 4));
      rm = fmaxf(rm, __shfl_xor(rm, 8));
      float mn = fmaxf(mrun[r], rm);
      float al = __expf(mrun[r] - mn);
      float ps[4], rsum = 0.f;
      #pragma unroll
      for (int t = 0; t < 4; ++t){ ps[t] = __expf(st[t][r] - mn); rsum += ps[t]; }
      rsum += __shfl_xor(rsum, 1);
      rsum += __shfl_xor(rsum, 2);
      rsum += __shfl_xor(rsum, 4);
      rsum += __shfl_xor(rsum, 8);
      zrun[r] = zrun[r]*al + rsum;
      mrun[r] = mn;
      alr[r] = al;
      const int prow = quad*4 + r, pswz = prow & 7;
      #pragma unroll
      for (int t = 0; t < 4; ++t)
        Pl[w*1024 + prow*64 + (((t*2 + (col >> 3)) ^ pswz)*8) + (col & 7)] = (f16)ps[t];
    }
    #pragma unroll
    for (int dt = 0; dt < 8; ++dt)
      #pragma unroll
      for (int r = 0; r < 4; ++r) O[dt][r] *= alr[r];
    __builtin_amdgcn_wave_barrier();
    // ---- PV from LDS ----
    #pragma unroll
    for (int kk = 0; kk < 2; ++kk){
      f16x8 ap = *(const f16x8*)&Pl[w*1024 + col*64 + (((kk*4 + quad) ^ (col & 7))*8)];
      #pragma unroll
      for (int dt = 0; dt < 8; ++dt){
        const int d = col + dt*16;
        f16x8 bv = *(const f16x8*)&Vl[d*64 + (((kk*4 + quad) ^ (d & 7))*8)];
        O[dt] = __builtin_amdgcn_mfma_f32_16x16x32_f16(ap, bv, O[dt], 0, 0, 0);
      }
    }
    __builtin_amdgcn_wave_barrier();
  }
#undef LOADKV
  const int growb = b*LQ + l0 + w*16 + quad*4;
  #pragma unroll
  for (int r = 0; r < 4; ++r){
    f16* od = Opart + ((size_t)sp*NROW + growb + r)*128 + col;
    #pragma unroll
    for (int dt = 0; dt < 8; ++dt) od[dt*16] = (f16)O[dt][r];
  }
  if (col == 0){
    #pragma unroll
    for (int r = 0; r < 4; ++r){
      ((float2*)mZ)[(size_t)sp*NROW + growb + r] = make_float2(mrun[r], zrun[r]);
    }
  }
}

// ========== combine splits (f16 partials) -> cat16 H columns [512,640) ==========
__global__ __launch_bounds__(256) void k_comb(const f16* __restrict__ Opart,
    const float* __restrict__ mZ, f16* __restrict__ cat)
{
  int i = blockIdx.x*256 + threadIdx.x;         // NROW*64
  int row = i >> 6, d2 = (i & 63)*2;
  float ms[NSPLIT], zs[NSPLIT];
  float M = -1e30f;
  #pragma unroll
  for (int s = 0; s < NSPLIT; ++s){
    float2 v = ((const float2*)mZ)[(size_t)s*NROW + row];
    ms[s] = v.x; zs[s] = v.y;
    M = fmaxf(M, v.x);
  }
  float Zt = 0.f, ax = 0.f, ay = 0.f;
  #pragma unroll
  for (int s = 0; s < NSPLIT; ++s){
    float e = __expf(ms[s] - M);
    Zt += zs[s]*e;
    f16x2 op = *(const f16x2*)(Opart + ((size_t)s*NROW + row)*128 + d2);
    ax += e*(float)op.x; ay += e*(float)op.y;
  }
  float inv = 1.f/Zt;
  f16x2 o = { (f16)(ax*inv), (f16)(ay*inv) };
  *(f16x2*)(cat + (size_t)row*640 + 512 + d2) = o;
}

// ========== prep for final MFMA GEMM: cat16 x-part + W^T f16.
// blocks [0,2048): x f32 -> cat16 cols [0,512).  [2048,2208): w16[n][k] = W[k][n]. ==========
__global__ __launch_bounds__(256) void k_prep(const float* __restrict__ x,
    const float* __restrict__ Wsg, const float* __restrict__ Wtn,
    f16* __restrict__ cat, f16* __restrict__ w16)
{
  if (blockIdx.x < 2048){
    int id = blockIdx.x*256 + threadIdx.x;     // 524288 = 4096 rows * 128 quads
    int row = id >> 7, c4 = (id & 127)*4;
    float4 v = *(const float4*)(x + (size_t)row*512 + c4);
    f16x4 o = { (f16)v.x, (f16)v.y, (f16)v.z, (f16)v.w };
    *(f16x4*)(cat + (size_t)row*640 + c4) = o;
  } else {
    int id = (blockIdx.x - 2048)*256 + threadIdx.x;   // 40960 = 256 n * 160 k-quads
    int n = id / 160;
    int k0 = (id - n*160)*4;
    const float* src = n < 128 ? (Wsg + n) : (Wtn + (n - 128));
    f16x4 o = { (f16)src[(k0+0)*128], (f16)src[(k0+1)*128],
                (f16)src[(k0+2)*128], (f16)src[(k0+3)*128] };
    *(f16x4*)(w16 + (size_t)n*640 + k0) = o;
  }
}

// ========== final MFMA GEMM: out[4096][256] = act(cat16 @ w16^T + bias).
// 1 wave per 16 rows, 16 n-tiles, K=640 in 20 mfma steps. n<128: sigmoid, else tanh ==========
__global__ __launch_bounds__(64) void k_fin2(const f16* __restrict__ cat,
    const f16* __restrict__ w16, const float* __restrict__ bsg,
    const float* __restrict__ btn, float* __restrict__ out)
{
  const int lane = threadIdx.x;
  const int quad = lane >> 4, col = lane & 15;
  const int koff = quad*8;
  const int row0 = blockIdx.x * 16;
  const f16* ar = cat + (size_t)(row0 + col)*640 + koff;
  const f16* br = w16 + (size_t)col*640 + koff;
  f32x4 acc[16];
  #pragma unroll
  for (int nt = 0; nt < 16; ++nt) acc[nt] = (f32x4){0.f,0.f,0.f,0.f};
  for (int ks = 0; ks < 20; ++ks){
    f16x8 a = *(const f16x8*)(ar + ks*32);
    #pragma unroll
    for (int nt = 0; nt < 16; ++nt){
      f16x8 b = *(const f16x8*)(br + (size_t)nt*16*640 + ks*32);
      acc[nt] = __builtin_amdgcn_mfma_f32_16x16x32_f16(a, b, acc[nt], 0, 0, 0);
    }
  }
  #pragma unroll
  for (int nt = 0; nt < 16; ++nt){
    int n = nt*16 + col;
    float bv = n < 128 ? bsg[n] : btn[n - 128];
    #pragma unroll
    for (int r = 0; r < 4; ++r){
      float v = acc[nt][r] + bv;
      v = n < 128 ? 1.f/(1.f + __expf(-v)) : tanhf(v);
      out[(size_t)(row0 + quad*4 + r)*256 + n] = v;
    }
  }
}

extern "C" void kernel_launch(void* const* d_in, const int* in_sizes, int n_in,
                              void* d_out, int out_size, void* d_ws, size_t ws_size,
                              hipStream_t stream)
{
  const float* x    = (const float*)d_in[0];
  const float* nfr  = (const float*)d_in[1];
  const int*   eidx = (const int*)d_in[2];
  const int*   hidx = (const int*)d_in[3];
  const float *Wg1=(const float*)d_in[4],  *bg1=(const float*)d_in[5];
  const float *Wg2=(const float*)d_in[6],  *bg2=(const float*)d_in[7];
  const float *Wh1=(const float*)d_in[8],  *bh1=(const float*)d_in[9];
  const float *Wh2=(const float*)d_in[10], *bh2=(const float*)d_in[11];
  const float *Wm =(const float*)d_in[12], *bm =(const float*)d_in[13];
  const float *Wm2=(const float*)d_in[14], *bm2=(const float*)d_in[15];
  const float *Wsg=(const float*)d_in[16], *bsg=(const float*)d_in[17];
  const float *Wtn=(const float*)d_in[18], *btn=(const float*)d_in[19];
  float* out = (float*)d_out;

  // ---- workspace layout. Aliases:
  //  h4_16 at base; bins + gcur live only until k_csr, alias agg16 region;
  //  cat16/w16 alias agg16 region too (live only in attention phase, after
  //  agg16's last use); Opart f16 (16MB) aliases dead bufA;
  //  kb/gT alias csr_dst/csr_pn. ----
  char* base = (char*)d_ws;
  f16*   h4_16  = (f16*)(base);                          // 16 MB
  f16*   agg16  = (f16*)(base + 33554432);               // 16 MB (graph phase only)
  u32*   bin_e  = (u32*)(base + 33554432);               // 5 MB   (aliases agg16)
  u32*   bin_pn = (u32*)(base + 38797312);               // 5 MB
  u32*   bin_pe = (u32*)(base + 44040192);               // 4.5 MB
  int*   gcur   = (int*)(base + 48758784);               // 1.25 KB
  f16*   cat16  = (f16*)(base + 33554432);               // 5.24 MB (attention phase)
  f16*   w16    = (f16*)(base + 38797312);               // 320 KB  (attention phase)
  f16*   bufA   = (f16*)(base + 67108864);               // 16 MB  (nfr16 / h2_16)
  f16*   bufB   = (f16*)(base + 83886080);               // 16 MB  (h1_16 / h3_16)
  f16*   Opart  = (f16*)(base + 67108864);               // 16 MB f16 (aliases bufA)
  u16*   csr_dst= (u16*)(base + 100663296);              // 8 MB used of 16 MB region
  f16*   kb     = (f16*)(base + 100663296);              //   (aliases csr_dst)
  u16*   csr_pn = (u16*)(base + 117440512);              // 8 MB used of 16 MB region
  f16*   gT     = (f16*)(base + 117440512);              //   (aliases csr_pn)
  u16*   csr_pe = (u16*)(base + 134217728);              // 3 MB used of 6 MB region
  int*   cnt_dst= (int*)(base + 140509184);
  int*   cnt_pn = (int*)(base + 140771328);
  int*   cnt_pe = (int*)(base + 141033472);
  int*   du     = (int*)(base + 141049856);              // 256 KB
  float* ef0    = (float*)(base + 141312000);            // 2 MB
  f16*   ef1    = (f16*)(base + 143409152);              // 1 MB (f16)
  f16*   qb     = (f16*)(base + 145506304);              // 1 MB
  float* mZ     = (float*)(base + 146554880);            // 512 KB (NSPLIT16)
  const size_t needB = (size_t)147079168;
  if (ws_size < needB) return;

  // ---- CSR build: bin (phase A) then per-bucket insert (phase B) ----
  hipMemsetAsync(du, 0, 262144, stream);
  hipMemsetAsync(gcur, 0, 1280, stream);
  k_bin<<<1024, 256, 0, stream>>>(eidx, hidx, du, gcur, bin_e, bin_pn, bin_pe);
  k_csr<<<320, 256, 0, stream>>>(gcur, bin_e, bin_pn, bin_pe,
                                 cnt_dst, csr_dst, cnt_pn, csr_pn, cnt_pe, csr_pe);

  // ---- layer 1 ----
  k_pre<<<NNODE*64/256, 256, 0, stream>>>(nfr, du, bufA);
  k_gagg16<<<NNODE/4, 256, 0, stream>>>(cnt_dst, csr_dst, bufA, agg16);
  k_gemm<1,1><<<NNODE/32, 256, 0, stream>>>(agg16, Wg1, cnt_dst, bg1, bufB);
  k_hea16<<<NHE/4, 256, 0, stream>>>(cnt_pe, csr_pe, bufB, ef0);
  k_gemm<3,0><<<NHE/32, 256, 0, stream>>>(ef0, Wh1, nullptr, nullptr, ef1);
  k_nha<1><<<NNODE/4, 256, 0, stream>>>(cnt_pn, csr_pn, ef1, bh1, nfr, du, bufA);

  // ---- layer 2 ----
  k_gagg16<<<NNODE/4, 256, 0, stream>>>(cnt_dst, csr_dst, bufA, agg16);
  k_gemm<1,1><<<NNODE/32, 256, 0, stream>>>(agg16, Wg2, cnt_dst, bg2, bufB);
  k_hea16<<<NHE/4, 256, 0, stream>>>(cnt_pe, csr_pe, bufB, ef0);
  k_gemm<3,0><<<NHE/32, 256, 0, stream>>>(ef0, Wh2, nullptr, nullptr, ef1);
  k_nha<0><<<NNODE/4, 256, 0, stream>>>(cnt_pn, csr_pn, ef1, bh2, nfr, nullptr, h4_16);

  // ---- attention (agg16/bins dead from here: cat16/w16 safe) ----
  k_prep<<<2208, 256, 0, stream>>>(x, Wsg, Wtn, cat16, w16);
  k_qgemm<<<NROW/16, 256, 0, stream>>>(x, Wm, bm, qb);
  k_gemm<2,1><<<NNODE/32, 256, 0, stream>>>(h4_16, Wm2, nullptr, bm2, kb);
  k_gt<<<dim3(NPER/64, 2, BSZ), 256, 0, stream>>>(h4_16, gT);
  k_flash<<<dim3(NSPLIT, LQ/128, BSZ), 512, 0, stream>>>(qb, kb, gT, Opart, mZ);
  k_comb<<<NROW*64/256, 256, 0, stream>>>(Opart, mZ, cat16);
  k_fin2<<<NROW/16, 64, 0, stream>>>(cat16, w16, bsg, btn, out);

  (void)in_sizes; (void)n_in; (void)out_size;
}

// Round 10
// 647.076 us; speedup vs baseline: 1.8944x; 1.0840x over previous
//
#include <hip/hip_runtime.h>
#include <hip/hip_bf16.h>

#define BSZ   8
#define NPER  8192
#define NNODE 65536       // BSZ*NPER
#define EPG   131072      // edges per graph
#define EMB   128
#define ENCD  512
#define LQ    512
#define NHE   4096
#define NE    1048576
#define NP    1048576
#define NROW  4096        // BSZ*LQ
#define NSPLIT 16
#define SLOT_N 64
#define SLOT_E 384
// binning: 128 node-buckets (512 nodes), 64 he-buckets (64 hyperedges)
#define CAP_E  10240      // per node-bucket capacity, edges  (mean 8192, +22 sigma)
#define CAP_PN 10240      // per node-bucket capacity, pairs  (mean 8192)
#define CAP_PE 18432      // per he-bucket capacity, pairs    (mean 16384, +16 sigma)

typedef _Float16 f16;
typedef _Float16 f16x2 __attribute__((ext_vector_type(2)));
typedef _Float16 f16x4 __attribute__((ext_vector_type(4)));
typedef _Float16 f16x8 __attribute__((ext_vector_type(8)));
typedef float f32x4 __attribute__((ext_vector_type(4)));
typedef unsigned short u16;
typedef unsigned int u32;

// ========== phase A: bin edges (by dst) and pairs (by pn and by pe) into
// contiguous per-bucket arrays; du via global atomics.
// gcur layout: [0,128) edge-dst, [128,256) pn, [256,320) pe ==========
__global__ __launch_bounds__(256) void k_bin(const int* __restrict__ eidx,
    const int* __restrict__ hidx, int* __restrict__ du, int* __restrict__ gcur,
    u32* __restrict__ bin_e, u32* __restrict__ bin_pn, u32* __restrict__ bin_pe)
{
  __shared__ int lh[320];
  __shared__ int gb[320];
  const int tid = threadIdx.x;
  for (int i = tid; i < 320; i += 256) lh[i] = 0;
  __syncthreads();
  if (blockIdx.x < 512){
    // 2048 edges per block
    const int eb4 = blockIdx.x*512;
    int4 sa = ((const int4*)eidx)[eb4 + tid];
    int4 sb = ((const int4*)eidx)[eb4 + 256 + tid];
    int4 da = ((const int4*)(eidx + NE))[eb4 + tid];
    int4 db = ((const int4*)(eidx + NE))[eb4 + 256 + tid];
    int ss[8] = {sa.x,sa.y,sa.z,sa.w, sb.x,sb.y,sb.z,sb.w};
    int dd[8] = {da.x,da.y,da.z,da.w, db.x,db.y,db.z,db.w};
    int rr[8];
    #pragma unroll
    for (int u = 0; u < 8; ++u){
      atomicAdd(&du[ss[u]], 1);
      rr[u] = atomicAdd(&lh[dd[u] >> 9], 1);
    }
    __syncthreads();
    if (tid < 128 && lh[tid]) gb[tid] = atomicAdd(&gcur[tid], lh[tid]);
    __syncthreads();
    #pragma unroll
    for (int u = 0; u < 8; ++u){
      int b = dd[u] >> 9;
      int pos = gb[b] + rr[u];
      if (pos < CAP_E)
        bin_e[(size_t)b*CAP_E + pos] = (u32)(dd[u] & 0xffff) | ((u32)ss[u] << 16);
    }
  } else {
    // 2048 pairs per block, binned both directions
    const int pb4 = (blockIdx.x - 512)*1024;
    int4 pa = ((const int4*)hidx)[pb4 + tid];
    int4 pb = ((const int4*)hidx)[pb4 + 256 + tid];
    int4 pc = ((const int4*)hidx)[pb4 + 512 + tid];
    int4 pd = ((const int4*)hidx)[pb4 + 768 + tid];
    int pn[8] = {pa.x,pa.z, pb.x,pb.z, pc.x,pc.z, pd.x,pd.z};
    int pe[8] = {pa.y,pa.w, pb.y,pb.w, pc.y,pc.w, pd.y,pd.w};
    int rn[8], re[8];
    #pragma unroll
    for (int u = 0; u < 8; ++u){
      rn[u] = atomicAdd(&lh[128 + (pn[u] >> 9)], 1);
      re[u] = atomicAdd(&lh[256 + (pe[u] >> 6)], 1);
    }
    __syncthreads();
    if (tid < 192 && lh[128 + tid]) gb[128 + tid] = atomicAdd(&gcur[128 + tid], lh[128 + tid]);
    __syncthreads();
    #pragma unroll
    for (int u = 0; u < 8; ++u){
      int bn = pn[u] >> 9;
      int pos = gb[128 + bn] + rn[u];
      if (pos < CAP_PN)
        bin_pn[(size_t)bn*CAP_PN + pos] = (u32)pn[u] | ((u32)pe[u] << 16);
      int be = pe[u] >> 6;
      int pos2 = gb[256 + be] + re[u];
      if (pos2 < CAP_PE)
        bin_pe[(size_t)be*CAP_PE + pos2] = (u32)pe[u] | ((u32)pn[u] << 16);
    }
  }
}

// ========== phase B: per-bucket CSR insert (LDS cursors, windowed u16 writes).
// blocks [0,128) edge-dst, [128,256) pn, [256,320) pe ==========
__global__ __launch_bounds__(256) void k_csr(const int* __restrict__ gcur,
    const u32* __restrict__ bin_e, const u32* __restrict__ bin_pn,
    const u32* __restrict__ bin_pe,
    int* __restrict__ cnt_dst, u16* __restrict__ csr_dst,
    int* __restrict__ cnt_pn, u16* __restrict__ csr_pn,
    int* __restrict__ cnt_pe, u16* __restrict__ csr_pe)
{
  const int tid = threadIdx.x;
  if (blockIdx.x < 256){
    __shared__ int cur[512];
    const int isP = blockIdx.x >= 128;
    const int b = blockIdx.x & 127;
    cur[tid] = 0; cur[tid + 256] = 0;
    __syncthreads();
    const int n0 = b*512;
    const int cap = isP ? CAP_PN : CAP_E;
    int raw = gcur[isP ? 128 + b : b];
    int count = raw < cap ? raw : cap;
    const u32* bin = (isP ? bin_pn : bin_e) + (size_t)b*cap;
    u16* csr = isP ? csr_pn : csr_dst;
    for (int i = tid; i < count; i += 256){
      u32 v = bin[i];
      int row = v & 0xffff, val = v >> 16;
      int c = atomicAdd(&cur[row - n0], 1);
      if (c < SLOT_N) csr[(size_t)row*SLOT_N + c] = (u16)val;
    }
    __syncthreads();
    int* cnt = isP ? cnt_pn : cnt_dst;
    cnt[n0 + tid]       = cur[tid];
    cnt[n0 + 256 + tid] = cur[tid + 256];
  } else {
    __shared__ int cur[64];
    const int b = blockIdx.x - 256;
    if (tid < 64) cur[tid] = 0;
    __syncthreads();
    const int e0 = b*64;
    int raw = gcur[256 + b];
    int count = raw < CAP_PE ? raw : CAP_PE;
    const u32* bin = bin_pe + (size_t)b*CAP_PE;
    for (int i = tid; i < count; i += 256){
      u32 v = bin[i];
      int row = v & 0xffff, val = v >> 16;
      int c = atomicAdd(&cur[row - e0], 1);
      if (c < SLOT_E) csr_pe[(size_t)row*SLOT_E + c] = (u16)val;
    }
    __syncthreads();
    if (tid < 64) cnt_pe[e0 + tid] = cur[tid];
  }
}

// ========== nfr16 = f16(nfr * rsqrt(max(du,1))) ==========
__global__ __launch_bounds__(256) void k_pre(const float* __restrict__ nfr,
    const int* __restrict__ du, f16* __restrict__ out)
{
  int i = blockIdx.x*256 + threadIdx.x;         // NNODE*64
  int node = i >> 6, j = i & 63;
  float ds = rsqrtf(fmaxf((float)du[node], 1.f));
  float2 v = ((const float2*)(nfr + (size_t)node*128))[j];
  f16x2 o = { (f16)(v.x*ds), (f16)(v.y*ds) };
  ((f16x2*)(out + (size_t)node*128))[j] = o;
}

// ========== gconv gather (f16 src): 1 wave per node, branchless 8-batches.
// Indices loaded as int4 (8 u16) per batch; masked slots redirect to row[0]
// (hot line) with adds skipped.  Graph->XCD swizzle keeps each graph's
// source slab in one XCD's L2. ==========
__global__ __launch_bounds__(256) void k_gagg16(const int* __restrict__ cnt,
    const u16* __restrict__ csr, const f16* __restrict__ src, f16* __restrict__ agg)
{
  const int wv = threadIdx.x >> 6, lane = threadIdx.x & 63;
  const int blk = blockIdx.x;                   // NNODE/4 blocks
  const int n = (blk & 7)*NPER + (blk >> 3)*4 + wv;
  const int nd = cnt[n];
  const int c = nd < SLOT_N ? nd : SLOT_N;
  const u16* row = csr + (size_t)n*SLOT_N;
  const f16x2* s2 = (const f16x2*)src;
  float ax = 0.f, ay = 0.f;
  if (c > 0){
    const int i0 = row[0];
    #pragma unroll 1
    for (int b = 0; b < 8; ++b){
      if (b*8 >= c) break;                      // wave-uniform
      int4 iv = *(const int4*)(row + b*8);
      int ix[8] = { iv.x & 0xffff, (iv.x >> 16) & 0xffff,
                    iv.y & 0xffff, (iv.y >> 16) & 0xffff,
                    iv.z & 0xffff, (iv.z >> 16) & 0xffff,
                    iv.w & 0xffff, (iv.w >> 16) & 0xffff };
      f16x2 vv[8];
      #pragma unroll
      for (int k = 0; k < 8; ++k){
        int id = (b*8 + k < c) ? ix[k] : i0;
        vv[k] = s2[(size_t)id*64 + lane];
      }
      #pragma unroll
      for (int k = 0; k < 8; ++k){
        if (b*8 + k < c){ ax += (float)vv[k].x; ay += (float)vv[k].y; }
      }
    }
  }
  ((f16x2*)(agg + (size_t)n*128))[lane] = (f16x2){ (f16)ax, (f16)ay };
}

// ========== hconv stage 1 (f16 source): ef0[e] = (1/|e|) * sum src16[pn].
// 1 wave per hyperedge (4/block), 8-deep unrolled gather -> 8 loads in flight ==========
__global__ __launch_bounds__(256) void k_hea16(const int* __restrict__ cnt,
    const u16* __restrict__ csr, const f16* __restrict__ src, float* __restrict__ ef)
{
  const int wv = threadIdx.x >> 6, lane = threadIdx.x & 63;
  const int e = blockIdx.x*4 + wv;
  const int nd = cnt[e];
  const int n = nd < SLOT_E ? nd : SLOT_E;
  const u16* row = csr + (size_t)e*SLOT_E;
  const f16x2* s2 = (const f16x2*)src;
  float ax = 0.f, ay = 0.f;
  int j = 0;
  for (; j + 7 < n; j += 8){
    int p0 = row[j],   p1 = row[j+1], p2 = row[j+2], p3 = row[j+3];
    int p4 = row[j+4], p5 = row[j+5], p6 = row[j+6], p7 = row[j+7];
    f16x2 v0 = s2[(size_t)p0*64 + lane];
    f16x2 v1 = s2[(size_t)p1*64 + lane];
    f16x2 v2 = s2[(size_t)p2*64 + lane];
    f16x2 v3 = s2[(size_t)p3*64 + lane];
    f16x2 v4 = s2[(size_t)p4*64 + lane];
    f16x2 v5 = s2[(size_t)p5*64 + lane];
    f16x2 v6 = s2[(size_t)p6*64 + lane];
    f16x2 v7 = s2[(size_t)p7*64 + lane];
    ax += (((float)v0.x + (float)v1.x) + ((float)v2.x + (float)v3.x))
        + (((float)v4.x + (float)v5.x) + ((float)v6.x + (float)v7.x));
    ay += (((float)v0.y + (float)v1.y) + ((float)v2.y + (float)v3.y))
        + (((float)v4.y + (float)v5.y) + ((float)v6.y + (float)v7.y));
  }
  for (; j < n; ++j){
    f16x2 v = s2[(size_t)row[j]*64 + lane];
    ax += (float)v.x; ay += (float)v.y;
  }
  float s = nd > 0 ? 1.f/(float)nd : 0.f;
  ((float2*)(ef + (size_t)e*128))[lane] = make_float2(ax*s, ay*s);
}

// ========== register-blocked 128x128 GEMM.  IN16: input rows are f16.
// MODE 0: f32 raw  MODE 1: f16(acc*rsqrt(max(cnt,1))+bias)  MODE 2: f16(relu(acc+bias))
// MODE 3: f16 raw ==========
template<int MODE, int IN16>
__global__ __launch_bounds__(256, 2) void k_gemm(const void* __restrict__ inp,
    const float* __restrict__ W, const int* __restrict__ cnt,
    const float* __restrict__ bias, void* __restrict__ outp)
{
  __shared__ float Wl[128*128];
  __shared__ float Rl[32*128];
  const int tid = threadIdx.x;
  const int rbase = blockIdx.x*32;
  for (int i = tid; i < 16384; i += 256) Wl[i] = W[i];
  if (IN16){
    const f16x2* s2 = (const f16x2*)(((const f16*)inp) + (size_t)rbase*128);
    for (int i = tid; i < 2048; i += 256){
      f16x2 v = s2[i];
      ((float2*)Rl)[i] = make_float2((float)v.x, (float)v.y);
    }
  } else {
    const float* src = ((const float*)inp) + (size_t)rbase*128;
    for (int i = tid; i < 4096; i += 256) Rl[i] = src[i];
  }
  __syncthreads();
  const int c0 = (tid & 31)*4;
  const int r0 = (tid >> 5)*4;
  f32x4 acc[4];
  #pragma unroll
  for (int j = 0; j < 4; ++j) acc[j] = (f32x4){0.f,0.f,0.f,0.f};
  for (int d = 0; d < 128; d += 4){
    f32x4 w0 = *(const f32x4*)&Wl[(d+0)*128 + c0];
    f32x4 w1 = *(const f32x4*)&Wl[(d+1)*128 + c0];
    f32x4 w2 = *(const f32x4*)&Wl[(d+2)*128 + c0];
    f32x4 w3 = *(const f32x4*)&Wl[(d+3)*128 + c0];
    #pragma unroll
    for (int j = 0; j < 4; ++j){
      f32x4 rr = *(const f32x4*)&Rl[(r0+j)*128 + d];
      acc[j] += rr.x*w0 + rr.y*w1 + rr.z*w2 + rr.w*w3;
    }
  }
  #pragma unroll
  for (int j = 0; j < 4; ++j){
    const int row = rbase + r0 + j;
    if (MODE == 0){
      *(f32x4*)(((float*)outp) + (size_t)row*128 + c0) = acc[j];
    } else if (MODE == 1){
      float sc = rsqrtf(fmaxf((float)cnt[row], 1.f));
      f16* o = ((f16*)outp) + (size_t)row*128 + c0;
      #pragma unroll
      for (int k = 0; k < 4; ++k) o[k] = (f16)(acc[j][k]*sc + bias[c0+k]);
    } else if (MODE == 2){
      f16* o = ((f16*)outp) + (size_t)row*128 + c0;
      #pragma unroll
      for (int k = 0; k < 4; ++k) o[k] = (f16)fmaxf(acc[j][k] + bias[c0+k], 0.f);
    } else {
      f16* o = ((f16*)outp) + (size_t)row*128 + c0;
      #pragma unroll
      for (int k = 0; k < 4; ++k) o[k] = (f16)acc[j][k];
    }
  }
}

// ========== hconv stage 2 + relu + residual: 1 wave per node, branchless
// 8-batches (int4 index loads, masked adds, row[0] redirect).  f16 ef source,
// early nfr (HBM) load overlaps the gathers.  f16 out.
// PRES: scale by rsqrt(du) (for next layer's prescaled input) ==========
template<int PRES>
__global__ __launch_bounds__(256) void k_nha(const int* __restrict__ cnt,
    const u16* __restrict__ csr, const f16* __restrict__ ef,
    const float* __restrict__ bias, const float* __restrict__ nfr,
    const int* __restrict__ du, f16* __restrict__ outp)
{
  const int wv = threadIdx.x >> 6, lane = threadIdx.x & 63;
  const int n = blockIdx.x*4 + wv;
  const int nd = cnt[n];
  const int c = nd < SLOT_N ? nd : SLOT_N;
  const u16* row = csr + (size_t)n*SLOT_N;
  const f16x2* s2 = (const f16x2*)ef;
  float2 nf = ((const float2*)(nfr + (size_t)n*128))[lane];   // early: hides under gathers
  float e0 = PRES ? rsqrtf(fmaxf((float)du[n], 1.f)) : 1.f;
  float ax = 0.f, ay = 0.f;
  if (c > 0){
    const int i0 = row[0];
    #pragma unroll 1
    for (int b = 0; b < 8; ++b){
      if (b*8 >= c) break;                      // wave-uniform
      int4 iv = *(const int4*)(row + b*8);
      int ix[8] = { iv.x & 0xffff, (iv.x >> 16) & 0xffff,
                    iv.y & 0xffff, (iv.y >> 16) & 0xffff,
                    iv.z & 0xffff, (iv.z >> 16) & 0xffff,
                    iv.w & 0xffff, (iv.w >> 16) & 0xffff };
      f16x2 vv[8];
      #pragma unroll
      for (int k = 0; k < 8; ++k){
        int id = (b*8 + k < c) ? ix[k] : i0;
        vv[k] = s2[(size_t)id*64 + lane];
      }
      #pragma unroll
      for (int k = 0; k < 8; ++k){
        if (b*8 + k < c){ ax += (float)vv[k].x; ay += (float)vv[k].y; }
      }
    }
  }
  float bx = bias[lane*2], by = bias[lane*2+1];
  float s = nd > 0 ? 1.f/(float)nd : 0.f;
  float vx = fmaxf(ax*s + bx, 0.f) + nf.x;
  float vy = fmaxf(ay*s + by, 0.f) + nf.y;
  ((f16x2*)(outp + (size_t)n*128))[lane] = (f16x2){ (f16)(vx*e0), (f16)(vy*e0) };
}

// ========== gT[b][c][n] = h16[b*NPER+n][c]  (f16 transpose) ==========
__global__ __launch_bounds__(256) void k_gt(const f16* __restrict__ g, f16* __restrict__ gT)
{
  __shared__ f16 t[64][66];
  int b = blockIdx.z, n0 = blockIdx.x*64, c0 = blockIdx.y*64;
  for (int i = threadIdx.x; i < 64*64; i += 256){
    int n = i >> 6, c = i & 63;
    t[n][c] = g[((size_t)(b*NPER + n0 + n))*128 + c0 + c];
  }
  __syncthreads();
  for (int i = threadIdx.x; i < 64*64; i += 256){
    int c = i >> 6, n = i & 63;
    gT[((size_t)(b*128 + c0 + c))*NPER + n0 + n] = t[n][c];
  }
}

// ========== flash attention (R6): 128 q-rows/block (8 waves), n-slab 512, n-chunk 64,
// cooperative XOR-swizzled LDS staging, register prefetch, f16 Opart.
// 48 KB LDS, launch_bounds(512,4) -> 2 blocks/CU, 128 VGPR cap. ==========
#define NCH 64
__global__ __launch_bounds__(512, 4) void k_flash(const f16* __restrict__ qb,
    const f16* __restrict__ kb, const f16* __restrict__ gT,
    f16* __restrict__ Opart, float* __restrict__ mZ)
{
  __shared__ f16 Kl[64*128];        // 16 KB  [n 64][k 128], chunk-swizzled
  __shared__ f16 Vl[128*64];        // 16 KB  [d 128][n 64], chunk-swizzled
  __shared__ f16 Pl[8*16*64];       // 16 KB  per-wave [q 16][n 64], chunk-swizzled
  const int sp = blockIdx.x, l0 = blockIdx.y*128, b = blockIdx.z;
  const int tid = threadIdx.x;
  const int w = tid >> 6, lane = tid & 63;
  const int quad = lane >> 4, col = lane & 15;
  const int koff = quad*8;
  // staging lane mapping (512 threads)
  const int krow = tid >> 4;        // K: rows 0..31 (+32), chunks 0..15
  const int kc8  = tid & 15;
  const int vrow = tid >> 3;        // V: rows 0..63 (+64), chunks 0..7
  const int vc8  = tid & 7;

  const f16* qrow = qb + ((size_t)(b*LQ + l0 + w*16 + col))*128 + koff;
  f16x8 aq[4];
  #pragma unroll
  for (int ks = 0; ks < 4; ++ks) aq[ks] = *(const f16x8*)(qrow + ks*32);
  float mrun[4] = {-1e30f,-1e30f,-1e30f,-1e30f};
  float zrun[4] = {0.f,0.f,0.f,0.f};
  f32x4 O[8];
  #pragma unroll
  for (int i = 0; i < 8; ++i) O[i] = (f32x4){0.f,0.f,0.f,0.f};

  const int nbase = sp*(NPER/NSPLIT);          // 512-wide n slab
  f16x8 kr[2], vr[2];
#define LOADKV(N0)                                                           \
  { _Pragma("unroll")                                                        \
    for (int i2 = 0; i2 < 2; ++i2){                                          \
      kr[i2] = *(const f16x8*)(kb + ((size_t)(b*NPER + (N0) + krow + i2*32))*128 + kc8*8); \
      vr[i2] = *(const f16x8*)(gT + ((size_t)(b*128 + vrow + i2*64))*NPER + (N0) + vc8*8); \
    } }
  LOADKV(nbase);
  #pragma unroll 1
  for (int it = 0; it < (NPER/NSPLIT)/NCH; ++it){
    const int n0 = nbase + it*NCH;
    __syncthreads();                            // prior-iter LDS reads done
    #pragma unroll
    for (int i2 = 0; i2 < 2; ++i2){
      int r = krow + i2*32;
      *(f16x8*)&Kl[r*128 + ((kc8 ^ (r & 7))*8)] = kr[i2];
      int d = vrow + i2*64;
      *(f16x8*)&Vl[d*64  + ((vc8 ^ (d & 7))*8)] = vr[i2];
    }
    __syncthreads();                            // staging visible
    if (it < (NPER/NSPLIT)/NCH - 1) LOADKV(n0 + NCH);   // prefetch next tile

    // ---- QK^T from LDS ----
    f32x4 st[4];
    #pragma unroll
    for (int t = 0; t < 4; ++t){
      st[t] = (f32x4){0.f,0.f,0.f,0.f};
      const int r = t*16 + col, rs = r & 7;
      #pragma unroll
      for (int ks = 0; ks < 4; ++ks){
        f16x8 bf = *(const f16x8*)&Kl[r*128 + (((ks*4 + quad) ^ rs)*8)];
        st[t] = __builtin_amdgcn_mfma_f32_16x16x32_f16(aq[ks], bf, st[t], 0, 0, 0);
      }
    }
    // ---- softmax over 64 n ----
    float alr[4];
    #pragma unroll
    for (int r = 0; r < 4; ++r){
      float rm = st[0][r];
      #pragma unroll
      for (int t = 1; t < 4; ++t) rm = fmaxf(rm, st[t][r]);
      rm = fmaxf(rm, __shfl_xor(rm, 1));
      rm = fmaxf(rm, __shfl_xor(rm, 2));
      rm = fmaxf(rm, __shfl_xor(rm, 4));
      rm = fmaxf(rm, __shfl_xor(rm, 8));
      float mn = fmaxf(mrun[r], rm);
      float al = __expf(mrun[r] - mn);
      float ps[4], rsum = 0.f;
      #pragma unroll
      for (int t = 0; t < 4; ++t){ ps[t] = __expf(st[t][r] - mn); rsum += ps[t]; }
      rsum += __shfl_xor(rsum, 1);
      rsum += __shfl_xor(rsum, 2);
      rsum += __shfl_xor(rsum, 4);
      rsum += __shfl_xor(rsum, 8);
      zrun[r] = zrun[r]*al + rsum;
      mrun[r] = mn;
      alr[r] = al;
      const int prow = quad*4 + r, pswz = prow & 7;
      #pragma unroll
      for (int t = 0; t < 4; ++t)
        Pl[w*1024 + prow*64 + (((t*2 + (col >> 3)) ^ pswz)*8) + (col & 7)] = (f16)ps[t];
    }
    #pragma unroll
    for (int dt = 0; dt < 8; ++dt)
      #pragma unroll
      for (int r = 0; r < 4; ++r) O[dt][r] *= alr[r];
    __builtin_amdgcn_wave_barrier();
    // ---- PV from LDS ----
    #pragma unroll
    for (int kk = 0; kk < 2; ++kk){
      f16x8 ap = *(const f16x8*)&Pl[w*1024 + col*64 + (((kk*4 + quad) ^ (col & 7))*8)];
      #pragma unroll
      for (int dt = 0; dt < 8; ++dt){
        const int d = col + dt*16;
        f16x8 bv = *(const f16x8*)&Vl[d*64 + (((kk*4 + quad) ^ (d & 7))*8)];
        O[dt] = __builtin_amdgcn_mfma_f32_16x16x32_f16(ap, bv, O[dt], 0, 0, 0);
      }
    }
    __builtin_amdgcn_wave_barrier();
  }
#undef LOADKV
  const int growb = b*LQ + l0 + w*16 + quad*4;
  #pragma unroll
  for (int r = 0; r < 4; ++r){
    f16* od = Opart + ((size_t)sp*NROW + growb + r)*128 + col;
    #pragma unroll
    for (int dt = 0; dt < 8; ++dt) od[dt*16] = (f16)O[dt][r];
  }
  if (col == 0){
    #pragma unroll
    for (int r = 0; r < 4; ++r){
      ((float2*)mZ)[(size_t)sp*NROW + growb + r] = make_float2(mrun[r], zrun[r]);
    }
  }
}

// ========== combine splits (f16 partials) -> cat16 H columns [512,640) ==========
__global__ __launch_bounds__(256) void k_comb(const f16* __restrict__ Opart,
    const float* __restrict__ mZ, f16* __restrict__ cat)
{
  int i = blockIdx.x*256 + threadIdx.x;         // NROW*64
  int row = i >> 6, d2 = (i & 63)*2;
  float ms[NSPLIT], zs[NSPLIT];
  float M = -1e30f;
  #pragma unroll
  for (int s = 0; s < NSPLIT; ++s){
    float2 v = ((const float2*)mZ)[(size_t)s*NROW + row];
    ms[s] = v.x; zs[s] = v.y;
    M = fmaxf(M, v.x);
  }
  float Zt = 0.f, ax = 0.f, ay = 0.f;
  #pragma unroll
  for (int s = 0; s < NSPLIT; ++s){
    float e = __expf(ms[s] - M);
    Zt += zs[s]*e;
    f16x2 op = *(const f16x2*)(Opart + ((size_t)s*NROW + row)*128 + d2);
    ax += e*(float)op.x; ay += e*(float)op.y;
  }
  float inv = 1.f/Zt;
  f16x2 o = { (f16)(ax*inv), (f16)(ay*inv) };
  *(f16x2*)(cat + (size_t)row*640 + 512 + d2) = o;
}

// ========== prep for MFMA GEMMs: cat16 x-part + W^T f16 + Wm^T f16.
// blocks [0,2048): x f32 -> cat16 cols [0,512).
// [2048,2208): w16[n][k] = W[k][n] (n<128: Wsg, else Wtn), k<640.
// [2208,2272): wm16[n][k] = Wm[k][n], n<128, k<512. ==========
__global__ __launch_bounds__(256) void k_prep(const float* __restrict__ x,
    const float* __restrict__ Wsg, const float* __restrict__ Wtn,
    const float* __restrict__ Wm,
    f16* __restrict__ cat, f16* __restrict__ w16, f16* __restrict__ wm16)
{
  if (blockIdx.x < 2048){
    int id = blockIdx.x*256 + threadIdx.x;     // 524288 = 4096 rows * 128 quads
    int row = id >> 7, c4 = (id & 127)*4;
    float4 v = *(const float4*)(x + (size_t)row*512 + c4);
    f16x4 o = { (f16)v.x, (f16)v.y, (f16)v.z, (f16)v.w };
    *(f16x4*)(cat + (size_t)row*640 + c4) = o;
  } else if (blockIdx.x < 2208){
    int id = (blockIdx.x - 2048)*256 + threadIdx.x;   // 40960 = 256 n * 160 k-quads
    int n = id / 160;
    int k0 = (id - n*160)*4;
    const float* src = n < 128 ? (Wsg + n) : (Wtn + (n - 128));
    f16x4 o = { (f16)src[(k0+0)*128], (f16)src[(k0+1)*128],
                (f16)src[(k0+2)*128], (f16)src[(k0+3)*128] };
    *(f16x4*)(w16 + (size_t)n*640 + k0) = o;
  } else {
    int id = (blockIdx.x - 2208)*256 + threadIdx.x;   // 16384 = 128 n * 128 k-quads
    int n = id >> 7;
    int k0 = (id & 127)*4;
    const float* src = Wm + n;
    f16x4 o = { (f16)src[(k0+0)*128], (f16)src[(k0+1)*128],
                (f16)src[(k0+2)*128], (f16)src[(k0+3)*128] };
    *(f16x4*)(wm16 + (size_t)n*512 + k0) = o;
  }
}

// ========== q MFMA GEMM: q[4096][128] = f16(relu(cat16[:, :512] @ wm16^T + bm)).
// 1 wave per 16 rows, 8 n-tiles, K=512 in 16 mfma steps. ==========
__global__ __launch_bounds__(64) void k_qgemm2(const f16* __restrict__ cat,
    const f16* __restrict__ wm16, const float* __restrict__ bm, f16* __restrict__ q)
{
  const int lane = threadIdx.x;
  const int quad = lane >> 4, col = lane & 15;
  const int koff = quad*8;
  const int row0 = blockIdx.x * 16;
  const f16* ar = cat + (size_t)(row0 + col)*640 + koff;
  const f16* br = wm16 + (size_t)col*512 + koff;
  f32x4 acc[8];
  #pragma unroll
  for (int nt = 0; nt < 8; ++nt) acc[nt] = (f32x4){0.f,0.f,0.f,0.f};
  for (int ks = 0; ks < 16; ++ks){
    f16x8 a = *(const f16x8*)(ar + ks*32);
    #pragma unroll
    for (int nt = 0; nt < 8; ++nt){
      f16x8 b = *(const f16x8*)(br + (size_t)nt*16*512 + ks*32);
      acc[nt] = __builtin_amdgcn_mfma_f32_16x16x32_f16(a, b, acc[nt], 0, 0, 0);
    }
  }
  #pragma unroll
  for (int nt = 0; nt < 8; ++nt){
    int n = nt*16 + col;
    float bv = bm[n];
    #pragma unroll
    for (int r = 0; r < 4; ++r){
      float v = fmaxf(acc[nt][r] + bv, 0.f);
      q[(size_t)(row0 + quad*4 + r)*128 + n] = (f16)v;
    }
  }
}

// ========== final MFMA GEMM: out[4096][256] = act(cat16 @ w16^T + bias).
// 1 wave per 16 rows, 16 n-tiles, K=640 in 20 mfma steps. n<128: sigmoid, else tanh ==========
__global__ __launch_bounds__(64) void k_fin2(const f16* __restrict__ cat,
    const f16* __restrict__ w16, const float* __restrict__ bsg,
    const float* __restrict__ btn, float* __restrict__ out)
{
  const int lane = threadIdx.x;
  const int quad = lane >> 4, col = lane & 15;
  const int koff = quad*8;
  const int row0 = blockIdx.x * 16;
  const f16* ar = cat + (size_t)(row0 + col)*640 + koff;
  const f16* br = w16 + (size_t)col*640 + koff;
  f32x4 acc[16];
  #pragma unroll
  for (int nt = 0; nt < 16; ++nt) acc[nt] = (f32x4){0.f,0.f,0.f,0.f};
  for (int ks = 0; ks < 20; ++ks){
    f16x8 a = *(const f16x8*)(ar + ks*32);
    #pragma unroll
    for (int nt = 0; nt < 16; ++nt){
      f16x8 b = *(const f16x8*)(br + (size_t)nt*16*640 + ks*32);
      acc[nt] = __builtin_amdgcn_mfma_f32_16x16x32_f16(a, b, acc[nt], 0, 0, 0);
    }
  }
  #pragma unroll
  for (int nt = 0; nt < 16; ++nt){
    int n = nt*16 + col;
    float bv = n < 128 ? bsg[n] : btn[n - 128];
    #pragma unroll
    for (int r = 0; r < 4; ++r){
      float v = acc[nt][r] + bv;
      v = n < 128 ? 1.f/(1.f + __expf(-v)) : tanhf(v);
      out[(size_t)(row0 + quad*4 + r)*256 + n] = v;
    }
  }
}

extern "C" void kernel_launch(void* const* d_in, const int* in_sizes, int n_in,
                              void* d_out, int out_size, void* d_ws, size_t ws_size,
                              hipStream_t stream)
{
  const float* x    = (const float*)d_in[0];
  const float* nfr  = (const float*)d_in[1];
  const int*   eidx = (const int*)d_in[2];
  const int*   hidx = (const int*)d_in[3];
  const float *Wg1=(const float*)d_in[4],  *bg1=(const float*)d_in[5];
  const float *Wg2=(const float*)d_in[6],  *bg2=(const float*)d_in[7];
  const float *Wh1=(const float*)d_in[8],  *bh1=(const float*)d_in[9];
  const float *Wh2=(const float*)d_in[10], *bh2=(const float*)d_in[11];
  const float *Wm =(const float*)d_in[12], *bm =(const float*)d_in[13];
  const float *Wm2=(const float*)d_in[14], *bm2=(const float*)d_in[15];
  const float *Wsg=(const float*)d_in[16], *bsg=(const float*)d_in[17];
  const float *Wtn=(const float*)d_in[18], *btn=(const float*)d_in[19];
  float* out = (float*)d_out;

  // ---- workspace layout. Aliases:
  //  h4_16 at base; bins + gcur live only until k_csr, alias agg16 region;
  //  cat16/w16/wm16 alias agg16+bins region (attention phase only);
  //  Opart f16 (16MB) aliases dead bufA; kb/gT alias csr_dst/csr_pn. ----
  char* base = (char*)d_ws;
  f16*   h4_16  = (f16*)(base);                          // 16 MB
  f16*   agg16  = (f16*)(base + 33554432);               // 16 MB (graph phase only)
  u32*   bin_e  = (u32*)(base + 33554432);               // 5 MB   (aliases agg16)
  u32*   bin_pn = (u32*)(base + 38797312);               // 5 MB
  u32*   bin_pe = (u32*)(base + 44040192);               // 4.5 MB
  int*   gcur   = (int*)(base + 48758784);               // 1.25 KB
  f16*   cat16  = (f16*)(base + 33554432);               // 5.24 MB (attention phase)
  f16*   w16    = (f16*)(base + 38797312);               // 320 KB  (attention phase)
  f16*   wm16   = (f16*)(base + 39124992);               // 128 KB  (attention phase)
  f16*   bufA   = (f16*)(base + 67108864);               // 16 MB  (nfr16 / h2_16)
  f16*   bufB   = (f16*)(base + 83886080);               // 16 MB  (h1_16 / h3_16)
  f16*   Opart  = (f16*)(base + 67108864);               // 16 MB f16 (aliases bufA)
  u16*   csr_dst= (u16*)(base + 100663296);              // 8 MB used of 16 MB region
  f16*   kb     = (f16*)(base + 100663296);              //   (aliases csr_dst)
  u16*   csr_pn = (u16*)(base + 117440512);              // 8 MB used of 16 MB region
  f16*   gT     = (f16*)(base + 117440512);              //   (aliases csr_pn)
  u16*   csr_pe = (u16*)(base + 134217728);              // 3 MB used of 6 MB region
  int*   cnt_dst= (int*)(base + 140509184);
  int*   cnt_pn = (int*)(base + 140771328);
  int*   cnt_pe = (int*)(base + 141033472);
  int*   du     = (int*)(base + 141049856);              // 256 KB
  float* ef0    = (float*)(base + 141312000);            // 2 MB
  f16*   ef1    = (f16*)(base + 143409152);              // 1 MB (f16)
  f16*   qb     = (f16*)(base + 145506304);              // 1 MB
  float* mZ     = (float*)(base + 146554880);            // 512 KB (NSPLIT16)
  const size_t needB = (size_t)147079168;
  if (ws_size < needB) return;

  // ---- CSR build: bin (phase A) then per-bucket insert (phase B) ----
  hipMemsetAsync(du, 0, 262144, stream);
  hipMemsetAsync(gcur, 0, 1280, stream);
  k_bin<<<1024, 256, 0, stream>>>(eidx, hidx, du, gcur, bin_e, bin_pn, bin_pe);
  k_csr<<<320, 256, 0, stream>>>(gcur, bin_e, bin_pn, bin_pe,
                                 cnt_dst, csr_dst, cnt_pn, csr_pn, cnt_pe, csr_pe);

  // ---- layer 1 ----
  k_pre<<<NNODE*64/256, 256, 0, stream>>>(nfr, du, bufA);
  k_gagg16<<<NNODE/4, 256, 0, stream>>>(cnt_dst, csr_dst, bufA, agg16);
  k_gemm<1,1><<<NNODE/32, 256, 0, stream>>>(agg16, Wg1, cnt_dst, bg1, bufB);
  k_hea16<<<NHE/4, 256, 0, stream>>>(cnt_pe, csr_pe, bufB, ef0);
  k_gemm<3,0><<<NHE/32, 256, 0, stream>>>(ef0, Wh1, nullptr, nullptr, ef1);
  k_nha<1><<<NNODE/4, 256, 0, stream>>>(cnt_pn, csr_pn, ef1, bh1, nfr, du, bufA);

  // ---- layer 2 ----
  k_gagg16<<<NNODE/4, 256, 0, stream>>>(cnt_dst, csr_dst, bufA, agg16);
  k_gemm<1,1><<<NNODE/32, 256, 0, stream>>>(agg16, Wg2, cnt_dst, bg2, bufB);
  k_hea16<<<NHE/4, 256, 0, stream>>>(cnt_pe, csr_pe, bufB, ef0);
  k_gemm<3,0><<<NHE/32, 256, 0, stream>>>(ef0, Wh2, nullptr, nullptr, ef1);
  k_nha<0><<<NNODE/4, 256, 0, stream>>>(cnt_pn, csr_pn, ef1, bh2, nfr, nullptr, h4_16);

  // ---- attention (agg16/bins dead from here: cat16/w16/wm16 safe) ----
  k_prep<<<2272, 256, 0, stream>>>(x, Wsg, Wtn, Wm, cat16, w16, wm16);
  k_qgemm2<<<NROW/16, 64, 0, stream>>>(cat16, wm16, bm, qb);
  k_gemm<2,1><<<NNODE/32, 256, 0, stream>>>(h4_16, Wm2, nullptr, bm2, kb);
  k_gt<<<dim3(NPER/64, 2, BSZ), 256, 0, stream>>>(h4_16, gT);
  k_flash<<<dim3(NSPLIT, LQ/128, BSZ), 512, 0, stream>>>(qb, kb, gT, Opart, mZ);
  k_comb<<<NROW*64/256, 256, 0, stream>>>(Opart, mZ, cat16);
  k_fin2<<<NROW/16, 64, 0, stream>>>(cat16, w16, bsg, btn, out);

  (void)in_sizes; (void)n_in; (void)out_size;
}

// Round 11
// 609.748 us; speedup vs baseline: 2.0104x; 1.0612x over previous
//
#include <hip/hip_runtime.h>
#include <hip/hip_bf16.h>

#define BSZ   8
#define NPER  8192
#define NNODE 65536       // BSZ*NPER
#define EPG   131072      // edges per graph
#define EMB   128
#define ENCD  512
#define LQ    512
#define NHE   4096
#define NE    1048576
#define NP    1048576
#define NROW  4096        // BSZ*LQ
#define NSPLIT 16
#define SLOT_N 64
#define SLOT_E 384
// binning: 128 node-buckets (512 nodes), 64 he-buckets (64 hyperedges)
#define CAP_E  10240      // per node-bucket capacity, edges  (mean 8192, +22 sigma)
#define CAP_PN 10240      // per node-bucket capacity, pairs  (mean 8192)
#define CAP_PE 18432      // per he-bucket capacity, pairs    (mean 16384, +16 sigma)

typedef _Float16 f16;
typedef _Float16 f16x2 __attribute__((ext_vector_type(2)));
typedef _Float16 f16x4 __attribute__((ext_vector_type(4)));
typedef _Float16 f16x8 __attribute__((ext_vector_type(8)));
typedef float f32x4 __attribute__((ext_vector_type(4)));
typedef unsigned short u16;
typedef unsigned int u32;

// ========== phase A: bin edges (by dst AND by src) and pairs (by pn and pe)
// into contiguous per-bucket arrays.  NO global du atomics (du comes from
// bin_s counting in phase B).  4096 items/block halves boundary-line waste.
// gcur layout: [0,128) edge-dst, [128,256) pn, [256,320) pe, [320,448) edge-src ==========
__global__ __launch_bounds__(256) void k_bin(const int* __restrict__ eidx,
    const int* __restrict__ hidx, int* __restrict__ gcur,
    u32* __restrict__ bin_e, u32* __restrict__ bin_s,
    u32* __restrict__ bin_pn, u32* __restrict__ bin_pe)
{
  __shared__ int lh[448];
  __shared__ int gb[448];
  const int tid = threadIdx.x;
  for (int i = tid; i < 448; i += 256) lh[i] = 0;
  __syncthreads();
  if (blockIdx.x < 256){
    // 4096 edges per block: dst-bin via lh[0,128), src-bin via lh[128,256)->gcur[320,448)
    const int eb4 = blockIdx.x*1024;
    int ss[16], dd[16];
    #pragma unroll
    for (int t = 0; t < 4; ++t){
      int4 s4 = ((const int4*)eidx)[eb4 + t*256 + tid];
      int4 d4 = ((const int4*)(eidx + NE))[eb4 + t*256 + tid];
      ss[t*4+0]=s4.x; ss[t*4+1]=s4.y; ss[t*4+2]=s4.z; ss[t*4+3]=s4.w;
      dd[t*4+0]=d4.x; dd[t*4+1]=d4.y; dd[t*4+2]=d4.z; dd[t*4+3]=d4.w;
    }
    int rd[16], rs[16];
    #pragma unroll
    for (int u = 0; u < 16; ++u){
      rd[u] = atomicAdd(&lh[dd[u] >> 9], 1);
      rs[u] = atomicAdd(&lh[128 + (ss[u] >> 9)], 1);
    }
    __syncthreads();
    if (tid < 128){
      if (lh[tid]) gb[tid] = atomicAdd(&gcur[tid], lh[tid]);
    } else {
      if (lh[tid]) gb[tid] = atomicAdd(&gcur[192 + tid], lh[tid]);   // gcur[320 + (tid-128)]
    }
    __syncthreads();
    #pragma unroll
    for (int u = 0; u < 16; ++u){
      int b = dd[u] >> 9;
      int pos = gb[b] + rd[u];
      if (pos < CAP_E)
        bin_e[(size_t)b*CAP_E + pos] = (u32)(dd[u] & 0xffff) | ((u32)ss[u] << 16);
      int bs = ss[u] >> 9;
      int pos2 = gb[128 + bs] + rs[u];
      if (pos2 < CAP_E)
        bin_s[(size_t)bs*CAP_E + pos2] = (u32)(ss[u] & 0xffff);
    }
  } else {
    // 4096 pairs per block, binned both directions
    const int pb4 = (blockIdx.x - 256)*2048;
    int pn[16], pe[16];
    #pragma unroll
    for (int t = 0; t < 8; ++t){
      int4 p = ((const int4*)hidx)[pb4 + t*256 + tid];
      pn[t*2+0] = p.x; pe[t*2+0] = p.y;
      pn[t*2+1] = p.z; pe[t*2+1] = p.w;
    }
    int rn[16], re[16];
    #pragma unroll
    for (int u = 0; u < 16; ++u){
      rn[u] = atomicAdd(&lh[128 + (pn[u] >> 9)], 1);
      re[u] = atomicAdd(&lh[256 + (pe[u] >> 6)], 1);
    }
    __syncthreads();
    if (tid < 192 && lh[128 + tid]) gb[128 + tid] = atomicAdd(&gcur[128 + tid], lh[128 + tid]);
    __syncthreads();
    #pragma unroll
    for (int u = 0; u < 16; ++u){
      int bn = pn[u] >> 9;
      int pos = gb[128 + bn] + rn[u];
      if (pos < CAP_PN)
        bin_pn[(size_t)bn*CAP_PN + pos] = (u32)pn[u] | ((u32)pe[u] << 16);
      int be = pe[u] >> 6;
      int pos2 = gb[256 + be] + re[u];
      if (pos2 < CAP_PE)
        bin_pe[(size_t)be*CAP_PE + pos2] = (u32)pe[u] | ((u32)pn[u] << 16);
    }
  }
}

// ========== phase B: per-bucket CSR insert (LDS cursors, windowed u16 writes)
// + du (src out-degree) counting from bin_s.
// blocks [0,128) edge-dst, [128,256) pn, [256,320) pe, [320,448) src->du ==========
__global__ __launch_bounds__(256) void k_csr(const int* __restrict__ gcur,
    const u32* __restrict__ bin_e, const u32* __restrict__ bin_s,
    const u32* __restrict__ bin_pn, const u32* __restrict__ bin_pe,
    int* __restrict__ cnt_dst, u16* __restrict__ csr_dst,
    int* __restrict__ cnt_pn, u16* __restrict__ csr_pn,
    int* __restrict__ cnt_pe, u16* __restrict__ csr_pe,
    int* __restrict__ du)
{
  const int tid = threadIdx.x;
  if (blockIdx.x < 256){
    __shared__ int cur[512];
    const int isP = blockIdx.x >= 128;
    const int b = blockIdx.x & 127;
    cur[tid] = 0; cur[tid + 256] = 0;
    __syncthreads();
    const int n0 = b*512;
    const int cap = isP ? CAP_PN : CAP_E;
    int raw = gcur[isP ? 128 + b : b];
    int count = raw < cap ? raw : cap;
    const u32* bin = (isP ? bin_pn : bin_e) + (size_t)b*cap;
    u16* csr = isP ? csr_pn : csr_dst;
    for (int i = tid; i < count; i += 256){
      u32 v = bin[i];
      int row = v & 0xffff, val = v >> 16;
      int c = atomicAdd(&cur[row - n0], 1);
      if (c < SLOT_N) csr[(size_t)row*SLOT_N + c] = (u16)val;
    }
    __syncthreads();
    int* cnt = isP ? cnt_pn : cnt_dst;
    cnt[n0 + tid]       = cur[tid];
    cnt[n0 + 256 + tid] = cur[tid + 256];
  } else if (blockIdx.x < 320){
    __shared__ int cur[64];
    const int b = blockIdx.x - 256;
    if (tid < 64) cur[tid] = 0;
    __syncthreads();
    const int e0 = b*64;
    int raw = gcur[256 + b];
    int count = raw < CAP_PE ? raw : CAP_PE;
    const u32* bin = bin_pe + (size_t)b*CAP_PE;
    for (int i = tid; i < count; i += 256){
      u32 v = bin[i];
      int row = v & 0xffff, val = v >> 16;
      int c = atomicAdd(&cur[row - e0], 1);
      if (c < SLOT_E) csr_pe[(size_t)row*SLOT_E + c] = (u16)val;
    }
    __syncthreads();
    if (tid < 64) cnt_pe[e0 + tid] = cur[tid];
  } else {
    // src out-degree counting -> du (no CSR payload)
    __shared__ int cur[512];
    const int b = blockIdx.x - 320;
    cur[tid] = 0; cur[tid + 256] = 0;
    __syncthreads();
    const int n0 = b*512;
    int raw = gcur[320 + b];
    int count = raw < CAP_E ? raw : CAP_E;
    const u32* bin = bin_s + (size_t)b*CAP_E;
    for (int i = tid; i < count; i += 256){
      int row = (int)(bin[i] & 0xffff);
      atomicAdd(&cur[row - n0], 1);
    }
    __syncthreads();
    du[n0 + tid]       = cur[tid];
    du[n0 + 256 + tid] = cur[tid + 256];
  }
}

// ========== nfr16 = f16(nfr * rsqrt(max(du,1))) ==========
__global__ __launch_bounds__(256) void k_pre(const float* __restrict__ nfr,
    const int* __restrict__ du, f16* __restrict__ out)
{
  int i = blockIdx.x*256 + threadIdx.x;         // NNODE*64
  int node = i >> 6, j = i & 63;
  float ds = rsqrtf(fmaxf((float)du[node], 1.f));
  float2 v = ((const float2*)(nfr + (size_t)node*128))[j];
  f16x2 o = { (f16)(v.x*ds), (f16)(v.y*ds) };
  ((f16x2*)(out + (size_t)node*128))[j] = o;
}

// ========== gconv gather (f16 src): 1 wave per node, branchless 8-batches.
// Indices loaded as int4 (8 u16) per batch; masked slots redirect to row[0]
// (hot line) with adds skipped.  Graph->XCD swizzle keeps each graph's
// source slab in one XCD's L2. ==========
__global__ __launch_bounds__(256) void k_gagg16(const int* __restrict__ cnt,
    const u16* __restrict__ csr, const f16* __restrict__ src, f16* __restrict__ agg)
{
  const int wv = threadIdx.x >> 6, lane = threadIdx.x & 63;
  const int blk = blockIdx.x;                   // NNODE/4 blocks
  const int n = (blk & 7)*NPER + (blk >> 3)*4 + wv;
  const int nd = cnt[n];
  const int c = nd < SLOT_N ? nd : SLOT_N;
  const u16* row = csr + (size_t)n*SLOT_N;
  const f16x2* s2 = (const f16x2*)src;
  float ax = 0.f, ay = 0.f;
  if (c > 0){
    const int i0 = row[0];
    #pragma unroll 1
    for (int b = 0; b < 8; ++b){
      if (b*8 >= c) break;                      // wave-uniform
      int4 iv = *(const int4*)(row + b*8);
      int ix[8] = { iv.x & 0xffff, (iv.x >> 16) & 0xffff,
                    iv.y & 0xffff, (iv.y >> 16) & 0xffff,
                    iv.z & 0xffff, (iv.z >> 16) & 0xffff,
                    iv.w & 0xffff, (iv.w >> 16) & 0xffff };
      f16x2 vv[8];
      #pragma unroll
      for (int k = 0; k < 8; ++k){
        int id = (b*8 + k < c) ? ix[k] : i0;
        vv[k] = s2[(size_t)id*64 + lane];
      }
      #pragma unroll
      for (int k = 0; k < 8; ++k){
        if (b*8 + k < c){ ax += (float)vv[k].x; ay += (float)vv[k].y; }
      }
    }
  }
  ((f16x2*)(agg + (size_t)n*128))[lane] = (f16x2){ (f16)ax, (f16)ay };
}

// ========== hconv stage 1 (f16 source): ef0[e] = (1/|e|) * sum src16[pn].
// 1 wave per hyperedge (4/block), 8-deep unrolled gather -> 8 loads in flight ==========
__global__ __launch_bounds__(256) void k_hea16(const int* __restrict__ cnt,
    const u16* __restrict__ csr, const f16* __restrict__ src, float* __restrict__ ef)
{
  const int wv = threadIdx.x >> 6, lane = threadIdx.x & 63;
  const int e = blockIdx.x*4 + wv;
  const int nd = cnt[e];
  const int n = nd < SLOT_E ? nd : SLOT_E;
  const u16* row = csr + (size_t)e*SLOT_E;
  const f16x2* s2 = (const f16x2*)src;
  float ax = 0.f, ay = 0.f;
  int j = 0;
  for (; j + 7 < n; j += 8){
    int p0 = row[j],   p1 = row[j+1], p2 = row[j+2], p3 = row[j+3];
    int p4 = row[j+4], p5 = row[j+5], p6 = row[j+6], p7 = row[j+7];
    f16x2 v0 = s2[(size_t)p0*64 + lane];
    f16x2 v1 = s2[(size_t)p1*64 + lane];
    f16x2 v2 = s2[(size_t)p2*64 + lane];
    f16x2 v3 = s2[(size_t)p3*64 + lane];
    f16x2 v4 = s2[(size_t)p4*64 + lane];
    f16x2 v5 = s2[(size_t)p5*64 + lane];
    f16x2 v6 = s2[(size_t)p6*64 + lane];
    f16x2 v7 = s2[(size_t)p7*64 + lane];
    ax += (((float)v0.x + (float)v1.x) + ((float)v2.x + (float)v3.x))
        + (((float)v4.x + (float)v5.x) + ((float)v6.x + (float)v7.x));
    ay += (((float)v0.y + (float)v1.y) + ((float)v2.y + (float)v3.y))
        + (((float)v4.y + (float)v5.y) + ((float)v6.y + (float)v7.y));
  }
  for (; j < n; ++j){
    f16x2 v = s2[(size_t)row[j]*64 + lane];
    ax += (float)v.x; ay += (float)v.y;
  }
  float s = nd > 0 ? 1.f/(float)nd : 0.f;
  ((float2*)(ef + (size_t)e*128))[lane] = make_float2(ax*s, ay*s);
}

// ========== register-blocked 128x128 GEMM.  IN16: input rows are f16.
// MODE 0: f32 raw  MODE 1: f16(acc*rsqrt(max(cnt,1))+bias)  MODE 2: f16(relu(acc+bias))
// MODE 3: f16 raw ==========
template<int MODE, int IN16>
__global__ __launch_bounds__(256, 2) void k_gemm(const void* __restrict__ inp,
    const float* __restrict__ W, const int* __restrict__ cnt,
    const float* __restrict__ bias, void* __restrict__ outp)
{
  __shared__ float Wl[128*128];
  __shared__ float Rl[32*128];
  const int tid = threadIdx.x;
  const int rbase = blockIdx.x*32;
  for (int i = tid; i < 16384; i += 256) Wl[i] = W[i];
  if (IN16){
    const f16x2* s2 = (const f16x2*)(((const f16*)inp) + (size_t)rbase*128);
    for (int i = tid; i < 2048; i += 256){
      f16x2 v = s2[i];
      ((float2*)Rl)[i] = make_float2((float)v.x, (float)v.y);
    }
  } else {
    const float* src = ((const float*)inp) + (size_t)rbase*128;
    for (int i = tid; i < 4096; i += 256) Rl[i] = src[i];
  }
  __syncthreads();
  const int c0 = (tid & 31)*4;
  const int r0 = (tid >> 5)*4;
  f32x4 acc[4];
  #pragma unroll
  for (int j = 0; j < 4; ++j) acc[j] = (f32x4){0.f,0.f,0.f,0.f};
  for (int d = 0; d < 128; d += 4){
    f32x4 w0 = *(const f32x4*)&Wl[(d+0)*128 + c0];
    f32x4 w1 = *(const f32x4*)&Wl[(d+1)*128 + c0];
    f32x4 w2 = *(const f32x4*)&Wl[(d+2)*128 + c0];
    f32x4 w3 = *(const f32x4*)&Wl[(d+3)*128 + c0];
    #pragma unroll
    for (int j = 0; j < 4; ++j){
      f32x4 rr = *(const f32x4*)&Rl[(r0+j)*128 + d];
      acc[j] += rr.x*w0 + rr.y*w1 + rr.z*w2 + rr.w*w3;
    }
  }
  #pragma unroll
  for (int j = 0; j < 4; ++j){
    const int row = rbase + r0 + j;
    if (MODE == 0){
      *(f32x4*)(((float*)outp) + (size_t)row*128 + c0) = acc[j];
    } else if (MODE == 1){
      float sc = rsqrtf(fmaxf((float)cnt[row], 1.f));
      f16* o = ((f16*)outp) + (size_t)row*128 + c0;
      #pragma unroll
      for (int k = 0; k < 4; ++k) o[k] = (f16)(acc[j][k]*sc + bias[c0+k]);
    } else if (MODE == 2){
      f16* o = ((f16*)outp) + (size_t)row*128 + c0;
      #pragma unroll
      for (int k = 0; k < 4; ++k) o[k] = (f16)fmaxf(acc[j][k] + bias[c0+k], 0.f);
    } else {
      f16* o = ((f16*)outp) + (size_t)row*128 + c0;
      #pragma unroll
      for (int k = 0; k < 4; ++k) o[k] = (f16)acc[j][k];
    }
  }
}

// ========== hconv stage 2 + relu + residual: 1 wave per node, branchless
// 8-batches (int4 index loads, masked adds, row[0] redirect).  f16 ef source,
// early nfr (HBM) load overlaps the gathers.  f16 out.
// PRES: scale by rsqrt(du) (for next layer's prescaled input) ==========
template<int PRES>
__global__ __launch_bounds__(256) void k_nha(const int* __restrict__ cnt,
    const u16* __restrict__ csr, const f16* __restrict__ ef,
    const float* __restrict__ bias, const float* __restrict__ nfr,
    const int* __restrict__ du, f16* __restrict__ outp)
{
  const int wv = threadIdx.x >> 6, lane = threadIdx.x & 63;
  const int n = blockIdx.x*4 + wv;
  const int nd = cnt[n];
  const int c = nd < SLOT_N ? nd : SLOT_N;
  const u16* row = csr + (size_t)n*SLOT_N;
  const f16x2* s2 = (const f16x2*)ef;
  float2 nf = ((const float2*)(nfr + (size_t)n*128))[lane];   // early: hides under gathers
  float e0 = PRES ? rsqrtf(fmaxf((float)du[n], 1.f)) : 1.f;
  float ax = 0.f, ay = 0.f;
  if (c > 0){
    const int i0 = row[0];
    #pragma unroll 1
    for (int b = 0; b < 8; ++b){
      if (b*8 >= c) break;                      // wave-uniform
      int4 iv = *(const int4*)(row + b*8);
      int ix[8] = { iv.x & 0xffff, (iv.x >> 16) & 0xffff,
                    iv.y & 0xffff, (iv.y >> 16) & 0xffff,
                    iv.z & 0xffff, (iv.z >> 16) & 0xffff,
                    iv.w & 0xffff, (iv.w >> 16) & 0xffff };
      f16x2 vv[8];
      #pragma unroll
      for (int k = 0; k < 8; ++k){
        int id = (b*8 + k < c) ? ix[k] : i0;
        vv[k] = s2[(size_t)id*64 + lane];
      }
      #pragma unroll
      for (int k = 0; k < 8; ++k){
        if (b*8 + k < c){ ax += (float)vv[k].x; ay += (float)vv[k].y; }
      }
    }
  }
  float bx = bias[lane*2], by = bias[lane*2+1];
  float s = nd > 0 ? 1.f/(float)nd : 0.f;
  float vx = fmaxf(ax*s + bx, 0.f) + nf.x;
  float vy = fmaxf(ay*s + by, 0.f) + nf.y;
  ((f16x2*)(outp + (size_t)n*128))[lane] = (f16x2){ (f16)(vx*e0), (f16)(vy*e0) };
}

// ========== gT[b][c][n] = h16[b*NPER+n][c]  (f16 transpose) ==========
__global__ __launch_bounds__(256) void k_gt(const f16* __restrict__ g, f16* __restrict__ gT)
{
  __shared__ f16 t[64][66];
  int b = blockIdx.z, n0 = blockIdx.x*64, c0 = blockIdx.y*64;
  for (int i = threadIdx.x; i < 64*64; i += 256){
    int n = i >> 6, c = i & 63;
    t[n][c] = g[((size_t)(b*NPER + n0 + n))*128 + c0 + c];
  }
  __syncthreads();
  for (int i = threadIdx.x; i < 64*64; i += 256){
    int c = i >> 6, n = i & 63;
    gT[((size_t)(b*128 + c0 + c))*NPER + n0 + n] = t[n][c];
  }
}

// ========== flash attention (R6): 128 q-rows/block (8 waves), n-slab 512, n-chunk 64,
// cooperative XOR-swizzled LDS staging, register prefetch, f16 Opart.
// 48 KB LDS, launch_bounds(512,4) -> 2 blocks/CU, 128 VGPR cap. ==========
#define NCH 64
__global__ __launch_bounds__(512, 4) void k_flash(const f16* __restrict__ qb,
    const f16* __restrict__ kb, const f16* __restrict__ gT,
    f16* __restrict__ Opart, float* __restrict__ mZ)
{
  __shared__ f16 Kl[64*128];        // 16 KB  [n 64][k 128], chunk-swizzled
  __shared__ f16 Vl[128*64];        // 16 KB  [d 128][n 64], chunk-swizzled
  __shared__ f16 Pl[8*16*64];       // 16 KB  per-wave [q 16][n 64], chunk-swizzled
  const int sp = blockIdx.x, l0 = blockIdx.y*128, b = blockIdx.z;
  const int tid = threadIdx.x;
  const int w = tid >> 6, lane = tid & 63;
  const int quad = lane >> 4, col = lane & 15;
  const int koff = quad*8;
  // staging lane mapping (512 threads)
  const int krow = tid >> 4;        // K: rows 0..31 (+32), chunks 0..15
  const int kc8  = tid & 15;
  const int vrow = tid >> 3;        // V: rows 0..63 (+64), chunks 0..7
  const int vc8  = tid & 7;

  const f16* qrow = qb + ((size_t)(b*LQ + l0 + w*16 + col))*128 + koff;
  f16x8 aq[4];
  #pragma unroll
  for (int ks = 0; ks < 4; ++ks) aq[ks] = *(const f16x8*)(qrow + ks*32);
  float mrun[4] = {-1e30f,-1e30f,-1e30f,-1e30f};
  float zrun[4] = {0.f,0.f,0.f,0.f};
  f32x4 O[8];
  #pragma unroll
  for (int i = 0; i < 8; ++i) O[i] = (f32x4){0.f,0.f,0.f,0.f};

  const int nbase = sp*(NPER/NSPLIT);          // 512-wide n slab
  f16x8 kr[2], vr[2];
#define LOADKV(N0)                                                           \
  { _Pragma("unroll")                                                        \
    for (int i2 = 0; i2 < 2; ++i2){                                          \
      kr[i2] = *(const f16x8*)(kb + ((size_t)(b*NPER + (N0) + krow + i2*32))*128 + kc8*8); \
      vr[i2] = *(const f16x8*)(gT + ((size_t)(b*128 + vrow + i2*64))*NPER + (N0) + vc8*8); \
    } }
  LOADKV(nbase);
  #pragma unroll 1
  for (int it = 0; it < (NPER/NSPLIT)/NCH; ++it){
    const int n0 = nbase + it*NCH;
    __syncthreads();                            // prior-iter LDS reads done
    #pragma unroll
    for (int i2 = 0; i2 < 2; ++i2){
      int r = krow + i2*32;
      *(f16x8*)&Kl[r*128 + ((kc8 ^ (r & 7))*8)] = kr[i2];
      int d = vrow + i2*64;
      *(f16x8*)&Vl[d*64  + ((vc8 ^ (d & 7))*8)] = vr[i2];
    }
    __syncthreads();                            // staging visible
    if (it < (NPER/NSPLIT)/NCH - 1) LOADKV(n0 + NCH);   // prefetch next tile

    // ---- QK^T from LDS ----
    f32x4 st[4];
    #pragma unroll
    for (int t = 0; t < 4; ++t){
      st[t] = (f32x4){0.f,0.f,0.f,0.f};
      const int r = t*16 + col, rs = r & 7;
      #pragma unroll
      for (int ks = 0; ks < 4; ++ks){
        f16x8 bf = *(const f16x8*)&Kl[r*128 + (((ks*4 + quad) ^ rs)*8)];
        st[t] = __builtin_amdgcn_mfma_f32_16x16x32_f16(aq[ks], bf, st[t], 0, 0, 0);
      }
    }
    // ---- softmax over 64 n ----
    float alr[4];
    #pragma unroll
    for (int r = 0; r < 4; ++r){
      float rm = st[0][r];
      #pragma unroll
      for (int t = 1; t < 4; ++t) rm = fmaxf(rm, st[t][r]);
      rm = fmaxf(rm, __shfl_xor(rm, 1));
      rm = fmaxf(rm, __shfl_xor(rm, 2));
      rm = fmaxf(rm, __shfl_xor(rm, 4));
      rm = fmaxf(rm, __shfl_xor(rm, 8));
      float mn = fmaxf(mrun[r], rm);
      float al = __expf(mrun[r] - mn);
      float ps[4], rsum = 0.f;
      #pragma unroll
      for (int t = 0; t < 4; ++t){ ps[t] = __expf(st[t][r] - mn); rsum += ps[t]; }
      rsum += __shfl_xor(rsum, 1);
      rsum += __shfl_xor(rsum, 2);
      rsum += __shfl_xor(rsum, 4);
      rsum += __shfl_xor(rsum, 8);
      zrun[r] = zrun[r]*al + rsum;
      mrun[r] = mn;
      alr[r] = al;
      const int prow = quad*4 + r, pswz = prow & 7;
      #pragma unroll
      for (int t = 0; t < 4; ++t)
        Pl[w*1024 + prow*64 + (((t*2 + (col >> 3)) ^ pswz)*8) + (col & 7)] = (f16)ps[t];
    }
    #pragma unroll
    for (int dt = 0; dt < 8; ++dt)
      #pragma unroll
      for (int r = 0; r < 4; ++r) O[dt][r] *= alr[r];
    __builtin_amdgcn_wave_barrier();
    // ---- PV from LDS ----
    #pragma unroll
    for (int kk = 0; kk < 2; ++kk){
      f16x8 ap = *(const f16x8*)&Pl[w*1024 + col*64 + (((kk*4 + quad) ^ (col & 7))*8)];
      #pragma unroll
      for (int dt = 0; dt < 8; ++dt){
        const int d = col + dt*16;
        f16x8 bv = *(const f16x8*)&Vl[d*64 + (((kk*4 + quad) ^ (d & 7))*8)];
        O[dt] = __builtin_amdgcn_mfma_f32_16x16x32_f16(ap, bv, O[dt], 0, 0, 0);
      }
    }
    __builtin_amdgcn_wave_barrier();
  }
#undef LOADKV
  const int growb = b*LQ + l0 + w*16 + quad*4;
  #pragma unroll
  for (int r = 0; r < 4; ++r){
    f16* od = Opart + ((size_t)sp*NROW + growb + r)*128 + col;
    #pragma unroll
    for (int dt = 0; dt < 8; ++dt) od[dt*16] = (f16)O[dt][r];
  }
  if (col == 0){
    #pragma unroll
    for (int r = 0; r < 4; ++r){
      ((float2*)mZ)[(size_t)sp*NROW + growb + r] = make_float2(mrun[r], zrun[r]);
    }
  }
}

// ========== combine splits (f16 partials) -> cat16 H columns [512,640) ==========
__global__ __launch_bounds__(256) void k_comb(const f16* __restrict__ Opart,
    const float* __restrict__ mZ, f16* __restrict__ cat)
{
  int i = blockIdx.x*256 + threadIdx.x;         // NROW*64
  int row = i >> 6, d2 = (i & 63)*2;
  float ms[NSPLIT], zs[NSPLIT];
  float M = -1e30f;
  #pragma unroll
  for (int s = 0; s < NSPLIT; ++s){
    float2 v = ((const float2*)mZ)[(size_t)s*NROW + row];
    ms[s] = v.x; zs[s] = v.y;
    M = fmaxf(M, v.x);
  }
  float Zt = 0.f, ax = 0.f, ay = 0.f;
  #pragma unroll
  for (int s = 0; s < NSPLIT; ++s){
    float e = __expf(ms[s] - M);
    Zt += zs[s]*e;
    f16x2 op = *(const f16x2*)(Opart + ((size_t)s*NROW + row)*128 + d2);
    ax += e*(float)op.x; ay += e*(float)op.y;
  }
  float inv = 1.f/Zt;
  f16x2 o = { (f16)(ax*inv), (f16)(ay*inv) };
  *(f16x2*)(cat + (size_t)row*640 + 512 + d2) = o;
}

// ========== prep for MFMA GEMMs: cat16 x-part + W^T f16 + Wm^T f16.
// blocks [0,2048): x f32 -> cat16 cols [0,512).
// [2048,2208): w16[n][k] = W[k][n] (n<128: Wsg, else Wtn), k<640.
// [2208,2272): wm16[n][k] = Wm[k][n], n<128, k<512. ==========
__global__ __launch_bounds__(256) void k_prep(const float* __restrict__ x,
    const float* __restrict__ Wsg, const float* __restrict__ Wtn,
    const float* __restrict__ Wm,
    f16* __restrict__ cat, f16* __restrict__ w16, f16* __restrict__ wm16)
{
  if (blockIdx.x < 2048){
    int id = blockIdx.x*256 + threadIdx.x;     // 524288 = 4096 rows * 128 quads
    int row = id >> 7, c4 = (id & 127)*4;
    float4 v = *(const float4*)(x + (size_t)row*512 + c4);
    f16x4 o = { (f16)v.x, (f16)v.y, (f16)v.z, (f16)v.w };
    *(f16x4*)(cat + (size_t)row*640 + c4) = o;
  } else if (blockIdx.x < 2208){
    int id = (blockIdx.x - 2048)*256 + threadIdx.x;   // 40960 = 256 n * 160 k-quads
    int n = id / 160;
    int k0 = (id - n*160)*4;
    const float* src = n < 128 ? (Wsg + n) : (Wtn + (n - 128));
    f16x4 o = { (f16)src[(k0+0)*128], (f16)src[(k0+1)*128],
                (f16)src[(k0+2)*128], (f16)src[(k0+3)*128] };
    *(f16x4*)(w16 + (size_t)n*640 + k0) = o;
  } else {
    int id = (blockIdx.x - 2208)*256 + threadIdx.x;   // 16384 = 128 n * 128 k-quads
    int n = id >> 7;
    int k0 = (id & 127)*4;
    const float* src = Wm + n;
    f16x4 o = { (f16)src[(k0+0)*128], (f16)src[(k0+1)*128],
                (f16)src[(k0+2)*128], (f16)src[(k0+3)*128] };
    *(f16x4*)(wm16 + (size_t)n*512 + k0) = o;
  }
}

// ========== q MFMA GEMM: q[4096][128] = f16(relu(cat16[:, :512] @ wm16^T + bm)).
// 1 wave per 16 rows, 8 n-tiles, K=512 in 16 mfma steps. ==========
__global__ __launch_bounds__(64) void k_qgemm2(const f16* __restrict__ cat,
    const f16* __restrict__ wm16, const float* __restrict__ bm, f16* __restrict__ q)
{
  const int lane = threadIdx.x;
  const int quad = lane >> 4, col = lane & 15;
  const int koff = quad*8;
  const int row0 = blockIdx.x * 16;
  const f16* ar = cat + (size_t)(row0 + col)*640 + koff;
  const f16* br = wm16 + (size_t)col*512 + koff;
  f32x4 acc[8];
  #pragma unroll
  for (int nt = 0; nt < 8; ++nt) acc[nt] = (f32x4){0.f,0.f,0.f,0.f};
  for (int ks = 0; ks < 16; ++ks){
    f16x8 a = *(const f16x8*)(ar + ks*32);
    #pragma unroll
    for (int nt = 0; nt < 8; ++nt){
      f16x8 b = *(const f16x8*)(br + (size_t)nt*16*512 + ks*32);
      acc[nt] = __builtin_amdgcn_mfma_f32_16x16x32_f16(a, b, acc[nt], 0, 0, 0);
    }
  }
  #pragma unroll
  for (int nt = 0; nt < 8; ++nt){
    int n = nt*16 + col;
    float bv = bm[n];
    #pragma unroll
    for (int r = 0; r < 4; ++r){
      float v = fmaxf(acc[nt][r] + bv, 0.f);
      q[(size_t)(row0 + quad*4 + r)*128 + n] = (f16)v;
    }
  }
}

// ========== final MFMA GEMM: out[4096][256] = act(cat16 @ w16^T + bias).
// 1 wave per 16 rows, 16 n-tiles, K=640 in 20 mfma steps. n<128: sigmoid, else tanh ==========
__global__ __launch_bounds__(64) void k_fin2(const f16* __restrict__ cat,
    const f16* __restrict__ w16, const float* __restrict__ bsg,
    const float* __restrict__ btn, float* __restrict__ out)
{
  const int lane = threadIdx.x;
  const int quad = lane >> 4, col = lane & 15;
  const int koff = quad*8;
  const int row0 = blockIdx.x * 16;
  const f16* ar = cat + (size_t)(row0 + col)*640 + koff;
  const f16* br = w16 + (size_t)col*640 + koff;
  f32x4 acc[16];
  #pragma unroll
  for (int nt = 0; nt < 16; ++nt) acc[nt] = (f32x4){0.f,0.f,0.f,0.f};
  for (int ks = 0; ks < 20; ++ks){
    f16x8 a = *(const f16x8*)(ar + ks*32);
    #pragma unroll
    for (int nt = 0; nt < 16; ++nt){
      f16x8 b = *(const f16x8*)(br + (size_t)nt*16*640 + ks*32);
      acc[nt] = __builtin_amdgcn_mfma_f32_16x16x32_f16(a, b, acc[nt], 0, 0, 0);
    }
  }
  #pragma unroll
  for (int nt = 0; nt < 16; ++nt){
    int n = nt*16 + col;
    float bv = n < 128 ? bsg[n] : btn[n - 128];
    #pragma unroll
    for (int r = 0; r < 4; ++r){
      float v = acc[nt][r] + bv;
      v = n < 128 ? 1.f/(1.f + __expf(-v)) : tanhf(v);
      out[(size_t)(row0 + quad*4 + r)*256 + n] = v;
    }
  }
}

extern "C" void kernel_launch(void* const* d_in, const int* in_sizes, int n_in,
                              void* d_out, int out_size, void* d_ws, size_t ws_size,
                              hipStream_t stream)
{
  const float* x    = (const float*)d_in[0];
  const float* nfr  = (const float*)d_in[1];
  const int*   eidx = (const int*)d_in[2];
  const int*   hidx = (const int*)d_in[3];
  const float *Wg1=(const float*)d_in[4],  *bg1=(const float*)d_in[5];
  const float *Wg2=(const float*)d_in[6],  *bg2=(const float*)d_in[7];
  const float *Wh1=(const float*)d_in[8],  *bh1=(const float*)d_in[9];
  const float *Wh2=(const float*)d_in[10], *bh2=(const float*)d_in[11];
  const float *Wm =(const float*)d_in[12], *bm =(const float*)d_in[13];
  const float *Wm2=(const float*)d_in[14], *bm2=(const float*)d_in[15];
  const float *Wsg=(const float*)d_in[16], *bsg=(const float*)d_in[17];
  const float *Wtn=(const float*)d_in[18], *btn=(const float*)d_in[19];
  float* out = (float*)d_out;

  // ---- workspace layout. Aliases:
  //  h4_16 at base; bins + gcur live only until k_csr, alias agg16 region
  //  (bin_s in the otherwise-free [50.3MB, 67.1MB) hole);
  //  cat16/w16/wm16 alias agg16+bins region (attention phase only);
  //  Opart f16 (16MB) aliases dead bufA; kb/gT alias csr_dst/csr_pn. ----
  char* base = (char*)d_ws;
  f16*   h4_16  = (f16*)(base);                          // 16 MB
  f16*   agg16  = (f16*)(base + 33554432);               // 16 MB (graph phase only)
  u32*   bin_e  = (u32*)(base + 33554432);               // 5 MB   (aliases agg16)
  u32*   bin_pn = (u32*)(base + 38797312);               // 5 MB
  u32*   bin_pe = (u32*)(base + 44040192);               // 4.5 MB
  int*   gcur   = (int*)(base + 48758784);               // 1.75 KB
  u32*   bin_s  = (u32*)(base + 50331648);               // 5 MB (free hole)
  f16*   cat16  = (f16*)(base + 33554432);               // 5.24 MB (attention phase)
  f16*   w16    = (f16*)(base + 38797312);               // 320 KB  (attention phase)
  f16*   wm16   = (f16*)(base + 39124992);               // 128 KB  (attention phase)
  f16*   bufA   = (f16*)(base + 67108864);               // 16 MB  (nfr16 / h2_16)
  f16*   bufB   = (f16*)(base + 83886080);               // 16 MB  (h1_16 / h3_16)
  f16*   Opart  = (f16*)(base + 67108864);               // 16 MB f16 (aliases bufA)
  u16*   csr_dst= (u16*)(base + 100663296);              // 8 MB used of 16 MB region
  f16*   kb     = (f16*)(base + 100663296);              //   (aliases csr_dst)
  u16*   csr_pn = (u16*)(base + 117440512);              // 8 MB used of 16 MB region
  f16*   gT     = (f16*)(base + 117440512);              //   (aliases csr_pn)
  u16*   csr_pe = (u16*)(base + 134217728);              // 3 MB used of 6 MB region
  int*   cnt_dst= (int*)(base + 140509184);
  int*   cnt_pn = (int*)(base + 140771328);
  int*   cnt_pe = (int*)(base + 141033472);
  int*   du     = (int*)(base + 141049856);              // 256 KB
  float* ef0    = (float*)(base + 141312000);            // 2 MB
  f16*   ef1    = (f16*)(base + 143409152);              // 1 MB (f16)
  f16*   qb     = (f16*)(base + 145506304);              // 1 MB
  float* mZ     = (float*)(base + 146554880);            // 512 KB (NSPLIT16)
  const size_t needB = (size_t)147079168;
  if (ws_size < needB) return;

  // ---- CSR build: bin (phase A, 4096 items/block, dst+src+pn+pe) then
  //      per-bucket insert + du counting (phase B) ----
  hipMemsetAsync(gcur, 0, 1792, stream);
  k_bin<<<512, 256, 0, stream>>>(eidx, hidx, gcur, bin_e, bin_s, bin_pn, bin_pe);
  k_csr<<<448, 256, 0, stream>>>(gcur, bin_e, bin_s, bin_pn, bin_pe,
                                 cnt_dst, csr_dst, cnt_pn, csr_pn, cnt_pe, csr_pe, du);

  // ---- layer 1 ----
  k_pre<<<NNODE*64/256, 256, 0, stream>>>(nfr, du, bufA);
  k_gagg16<<<NNODE/4, 256, 0, stream>>>(cnt_dst, csr_dst, bufA, agg16);
  k_gemm<1,1><<<NNODE/32, 256, 0, stream>>>(agg16, Wg1, cnt_dst, bg1, bufB);
  k_hea16<<<NHE/4, 256, 0, stream>>>(cnt_pe, csr_pe, bufB, ef0);
  k_gemm<3,0><<<NHE/32, 256, 0, stream>>>(ef0, Wh1, nullptr, nullptr, ef1);
  k_nha<1><<<NNODE/4, 256, 0, stream>>>(cnt_pn, csr_pn, ef1, bh1, nfr, du, bufA);

  // ---- layer 2 ----
  k_gagg16<<<NNODE/4, 256, 0, stream>>>(cnt_dst, csr_dst, bufA, agg16);
  k_gemm<1,1><<<NNODE/32, 256, 0, stream>>>(agg16, Wg2, cnt_dst, bg2, bufB);
  k_hea16<<<NHE/4, 256, 0, stream>>>(cnt_pe, csr_pe, bufB, ef0);
  k_gemm<3,0><<<NHE/32, 256, 0, stream>>>(ef0, Wh2, nullptr, nullptr, ef1);
  k_nha<0><<<NNODE/4, 256, 0, stream>>>(cnt_pn, csr_pn, ef1, bh2, nfr, nullptr, h4_16);

  // ---- attention (agg16/bins dead from here: cat16/w16/wm16 safe) ----
  k_prep<<<2272, 256, 0, stream>>>(x, Wsg, Wtn, Wm, cat16, w16, wm16);
  k_qgemm2<<<NROW/16, 64, 0, stream>>>(cat16, wm16, bm, qb);
  k_gemm<2,1><<<NNODE/32, 256, 0, stream>>>(h4_16, Wm2, nullptr, bm2, kb);
  k_gt<<<dim3(NPER/64, 2, BSZ), 256, 0, stream>>>(h4_16, gT);
  k_flash<<<dim3(NSPLIT, LQ/128, BSZ), 512, 0, stream>>>(qb, kb, gT, Opart, mZ);
  k_comb<<<NROW*64/256, 256, 0, stream>>>(Opart, mZ, cat16);
  k_fin2<<<NROW/16, 64, 0, stream>>>(cat16, w16, bsg, btn, out);

  (void)in_sizes; (void)n_in; (void)out_size;
}

// Round 12
// 550.140 us; speedup vs baseline: 2.2282x; 1.1084x over previous
//
#include <hip/hip_runtime.h>
#include <hip/hip_bf16.h>

#define BSZ   8
#define NPER  8192
#define NNODE 65536       // BSZ*NPER
#define EPG   131072      // edges per graph
#define EMB   128
#define ENCD  512
#define LQ    512
#define NHE   4096
#define NE    1048576
#define NP    1048576
#define NROW  4096        // BSZ*LQ
#define NSPLIT 16
#define SLOT_N 64
#define SLOT_E 384
// binning: 128 node-buckets (512 nodes), 64 he-buckets (64 hyperedges)
#define CAP_E  10240      // per node-bucket capacity, edges  (mean 8192, +22 sigma)
#define CAP_PN 10240      // per node-bucket capacity, pairs  (mean 8192)
#define CAP_PE 18432      // per he-bucket capacity, pairs    (mean 16384, +16 sigma)

typedef _Float16 f16;
typedef _Float16 f16x2 __attribute__((ext_vector_type(2)));
typedef _Float16 f16x4 __attribute__((ext_vector_type(4)));
typedef _Float16 f16x8 __attribute__((ext_vector_type(8)));
typedef float f32x4 __attribute__((ext_vector_type(4)));
typedef unsigned short u16;
typedef unsigned int u32;

// ========== phase A: bin edges (by dst AND by src) and pairs (by pn and pe)
// into contiguous per-bucket arrays.  NO global du atomics (du comes from
// bin_s counting in phase B).  4096 items/block halves boundary-line waste.
// gcur layout: [0,128) edge-dst, [128,256) pn, [256,320) pe, [320,448) edge-src ==========
__global__ __launch_bounds__(256) void k_bin(const int* __restrict__ eidx,
    const int* __restrict__ hidx, int* __restrict__ gcur,
    u32* __restrict__ bin_e, u32* __restrict__ bin_s,
    u32* __restrict__ bin_pn, u32* __restrict__ bin_pe)
{
  __shared__ int lh[448];
  __shared__ int gb[448];
  const int tid = threadIdx.x;
  for (int i = tid; i < 448; i += 256) lh[i] = 0;
  __syncthreads();
  if (blockIdx.x < 256){
    // 4096 edges per block: dst-bin via lh[0,128), src-bin via lh[128,256)->gcur[320,448)
    const int eb4 = blockIdx.x*1024;
    int ss[16], dd[16];
    #pragma unroll
    for (int t = 0; t < 4; ++t){
      int4 s4 = ((const int4*)eidx)[eb4 + t*256 + tid];
      int4 d4 = ((const int4*)(eidx + NE))[eb4 + t*256 + tid];
      ss[t*4+0]=s4.x; ss[t*4+1]=s4.y; ss[t*4+2]=s4.z; ss[t*4+3]=s4.w;
      dd[t*4+0]=d4.x; dd[t*4+1]=d4.y; dd[t*4+2]=d4.z; dd[t*4+3]=d4.w;
    }
    int rd[16], rs[16];
    #pragma unroll
    for (int u = 0; u < 16; ++u){
      rd[u] = atomicAdd(&lh[dd[u] >> 9], 1);
      rs[u] = atomicAdd(&lh[128 + (ss[u] >> 9)], 1);
    }
    __syncthreads();
    if (tid < 128){
      if (lh[tid]) gb[tid] = atomicAdd(&gcur[tid], lh[tid]);
    } else {
      if (lh[tid]) gb[tid] = atomicAdd(&gcur[192 + tid], lh[tid]);   // gcur[320 + (tid-128)]
    }
    __syncthreads();
    #pragma unroll
    for (int u = 0; u < 16; ++u){
      int b = dd[u] >> 9;
      int pos = gb[b] + rd[u];
      if (pos < CAP_E)
        bin_e[(size_t)b*CAP_E + pos] = (u32)(dd[u] & 0xffff) | ((u32)ss[u] << 16);
      int bs = ss[u] >> 9;
      int pos2 = gb[128 + bs] + rs[u];
      if (pos2 < CAP_E)
        bin_s[(size_t)bs*CAP_E + pos2] = (u32)(ss[u] & 0xffff);
    }
  } else {
    // 4096 pairs per block, binned both directions
    const int pb4 = (blockIdx.x - 256)*2048;
    int pn[16], pe[16];
    #pragma unroll
    for (int t = 0; t < 8; ++t){
      int4 p = ((const int4*)hidx)[pb4 + t*256 + tid];
      pn[t*2+0] = p.x; pe[t*2+0] = p.y;
      pn[t*2+1] = p.z; pe[t*2+1] = p.w;
    }
    int rn[16], re[16];
    #pragma unroll
    for (int u = 0; u < 16; ++u){
      rn[u] = atomicAdd(&lh[128 + (pn[u] >> 9)], 1);
      re[u] = atomicAdd(&lh[256 + (pe[u] >> 6)], 1);
    }
    __syncthreads();
    if (tid < 192 && lh[128 + tid]) gb[128 + tid] = atomicAdd(&gcur[128 + tid], lh[128 + tid]);
    __syncthreads();
    #pragma unroll
    for (int u = 0; u < 16; ++u){
      int bn = pn[u] >> 9;
      int pos = gb[128 + bn] + rn[u];
      if (pos < CAP_PN)
        bin_pn[(size_t)bn*CAP_PN + pos] = (u32)pn[u] | ((u32)pe[u] << 16);
      int be = pe[u] >> 6;
      int pos2 = gb[256 + be] + re[u];
      if (pos2 < CAP_PE)
        bin_pe[(size_t)be*CAP_PE + pos2] = (u32)pe[u] | ((u32)pn[u] << 16);
    }
  }
}

// ========== phase B: per-bucket CSR insert (LDS cursors, windowed u16 writes)
// + du (src out-degree) counting from bin_s.
// blocks [0,128) edge-dst, [128,256) pn, [256,320) pe, [320,448) src->du ==========
__global__ __launch_bounds__(256) void k_csr(const int* __restrict__ gcur,
    const u32* __restrict__ bin_e, const u32* __restrict__ bin_s,
    const u32* __restrict__ bin_pn, const u32* __restrict__ bin_pe,
    int* __restrict__ cnt_dst, u16* __restrict__ csr_dst,
    int* __restrict__ cnt_pn, u16* __restrict__ csr_pn,
    int* __restrict__ cnt_pe, u16* __restrict__ csr_pe,
    int* __restrict__ du)
{
  const int tid = threadIdx.x;
  if (blockIdx.x < 256){
    __shared__ int cur[512];
    const int isP = blockIdx.x >= 128;
    const int b = blockIdx.x & 127;
    cur[tid] = 0; cur[tid + 256] = 0;
    __syncthreads();
    const int n0 = b*512;
    const int cap = isP ? CAP_PN : CAP_E;
    int raw = gcur[isP ? 128 + b : b];
    int count = raw < cap ? raw : cap;
    const u32* bin = (isP ? bin_pn : bin_e) + (size_t)b*cap;
    u16* csr = isP ? csr_pn : csr_dst;
    for (int i = tid; i < count; i += 256){
      u32 v = bin[i];
      int row = v & 0xffff, val = v >> 16;
      int c = atomicAdd(&cur[row - n0], 1);
      if (c < SLOT_N) csr[(size_t)row*SLOT_N + c] = (u16)val;
    }
    __syncthreads();
    int* cnt = isP ? cnt_pn : cnt_dst;
    cnt[n0 + tid]       = cur[tid];
    cnt[n0 + 256 + tid] = cur[tid + 256];
  } else if (blockIdx.x < 320){
    __shared__ int cur[64];
    const int b = blockIdx.x - 256;
    if (tid < 64) cur[tid] = 0;
    __syncthreads();
    const int e0 = b*64;
    int raw = gcur[256 + b];
    int count = raw < CAP_PE ? raw : CAP_PE;
    const u32* bin = bin_pe + (size_t)b*CAP_PE;
    for (int i = tid; i < count; i += 256){
      u32 v = bin[i];
      int row = v & 0xffff, val = v >> 16;
      int c = atomicAdd(&cur[row - e0], 1);
      if (c < SLOT_E) csr_pe[(size_t)row*SLOT_E + c] = (u16)val;
    }
    __syncthreads();
    if (tid < 64) cnt_pe[e0 + tid] = cur[tid];
  } else {
    // src out-degree counting -> du (no CSR payload)
    __shared__ int cur[512];
    const int b = blockIdx.x - 320;
    cur[tid] = 0; cur[tid + 256] = 0;
    __syncthreads();
    const int n0 = b*512;
    int raw = gcur[320 + b];
    int count = raw < CAP_E ? raw : CAP_E;
    const u32* bin = bin_s + (size_t)b*CAP_E;
    for (int i = tid; i < count; i += 256){
      int row = (int)(bin[i] & 0xffff);
      atomicAdd(&cur[row - n0], 1);
    }
    __syncthreads();
    du[n0 + tid]       = cur[tid];
    du[n0 + 256 + tid] = cur[tid + 256];
  }
}

// ========== weight prep (runs once, up front): wT[n][k] = f16(W[k][n]) for
// Wg1 / Wg2 / Wm2 (128x128 each).  48 blocks. ==========
__global__ __launch_bounds__(256) void k_wprep(const float* __restrict__ Wg1,
    const float* __restrict__ Wg2, const float* __restrict__ Wm2,
    f16* __restrict__ wg1, f16* __restrict__ wg2, f16* __restrict__ wm2)
{
  int id = blockIdx.x*256 + threadIdx.x;        // 3*4096
  int wsel = id >> 12;
  int r = id & 4095;
  int n = r >> 5, k0 = (r & 31)*4;
  const float* src = (wsel == 0 ? Wg1 : wsel == 1 ? Wg2 : Wm2) + n;
  f16* dst = wsel == 0 ? wg1 : wsel == 1 ? wg2 : wm2;
  f16x4 o = { (f16)src[(k0+0)*128], (f16)src[(k0+1)*128],
              (f16)src[(k0+2)*128], (f16)src[(k0+3)*128] };
  *(f16x4*)(dst + n*128 + k0) = o;
}

// ========== nfr16 = f16(nfr * rsqrt(max(du,1))) ==========
__global__ __launch_bounds__(256) void k_pre(const float* __restrict__ nfr,
    const int* __restrict__ du, f16* __restrict__ out)
{
  int i = blockIdx.x*256 + threadIdx.x;         // NNODE*64
  int node = i >> 6, j = i & 63;
  float ds = rsqrtf(fmaxf((float)du[node], 1.f));
  float2 v = ((const float2*)(nfr + (size_t)node*128))[j];
  f16x2 o = { (f16)(v.x*ds), (f16)(v.y*ds) };
  ((f16x2*)(out + (size_t)node*128))[j] = o;
}

// ========== gconv gather (f16 src): 1 wave per node, branchless 8-batches.
// Indices loaded as int4 (8 u16) per batch; masked slots redirect to row[0]
// (hot line) with adds skipped.  Graph->XCD swizzle keeps each graph's
// source slab in one XCD's L2. ==========
__global__ __launch_bounds__(256) void k_gagg16(const int* __restrict__ cnt,
    const u16* __restrict__ csr, const f16* __restrict__ src, f16* __restrict__ agg)
{
  const int wv = threadIdx.x >> 6, lane = threadIdx.x & 63;
  const int blk = blockIdx.x;                   // NNODE/4 blocks
  const int n = (blk & 7)*NPER + (blk >> 3)*4 + wv;
  const int nd = cnt[n];
  const int c = nd < SLOT_N ? nd : SLOT_N;
  const u16* row = csr + (size_t)n*SLOT_N;
  const f16x2* s2 = (const f16x2*)src;
  float ax = 0.f, ay = 0.f;
  if (c > 0){
    const int i0 = row[0];
    #pragma unroll 1
    for (int b = 0; b < 8; ++b){
      if (b*8 >= c) break;                      // wave-uniform
      int4 iv = *(const int4*)(row + b*8);
      int ix[8] = { iv.x & 0xffff, (iv.x >> 16) & 0xffff,
                    iv.y & 0xffff, (iv.y >> 16) & 0xffff,
                    iv.z & 0xffff, (iv.z >> 16) & 0xffff,
                    iv.w & 0xffff, (iv.w >> 16) & 0xffff };
      f16x2 vv[8];
      #pragma unroll
      for (int k = 0; k < 8; ++k){
        int id = (b*8 + k < c) ? ix[k] : i0;
        vv[k] = s2[(size_t)id*64 + lane];
      }
      #pragma unroll
      for (int k = 0; k < 8; ++k){
        if (b*8 + k < c){ ax += (float)vv[k].x; ay += (float)vv[k].y; }
      }
    }
  }
  ((f16x2*)(agg + (size_t)n*128))[lane] = (f16x2){ (f16)ax, (f16)ay };
}

// ========== hconv stage 1 (f16 source): ef0[e] = (1/|e|) * sum src16[pn].
// 1 wave per hyperedge (4/block), 8-deep unrolled gather -> 8 loads in flight ==========
__global__ __launch_bounds__(256) void k_hea16(const int* __restrict__ cnt,
    const u16* __restrict__ csr, const f16* __restrict__ src, float* __restrict__ ef)
{
  const int wv = threadIdx.x >> 6, lane = threadIdx.x & 63;
  const int e = blockIdx.x*4 + wv;
  const int nd = cnt[e];
  const int n = nd < SLOT_E ? nd : SLOT_E;
  const u16* row = csr + (size_t)e*SLOT_E;
  const f16x2* s2 = (const f16x2*)src;
  float ax = 0.f, ay = 0.f;
  int j = 0;
  for (; j + 7 < n; j += 8){
    int p0 = row[j],   p1 = row[j+1], p2 = row[j+2], p3 = row[j+3];
    int p4 = row[j+4], p5 = row[j+5], p6 = row[j+6], p7 = row[j+7];
    f16x2 v0 = s2[(size_t)p0*64 + lane];
    f16x2 v1 = s2[(size_t)p1*64 + lane];
    f16x2 v2 = s2[(size_t)p2*64 + lane];
    f16x2 v3 = s2[(size_t)p3*64 + lane];
    f16x2 v4 = s2[(size_t)p4*64 + lane];
    f16x2 v5 = s2[(size_t)p5*64 + lane];
    f16x2 v6 = s2[(size_t)p6*64 + lane];
    f16x2 v7 = s2[(size_t)p7*64 + lane];
    ax += (((float)v0.x + (float)v1.x) + ((float)v2.x + (float)v3.x))
        + (((float)v4.x + (float)v5.x) + ((float)v6.x + (float)v7.x));
    ay += (((float)v0.y + (float)v1.y) + ((float)v2.y + (float)v3.y))
        + (((float)v4.y + (float)v5.y) + ((float)v6.y + (float)v7.y));
  }
  for (; j < n; ++j){
    f16x2 v = s2[(size_t)row[j]*64 + lane];
    ax += (float)v.x; ay += (float)v.y;
  }
  float s = nd > 0 ? 1.f/(float)nd : 0.f;
  ((float2*)(ef + (size_t)e*128))[lane] = make_float2(ax*s, ay*s);
}

// ========== MFMA node GEMM: out[NNODE][128] = act(in16 @ wT^T + bias).
// 1 wave per 16 rows (4 waves/block), 8 n-tiles, K=128 in 4 mfma steps.
// MODE 1: f16(acc*rsqrt(max(cnt,1)) + bias)   MODE 2: f16(relu(acc + bias)) ==========
template<int MODE>
__global__ __launch_bounds__(256) void k_ngemm(const f16* __restrict__ inp,
    const f16* __restrict__ wT, const int* __restrict__ cnt,
    const float* __restrict__ bias, f16* __restrict__ outp)
{
  const int wv = threadIdx.x >> 6, lane = threadIdx.x & 63;
  const int quad = lane >> 4, col = lane & 15;
  const int koff = quad*8;
  const int row0 = blockIdx.x*64 + wv*16;
  const f16* ar = inp + (size_t)(row0 + col)*128 + koff;
  const f16* br = wT + (size_t)col*128 + koff;
  f32x4 acc[8];
  #pragma unroll
  for (int nt = 0; nt < 8; ++nt) acc[nt] = (f32x4){0.f,0.f,0.f,0.f};
  #pragma unroll
  for (int ks = 0; ks < 4; ++ks){
    f16x8 a = *(const f16x8*)(ar + ks*32);
    #pragma unroll
    for (int nt = 0; nt < 8; ++nt){
      f16x8 b = *(const f16x8*)(br + (size_t)nt*16*128 + ks*32);
      acc[nt] = __builtin_amdgcn_mfma_f32_16x16x32_f16(a, b, acc[nt], 0, 0, 0);
    }
  }
  float sc[4];
  #pragma unroll
  for (int r = 0; r < 4; ++r)
    sc[r] = (MODE == 1) ? rsqrtf(fmaxf((float)cnt[row0 + quad*4 + r], 1.f)) : 1.f;
  #pragma unroll
  for (int nt = 0; nt < 8; ++nt){
    int n = nt*16 + col;
    float bv = bias[n];
    #pragma unroll
    for (int r = 0; r < 4; ++r){
      float v = acc[nt][r];
      if (MODE == 1) v = v*sc[r] + bv;
      else           v = fmaxf(v + bv, 0.f);
      outp[(size_t)(row0 + quad*4 + r)*128 + n] = (f16)v;
    }
  }
}

// ========== register-blocked 128x128 GEMM (small NHE rows only).
// MODE 3: f16 raw, f32 input ==========
template<int MODE, int IN16>
__global__ __launch_bounds__(256, 2) void k_gemm(const void* __restrict__ inp,
    const float* __restrict__ W, const int* __restrict__ cnt,
    const float* __restrict__ bias, void* __restrict__ outp)
{
  __shared__ float Wl[128*128];
  __shared__ float Rl[32*128];
  const int tid = threadIdx.x;
  const int rbase = blockIdx.x*32;
  for (int i = tid; i < 16384; i += 256) Wl[i] = W[i];
  if (IN16){
    const f16x2* s2 = (const f16x2*)(((const f16*)inp) + (size_t)rbase*128);
    for (int i = tid; i < 2048; i += 256){
      f16x2 v = s2[i];
      ((float2*)Rl)[i] = make_float2((float)v.x, (float)v.y);
    }
  } else {
    const float* src = ((const float*)inp) + (size_t)rbase*128;
    for (int i = tid; i < 4096; i += 256) Rl[i] = src[i];
  }
  __syncthreads();
  const int c0 = (tid & 31)*4;
  const int r0 = (tid >> 5)*4;
  f32x4 acc[4];
  #pragma unroll
  for (int j = 0; j < 4; ++j) acc[j] = (f32x4){0.f,0.f,0.f,0.f};
  for (int d = 0; d < 128; d += 4){
    f32x4 w0 = *(const f32x4*)&Wl[(d+0)*128 + c0];
    f32x4 w1 = *(const f32x4*)&Wl[(d+1)*128 + c0];
    f32x4 w2 = *(const f32x4*)&Wl[(d+2)*128 + c0];
    f32x4 w3 = *(const f32x4*)&Wl[(d+3)*128 + c0];
    #pragma unroll
    for (int j = 0; j < 4; ++j){
      f32x4 rr = *(const f32x4*)&Rl[(r0+j)*128 + d];
      acc[j] += rr.x*w0 + rr.y*w1 + rr.z*w2 + rr.w*w3;
    }
  }
  #pragma unroll
  for (int j = 0; j < 4; ++j){
    const int row = rbase + r0 + j;
    if (MODE == 0){
      *(f32x4*)(((float*)outp) + (size_t)row*128 + c0) = acc[j];
    } else if (MODE == 1){
      float sc = rsqrtf(fmaxf((float)cnt[row], 1.f));
      f16* o = ((f16*)outp) + (size_t)row*128 + c0;
      #pragma unroll
      for (int k = 0; k < 4; ++k) o[k] = (f16)(acc[j][k]*sc + bias[c0+k]);
    } else if (MODE == 2){
      f16* o = ((f16*)outp) + (size_t)row*128 + c0;
      #pragma unroll
      for (int k = 0; k < 4; ++k) o[k] = (f16)fmaxf(acc[j][k] + bias[c0+k], 0.f);
    } else {
      f16* o = ((f16*)outp) + (size_t)row*128 + c0;
      #pragma unroll
      for (int k = 0; k < 4; ++k) o[k] = (f16)acc[j][k];
    }
  }
}

// ========== hconv stage 2 + relu + residual: 1 wave per node, branchless
// 8-batches (int4 index loads, masked adds, row[0] redirect).  f16 ef source,
// early nfr (HBM) load overlaps the gathers.  f16 out.
// PRES: scale by rsqrt(du) (for next layer's prescaled input) ==========
template<int PRES>
__global__ __launch_bounds__(256) void k_nha(const int* __restrict__ cnt,
    const u16* __restrict__ csr, const f16* __restrict__ ef,
    const float* __restrict__ bias, const float* __restrict__ nfr,
    const int* __restrict__ du, f16* __restrict__ outp)
{
  const int wv = threadIdx.x >> 6, lane = threadIdx.x & 63;
  const int n = blockIdx.x*4 + wv;
  const int nd = cnt[n];
  const int c = nd < SLOT_N ? nd : SLOT_N;
  const u16* row = csr + (size_t)n*SLOT_N;
  const f16x2* s2 = (const f16x2*)ef;
  float2 nf = ((const float2*)(nfr + (size_t)n*128))[lane];   // early: hides under gathers
  float e0 = PRES ? rsqrtf(fmaxf((float)du[n], 1.f)) : 1.f;
  float ax = 0.f, ay = 0.f;
  if (c > 0){
    const int i0 = row[0];
    #pragma unroll 1
    for (int b = 0; b < 8; ++b){
      if (b*8 >= c) break;                      // wave-uniform
      int4 iv = *(const int4*)(row + b*8);
      int ix[8] = { iv.x & 0xffff, (iv.x >> 16) & 0xffff,
                    iv.y & 0xffff, (iv.y >> 16) & 0xffff,
                    iv.z & 0xffff, (iv.z >> 16) & 0xffff,
                    iv.w & 0xffff, (iv.w >> 16) & 0xffff };
      f16x2 vv[8];
      #pragma unroll
      for (int k = 0; k < 8; ++k){
        int id = (b*8 + k < c) ? ix[k] : i0;
        vv[k] = s2[(size_t)id*64 + lane];
      }
      #pragma unroll
      for (int k = 0; k < 8; ++k){
        if (b*8 + k < c){ ax += (float)vv[k].x; ay += (float)vv[k].y; }
      }
    }
  }
  float bx = bias[lane*2], by = bias[lane*2+1];
  float s = nd > 0 ? 1.f/(float)nd : 0.f;
  float vx = fmaxf(ax*s + bx, 0.f) + nf.x;
  float vy = fmaxf(ay*s + by, 0.f) + nf.y;
  ((f16x2*)(outp + (size_t)n*128))[lane] = (f16x2){ (f16)(vx*e0), (f16)(vy*e0) };
}

// ========== gT[b][c][n] = h16[b*NPER+n][c]  (f16 transpose) ==========
__global__ __launch_bounds__(256) void k_gt(const f16* __restrict__ g, f16* __restrict__ gT)
{
  __shared__ f16 t[64][66];
  int b = blockIdx.z, n0 = blockIdx.x*64, c0 = blockIdx.y*64;
  for (int i = threadIdx.x; i < 64*64; i += 256){
    int n = i >> 6, c = i & 63;
    t[n][c] = g[((size_t)(b*NPER + n0 + n))*128 + c0 + c];
  }
  __syncthreads();
  for (int i = threadIdx.x; i < 64*64; i += 256){
    int c = i >> 6, n = i & 63;
    gT[((size_t)(b*128 + c0 + c))*NPER + n0 + n] = t[n][c];
  }
}

// ========== flash attention (R6): 128 q-rows/block (8 waves), n-slab 512, n-chunk 64,
// cooperative XOR-swizzled LDS staging, register prefetch, f16 Opart.
// 48 KB LDS, launch_bounds(512,4) -> 2 blocks/CU, 128 VGPR cap. ==========
#define NCH 64
__global__ __launch_bounds__(512, 4) void k_flash(const f16* __restrict__ qb,
    const f16* __restrict__ kb, const f16* __restrict__ gT,
    f16* __restrict__ Opart, float* __restrict__ mZ)
{
  __shared__ f16 Kl[64*128];        // 16 KB  [n 64][k 128], chunk-swizzled
  __shared__ f16 Vl[128*64];        // 16 KB  [d 128][n 64], chunk-swizzled
  __shared__ f16 Pl[8*16*64];       // 16 KB  per-wave [q 16][n 64], chunk-swizzled
  const int sp = blockIdx.x, l0 = blockIdx.y*128, b = blockIdx.z;
  const int tid = threadIdx.x;
  const int w = tid >> 6, lane = tid & 63;
  const int quad = lane >> 4, col = lane & 15;
  const int koff = quad*8;
  // staging lane mapping (512 threads)
  const int krow = tid >> 4;        // K: rows 0..31 (+32), chunks 0..15
  const int kc8  = tid & 15;
  const int vrow = tid >> 3;        // V: rows 0..63 (+64), chunks 0..7
  const int vc8  = tid & 7;

  const f16* qrow = qb + ((size_t)(b*LQ + l0 + w*16 + col))*128 + koff;
  f16x8 aq[4];
  #pragma unroll
  for (int ks = 0; ks < 4; ++ks) aq[ks] = *(const f16x8*)(qrow + ks*32);
  float mrun[4] = {-1e30f,-1e30f,-1e30f,-1e30f};
  float zrun[4] = {0.f,0.f,0.f,0.f};
  f32x4 O[8];
  #pragma unroll
  for (int i = 0; i < 8; ++i) O[i] = (f32x4){0.f,0.f,0.f,0.f};

  const int nbase = sp*(NPER/NSPLIT);          // 512-wide n slab
  f16x8 kr[2], vr[2];
#define LOADKV(N0)                                                           \
  { _Pragma("unroll")                                                        \
    for (int i2 = 0; i2 < 2; ++i2){                                          \
      kr[i2] = *(const f16x8*)(kb + ((size_t)(b*NPER + (N0) + krow + i2*32))*128 + kc8*8); \
      vr[i2] = *(const f16x8*)(gT + ((size_t)(b*128 + vrow + i2*64))*NPER + (N0) + vc8*8); \
    } }
  LOADKV(nbase);
  #pragma unroll 1
  for (int it = 0; it < (NPER/NSPLIT)/NCH; ++it){
    const int n0 = nbase + it*NCH;
    __syncthreads();                            // prior-iter LDS reads done
    #pragma unroll
    for (int i2 = 0; i2 < 2; ++i2){
      int r = krow + i2*32;
      *(f16x8*)&Kl[r*128 + ((kc8 ^ (r & 7))*8)] = kr[i2];
      int d = vrow + i2*64;
      *(f16x8*)&Vl[d*64  + ((vc8 ^ (d & 7))*8)] = vr[i2];
    }
    __syncthreads();                            // staging visible
    if (it < (NPER/NSPLIT)/NCH - 1) LOADKV(n0 + NCH);   // prefetch next tile

    // ---- QK^T from LDS ----
    f32x4 st[4];
    #pragma unroll
    for (int t = 0; t < 4; ++t){
      st[t] = (f32x4){0.f,0.f,0.f,0.f};
      const int r = t*16 + col, rs = r & 7;
      #pragma unroll
      for (int ks = 0; ks < 4; ++ks){
        f16x8 bf = *(const f16x8*)&Kl[r*128 + (((ks*4 + quad) ^ rs)*8)];
        st[t] = __builtin_amdgcn_mfma_f32_16x16x32_f16(aq[ks], bf, st[t], 0, 0, 0);
      }
    }
    // ---- softmax over 64 n ----
    float alr[4];
    #pragma unroll
    for (int r = 0; r < 4; ++r){
      float rm = st[0][r];
      #pragma unroll
      for (int t = 1; t < 4; ++t) rm = fmaxf(rm, st[t][r]);
      rm = fmaxf(rm, __shfl_xor(rm, 1));
      rm = fmaxf(rm, __shfl_xor(rm, 2));
      rm = fmaxf(rm, __shfl_xor(rm, 4));
      rm = fmaxf(rm, __shfl_xor(rm, 8));
      float mn = fmaxf(mrun[r], rm);
      float al = __expf(mrun[r] - mn);
      float ps[4], rsum = 0.f;
      #pragma unroll
      for (int t = 0; t < 4; ++t){ ps[t] = __expf(st[t][r] - mn); rsum += ps[t]; }
      rsum += __shfl_xor(rsum, 1);
      rsum += __shfl_xor(rsum, 2);
      rsum += __shfl_xor(rsum, 4);
      rsum += __shfl_xor(rsum, 8);
      zrun[r] = zrun[r]*al + rsum;
      mrun[r] = mn;
      alr[r] = al;
      const int prow = quad*4 + r, pswz = prow & 7;
      #pragma unroll
      for (int t = 0; t < 4; ++t)
        Pl[w*1024 + prow*64 + (((t*2 + (col >> 3)) ^ pswz)*8) + (col & 7)] = (f16)ps[t];
    }
    #pragma unroll
    for (int dt = 0; dt < 8; ++dt)
      #pragma unroll
      for (int r = 0; r < 4; ++r) O[dt][r] *= alr[r];
    __builtin_amdgcn_wave_barrier();
    // ---- PV from LDS ----
    #pragma unroll
    for (int kk = 0; kk < 2; ++kk){
      f16x8 ap = *(const f16x8*)&Pl[w*1024 + col*64 + (((kk*4 + quad) ^ (col & 7))*8)];
      #pragma unroll
      for (int dt = 0; dt < 8; ++dt){
        const int d = col + dt*16;
        f16x8 bv = *(const f16x8*)&Vl[d*64 + (((kk*4 + quad) ^ (d & 7))*8)];
        O[dt] = __builtin_amdgcn_mfma_f32_16x16x32_f16(ap, bv, O[dt], 0, 0, 0);
      }
    }
    __builtin_amdgcn_wave_barrier();
  }
#undef LOADKV
  const int growb = b*LQ + l0 + w*16 + quad*4;
  #pragma unroll
  for (int r = 0; r < 4; ++r){
    f16* od = Opart + ((size_t)sp*NROW + growb + r)*128 + col;
    #pragma unroll
    for (int dt = 0; dt < 8; ++dt) od[dt*16] = (f16)O[dt][r];
  }
  if (col == 0){
    #pragma unroll
    for (int r = 0; r < 4; ++r){
      ((float2*)mZ)[(size_t)sp*NROW + growb + r] = make_float2(mrun[r], zrun[r]);
    }
  }
}

// ========== combine splits (f16 partials) -> cat16 H columns [512,640) ==========
__global__ __launch_bounds__(256) void k_comb(const f16* __restrict__ Opart,
    const float* __restrict__ mZ, f16* __restrict__ cat)
{
  int i = blockIdx.x*256 + threadIdx.x;         // NROW*64
  int row = i >> 6, d2 = (i & 63)*2;
  float ms[NSPLIT], zs[NSPLIT];
  float M = -1e30f;
  #pragma unroll
  for (int s = 0; s < NSPLIT; ++s){
    float2 v = ((const float2*)mZ)[(size_t)s*NROW + row];
    ms[s] = v.x; zs[s] = v.y;
    M = fmaxf(M, v.x);
  }
  float Zt = 0.f, ax = 0.f, ay = 0.f;
  #pragma unroll
  for (int s = 0; s < NSPLIT; ++s){
    float e = __expf(ms[s] - M);
    Zt += zs[s]*e;
    f16x2 op = *(const f16x2*)(Opart + ((size_t)s*NROW + row)*128 + d2);
    ax += e*(float)op.x; ay += e*(float)op.y;
  }
  float inv = 1.f/Zt;
  f16x2 o = { (f16)(ax*inv), (f16)(ay*inv) };
  *(f16x2*)(cat + (size_t)row*640 + 512 + d2) = o;
}

// ========== prep for MFMA GEMMs: cat16 x-part + W^T f16 + Wm^T f16.
// blocks [0,2048): x f32 -> cat16 cols [0,512).
// [2048,2208): w16[n][k] = W[k][n] (n<128: Wsg, else Wtn), k<640.
// [2208,2272): wm16[n][k] = Wm[k][n], n<128, k<512. ==========
__global__ __launch_bounds__(256) void k_prep(const float* __restrict__ x,
    const float* __restrict__ Wsg, const float* __restrict__ Wtn,
    const float* __restrict__ Wm,
    f16* __restrict__ cat, f16* __restrict__ w16, f16* __restrict__ wm16)
{
  if (blockIdx.x < 2048){
    int id = blockIdx.x*256 + threadIdx.x;     // 524288 = 4096 rows * 128 quads
    int row = id >> 7, c4 = (id & 127)*4;
    float4 v = *(const float4*)(x + (size_t)row*512 + c4);
    f16x4 o = { (f16)v.x, (f16)v.y, (f16)v.z, (f16)v.w };
    *(f16x4*)(cat + (size_t)row*640 + c4) = o;
  } else if (blockIdx.x < 2208){
    int id = (blockIdx.x - 2048)*256 + threadIdx.x;   // 40960 = 256 n * 160 k-quads
    int n = id / 160;
    int k0 = (id - n*160)*4;
    const float* src = n < 128 ? (Wsg + n) : (Wtn + (n - 128));
    f16x4 o = { (f16)src[(k0+0)*128], (f16)src[(k0+1)*128],
                (f16)src[(k0+2)*128], (f16)src[(k0+3)*128] };
    *(f16x4*)(w16 + (size_t)n*640 + k0) = o;
  } else {
    int id = (blockIdx.x - 2208)*256 + threadIdx.x;   // 16384 = 128 n * 128 k-quads
    int n = id >> 7;
    int k0 = (id & 127)*4;
    const float* src = Wm + n;
    f16x4 o = { (f16)src[(k0+0)*128], (f16)src[(k0+1)*128],
                (f16)src[(k0+2)*128], (f16)src[(k0+3)*128] };
    *(f16x4*)(wm16 + (size_t)n*512 + k0) = o;
  }
}

// ========== q MFMA GEMM: q[4096][128] = f16(relu(cat16[:, :512] @ wm16^T + bm)).
// 1 wave per 16 rows, 8 n-tiles, K=512 in 16 mfma steps. ==========
__global__ __launch_bounds__(64) void k_qgemm2(const f16* __restrict__ cat,
    const f16* __restrict__ wm16, const float* __restrict__ bm, f16* __restrict__ q)
{
  const int lane = threadIdx.x;
  const int quad = lane >> 4, col = lane & 15;
  const int koff = quad*8;
  const int row0 = blockIdx.x * 16;
  const f16* ar = cat + (size_t)(row0 + col)*640 + koff;
  const f16* br = wm16 + (size_t)col*512 + koff;
  f32x4 acc[8];
  #pragma unroll
  for (int nt = 0; nt < 8; ++nt) acc[nt] = (f32x4){0.f,0.f,0.f,0.f};
  for (int ks = 0; ks < 16; ++ks){
    f16x8 a = *(const f16x8*)(ar + ks*32);
    #pragma unroll
    for (int nt = 0; nt < 8; ++nt){
      f16x8 b = *(const f16x8*)(br + (size_t)nt*16*512 + ks*32);
      acc[nt] = __builtin_amdgcn_mfma_f32_16x16x32_f16(a, b, acc[nt], 0, 0, 0);
    }
  }
  #pragma unroll
  for (int nt = 0; nt < 8; ++nt){
    int n = nt*16 + col;
    float bv = bm[n];
    #pragma unroll
    for (int r = 0; r < 4; ++r){
      float v = fmaxf(acc[nt][r] + bv, 0.f);
      q[(size_t)(row0 + quad*4 + r)*128 + n] = (f16)v;
    }
  }
}

// ========== final MFMA GEMM: out[4096][256] = act(cat16 @ w16^T + bias).
// 1 wave per 16 rows, 16 n-tiles, K=640 in 20 mfma steps. n<128: sigmoid, else tanh ==========
__global__ __launch_bounds__(64) void k_fin2(const f16* __restrict__ cat,
    const f16* __restrict__ w16, const float* __restrict__ bsg,
    const float* __restrict__ btn, float* __restrict__ out)
{
  const int lane = threadIdx.x;
  const int quad = lane >> 4, col = lane & 15;
  const int koff = quad*8;
  const int row0 = blockIdx.x * 16;
  const f16* ar = cat + (size_t)(row0 + col)*640 + koff;
  const f16* br = w16 + (size_t)col*640 + koff;
  f32x4 acc[16];
  #pragma unroll
  for (int nt = 0; nt < 16; ++nt) acc[nt] = (f32x4){0.f,0.f,0.f,0.f};
  for (int ks = 0; ks < 20; ++ks){
    f16x8 a = *(const f16x8*)(ar + ks*32);
    #pragma unroll
    for (int nt = 0; nt < 16; ++nt){
      f16x8 b = *(const f16x8*)(br + (size_t)nt*16*640 + ks*32);
      acc[nt] = __builtin_amdgcn_mfma_f32_16x16x32_f16(a, b, acc[nt], 0, 0, 0);
    }
  }
  #pragma unroll
  for (int nt = 0; nt < 16; ++nt){
    int n = nt*16 + col;
    float bv = n < 128 ? bsg[n] : btn[n - 128];
    #pragma unroll
    for (int r = 0; r < 4; ++r){
      float v = acc[nt][r] + bv;
      v = n < 128 ? 1.f/(1.f + __expf(-v)) : tanhf(v);
      out[(size_t)(row0 + quad*4 + r)*256 + n] = v;
    }
  }
}

extern "C" void kernel_launch(void* const* d_in, const int* in_sizes, int n_in,
                              void* d_out, int out_size, void* d_ws, size_t ws_size,
                              hipStream_t stream)
{
  const float* x    = (const float*)d_in[0];
  const float* nfr  = (const float*)d_in[1];
  const int*   eidx = (const int*)d_in[2];
  const int*   hidx = (const int*)d_in[3];
  const float *Wg1=(const float*)d_in[4],  *bg1=(const float*)d_in[5];
  const float *Wg2=(const float*)d_in[6],  *bg2=(const float*)d_in[7];
  const float *Wh1=(const float*)d_in[8],  *bh1=(const float*)d_in[9];
  const float *Wh2=(const float*)d_in[10], *bh2=(const float*)d_in[11];
  const float *Wm =(const float*)d_in[12], *bm =(const float*)d_in[13];
  const float *Wm2=(const float*)d_in[14], *bm2=(const float*)d_in[15];
  const float *Wsg=(const float*)d_in[16], *bsg=(const float*)d_in[17];
  const float *Wtn=(const float*)d_in[18], *btn=(const float*)d_in[19];
  float* out = (float*)d_out;

  // ---- workspace layout. Aliases:
  //  h4_16 at base; bins + gcur live only until k_csr, alias agg16 region
  //  (bin_s in the otherwise-free [50.3MB, 67.1MB) hole; wg*/wm2 f16 weights
  //  persist at [55.6MB, 55.7MB));
  //  cat16/w16/wm16 alias agg16+bins region (attention phase only);
  //  Opart f16 (16MB) aliases dead bufA; kb/gT alias csr_dst/csr_pn. ----
  char* base = (char*)d_ws;
  f16*   h4_16  = (f16*)(base);                          // 16 MB
  f16*   agg16  = (f16*)(base + 33554432);               // 16 MB (graph phase only)
  u32*   bin_e  = (u32*)(base + 33554432);               // 5 MB   (aliases agg16)
  u32*   bin_pn = (u32*)(base + 38797312);               // 5 MB
  u32*   bin_pe = (u32*)(base + 44040192);               // 4.5 MB
  int*   gcur   = (int*)(base + 48758784);               // 1.75 KB
  u32*   bin_s  = (u32*)(base + 50331648);               // 5 MB (free hole)
  f16*   wg1_16 = (f16*)(base + 55574528);               // 32 KB (persists all run)
  f16*   wg2_16 = (f16*)(base + 55607296);               // 32 KB
  f16*   wm2_16 = (f16*)(base + 55640064);               // 32 KB
  f16*   cat16  = (f16*)(base + 33554432);               // 5.24 MB (attention phase)
  f16*   w16    = (f16*)(base + 38797312);               // 320 KB  (attention phase)
  f16*   wm16   = (f16*)(base + 39124992);               // 128 KB  (attention phase)
  f16*   bufA   = (f16*)(base + 67108864);               // 16 MB  (nfr16 / h2_16)
  f16*   bufB   = (f16*)(base + 83886080);               // 16 MB  (h1_16 / h3_16)
  f16*   Opart  = (f16*)(base + 67108864);               // 16 MB f16 (aliases bufA)
  u16*   csr_dst= (u16*)(base + 100663296);              // 8 MB used of 16 MB region
  f16*   kb     = (f16*)(base + 100663296);              //   (aliases csr_dst)
  u16*   csr_pn = (u16*)(base + 117440512);              // 8 MB used of 16 MB region
  f16*   gT     = (f16*)(base + 117440512);              //   (aliases csr_pn)
  u16*   csr_pe = (u16*)(base + 134217728);              // 3 MB used of 6 MB region
  int*   cnt_dst= (int*)(base + 140509184);
  int*   cnt_pn = (int*)(base + 140771328);
  int*   cnt_pe = (int*)(base + 141033472);
  int*   du     = (int*)(base + 141049856);              // 256 KB
  float* ef0    = (float*)(base + 141312000);            // 2 MB
  f16*   ef1    = (f16*)(base + 143409152);              // 1 MB (f16)
  f16*   qb     = (f16*)(base + 145506304);              // 1 MB
  float* mZ     = (float*)(base + 146554880);            // 512 KB (NSPLIT16)
  const size_t needB = (size_t)147079168;
  if (ws_size < needB) return;

  // ---- CSR build: bin (phase A, 4096 items/block, dst+src+pn+pe) then
  //      per-bucket insert + du counting (phase B); weight prep up front ----
  hipMemsetAsync(gcur, 0, 1792, stream);
  k_wprep<<<48, 256, 0, stream>>>(Wg1, Wg2, Wm2, wg1_16, wg2_16, wm2_16);
  k_bin<<<512, 256, 0, stream>>>(eidx, hidx, gcur, bin_e, bin_s, bin_pn, bin_pe);
  k_csr<<<448, 256, 0, stream>>>(gcur, bin_e, bin_s, bin_pn, bin_pe,
                                 cnt_dst, csr_dst, cnt_pn, csr_pn, cnt_pe, csr_pe, du);

  // ---- layer 1 ----
  k_pre<<<NNODE*64/256, 256, 0, stream>>>(nfr, du, bufA);
  k_gagg16<<<NNODE/4, 256, 0, stream>>>(cnt_dst, csr_dst, bufA, agg16);
  k_ngemm<1><<<NNODE/64, 256, 0, stream>>>(agg16, wg1_16, cnt_dst, bg1, bufB);
  k_hea16<<<NHE/4, 256, 0, stream>>>(cnt_pe, csr_pe, bufB, ef0);
  k_gemm<3,0><<<NHE/32, 256, 0, stream>>>(ef0, Wh1, nullptr, nullptr, ef1);
  k_nha<1><<<NNODE/4, 256, 0, stream>>>(cnt_pn, csr_pn, ef1, bh1, nfr, du, bufA);

  // ---- layer 2 ----
  k_gagg16<<<NNODE/4, 256, 0, stream>>>(cnt_dst, csr_dst, bufA, agg16);
  k_ngemm<1><<<NNODE/64, 256, 0, stream>>>(agg16, wg2_16, cnt_dst, bg2, bufB);
  k_hea16<<<NHE/4, 256, 0, stream>>>(cnt_pe, csr_pe, bufB, ef0);
  k_gemm<3,0><<<NHE/32, 256, 0, stream>>>(ef0, Wh2, nullptr, nullptr, ef1);
  k_nha<0><<<NNODE/4, 256, 0, stream>>>(cnt_pn, csr_pn, ef1, bh2, nfr, nullptr, h4_16);

  // ---- attention (agg16/bins dead from here: cat16/w16/wm16 safe) ----
  k_prep<<<2272, 256, 0, stream>>>(x, Wsg, Wtn, Wm, cat16, w16, wm16);
  k_qgemm2<<<NROW/16, 64, 0, stream>>>(cat16, wm16, bm, qb);
  k_ngemm<2><<<NNODE/64, 256, 0, stream>>>(h4_16, wm2_16, nullptr, bm2, kb);
  k_gt<<<dim3(NPER/64, 2, BSZ), 256, 0, stream>>>(h4_16, gT);
  k_flash<<<dim3(NSPLIT, LQ/128, BSZ), 512, 0, stream>>>(qb, kb, gT, Opart, mZ);
  k_comb<<<NROW*64/256, 256, 0, stream>>>(Opart, mZ, cat16);
  k_fin2<<<NROW/16, 64, 0, stream>>>(cat16, w16, bsg, btn, out);

  (void)in_sizes; (void)n_in; (void)out_size;
}